// Round 3
// baseline (2803.665 us; speedup 1.0000x reference)
//
#include <hip/hip_runtime.h>

#define B_ 16
#define N_ 8192
#define G_ 256
#define K_ 64
#define D_ 256
#define HID_ 1024
#define EPS_ 1e-5f

typedef __attribute__((ext_vector_type(8))) short bf16x8;
typedef __attribute__((ext_vector_type(4))) float f32x4;

__device__ __forceinline__ float bf16_to_f32(unsigned short u){
  unsigned int v = ((unsigned int)u) << 16;
  return __uint_as_float(v);
}
__device__ __forceinline__ unsigned short f32_to_bf16(float f){
  unsigned int u = __float_as_uint(f);
  unsigned int r = (u + 0x7FFFu + ((u >> 16) & 1u)) >> 16;
  return (unsigned short)r;
}
__device__ __forceinline__ float gelu_exact(float v){
  return 0.5f * v * (1.0f + erff(v * 0.70710678118654752440f));
}

// ---------------- fold BN into enc_w1/enc_w3 ----------------
__global__ void fold_kernel(const float* __restrict__ w1, const float* __restrict__ b1,
    const float* __restrict__ g1, const float* __restrict__ bb1,
    const float* __restrict__ w3, const float* __restrict__ b3,
    const float* __restrict__ g2, const float* __restrict__ bb2,
    float* __restrict__ w1f, float* __restrict__ b1f,
    float* __restrict__ w3f, float* __restrict__ b3f)
{
  int i = blockIdx.x * 256 + threadIdx.x;
  const float S = 0.99999500003749968f; // 1/sqrt(1+1e-5)
  if (i < 384) w1f[i] = w1[i] * g1[i & 127] * S;
  if (i < 128) b1f[i] = b1[i] * g1[i] * S + bb1[i];
  if (i < 262144) w3f[i] = w3[i] * g2[i & 511] * S;
  if (i < 512) b3f[i] = b3[i] * g2[i] * S + bb2[i];
}

// ---- pack weights into MFMA B-fragment layout, hi/lo bf16 split ----
// B frag for 16x16x32: lane holds B[k = (lane>>4)*8 + j][n = lane&15], j=0..7
// packed[((nt*KS + ks)*64 + lane)*8 + j],  KS = K/32
__global__ void pack_w_kernel(const float* __restrict__ W, unsigned short* __restrict__ hi,
                              unsigned short* __restrict__ lo, int N, int ksBits){
  int f = blockIdx.x * 256 + threadIdx.x; // total K*N
  int j = f & 7, lane = (f >> 3) & 63;
  int ks = (f >> 9) & ((1 << ksBits) - 1);
  int nt = f >> (9 + ksBits);
  int k = ks * 32 + ((lane >> 4) & 3) * 8 + j, c = nt * 16 + (lane & 15);
  float v = W[(size_t)k * N + c];
  unsigned short h = f32_to_bf16(v);
  hi[f] = h;
  lo[f] = f32_to_bf16(v - bf16_to_f32(h));
}
// variant for w3f bottom half (rows 256..511 of a 512x512)
__global__ void pack_w3_kernel(const float* __restrict__ w3f, unsigned short* __restrict__ hi, unsigned short* __restrict__ lo){
  int f = blockIdx.x * 256 + threadIdx.x; // 131072 = 32nt * 8ks * 64 * 8
  int j = f & 7, lane = (f >> 3) & 63, ks = (f >> 9) & 7, nt = f >> 12;
  int k = ks * 32 + ((lane >> 4) & 3) * 8 + j, c = nt * 16 + (lane & 15);
  float v = w3f[(size_t)(256 + k) * 512 + c];
  unsigned short h = f32_to_bf16(v);
  hi[f] = h;
  lo[f] = f32_to_bf16(v - bf16_to_f32(h));
}

// ---------------- FPS: one block per batch ----------------
__global__ __launch_bounds__(1024) void fps_kernel(const float* __restrict__ x, float* __restrict__ centers)
{
  int b = blockIdx.x;
  const float* xb = x + (size_t)b * N_ * 3;
  int tid = threadIdx.x;
  float px[8], py[8], pz[8], dist[8];
#pragma unroll
  for (int j = 0; j < 8; j++){
    int p = tid + j * 1024;
    px[j] = xb[p*3+0]; py[j] = xb[p*3+1]; pz[j] = xb[p*3+2];
    dist[j] = 1e10f;
  }
  __shared__ unsigned long long wred[16];
  __shared__ float sCen[3];
  if (tid == 0){ sCen[0] = xb[0]; sCen[1] = xb[1]; sCen[2] = xb[2]; }
  __syncthreads();
  for (int i = 0; i < G_; i++){
    float cx = sCen[0], cy = sCen[1], cz = sCen[2];
    if (tid < 3) centers[((size_t)b * G_ + i) * 3 + tid] = sCen[tid];
    unsigned long long best = 0ull;
#pragma unroll
    for (int j = 0; j < 8; j++){
      float dx = __fadd_rn(px[j], -cx);
      float dy = __fadd_rn(py[j], -cy);
      float dz = __fadd_rn(pz[j], -cz);
      float d  = __fadd_rn(__fadd_rn(__fmul_rn(dx,dx), __fmul_rn(dy,dy)), __fmul_rn(dz,dz));
      float dm = fminf(dist[j], d);
      dist[j] = dm;
      unsigned int pp = (unsigned int)(tid + j * 1024);
      unsigned long long key = (((unsigned long long)__float_as_uint(dm)) << 32) | (unsigned long long)(~pp);
      best = (key > best) ? key : best;
    }
#pragma unroll
    for (int o = 32; o; o >>= 1){
      unsigned long long t = __shfl_down(best, o);
      best = (t > best) ? t : best;
    }
    if ((tid & 63) == 0) wred[tid >> 6] = best;
    __syncthreads();
    unsigned long long m = wred[0];
#pragma unroll
    for (int w = 1; w < 16; w++){ unsigned long long t = wred[w]; m = (t > m) ? t : m; }
    int far = (int)(~(unsigned int)(m & 0xFFFFFFFFull));
    if (i + 1 < G_){
      if (tid == (far & 1023)){
        int jj = far >> 10;
        float fx=0.f, fy=0.f, fz=0.f;
#pragma unroll
        for (int j = 0; j < 8; j++) if (j == jj){ fx = px[j]; fy = py[j]; fz = pz[j]; }
        sCen[0] = fx; sCen[1] = fy; sCen[2] = fz;
      }
      __syncthreads();
    }
  }
}

// ---------------- KNN: one block per (b,g) ----------------
__global__ __launch_bounds__(256) void knn_kernel(const float* __restrict__ x, const float* __restrict__ centers,
                                                  int* __restrict__ knn_idx, float* __restrict__ neigh)
{
  int blk = blockIdx.x, b = blk >> 8;
  const float* xb = x + (size_t)b * N_ * 3;
  const float* cc = centers + (size_t)blk * 3;
  int tid = threadIdx.x;
  float c0 = cc[0], c1 = cc[1], c2v = cc[2];
  float c2s = __fadd_rn(__fadd_rn(__fmul_rn(c0,c0), __fmul_rn(c1,c1)), __fmul_rn(c2v,c2v));
  float d[32];
#pragma unroll
  for (int j = 0; j < 32; j++){
    int p = tid + j * 256;
    float x0 = xb[p*3+0], x1 = xb[p*3+1], x2 = xb[p*3+2];
    float xs = __fadd_rn(__fadd_rn(__fmul_rn(x0,x0), __fmul_rn(x1,x1)), __fmul_rn(x2,x2));
    float dt = __fadd_rn(__fadd_rn(__fmul_rn(c0,x0), __fmul_rn(c1,x1)), __fmul_rn(c2v,x2));
    d[j] = __fadd_rn(__fadd_rn(c2s, xs), -__fmul_rn(2.0f, dt));
  }
  const float FINF = __int_as_float(0x7F800000);
  float lmin = FINF; unsigned int lp = 0xFFFFFFFFu;
#pragma unroll
  for (int j = 0; j < 32; j++){ if (d[j] < lmin){ lmin = d[j]; lp = (unsigned int)(tid + j*256); } }
  __shared__ unsigned long long wred[2][4];
  for (int r = 0; r < K_; r++){
    unsigned int u = __float_as_uint(lmin);
    u = (u & 0x80000000u) ? ~u : (u | 0x80000000u);
    unsigned long long key = (((unsigned long long)u) << 32) | (unsigned long long)lp;
#pragma unroll
    for (int o = 32; o; o >>= 1){
      unsigned long long t = __shfl_down(key, o);
      key = (t < key) ? t : key;
    }
    int cur = r & 1;
    if ((tid & 63) == 0) wred[cur][tid >> 6] = key;
    __syncthreads();
    unsigned long long m = wred[cur][0];
#pragma unroll
    for (int w = 1; w < 4; w++){ unsigned long long t = wred[cur][w]; m = (t < m) ? t : m; }
    unsigned int p = (unsigned int)(m & 0xFFFFFFFFull);
    if (tid == (p & 255u)){
      knn_idx[(size_t)blk * K_ + r] = (int)p;
      float* np_ = neigh + ((size_t)blk * K_ + r) * 3;
      np_[0] = __fadd_rn(xb[p*3+0], -c0);
      np_[1] = __fadd_rn(xb[p*3+1], -c1);
      np_[2] = __fadd_rn(xb[p*3+2], -c2v);
      lmin = FINF; lp = 0xFFFFFFFFu;
#pragma unroll
      for (int j = 0; j < 32; j++){
        if ((unsigned int)(tid + j*256) == p) d[j] = FINF;
        if (d[j] < lmin){ lmin = d[j]; lp = (unsigned int)(tid + j*256); }
      }
    }
  }
}

// ---------------- fused group encoder (MFMA bf16): one block per (b,g) ----------------
// LDS = 17408 + 33792 + 1024 + 2048 = 54272 B -> 3 blocks/CU (<=54613)
__global__ __launch_bounds__(256, 3) void encoder_kernel(
    const float* __restrict__ neigh,
    const float* __restrict__ w1f, const float* __restrict__ b1f,
    const unsigned short* __restrict__ w2ph, const unsigned short* __restrict__ w2pl,
    const float* __restrict__ b2,
    const float* __restrict__ w3f, const float* __restrict__ b3f,
    const unsigned short* __restrict__ w3ph, const unsigned short* __restrict__ w3pl,
    const unsigned short* __restrict__ w4ph, const unsigned short* __restrict__ w4pl,
    const float* __restrict__ b4,
    float* __restrict__ tokens)
{
  __shared__ __align__(16) unsigned short sH1[64 * 136];  // h1 (64x128 bf16), reused as h3 chunk
  __shared__ __align__(16) unsigned short sH2[64 * 264];  // h2 (64x256 bf16)
  __shared__ float sGmax[256];
  __shared__ float sPartA[512];                            // aliased as sNeigh in phase 1
  float (*sNeigh)[4] = (float(*)[4])sPartA;

  int tid  = threadIdx.x;
  int wave = tid >> 6, lane = tid & 63, quad = lane >> 4, lrow = lane & 15;
  size_t gid = blockIdx.x;

  if (tid < 192) sNeigh[tid / 3][tid % 3] = neigh[gid * 192 + tid];
  __syncthreads();

  // ---- phase 1: h1 = relu(bn(neigh @ w1)) -> bf16 LDS ----
  for (int e = tid; e < 8192; e += 256){
    int r = e >> 7, c = e & 127;
    float v = fmaf(sNeigh[r][2], w1f[256 + c], fmaf(sNeigh[r][1], w1f[128 + c], fmaf(sNeigh[r][0], w1f[c], b1f[c])));
    sH1[r * 136 + c] = f32_to_bf16(fmaxf(v, 0.0f));
  }
  __syncthreads();

  // ---- phase 2: h2 = h1 @ w2 + b2 (MFMA, hi/lo) ----
  {
    f32x4 acc[4][4];
    const f32x4 z = {0.f, 0.f, 0.f, 0.f};
#pragma unroll
    for (int mt = 0; mt < 4; mt++)
#pragma unroll
      for (int nl = 0; nl < 4; nl++) acc[mt][nl] = z;
#pragma unroll
    for (int ks = 0; ks < 4; ks++){
      bf16x8 af[4];
#pragma unroll
      for (int mt = 0; mt < 4; mt++)
        af[mt] = *(const bf16x8*)&sH1[(mt*16 + lrow)*136 + ks*32 + quad*8];
#pragma unroll
      for (int nl = 0; nl < 4; nl++){
        size_t bo = (((size_t)(wave*4 + nl)*4 + ks)*64 + lane)*8;
        bf16x8 bh = *(const bf16x8*)&w2ph[bo];
        bf16x8 bl = *(const bf16x8*)&w2pl[bo];
#pragma unroll
        for (int mt = 0; mt < 4; mt++){
          acc[mt][nl] = __builtin_amdgcn_mfma_f32_16x16x32_bf16(af[mt], bh, acc[mt][nl], 0, 0, 0);
          acc[mt][nl] = __builtin_amdgcn_mfma_f32_16x16x32_bf16(af[mt], bl, acc[mt][nl], 0, 0, 0);
        }
      }
    }
#pragma unroll
    for (int nl = 0; nl < 4; nl++){
      int col = wave*64 + nl*16 + lrow;
      float bias = b2[col];
#pragma unroll
      for (int mt = 0; mt < 4; mt++)
#pragma unroll
        for (int rg = 0; rg < 4; rg++)
          sH2[(mt*16 + quad*4 + rg)*264 + col] = f32_to_bf16(acc[mt][nl][rg] + bias);
    }
  }
  __syncthreads();

  // ---- phase 3: gmax = colmax(h2) ----
  {
    float mx = -3.4e38f;
#pragma unroll 8
    for (int r = 0; r < 64; r++) mx = fmaxf(mx, bf16_to_f32(sH2[r*264 + tid]));
    sGmax[tid] = mx;
  }
  __syncthreads();

  // ---- phase 4: partA = gmax @ w3f[0:256] (f32, coalesced) ----
#pragma unroll
  for (int half = 0; half < 2; half++){
    int c = tid + half * 256;
    float s = 0.0f;
#pragma unroll 8
    for (int k = 0; k < 256; k++) s = fmaf(sGmax[k], w3f[(size_t)k * 512 + c], s);
    sPartA[c] = s;
  }
  __syncthreads();

  // ---- phase 5: h3 (chunks of 128 cols) + h4 accumulation (MFMA, hi/lo) ----
  f32x4 acc4[4][4];
  {
    const f32x4 z = {0.f, 0.f, 0.f, 0.f};
#pragma unroll
    for (int mt = 0; mt < 4; mt++)
#pragma unroll
      for (int nl = 0; nl < 4; nl++) acc4[mt][nl] = z;
  }
  for (int cc = 0; cc < 4; cc++){
    f32x4 acc3[4][2];
    {
      const f32x4 z = {0.f, 0.f, 0.f, 0.f};
#pragma unroll
      for (int mt = 0; mt < 4; mt++){ acc3[mt][0] = z; acc3[mt][1] = z; }
    }
#pragma unroll
    for (int ks = 0; ks < 8; ks++){
      bf16x8 af[4];
#pragma unroll
      for (int mt = 0; mt < 4; mt++)
        af[mt] = *(const bf16x8*)&sH2[(mt*16 + lrow)*264 + ks*32 + quad*8];
#pragma unroll
      for (int nl = 0; nl < 2; nl++){
        int nt = cc*8 + wave*2 + nl;
        size_t bo = (((size_t)nt*8 + ks)*64 + lane)*8;
        bf16x8 bh = *(const bf16x8*)&w3ph[bo];
        bf16x8 bl = *(const bf16x8*)&w3pl[bo];
#pragma unroll
        for (int mt = 0; mt < 4; mt++){
          acc3[mt][nl] = __builtin_amdgcn_mfma_f32_16x16x32_bf16(af[mt], bh, acc3[mt][nl], 0, 0, 0);
          acc3[mt][nl] = __builtin_amdgcn_mfma_f32_16x16x32_bf16(af[mt], bl, acc3[mt][nl], 0, 0, 0);
        }
      }
    }
    __syncthreads();
#pragma unroll
    for (int nl = 0; nl < 2; nl++){
      int cl = wave*32 + nl*16 + lrow;
      int c  = cc*128 + cl;
      float pb = sPartA[c] + b3f[c];
#pragma unroll
      for (int mt = 0; mt < 4; mt++)
#pragma unroll
        for (int rg = 0; rg < 4; rg++)
          sH1[(mt*16 + quad*4 + rg)*136 + cl] = f32_to_bf16(fmaxf(acc3[mt][nl][rg] + pb, 0.0f));
    }
    __syncthreads();
#pragma unroll
    for (int ks = 0; ks < 4; ks++){
      bf16x8 af[4];
#pragma unroll
      for (int mt = 0; mt < 4; mt++)
        af[mt] = *(const bf16x8*)&sH1[(mt*16 + lrow)*136 + ks*32 + quad*8];
#pragma unroll
      for (int nl = 0; nl < 4; nl++){
        int nt = wave*4 + nl;
        size_t bo = (((size_t)nt*16 + cc*4 + ks)*64 + lane)*8;
        bf16x8 bh = *(const bf16x8*)&w4ph[bo];
        bf16x8 bl = *(const bf16x8*)&w4pl[bo];
#pragma unroll
        for (int mt = 0; mt < 4; mt++){
          acc4[mt][nl] = __builtin_amdgcn_mfma_f32_16x16x32_bf16(af[mt], bh, acc4[mt][nl], 0, 0, 0);
          acc4[mt][nl] = __builtin_amdgcn_mfma_f32_16x16x32_bf16(af[mt], bl, acc4[mt][nl], 0, 0, 0);
        }
      }
    }
  }

  // ---- phase 6: tokens = colmax(h4) + b4 ----
#pragma unroll
  for (int nl = 0; nl < 4; nl++){
    float mx = -3.4e38f;
#pragma unroll
    for (int mt = 0; mt < 4; mt++)
#pragma unroll
      for (int rg = 0; rg < 4; rg++) mx = fmaxf(mx, acc4[mt][nl][rg]);
    mx = fmaxf(mx, __shfl_xor(mx, 16));
    mx = fmaxf(mx, __shfl_xor(mx, 32));
    if (quad == 0){
      int col = wave*64 + nl*16 + lrow;
      tokens[gid * 256 + col] = mx + b4[col];
    }
  }
}

// ---------------- pos embed + assemble xt/pt ----------------
__global__ __launch_bounds__(128) void pos_token_kernel(
    const float* __restrict__ centers, const float* __restrict__ tokens,
    const float* __restrict__ cls_token, const float* __restrict__ cls_pos,
    const float* __restrict__ pw1, const float* __restrict__ pb1,
    const float* __restrict__ pw2, const float* __restrict__ pb2,
    float* __restrict__ xt, float* __restrict__ pt)
{
  int row = blockIdx.x;
  int b = row / 257, n = row - b * 257;
  int tid = threadIdx.x;
  size_t ro = (size_t)row * 256;
  if (n == 0){
    xt[ro + tid] = cls_token[tid]; xt[ro + 128 + tid] = cls_token[128 + tid];
    pt[ro + tid] = cls_pos[tid];   pt[ro + 128 + tid] = cls_pos[128 + tid];
    return;
  }
  int g = n - 1;
  const float* c = centers + ((size_t)b * 256 + g) * 3;
  __shared__ float hS[128];
  float h = fmaf(c[2], pw1[256 + tid], fmaf(c[1], pw1[128 + tid], fmaf(c[0], pw1[tid], pb1[tid])));
  hS[tid] = gelu_exact(h);
  __syncthreads();
  const float* tok = tokens + ((size_t)b * 256 + g) * 256;
#pragma unroll
  for (int half = 0; half < 2; half++){
    int j = tid + half * 128;
    float s = pb2[j];
#pragma unroll 4
    for (int k = 0; k < 128; k++) s = fmaf(hS[k], pw2[(size_t)k * 256 + j], s);
    pt[ro + j] = s;
    xt[ro + j] = tok[j];
  }
}

// ---------------- add + layernorm (row of 256) ----------------
__global__ __launch_bounds__(256) void add_ln_kernel(const float* __restrict__ A, const float* __restrict__ Badd,
    float* __restrict__ xi_out, float* __restrict__ ln_out,
    const float* __restrict__ g, const float* __restrict__ be)
{
  __shared__ float red[4];
  int row = blockIdx.x, c = threadIdx.x;
  size_t off = (size_t)row * 256 + c;
  float v = A[off];
  if (Badd) v += Badd[off];
  if (xi_out) xi_out[off] = v;
  float s = v;
#pragma unroll
  for (int o = 32; o; o >>= 1) s += __shfl_down(s, o);
  if ((threadIdx.x & 63) == 0) red[threadIdx.x >> 6] = s;
  __syncthreads();
  float m = (red[0] + red[1] + red[2] + red[3]) * (1.0f / 256.0f);
  __syncthreads();
  float d = v - m;
  float s2 = d * d;
#pragma unroll
  for (int o = 32; o; o >>= 1) s2 += __shfl_down(s2, o);
  if ((threadIdx.x & 63) == 0) red[threadIdx.x >> 6] = s2;
  __syncthreads();
  float var = (red[0] + red[1] + red[2] + red[3]) * (1.0f / 256.0f);
  ln_out[off] = d / sqrtf(var + EPS_) * g[c] + be[c];
}

// ---------------- MFMA GEMM: C[M,N] = [res +] act(A@B + bias) ----------------
// A f32 row-major (converted to bf16 in LDS), B pre-packed bf16 hi/lo fragments.
// Tile: 64 rows x 128 cols per block (4 waves; wave w = cols w*32..w*32+31).
template<int ACT, int HASRES>
__global__ __launch_bounds__(256) void mfma_gemm(
    const float* __restrict__ A,
    const unsigned short* __restrict__ Bh, const unsigned short* __restrict__ Bl,
    const float* __restrict__ bias, const float* __restrict__ res,
    float* __restrict__ C, int M, int K, int N)
{
  __shared__ __align__(16) unsigned short sA[64 * 72];
  int tid = threadIdx.x;
  int wave = tid >> 6, lane = tid & 63, quad = lane >> 4, lrow = lane & 15;
  int row0 = blockIdx.x * 64;
  int col0 = blockIdx.y * 128;
  int ksTotal = K >> 5;
  f32x4 acc[4][2];
  const f32x4 z = {0.f, 0.f, 0.f, 0.f};
#pragma unroll
  for (int mt = 0; mt < 4; mt++){ acc[mt][0] = z; acc[mt][1] = z; }

  for (int k0 = 0; k0 < K; k0 += 64){
#pragma unroll
    for (int i = 0; i < 4; i++){
      int e = tid + i * 256;           // [0,1024): r = e>>4, c4 = (e&15)*4
      int r = e >> 4, c4 = (e & 15) * 4;
      int gr = row0 + r;
      float4 v = make_float4(0.f,0.f,0.f,0.f);
      if (gr < M) v = *(const float4*)(A + (size_t)gr * K + k0 + c4);
      unsigned short* dst = &sA[r * 72 + c4];
      dst[0] = f32_to_bf16(v.x); dst[1] = f32_to_bf16(v.y);
      dst[2] = f32_to_bf16(v.z); dst[3] = f32_to_bf16(v.w);
    }
    __syncthreads();
    int ksBase = k0 >> 5;
#pragma unroll
    for (int ks = 0; ks < 2; ks++){
      bf16x8 af[4];
#pragma unroll
      for (int mt = 0; mt < 4; mt++)
        af[mt] = *(const bf16x8*)&sA[(mt*16 + lrow)*72 + ks*32 + quad*8];
#pragma unroll
      for (int nl = 0; nl < 2; nl++){
        int nt = (col0 >> 4) + wave*2 + nl;
        size_t bo = (((size_t)nt * ksTotal + ksBase + ks)*64 + lane)*8;
        bf16x8 bh = *(const bf16x8*)&Bh[bo];
        bf16x8 bl = *(const bf16x8*)&Bl[bo];
#pragma unroll
        for (int mt = 0; mt < 4; mt++){
          acc[mt][nl] = __builtin_amdgcn_mfma_f32_16x16x32_bf16(af[mt], bh, acc[mt][nl], 0, 0, 0);
          acc[mt][nl] = __builtin_amdgcn_mfma_f32_16x16x32_bf16(af[mt], bl, acc[mt][nl], 0, 0, 0);
        }
      }
    }
    __syncthreads();
  }
#pragma unroll
  for (int nl = 0; nl < 2; nl++){
    int c = col0 + wave*32 + nl*16 + lrow;
    float bc = bias ? bias[c] : 0.0f;
#pragma unroll
    for (int mt = 0; mt < 4; mt++)
#pragma unroll
      for (int rg = 0; rg < 4; rg++){
        int r = row0 + mt*16 + quad*4 + rg;
        if (r < M){
          float v = acc[mt][nl][rg] + bc;
          if (ACT == 1) v = gelu_exact(v);
          if (HASRES) v += res[(size_t)r * N + c];
          C[(size_t)r * N + c] = v;
        }
      }
  }
}

// ---------------- attention: block per (b,h,qchunk), flash-style ----------------
__global__ __launch_bounds__(64) void attn_kernel(const float* __restrict__ qkv, float* __restrict__ obuf)
{
  int bh = blockIdx.x;
  int b = bh >> 3, h = bh & 7;
  int qrow = blockIdx.y * 64 + threadIdx.x;
  bool act = qrow < 257;
  __shared__ float kS[128][33];
  __shared__ float vS[128][33];
  const float* qb = qkv + (size_t)b * 257 * 768;
  int tid = threadIdx.x;
  float q[32], o[32];
  float mrun = -3.4e38f, l = 0.0f;
  if (act){
    const float* qr = qb + (size_t)qrow * 768 + h * 32;
#pragma unroll
    for (int j = 0; j < 32; j++){ q[j] = qr[j]; o[j] = 0.0f; }
  }
  const float scale = 0.17677669529663687f;
  for (int m0 = 0; m0 < 257; m0 += 128){
    int cnt = min(128, 257 - m0);
    for (int e = tid; e < cnt * 32; e += 64){
      int mm = e >> 5, j = e & 31;
      const float* rowp = qb + (size_t)(m0 + mm) * 768 + h * 32;
      kS[mm][j] = rowp[256 + j];
      vS[mm][j] = rowp[512 + j];
    }
    __syncthreads();
    if (act){
      for (int mm = 0; mm < cnt; mm++){
        float s = 0.0f;
#pragma unroll
        for (int j = 0; j < 32; j++) s = fmaf(q[j], kS[mm][j], s);
        s *= scale;
        float nm = fmaxf(mrun, s);
        float alpha = expf(mrun - nm);
        float p = expf(s - nm);
        l = fmaf(l, alpha, p);
#pragma unroll
        for (int j = 0; j < 32; j++) o[j] = fmaf(p, vS[mm][j], o[j] * alpha);
        mrun = nm;
      }
    }
    __syncthreads();
  }
  if (act){
    float inv = 1.0f / l;
    float* orow = obuf + (size_t)(b * 257 + qrow) * 256 + h * 32;
#pragma unroll
    for (int j = 0; j < 32; j++) orow[j] = o[j] * inv;
  }
}

// ---------------- head MLP + scatter: one block per (b,g) ----------------
__global__ __launch_bounds__(256) void head_kernel(
    const float* __restrict__ gfeat, const float* __restrict__ neigh, const int* __restrict__ knn_idx,
    const float* __restrict__ w1, const float* __restrict__ b1,
    const float* __restrict__ w2, const float* __restrict__ b2,
    float* __restrict__ sums, float* __restrict__ cnts)
{
  int blk = blockIdx.x, b = blk >> 8;
  __shared__ float xS[256];
  __shared__ float nS[64][4];
  __shared__ float partH[2][128];
  __shared__ float sharedH[128];
  __shared__ float w2S[128];
  __shared__ float wtail[3][128];
  int tid = threadIdx.x;
  xS[tid] = gfeat[((size_t)b * 257 + 1 + (blk & 255)) * 256 + tid];
  if (tid < 192) nS[tid / 3][tid % 3] = neigh[(size_t)blk * 192 + tid];
  if (tid < 128){
    w2S[tid] = w2[tid];
    wtail[0][tid] = w1[256 * 128 + tid];
    wtail[1][tid] = w1[257 * 128 + tid];
    wtail[2][tid] = w1[258 * 128 + tid];
  }
  __syncthreads();
  {
    int half = tid >> 7, j = tid & 127;
    float s = 0.0f;
#pragma unroll 8
    for (int k = 0; k < 128; k++) s = fmaf(xS[half * 128 + k], w1[(size_t)(half * 128 + k) * 128 + j], s);
    partH[half][j] = s;
  }
  __syncthreads();
  if (tid < 128) sharedH[tid] = partH[0][tid] + partH[1][tid] + b1[tid];
  __syncthreads();
  int r = tid >> 2, q = tid & 3;
  float n0 = nS[r][0], n1 = nS[r][1], n2 = nS[r][2];
  float s = 0.0f;
#pragma unroll
  for (int j0 = 0; j0 < 32; j0++){
    int j = q * 32 + j0;
    float h = fmaf(n2, wtail[2][j], fmaf(n1, wtail[1][j], fmaf(n0, wtail[0][j], sharedH[j])));
    s = fmaf(fmaxf(h, 0.0f), w2S[j], s);
  }
  s += __shfl_xor(s, 1);
  s += __shfl_xor(s, 2);
  if (q == 0){
    float lg = s + b2[0];
    int p = knn_idx[(size_t)blk * K_ + r];
    atomicAdd(&sums[(size_t)b * N_ + p], lg);
    atomicAdd(&cnts[(size_t)b * N_ + p], 1.0f);
  }
}

__global__ void finalize_kernel(const float* __restrict__ sums, const float* __restrict__ cnts, float* __restrict__ out)
{
  int i = blockIdx.x * 256 + threadIdx.x;
  out[i] = sums[i] / fmaxf(cnts[i], 1.0f);
}

extern "C" void kernel_launch(void* const* d_in, const int* in_sizes, int n_in,
                              void* d_out, int out_size, void* d_ws, size_t ws_size,
                              hipStream_t stream)
{
  (void)in_sizes; (void)n_in; (void)out_size; (void)ws_size;
  const float* x        = (const float*)d_in[0];
  const float* enc_w1   = (const float*)d_in[1];
  const float* enc_b1   = (const float*)d_in[2];
  const float* enc_bn1g = (const float*)d_in[3];
  const float* enc_bn1b = (const float*)d_in[4];
  const float* enc_w2   = (const float*)d_in[5];
  const float* enc_b2   = (const float*)d_in[6];
  const float* enc_w3   = (const float*)d_in[7];
  const float* enc_b3   = (const float*)d_in[8];
  const float* enc_bn2g = (const float*)d_in[9];
  const float* enc_bn2b = (const float*)d_in[10];
  const float* enc_w4   = (const float*)d_in[11];
  const float* enc_b4   = (const float*)d_in[12];
  const float* cls_tok  = (const float*)d_in[13];
  const float* cls_pos  = (const float*)d_in[14];
  const float* pos_w1   = (const float*)d_in[15];
  const float* pos_b1   = (const float*)d_in[16];
  const float* pos_w2   = (const float*)d_in[17];
  const float* pos_b2   = (const float*)d_in[18];
  const float* ln1_g    = (const float*)d_in[19];
  const float* ln1_b    = (const float*)d_in[20];
  const float* qkv_w    = (const float*)d_in[21];
  const float* proj_w   = (const float*)d_in[22];
  const float* proj_b   = (const float*)d_in[23];
  const float* ln2_g    = (const float*)d_in[24];
  const float* ln2_b    = (const float*)d_in[25];
  const float* fc1_w    = (const float*)d_in[26];
  const float* fc1_b    = (const float*)d_in[27];
  const float* fc2_w    = (const float*)d_in[28];
  const float* fc2_b    = (const float*)d_in[29];
  const float* norm_g   = (const float*)d_in[30];
  const float* norm_b   = (const float*)d_in[31];
  const float* head_w1  = (const float*)d_in[32];
  const float* head_b1  = (const float*)d_in[33];
  const float* head_w2  = (const float*)d_in[34];
  const float* head_b2  = (const float*)d_in[35];

  float* ws = (float*)d_ws;
  size_t off = 0;
  auto alloc = [&](size_t n)->float*{ float* p = ws + off; off += (n + 63) & ~(size_t)63; return p; };

  float* centers = alloc((size_t)B_ * G_ * 3);
  float* w1f     = alloc(384);
  float* b1f     = alloc(128);
  float* w3f     = alloc(512 * 512);
  float* b3f     = alloc(512);
  unsigned short* w2ph = (unsigned short*)alloc(16384);
  unsigned short* w2pl = (unsigned short*)alloc(16384);
  unsigned short* w3ph = (unsigned short*)alloc(65536);
  unsigned short* w3pl = (unsigned short*)alloc(65536);
  unsigned short* w4ph = (unsigned short*)alloc(65536);
  unsigned short* w4pl = (unsigned short*)alloc(65536);
  unsigned short* qkvPh = (unsigned short*)alloc(4 * 196608 / 2);
  unsigned short* qkvPl = (unsigned short*)alloc(4 * 196608 / 2);
  unsigned short* projPh = (unsigned short*)alloc(4 * 65536 / 2);
  unsigned short* projPl = (unsigned short*)alloc(4 * 65536 / 2);
  unsigned short* fc1Ph = (unsigned short*)alloc(4 * 262144 / 2);
  unsigned short* fc1Pl = (unsigned short*)alloc(4 * 262144 / 2);
  unsigned short* fc2Ph = (unsigned short*)alloc(4 * 262144 / 2);
  unsigned short* fc2Pl = (unsigned short*)alloc(4 * 262144 / 2);
  float* tokens  = alloc((size_t)B_ * G_ * D_);
  float* neigh   = alloc((size_t)B_ * G_ * K_ * 3);
  int*   knn_idx = (int*)alloc((size_t)B_ * G_ * K_);
  float* pt      = alloc((size_t)B_ * 257 * D_);
  float* xt      = alloc((size_t)B_ * 257 * D_);
  float* xi      = alloc((size_t)B_ * 257 * D_);
  float* lnbuf   = alloc((size_t)B_ * 257 * D_);
  float* obuf    = alloc((size_t)B_ * 257 * D_);
  float* bigbuf  = alloc((size_t)B_ * 257 * HID_);
  float* gfeat   = alloc((size_t)B_ * 257 * D_);
  float* sums    = alloc((size_t)B_ * N_);
  float* cnts    = alloc((size_t)B_ * N_);

  hipMemsetAsync(sums, 0, (size_t)2 * B_ * N_ * sizeof(float), stream);

  fold_kernel<<<1024, 256, 0, stream>>>(enc_w1, enc_b1, enc_bn1g, enc_bn1b,
                                        enc_w3, enc_b3, enc_bn2g, enc_bn2b,
                                        w1f, b1f, w3f, b3f);
  pack_w_kernel<<<128, 256, 0, stream>>>(enc_w2, w2ph, w2pl, 256, 2);   // K=128: KS=4 -> 2 bits
  pack_w3_kernel<<<512, 256, 0, stream>>>(w3f, w3ph, w3pl);
  pack_w_kernel<<<512, 256, 0, stream>>>(enc_w4, w4ph, w4pl, 256, 4);   // K=512: KS=16 -> 4 bits
  for (int l = 0; l < 4; l++){
    pack_w_kernel<<<768, 256, 0, stream>>>(qkv_w + (size_t)l*196608, qkvPh + (size_t)l*196608, qkvPl + (size_t)l*196608, 768, 3);
    pack_w_kernel<<<256, 256, 0, stream>>>(proj_w + (size_t)l*65536, projPh + (size_t)l*65536, projPl + (size_t)l*65536, 256, 3);
    pack_w_kernel<<<1024, 256, 0, stream>>>(fc1_w + (size_t)l*262144, fc1Ph + (size_t)l*262144, fc1Pl + (size_t)l*262144, 1024, 3);
    pack_w_kernel<<<1024, 256, 0, stream>>>(fc2_w + (size_t)l*262144, fc2Ph + (size_t)l*262144, fc2Pl + (size_t)l*262144, 256, 5);
  }

  fps_kernel<<<B_, 1024, 0, stream>>>(x, centers);
  knn_kernel<<<B_ * G_, 256, 0, stream>>>(x, centers, knn_idx, neigh);
  encoder_kernel<<<B_ * G_, 256, 0, stream>>>(neigh, w1f, b1f, w2ph, w2pl, enc_b2,
                                              w3f, b3f, w3ph, w3pl, w4ph, w4pl, enc_b4, tokens);
  pos_token_kernel<<<B_ * 257, 128, 0, stream>>>(centers, tokens, cls_tok, cls_pos,
                                                 pos_w1, pos_b1, pos_w2, pos_b2, xt, pt);
  const int M = B_ * 257; // 4112
  for (int l = 0; l < 4; l++){
    add_ln_kernel<<<M, 256, 0, stream>>>(xt, pt, xi, lnbuf, ln1_g + l*256, ln1_b + l*256);
    mfma_gemm<0,0><<<dim3(65, 6), 256, 0, stream>>>(lnbuf, qkvPh + (size_t)l*196608, qkvPl + (size_t)l*196608,
                                                    nullptr, nullptr, bigbuf, M, 256, 768);
    attn_kernel<<<dim3(B_ * 8, 5), 64, 0, stream>>>(bigbuf, obuf);
    mfma_gemm<0,1><<<dim3(65, 2), 256, 0, stream>>>(obuf, projPh + (size_t)l*65536, projPl + (size_t)l*65536,
                                                    proj_b + l*256, xi, xi, M, 256, 256);
    add_ln_kernel<<<M, 256, 0, stream>>>(xi, nullptr, nullptr, lnbuf, ln2_g + l*256, ln2_b + l*256);
    mfma_gemm<1,0><<<dim3(65, 8), 256, 0, stream>>>(lnbuf, fc1Ph + (size_t)l*262144, fc1Pl + (size_t)l*262144,
                                                    fc1_b + l*1024, nullptr, bigbuf, M, 256, 1024);
    mfma_gemm<0,1><<<dim3(65, 2), 256, 0, stream>>>(bigbuf, fc2Ph + (size_t)l*262144, fc2Pl + (size_t)l*262144,
                                                    fc2_b + l*256, xi, xt, M, 1024, 256);
  }
  add_ln_kernel<<<M, 256, 0, stream>>>(xt, nullptr, nullptr, gfeat, norm_g, norm_b);
  head_kernel<<<B_ * G_, 256, 0, stream>>>(gfeat, neigh, knn_idx, head_w1, head_b1, head_w2, head_b2, sums, cnts);
  finalize_kernel<<<(B_ * N_) / 256, 256, 0, stream>>>(sums, cnts, (float*)d_out);
}

// Round 4
// 2294.351 us; speedup vs baseline: 1.2220x; 1.2220x over previous
//
#include <hip/hip_runtime.h>

#define B_ 16
#define N_ 8192
#define G_ 256
#define K_ 64
#define D_ 256
#define HID_ 1024
#define EPS_ 1e-5f

typedef __attribute__((ext_vector_type(8))) short bf16x8;
typedef __attribute__((ext_vector_type(4))) float f32x4;

__device__ __forceinline__ float bf16_to_f32(unsigned short u){
  unsigned int v = ((unsigned int)u) << 16;
  return __uint_as_float(v);
}
__device__ __forceinline__ unsigned short f32_to_bf16(float f){
  unsigned int u = __float_as_uint(f);
  unsigned int r = (u + 0x7FFFu + ((u >> 16) & 1u)) >> 16;
  return (unsigned short)r;
}
__device__ __forceinline__ float gelu_exact(float v){
  return 0.5f * v * (1.0f + erff(v * 0.70710678118654752440f));
}

// ---------------- fold BN into enc_w1/enc_w3 ----------------
__global__ void fold_kernel(const float* __restrict__ w1, const float* __restrict__ b1,
    const float* __restrict__ g1, const float* __restrict__ bb1,
    const float* __restrict__ w3, const float* __restrict__ b3,
    const float* __restrict__ g2, const float* __restrict__ bb2,
    float* __restrict__ w1f, float* __restrict__ b1f,
    float* __restrict__ w3f, float* __restrict__ b3f)
{
  int i = blockIdx.x * 256 + threadIdx.x;
  const float S = 0.99999500003749968f; // 1/sqrt(1+1e-5)
  if (i < 384) w1f[i] = w1[i] * g1[i & 127] * S;
  if (i < 128) b1f[i] = b1[i] * g1[i] * S + bb1[i];
  if (i < 262144) w3f[i] = w3[i] * g2[i & 511] * S;
  if (i < 512) b3f[i] = b3[i] * g2[i] * S + bb2[i];
}

// ---------------- ONE packing kernel for all weights ----------------
// B frag for 16x16x32: lane holds B[k=(lane>>4)*8+j][n=lane&15], j=0..7
// packed[((nt*KS + ks)*64 + lane)*8 + j],  KS = K/32
__device__ __forceinline__ void packHi(const float* __restrict__ W, unsigned short* __restrict__ hi,
                                       int f, int N, int ksBits){
  int j = f & 7, lane = (f >> 3) & 63;
  int ks = (f >> 9) & ((1 << ksBits) - 1);
  int nt = f >> (9 + ksBits);
  int k = ks * 32 + ((lane >> 4) & 3) * 8 + j, c = nt * 16 + (lane & 15);
  hi[f] = f32_to_bf16(W[(size_t)k * N + c]);
}
__global__ void pack_all_kernel(const float* __restrict__ enc_w2, const float* __restrict__ w3f,
    const float* __restrict__ enc_w4, const float* __restrict__ qkv_w, const float* __restrict__ proj_w,
    const float* __restrict__ fc1_w, const float* __restrict__ fc2_w,
    unsigned short* __restrict__ w2ph, unsigned short* __restrict__ w2pl,
    unsigned short* __restrict__ w3ph, unsigned short* __restrict__ w4ph,
    unsigned short* __restrict__ qkvPh, unsigned short* __restrict__ projPh,
    unsigned short* __restrict__ fc1Ph, unsigned short* __restrict__ fc2Ph,
    unsigned short* __restrict__ w3th)
{
  int blk = blockIdx.x, tid = threadIdx.x;
  if (blk < 128){            // w2: hi+lo (K=128, N=256, ksBits=2)
    int f = blk * 256 + tid;
    int j = f & 7, lane = (f >> 3) & 63, ks = (f >> 9) & 3, nt = f >> 11;
    int k = ks * 32 + ((lane >> 4) & 3) * 8 + j, c = nt * 16 + (lane & 15);
    float v = enc_w2[(size_t)k * 256 + c];
    unsigned short h = f32_to_bf16(v);
    w2ph[f] = h; w2pl[f] = f32_to_bf16(v - bf16_to_f32(h));
  } else if (blk < 640){     // w3 bottom half (rows 256..511 of 512x512), ksBits=3
    int f = (blk - 128) * 256 + tid;
    int j = f & 7, lane = (f >> 3) & 63, ks = (f >> 9) & 7, nt = f >> 12;
    int k = ks * 32 + ((lane >> 4) & 3) * 8 + j, c = nt * 16 + (lane & 15);
    w3ph[f] = f32_to_bf16(w3f[(size_t)(256 + k) * 512 + c]);
  } else if (blk < 1152){    // w4 (K=512, N=256, ksBits=4)
    int f = (blk - 640) * 256 + tid;
    packHi(enc_w4, w4ph, f, 256, 4);
  } else if (blk < 4224){    // qkv x4 (K=256, N=768, ksBits=3)
    int f = (blk - 1152) * 256 + tid;
    int l = f / 196608, fl = f - l * 196608;
    packHi(qkv_w + (size_t)l * 196608, qkvPh + (size_t)l * 196608, fl, 768, 3);
  } else if (blk < 5248){    // proj x4 (K=256, N=256, ksBits=3)
    int f = (blk - 4224) * 256 + tid;
    int l = f >> 16, fl = f & 65535;
    packHi(proj_w + (size_t)l * 65536, projPh + (size_t)l * 65536, fl, 256, 3);
  } else if (blk < 9344){    // fc1 x4 (K=256, N=1024, ksBits=3)
    int f = (blk - 5248) * 256 + tid;
    int l = f >> 18, fl = f & 262143;
    packHi(fc1_w + (size_t)l * 262144, fc1Ph + (size_t)l * 262144, fl, 1024, 3);
  } else if (blk < 13440){   // fc2 x4 (K=1024, N=256, ksBits=5)
    int f = (blk - 9344) * 256 + tid;
    int l = f >> 18, fl = f & 262143;
    packHi(fc2_w + (size_t)l * 262144, fc2Ph + (size_t)l * 262144, fl, 256, 5);
  } else {                   // w3 top half (rows 0..255) row-major bf16 for the gmax GEMV
    int f = (blk - 13440) * 256 + tid;   // [0, 131072)
    int k = f >> 9, c = f & 511;
    w3th[f] = f32_to_bf16(w3f[(size_t)k * 512 + c]);
  }
}

// ---------------- FPS: one block per batch, 1 barrier/iter ----------------
__global__ __launch_bounds__(1024) void fps_kernel(const float* __restrict__ x, float* __restrict__ centers)
{
  int b = blockIdx.x;
  const float* xb = x + (size_t)b * N_ * 3;
  int tid = threadIdx.x, wave = tid >> 6, lane = tid & 63;
  float px[8], py[8], pz[8], dist[8];
#pragma unroll
  for (int j = 0; j < 8; j++){
    int p = tid + j * 1024;
    px[j] = xb[p*3+0]; py[j] = xb[p*3+1]; pz[j] = xb[p*3+2];
    dist[j] = 1e10f;
  }
  __shared__ unsigned long long wred[2][16];
  float cx = xb[0], cy = xb[1], cz = xb[2];
  for (int i = 0; i < G_; i++){
    if (tid == 0){
      float* cp = centers + ((size_t)b * G_ + i) * 3;
      cp[0] = cx; cp[1] = cy; cp[2] = cz;
    }
    unsigned long long best = 0ull;
#pragma unroll
    for (int j = 0; j < 8; j++){
      float dx = __fadd_rn(px[j], -cx);
      float dy = __fadd_rn(py[j], -cy);
      float dz = __fadd_rn(pz[j], -cz);
      float d  = __fadd_rn(__fadd_rn(__fmul_rn(dx,dx), __fmul_rn(dy,dy)), __fmul_rn(dz,dz));
      float dm = fminf(dist[j], d);
      dist[j] = dm;
      unsigned int pp = (unsigned int)(tid + j * 1024);
      unsigned long long key = (((unsigned long long)__float_as_uint(dm)) << 32) | (unsigned long long)(~pp);
      best = (key > best) ? key : best;
    }
#pragma unroll
    for (int o = 32; o; o >>= 1){
      unsigned long long t = __shfl_down(best, o);
      best = (t > best) ? t : best;
    }
    if (lane == 0) wred[i & 1][wave] = best;
    __syncthreads();
    unsigned long long m = wred[i & 1][0];
#pragma unroll
    for (int w = 1; w < 16; w++){ unsigned long long t = wred[i & 1][w]; m = (t > m) ? t : m; }
    int far = (int)(~(unsigned int)(m & 0xFFFFFFFFull));
    if (i + 1 < G_){
      const float* fp = xb + (size_t)far * 3;   // uniform address -> broadcast read
      cx = fp[0]; cy = fp[1]; cz = fp[2];
    }
  }
}

// ---------------- KNN: one block per (b,g) ----------------
__global__ __launch_bounds__(256) void knn_kernel(const float* __restrict__ x, const float* __restrict__ centers,
                                                  int* __restrict__ knn_idx, float* __restrict__ neigh)
{
  int blk = blockIdx.x, b = blk >> 8;
  const float* xb = x + (size_t)b * N_ * 3;
  const float* cc = centers + (size_t)blk * 3;
  int tid = threadIdx.x;
  float c0 = cc[0], c1 = cc[1], c2v = cc[2];
  float c2s = __fadd_rn(__fadd_rn(__fmul_rn(c0,c0), __fmul_rn(c1,c1)), __fmul_rn(c2v,c2v));
  float d[32];
#pragma unroll
  for (int j = 0; j < 32; j++){
    int p = tid + j * 256;
    float x0 = xb[p*3+0], x1 = xb[p*3+1], x2 = xb[p*3+2];
    float xs = __fadd_rn(__fadd_rn(__fmul_rn(x0,x0), __fmul_rn(x1,x1)), __fmul_rn(x2,x2));
    float dt = __fadd_rn(__fadd_rn(__fmul_rn(c0,x0), __fmul_rn(c1,x1)), __fmul_rn(c2v,x2));
    d[j] = __fadd_rn(__fadd_rn(c2s, xs), -__fmul_rn(2.0f, dt));
  }
  const float FINF = __int_as_float(0x7F800000);
  float lmin = FINF; unsigned int lp = 0xFFFFFFFFu;
#pragma unroll
  for (int j = 0; j < 32; j++){ if (d[j] < lmin){ lmin = d[j]; lp = (unsigned int)(tid + j*256); } }
  __shared__ unsigned long long wred[2][4];
  for (int r = 0; r < K_; r++){
    unsigned int u = __float_as_uint(lmin);
    u = (u & 0x80000000u) ? ~u : (u | 0x80000000u);
    unsigned long long key = (((unsigned long long)u) << 32) | (unsigned long long)lp;
#pragma unroll
    for (int o = 32; o; o >>= 1){
      unsigned long long t = __shfl_down(key, o);
      key = (t < key) ? t : key;
    }
    int cur = r & 1;
    if ((tid & 63) == 0) wred[cur][tid >> 6] = key;
    __syncthreads();
    unsigned long long m = wred[cur][0];
#pragma unroll
    for (int w = 1; w < 4; w++){ unsigned long long t = wred[cur][w]; m = (t < m) ? t : m; }
    unsigned int p = (unsigned int)(m & 0xFFFFFFFFull);
    if (tid == (p & 255u)){
      knn_idx[(size_t)blk * K_ + r] = (int)p;
      float* np_ = neigh + ((size_t)blk * K_ + r) * 3;
      np_[0] = __fadd_rn(xb[p*3+0], -c0);
      np_[1] = __fadd_rn(xb[p*3+1], -c1);
      np_[2] = __fadd_rn(xb[p*3+2], -c2v);
      lmin = FINF; lp = 0xFFFFFFFFu;
#pragma unroll
      for (int j = 0; j < 32; j++){
        if ((unsigned int)(tid + j*256) == p) d[j] = FINF;
        if (d[j] < lmin){ lmin = d[j]; lp = (unsigned int)(tid + j*256); }
      }
    }
  }
}

// ---------------- fused group encoder (MFMA bf16): one block per (b,g) ----------------
// LDS = 17408 + 33792 + 1024 + 2048 = 54272 B. NOTE: min-waves kept at 2 —
// forcing 3 caps VGPR at 84 and spills acc3/acc4 to scratch (R3: 248MB FETCH).
__global__ __launch_bounds__(256, 2) void encoder_kernel(
    const float* __restrict__ neigh,
    const float* __restrict__ w1f, const float* __restrict__ b1f,
    const unsigned short* __restrict__ w2ph, const unsigned short* __restrict__ w2pl,
    const float* __restrict__ b2,
    const float* __restrict__ b3f,
    const unsigned short* __restrict__ w3ph, const unsigned short* __restrict__ w3th,
    const unsigned short* __restrict__ w4ph,
    const float* __restrict__ b4,
    float* __restrict__ tokens)
{
  __shared__ __align__(16) unsigned short sH1[64 * 136];  // h1 (64x128 bf16), reused as h3 chunk
  __shared__ __align__(16) unsigned short sH2[64 * 264];  // h2 (64x256 bf16)
  __shared__ float sGmax[256];
  __shared__ float sPartA[512];                            // aliased as sNeigh in phase 1
  float (*sNeigh)[4] = (float(*)[4])sPartA;

  int tid  = threadIdx.x;
  int wave = tid >> 6, lane = tid & 63, quad = lane >> 4, lrow = lane & 15;
  size_t gid = blockIdx.x;

  if (tid < 192) sNeigh[tid / 3][tid % 3] = neigh[gid * 192 + tid];
  __syncthreads();

  // ---- phase 1: h1 = relu(bn(neigh @ w1)) -> bf16 LDS ----
  for (int e = tid; e < 8192; e += 256){
    int r = e >> 7, c = e & 127;
    float v = fmaf(sNeigh[r][2], w1f[256 + c], fmaf(sNeigh[r][1], w1f[128 + c], fmaf(sNeigh[r][0], w1f[c], b1f[c])));
    sH1[r * 136 + c] = f32_to_bf16(fmaxf(v, 0.0f));
  }
  __syncthreads();

  // ---- phase 2: h2 = h1 @ w2 + b2 (MFMA, hi/lo kept: first layer) ----
  {
    f32x4 acc[4][4];
    const f32x4 z = {0.f, 0.f, 0.f, 0.f};
#pragma unroll
    for (int mt = 0; mt < 4; mt++)
#pragma unroll
      for (int nl = 0; nl < 4; nl++) acc[mt][nl] = z;
#pragma unroll
    for (int ks = 0; ks < 4; ks++){
      bf16x8 af[4];
#pragma unroll
      for (int mt = 0; mt < 4; mt++)
        af[mt] = *(const bf16x8*)&sH1[(mt*16 + lrow)*136 + ks*32 + quad*8];
#pragma unroll
      for (int nl = 0; nl < 4; nl++){
        size_t bo = (((size_t)(wave*4 + nl)*4 + ks)*64 + lane)*8;
        bf16x8 bh = *(const bf16x8*)&w2ph[bo];
        bf16x8 bl = *(const bf16x8*)&w2pl[bo];
#pragma unroll
        for (int mt = 0; mt < 4; mt++){
          acc[mt][nl] = __builtin_amdgcn_mfma_f32_16x16x32_bf16(af[mt], bh, acc[mt][nl], 0, 0, 0);
          acc[mt][nl] = __builtin_amdgcn_mfma_f32_16x16x32_bf16(af[mt], bl, acc[mt][nl], 0, 0, 0);
        }
      }
    }
#pragma unroll
    for (int nl = 0; nl < 4; nl++){
      int col = wave*64 + nl*16 + lrow;
      float bias = b2[col];
#pragma unroll
      for (int mt = 0; mt < 4; mt++)
#pragma unroll
        for (int rg = 0; rg < 4; rg++)
          sH2[(mt*16 + quad*4 + rg)*264 + col] = f32_to_bf16(acc[mt][nl][rg] + bias);
    }
  }
  __syncthreads();

  // ---- phase 3: gmax = colmax(h2) ----
  {
    float mx = -3.4e38f;
#pragma unroll 8
    for (int r = 0; r < 64; r++) mx = fmaxf(mx, bf16_to_f32(sH2[r*264 + tid]));
    sGmax[tid] = mx;
  }
  __syncthreads();

  // ---- phase 4: partA = gmax @ w3[0:256] (bf16 weights, coalesced) ----
#pragma unroll
  for (int half = 0; half < 2; half++){
    int c = tid + half * 256;
    float s = 0.0f;
#pragma unroll 8
    for (int k = 0; k < 256; k++) s = fmaf(sGmax[k], bf16_to_f32(w3th[(size_t)k * 512 + c]), s);
    sPartA[c] = s;
  }
  __syncthreads();

  // ---- phase 5: h3 (chunks of 128 cols) + h4 accumulation (MFMA, single-bf16) ----
  f32x4 acc4[4][4];
  {
    const f32x4 z = {0.f, 0.f, 0.f, 0.f};
#pragma unroll
    for (int mt = 0; mt < 4; mt++)
#pragma unroll
      for (int nl = 0; nl < 4; nl++) acc4[mt][nl] = z;
  }
  for (int cc = 0; cc < 4; cc++){
    f32x4 acc3[4][2];
    {
      const f32x4 z = {0.f, 0.f, 0.f, 0.f};
#pragma unroll
      for (int mt = 0; mt < 4; mt++){ acc3[mt][0] = z; acc3[mt][1] = z; }
    }
#pragma unroll
    for (int ks = 0; ks < 8; ks++){
      bf16x8 af[4];
#pragma unroll
      for (int mt = 0; mt < 4; mt++)
        af[mt] = *(const bf16x8*)&sH2[(mt*16 + lrow)*264 + ks*32 + quad*8];
#pragma unroll
      for (int nl = 0; nl < 2; nl++){
        int nt = cc*8 + wave*2 + nl;
        size_t bo = (((size_t)nt*8 + ks)*64 + lane)*8;
        bf16x8 bh = *(const bf16x8*)&w3ph[bo];
#pragma unroll
        for (int mt = 0; mt < 4; mt++)
          acc3[mt][nl] = __builtin_amdgcn_mfma_f32_16x16x32_bf16(af[mt], bh, acc3[mt][nl], 0, 0, 0);
      }
    }
    __syncthreads();
#pragma unroll
    for (int nl = 0; nl < 2; nl++){
      int cl = wave*32 + nl*16 + lrow;
      int c  = cc*128 + cl;
      float pb = sPartA[c] + b3f[c];
#pragma unroll
      for (int mt = 0; mt < 4; mt++)
#pragma unroll
        for (int rg = 0; rg < 4; rg++)
          sH1[(mt*16 + quad*4 + rg)*136 + cl] = f32_to_bf16(fmaxf(acc3[mt][nl][rg] + pb, 0.0f));
    }
    __syncthreads();
#pragma unroll
    for (int ks = 0; ks < 4; ks++){
      bf16x8 af[4];
#pragma unroll
      for (int mt = 0; mt < 4; mt++)
        af[mt] = *(const bf16x8*)&sH1[(mt*16 + lrow)*136 + ks*32 + quad*8];
#pragma unroll
      for (int nl = 0; nl < 4; nl++){
        int nt = wave*4 + nl;
        size_t bo = (((size_t)nt*16 + cc*4 + ks)*64 + lane)*8;
        bf16x8 bh = *(const bf16x8*)&w4ph[bo];
#pragma unroll
        for (int mt = 0; mt < 4; mt++)
          acc4[mt][nl] = __builtin_amdgcn_mfma_f32_16x16x32_bf16(af[mt], bh, acc4[mt][nl], 0, 0, 0);
      }
    }
  }

  // ---- phase 6: tokens = colmax(h4) + b4 ----
#pragma unroll
  for (int nl = 0; nl < 4; nl++){
    float mx = -3.4e38f;
#pragma unroll
    for (int mt = 0; mt < 4; mt++)
#pragma unroll
      for (int rg = 0; rg < 4; rg++) mx = fmaxf(mx, acc4[mt][nl][rg]);
    mx = fmaxf(mx, __shfl_xor(mx, 16));
    mx = fmaxf(mx, __shfl_xor(mx, 32));
    if (quad == 0){
      int col = wave*64 + nl*16 + lrow;
      tokens[gid * 256 + col] = mx + b4[col];
    }
  }
}

// ---------------- pos embed + assemble + first LN (fused) ----------------
__global__ __launch_bounds__(128) void pos_ln_kernel(
    const float* __restrict__ centers, const float* __restrict__ tokens,
    const float* __restrict__ cls_token, const float* __restrict__ cls_pos,
    const float* __restrict__ pw1, const float* __restrict__ pb1,
    const float* __restrict__ pw2, const float* __restrict__ pb2,
    const float* __restrict__ lng, const float* __restrict__ lnb,
    float* __restrict__ pt, float* __restrict__ xi, float* __restrict__ lnbuf)
{
  __shared__ float hS[128];
  __shared__ float red[2][2];
  int row = blockIdx.x;
  int b = row / 257, n = row - b * 257;
  int tid = threadIdx.x;
  size_t ro = (size_t)row * 256;
  float u0, u1;
  if (n == 0){
    float p0 = cls_pos[tid], p1 = cls_pos[128 + tid];
    u0 = cls_token[tid] + p0; u1 = cls_token[128 + tid] + p1;
    pt[ro + tid] = p0; pt[ro + 128 + tid] = p1;
  } else {
    int g = n - 1;
    const float* c = centers + ((size_t)b * 256 + g) * 3;
    float h = fmaf(c[2], pw1[256 + tid], fmaf(c[1], pw1[128 + tid], fmaf(c[0], pw1[tid], pb1[tid])));
    hS[tid] = gelu_exact(h);
    __syncthreads();
    const float* tok = tokens + ((size_t)b * 256 + g) * 256;
    float s0 = pb2[tid], s1 = pb2[128 + tid];
#pragma unroll 4
    for (int k = 0; k < 128; k++){
      s0 = fmaf(hS[k], pw2[(size_t)k * 256 + tid], s0);
      s1 = fmaf(hS[k], pw2[(size_t)k * 256 + 128 + tid], s1);
    }
    pt[ro + tid] = s0; pt[ro + 128 + tid] = s1;
    u0 = tok[tid] + s0; u1 = tok[128 + tid] + s1;
  }
  float s = u0 + u1, q = u0*u0 + u1*u1;
#pragma unroll
  for (int o = 32; o; o >>= 1){ s += __shfl_down(s, o); q += __shfl_down(q, o); }
  int wv = tid >> 6;
  if ((tid & 63) == 0){ red[0][wv] = s; red[1][wv] = q; }
  __syncthreads();
  float m  = (red[0][0] + red[0][1]) * (1.0f / 256.0f);
  float var = (red[1][0] + red[1][1]) * (1.0f / 256.0f) - m * m;
  float rs = 1.0f / sqrtf(var + EPS_);
  xi[ro + tid] = u0; xi[ro + 128 + tid] = u1;
  lnbuf[ro + tid] = (u0 - m) * rs * lng[tid] + lnb[tid];
  lnbuf[ro + 128 + tid] = (u1 - m) * rs * lng[128 + tid] + lnb[128 + tid];
}

// ---------------- MFMA GEMM: C = act(A@B + bias) [no residual/LN] ----------------
// Tile 64 rows x 128 cols (wave w = cols w*32..w*32+31), single-bf16 B.
template<int ACT>
__global__ __launch_bounds__(256) void mfma_gemm(
    const float* __restrict__ A, const unsigned short* __restrict__ Bh,
    const float* __restrict__ bias, float* __restrict__ C, int M, int K, int N)
{
  __shared__ __align__(16) unsigned short sA[64 * 72];
  int tid = threadIdx.x;
  int wave = tid >> 6, lane = tid & 63, quad = lane >> 4, lrow = lane & 15;
  int row0 = blockIdx.x * 64;
  int col0 = blockIdx.y * 128;
  int ksTotal = K >> 5;
  f32x4 acc[4][2];
  const f32x4 z = {0.f, 0.f, 0.f, 0.f};
#pragma unroll
  for (int mt = 0; mt < 4; mt++){ acc[mt][0] = z; acc[mt][1] = z; }

  for (int k0 = 0; k0 < K; k0 += 64){
#pragma unroll
    for (int i = 0; i < 4; i++){
      int e = tid + i * 256;
      int r = e >> 4, c4 = (e & 15) * 4;
      int gr = row0 + r;
      float4 v = make_float4(0.f,0.f,0.f,0.f);
      if (gr < M) v = *(const float4*)(A + (size_t)gr * K + k0 + c4);
      unsigned short* dst = &sA[r * 72 + c4];
      dst[0] = f32_to_bf16(v.x); dst[1] = f32_to_bf16(v.y);
      dst[2] = f32_to_bf16(v.z); dst[3] = f32_to_bf16(v.w);
    }
    __syncthreads();
    int ksBase = k0 >> 5;
#pragma unroll
    for (int ks = 0; ks < 2; ks++){
      bf16x8 af[4];
#pragma unroll
      for (int mt = 0; mt < 4; mt++)
        af[mt] = *(const bf16x8*)&sA[(mt*16 + lrow)*72 + ks*32 + quad*8];
#pragma unroll
      for (int nl = 0; nl < 2; nl++){
        int nt = (col0 >> 4) + wave*2 + nl;
        size_t bo = (((size_t)nt * ksTotal + ksBase + ks)*64 + lane)*8;
        bf16x8 bh = *(const bf16x8*)&Bh[bo];
#pragma unroll
        for (int mt = 0; mt < 4; mt++)
          acc[mt][nl] = __builtin_amdgcn_mfma_f32_16x16x32_bf16(af[mt], bh, acc[mt][nl], 0, 0, 0);
      }
    }
    __syncthreads();
  }
#pragma unroll
  for (int nl = 0; nl < 2; nl++){
    int c = col0 + wave*32 + nl*16 + lrow;
    float bc = bias ? bias[c] : 0.0f;
#pragma unroll
    for (int mt = 0; mt < 4; mt++)
#pragma unroll
      for (int rg = 0; rg < 4; rg++){
        int r = row0 + mt*16 + quad*4 + rg;
        if (r < M){
          float v = acc[mt][nl][rg] + bc;
          if (ACT == 1) v = gelu_exact(v);
          C[(size_t)r * N + c] = v;
        }
      }
  }
}

// ---------------- MFMA GEMM + residual + LayerNorm epilogue (N=256 fixed) ----------------
// v = A@B + bias + res  -> C = v;  u = v (+ pt);  xiOut = u (opt);  lnOut = LN(u)*g+b
__global__ __launch_bounds__(256) void mfma_gemm_ln(
    const float* __restrict__ A, const unsigned short* __restrict__ Bh,
    const float* __restrict__ bias, const float* __restrict__ res,
    const float* __restrict__ ptb,   // nullable: add before LN
    float* __restrict__ C, float* __restrict__ xiOut, float* __restrict__ lnOut,
    const float* __restrict__ lng, const float* __restrict__ lnb, int M, int K)
{
  __shared__ __align__(16) unsigned short sA[64 * 72];
  __shared__ float sRed[2][64][4];
  int tid = threadIdx.x;
  int wave = tid >> 6, lane = tid & 63, quad = lane >> 4, lrow = lane & 15;
  int row0 = blockIdx.x * 64;
  int ksTotal = K >> 5;
  f32x4 acc[4][4];
  const f32x4 z = {0.f, 0.f, 0.f, 0.f};
#pragma unroll
  for (int mt = 0; mt < 4; mt++)
#pragma unroll
    for (int nl = 0; nl < 4; nl++) acc[mt][nl] = z;

  for (int k0 = 0; k0 < K; k0 += 64){
#pragma unroll
    for (int i = 0; i < 4; i++){
      int e = tid + i * 256;
      int r = e >> 4, c4 = (e & 15) * 4;
      int gr = row0 + r;
      float4 v = make_float4(0.f,0.f,0.f,0.f);
      if (gr < M) v = *(const float4*)(A + (size_t)gr * K + k0 + c4);
      unsigned short* dst = &sA[r * 72 + c4];
      dst[0] = f32_to_bf16(v.x); dst[1] = f32_to_bf16(v.y);
      dst[2] = f32_to_bf16(v.z); dst[3] = f32_to_bf16(v.w);
    }
    __syncthreads();
    int ksBase = k0 >> 5;
#pragma unroll
    for (int ks = 0; ks < 2; ks++){
      bf16x8 af[4];
#pragma unroll
      for (int mt = 0; mt < 4; mt++)
        af[mt] = *(const bf16x8*)&sA[(mt*16 + lrow)*72 + ks*32 + quad*8];
#pragma unroll
      for (int nl = 0; nl < 4; nl++){
        int nt = wave*4 + nl;
        size_t bo = (((size_t)nt * ksTotal + ksBase + ks)*64 + lane)*8;
        bf16x8 bh = *(const bf16x8*)&Bh[bo];
#pragma unroll
        for (int mt = 0; mt < 4; mt++)
          acc[mt][nl] = __builtin_amdgcn_mfma_f32_16x16x32_bf16(af[mt], bh, acc[mt][nl], 0, 0, 0);
      }
    }
    __syncthreads();
  }
  // epilogue: v = acc + bias + res; C = v; acc := u = v (+pt)
#pragma unroll
  for (int nl = 0; nl < 4; nl++){
    int c = wave*64 + nl*16 + lrow;
    float bc = bias[c];
#pragma unroll
    for (int mt = 0; mt < 4; mt++)
#pragma unroll
      for (int rg = 0; rg < 4; rg++){
        int r = row0 + mt*16 + quad*4 + rg;
        if (r < M){
          float v = acc[mt][nl][rg] + bc + res[(size_t)r * 256 + c];
          C[(size_t)r * 256 + c] = v;
          float u = v;
          if (ptb) u += ptb[(size_t)r * 256 + c];
          acc[mt][nl][rg] = u;
        }
      }
  }
  // row stats: sum over this wave's 64 cols via 16-lane butterfly, cross-wave via LDS
#pragma unroll
  for (int mt = 0; mt < 4; mt++)
#pragma unroll
    for (int rg = 0; rg < 4; rg++){
      int rloc = mt*16 + quad*4 + rg;
      float s = 0.0f, q = 0.0f;
#pragma unroll
      for (int nl = 0; nl < 4; nl++){ float u = acc[mt][nl][rg]; s += u; q += u*u; }
#pragma unroll
      for (int off = 1; off < 16; off <<= 1){ s += __shfl_xor(s, off); q += __shfl_xor(q, off); }
      if (lrow == 0){ sRed[0][rloc][wave] = s; sRed[1][rloc][wave] = q; }
    }
  __syncthreads();
#pragma unroll
  for (int mt = 0; mt < 4; mt++)
#pragma unroll
    for (int rg = 0; rg < 4; rg++){
      int rloc = mt*16 + quad*4 + rg;
      int r = row0 + rloc;
      if (r >= M) continue;
      float s = ((sRed[0][rloc][0] + sRed[0][rloc][1]) + sRed[0][rloc][2]) + sRed[0][rloc][3];
      float q = ((sRed[1][rloc][0] + sRed[1][rloc][1]) + sRed[1][rloc][2]) + sRed[1][rloc][3];
      float m  = s * (1.0f / 256.0f);
      float var = q * (1.0f / 256.0f) - m * m;
      float rs = 1.0f / sqrtf(var + EPS_);
#pragma unroll
      for (int nl = 0; nl < 4; nl++){
        int c = wave*64 + nl*16 + lrow;
        float u = acc[mt][nl][rg];
        lnOut[(size_t)r * 256 + c] = (u - m) * rs * lng[c] + lnb[c];
        if (xiOut) xiOut[(size_t)r * 256 + c] = u;
      }
    }
}

// ---------------- attention: block per (b,h,qchunk), flash-style ----------------
__global__ __launch_bounds__(64) void attn_kernel(const float* __restrict__ qkv, float* __restrict__ obuf)
{
  int bh = blockIdx.x;
  int b = bh >> 3, h = bh & 7;
  int qrow = blockIdx.y * 64 + threadIdx.x;
  bool act = qrow < 257;
  __shared__ float kS[128][33];
  __shared__ float vS[128][33];
  const float* qb = qkv + (size_t)b * 257 * 768;
  int tid = threadIdx.x;
  float q[32], o[32];
  float mrun = -3.4e38f, l = 0.0f;
  if (act){
    const float* qr = qb + (size_t)qrow * 768 + h * 32;
#pragma unroll
    for (int j = 0; j < 32; j++){ q[j] = qr[j]; o[j] = 0.0f; }
  }
  const float scale = 0.17677669529663687f;
  for (int m0 = 0; m0 < 257; m0 += 128){
    int cnt = min(128, 257 - m0);
    for (int e = tid; e < cnt * 32; e += 64){
      int mm = e >> 5, j = e & 31;
      const float* rowp = qb + (size_t)(m0 + mm) * 768 + h * 32;
      kS[mm][j] = rowp[256 + j];
      vS[mm][j] = rowp[512 + j];
    }
    __syncthreads();
    if (act){
      for (int mm = 0; mm < cnt; mm++){
        float s = 0.0f;
#pragma unroll
        for (int j = 0; j < 32; j++) s = fmaf(q[j], kS[mm][j], s);
        s *= scale;
        float nm = fmaxf(mrun, s);
        float alpha = expf(mrun - nm);
        float p = expf(s - nm);
        l = fmaf(l, alpha, p);
#pragma unroll
        for (int j = 0; j < 32; j++) o[j] = fmaf(p, vS[mm][j], o[j] * alpha);
        mrun = nm;
      }
    }
    __syncthreads();
  }
  if (act){
    float inv = 1.0f / l;
    float* orow = obuf + (size_t)(b * 257 + qrow) * 256 + h * 32;
#pragma unroll
    for (int j = 0; j < 32; j++) orow[j] = o[j] * inv;
  }
}

// ---------------- head MLP + scatter: one block per (b,g) ----------------
__global__ __launch_bounds__(256) void head_kernel(
    const float* __restrict__ gfeat, const float* __restrict__ neigh, const int* __restrict__ knn_idx,
    const float* __restrict__ w1, const float* __restrict__ b1,
    const float* __restrict__ w2, const float* __restrict__ b2,
    float* __restrict__ sums, float* __restrict__ cnts)
{
  int blk = blockIdx.x, b = blk >> 8;
  __shared__ float xS[256];
  __shared__ float nS[64][4];
  __shared__ float partH[2][128];
  __shared__ float sharedH[128];
  __shared__ float w2S[128];
  __shared__ float wtail[3][128];
  int tid = threadIdx.x;
  xS[tid] = gfeat[((size_t)b * 257 + 1 + (blk & 255)) * 256 + tid];
  if (tid < 192) nS[tid / 3][tid % 3] = neigh[(size_t)blk * 192 + tid];
  if (tid < 128){
    w2S[tid] = w2[tid];
    wtail[0][tid] = w1[256 * 128 + tid];
    wtail[1][tid] = w1[257 * 128 + tid];
    wtail[2][tid] = w1[258 * 128 + tid];
  }
  __syncthreads();
  {
    int half = tid >> 7, j = tid & 127;
    float s = 0.0f;
#pragma unroll 8
    for (int k = 0; k < 128; k++) s = fmaf(xS[half * 128 + k], w1[(size_t)(half * 128 + k) * 128 + j], s);
    partH[half][j] = s;
  }
  __syncthreads();
  if (tid < 128) sharedH[tid] = partH[0][tid] + partH[1][tid] + b1[tid];
  __syncthreads();
  int r = tid >> 2, q = tid & 3;
  float n0 = nS[r][0], n1 = nS[r][1], n2 = nS[r][2];
  float s = 0.0f;
#pragma unroll
  for (int j0 = 0; j0 < 32; j0++){
    int j = q * 32 + j0;
    float h = fmaf(n2, wtail[2][j], fmaf(n1, wtail[1][j], fmaf(n0, wtail[0][j], sharedH[j])));
    s = fmaf(fmaxf(h, 0.0f), w2S[j], s);
  }
  s += __shfl_xor(s, 1);
  s += __shfl_xor(s, 2);
  if (q == 0){
    float lg = s + b2[0];
    int p = knn_idx[(size_t)blk * K_ + r];
    atomicAdd(&sums[(size_t)b * N_ + p], lg);
    atomicAdd(&cnts[(size_t)b * N_ + p], 1.0f);
  }
}

__global__ void finalize_kernel(const float* __restrict__ sums, const float* __restrict__ cnts, float* __restrict__ out)
{
  int i = blockIdx.x * 256 + threadIdx.x;
  out[i] = sums[i] / fmaxf(cnts[i], 1.0f);
}

extern "C" void kernel_launch(void* const* d_in, const int* in_sizes, int n_in,
                              void* d_out, int out_size, void* d_ws, size_t ws_size,
                              hipStream_t stream)
{
  (void)in_sizes; (void)n_in; (void)out_size; (void)ws_size;
  const float* x        = (const float*)d_in[0];
  const float* enc_w1   = (const float*)d_in[1];
  const float* enc_b1   = (const float*)d_in[2];
  const float* enc_bn1g = (const float*)d_in[3];
  const float* enc_bn1b = (const float*)d_in[4];
  const float* enc_w2   = (const float*)d_in[5];
  const float* enc_b2   = (const float*)d_in[6];
  const float* enc_w3   = (const float*)d_in[7];
  const float* enc_b3   = (const float*)d_in[8];
  const float* enc_bn2g = (const float*)d_in[9];
  const float* enc_bn2b = (const float*)d_in[10];
  const float* enc_w4   = (const float*)d_in[11];
  const float* enc_b4   = (const float*)d_in[12];
  const float* cls_tok  = (const float*)d_in[13];
  const float* cls_pos  = (const float*)d_in[14];
  const float* pos_w1   = (const float*)d_in[15];
  const float* pos_b1   = (const float*)d_in[16];
  const float* pos_w2   = (const float*)d_in[17];
  const float* pos_b2   = (const float*)d_in[18];
  const float* ln1_g    = (const float*)d_in[19];
  const float* ln1_b    = (const float*)d_in[20];
  const float* qkv_w    = (const float*)d_in[21];
  const float* proj_w   = (const float*)d_in[22];
  const float* proj_b   = (const float*)d_in[23];
  const float* ln2_g    = (const float*)d_in[24];
  const float* ln2_b    = (const float*)d_in[25];
  const float* fc1_w    = (const float*)d_in[26];
  const float* fc1_b    = (const float*)d_in[27];
  const float* fc2_w    = (const float*)d_in[28];
  const float* fc2_b    = (const float*)d_in[29];
  const float* norm_g   = (const float*)d_in[30];
  const float* norm_b   = (const float*)d_in[31];
  const float* head_w1  = (const float*)d_in[32];
  const float* head_b1  = (const float*)d_in[33];
  const float* head_w2  = (const float*)d_in[34];
  const float* head_b2  = (const float*)d_in[35];

  float* ws = (float*)d_ws;
  size_t off = 0;
  auto alloc = [&](size_t n)->float*{ float* p = ws + off; off += (n + 63) & ~(size_t)63; return p; };

  float* centers = alloc((size_t)B_ * G_ * 3);
  float* w1f     = alloc(384);
  float* b1f     = alloc(128);
  float* w3f     = alloc(512 * 512);
  float* b3f     = alloc(512);
  unsigned short* w2ph = (unsigned short*)alloc(16384);
  unsigned short* w2pl = (unsigned short*)alloc(16384);
  unsigned short* w3ph = (unsigned short*)alloc(65536);
  unsigned short* w3th = (unsigned short*)alloc(65536);
  unsigned short* w4ph = (unsigned short*)alloc(65536);
  unsigned short* qkvPh = (unsigned short*)alloc(393216);
  unsigned short* projPh = (unsigned short*)alloc(131072);
  unsigned short* fc1Ph = (unsigned short*)alloc(524288);
  unsigned short* fc2Ph = (unsigned short*)alloc(524288);
  float* tokens  = alloc((size_t)B_ * G_ * D_);
  float* neigh   = alloc((size_t)B_ * G_ * K_ * 3);
  int*   knn_idx = (int*)alloc((size_t)B_ * G_ * K_);
  float* pt      = alloc((size_t)B_ * 257 * D_);
  float* xt      = alloc((size_t)B_ * 257 * D_);
  float* xi      = alloc((size_t)B_ * 257 * D_);
  float* lnbuf   = alloc((size_t)B_ * 257 * D_);
  float* obuf    = alloc((size_t)B_ * 257 * D_);
  float* bigbuf  = alloc((size_t)B_ * 257 * HID_);
  float* gfeat   = alloc((size_t)B_ * 257 * D_);
  float* sums    = alloc((size_t)B_ * N_);
  float* cnts    = alloc((size_t)B_ * N_);

  hipMemsetAsync(sums, 0, (size_t)2 * B_ * N_ * sizeof(float), stream);

  fold_kernel<<<1024, 256, 0, stream>>>(enc_w1, enc_b1, enc_bn1g, enc_bn1b,
                                        enc_w3, enc_b3, enc_bn2g, enc_bn2b,
                                        w1f, b1f, w3f, b3f);
  pack_all_kernel<<<13952, 256, 0, stream>>>(enc_w2, w3f, enc_w4, qkv_w, proj_w, fc1_w, fc2_w,
                                             w2ph, w2pl, w3ph, w4ph, qkvPh, projPh, fc1Ph, fc2Ph, w3th);

  fps_kernel<<<B_, 1024, 0, stream>>>(x, centers);
  knn_kernel<<<B_ * G_, 256, 0, stream>>>(x, centers, knn_idx, neigh);
  encoder_kernel<<<B_ * G_, 256, 0, stream>>>(neigh, w1f, b1f, w2ph, w2pl, enc_b2,
                                              b3f, w3ph, w3th, w4ph, enc_b4, tokens);
  pos_ln_kernel<<<B_ * 257, 128, 0, stream>>>(centers, tokens, cls_tok, cls_pos,
                                              pos_w1, pos_b1, pos_w2, pos_b2,
                                              ln1_g, ln1_b, pt, xi, lnbuf);
  const int M = B_ * 257; // 4112
  for (int l = 0; l < 4; l++){
    mfma_gemm<0><<<dim3(65, 6), 256, 0, stream>>>(lnbuf, qkvPh + (size_t)l*196608, nullptr, bigbuf, M, 256, 768);
    attn_kernel<<<dim3(B_ * 8, 5), 64, 0, stream>>>(bigbuf, obuf);
    // proj + residual + ln2 fused
    mfma_gemm_ln<<<65, 256, 0, stream>>>(obuf, projPh + (size_t)l*65536, proj_b + l*256, xi, nullptr,
                                         xi, nullptr, lnbuf, ln2_g + l*256, ln2_b + l*256, M, 256);
    mfma_gemm<1><<<dim3(65, 8), 256, 0, stream>>>(lnbuf, fc1Ph + (size_t)l*262144, fc1_b + l*1024, bigbuf, M, 256, 1024);
    if (l < 3){
      // fc2 + residual -> xt; +pt -> xi(next); ln1(l+1) -> lnbuf
      mfma_gemm_ln<<<65, 256, 0, stream>>>(bigbuf, fc2Ph + (size_t)l*262144, fc2_b + l*256, xi, pt,
                                           xt, xi, lnbuf, ln1_g + (l+1)*256, ln1_b + (l+1)*256, M, 1024);
    } else {
      // fc2 + residual -> xt; final norm -> gfeat
      mfma_gemm_ln<<<65, 256, 0, stream>>>(bigbuf, fc2Ph + (size_t)l*262144, fc2_b + l*256, xi, nullptr,
                                           xt, nullptr, gfeat, norm_g, norm_b, M, 1024);
    }
  }
  head_kernel<<<B_ * G_, 256, 0, stream>>>(gfeat, neigh, knn_idx, head_w1, head_b1, head_w2, head_b2, sums, cnts);
  finalize_kernel<<<(B_ * N_) / 256, 256, 0, stream>>>(sums, cnts, (float*)d_out);
}

// Round 5
// 2220.919 us; speedup vs baseline: 1.2624x; 1.0331x over previous
//
#include <hip/hip_runtime.h>
#include <hip/hip_bf16.h>

#define B_ 16
#define N_ 8192
#define G_ 256
#define K_ 64
#define D_ 256
#define HID_ 1024
#define EPS_ 1e-5f

typedef __attribute__((ext_vector_type(8))) short bf16x8;
typedef __attribute__((ext_vector_type(4))) float f32x4;

__device__ __forceinline__ float bf16_to_f32(unsigned short u){
  unsigned int v = ((unsigned int)u) << 16;
  return __uint_as_float(v);
}
__device__ __forceinline__ unsigned short f32_to_bf16(float f){
  unsigned int u = __float_as_uint(f);
  unsigned int r = (u + 0x7FFFu + ((u >> 16) & 1u)) >> 16;
  return (unsigned short)r;
}
// HW RNE converts (v_cvt_pk_bf16_f32)
__device__ __forceinline__ unsigned short bf16h(float a){
  __hip_bfloat16 h = __float2bfloat16(a);
  union { __hip_bfloat16 h; unsigned short u; } cv; cv.h = h; return cv.u;
}
__device__ __forceinline__ unsigned int pk_bf16(float a, float b){
  __hip_bfloat162 h = __float22bfloat162_rn(make_float2(a, b));
  union { __hip_bfloat162 h; unsigned int u; } cv; cv.h = h; return cv.u;
}
__device__ __forceinline__ float gelu_exact(float v){
  return 0.5f * v * (1.0f + erff(v * 0.70710678118654752440f));
}

// ---------------- fold BN into enc_w1/enc_w3 ----------------
__global__ void fold_kernel(const float* __restrict__ w1, const float* __restrict__ b1,
    const float* __restrict__ g1, const float* __restrict__ bb1,
    const float* __restrict__ w3, const float* __restrict__ b3,
    const float* __restrict__ g2, const float* __restrict__ bb2,
    float* __restrict__ w1f, float* __restrict__ b1f,
    float* __restrict__ w3f, float* __restrict__ b3f)
{
  int i = blockIdx.x * 256 + threadIdx.x;
  const float S = 0.99999500003749968f; // 1/sqrt(1+1e-5)
  if (i < 384) w1f[i] = w1[i] * g1[i & 127] * S;
  if (i < 128) b1f[i] = b1[i] * g1[i] * S + bb1[i];
  if (i < 262144) w3f[i] = w3[i] * g2[i & 511] * S;
  if (i < 512) b3f[i] = b3[i] * g2[i] * S + bb2[i];
}

// ---------------- ONE packing kernel for all weights ----------------
// B frag for 16x16x32: lane holds B[k=(lane>>4)*8+j][n=lane&15], j=0..7
// packed[((nt*KS + ks)*64 + lane)*8 + j],  KS = K/32
__device__ __forceinline__ void packHi(const float* __restrict__ W, unsigned short* __restrict__ hi,
                                       int f, int N, int ksBits){
  int j = f & 7, lane = (f >> 3) & 63;
  int ks = (f >> 9) & ((1 << ksBits) - 1);
  int nt = f >> (9 + ksBits);
  int k = ks * 32 + ((lane >> 4) & 3) * 8 + j, c = nt * 16 + (lane & 15);
  hi[f] = f32_to_bf16(W[(size_t)k * N + c]);
}
__global__ void pack_all_kernel(const float* __restrict__ enc_w2, const float* __restrict__ w3f,
    const float* __restrict__ enc_w4, const float* __restrict__ qkv_w, const float* __restrict__ proj_w,
    const float* __restrict__ fc1_w, const float* __restrict__ fc2_w,
    unsigned short* __restrict__ w2ph, unsigned short* __restrict__ w2pl,
    unsigned short* __restrict__ w3ph, unsigned short* __restrict__ w4ph,
    unsigned short* __restrict__ qkvPh, unsigned short* __restrict__ projPh,
    unsigned short* __restrict__ fc1Ph, unsigned short* __restrict__ fc2Ph,
    unsigned short* __restrict__ w3tp)
{
  int blk = blockIdx.x, tid = threadIdx.x;
  if (blk < 128){            // w2: hi+lo (K=128, N=256, ksBits=2)
    int f = blk * 256 + tid;
    int j = f & 7, lane = (f >> 3) & 63, ks = (f >> 9) & 3, nt = f >> 11;
    int k = ks * 32 + ((lane >> 4) & 3) * 8 + j, c = nt * 16 + (lane & 15);
    float v = enc_w2[(size_t)k * 256 + c];
    unsigned short h = f32_to_bf16(v);
    w2ph[f] = h; w2pl[f] = f32_to_bf16(v - bf16_to_f32(h));
  } else if (blk < 640){     // w3 bottom half (rows 256..511 of 512x512), ksBits=3
    int f = (blk - 128) * 256 + tid;
    int j = f & 7, lane = (f >> 3) & 63, ks = (f >> 9) & 7, nt = f >> 12;
    int k = ks * 32 + ((lane >> 4) & 3) * 8 + j, c = nt * 16 + (lane & 15);
    w3ph[f] = f32_to_bf16(w3f[(size_t)(256 + k) * 512 + c]);
  } else if (blk < 1152){    // w4 (K=512, N=256, ksBits=4)
    int f = (blk - 640) * 256 + tid;
    packHi(enc_w4, w4ph, f, 256, 4);
  } else if (blk < 4224){    // qkv x4 (K=256, N=768, ksBits=3)
    int f = (blk - 1152) * 256 + tid;
    int l = f / 196608, fl = f - l * 196608;
    packHi(qkv_w + (size_t)l * 196608, qkvPh + (size_t)l * 196608, fl, 768, 3);
  } else if (blk < 5248){    // proj x4 (K=256, N=256, ksBits=3)
    int f = (blk - 4224) * 256 + tid;
    int l = f >> 16, fl = f & 65535;
    packHi(proj_w + (size_t)l * 65536, projPh + (size_t)l * 65536, fl, 256, 3);
  } else if (blk < 9344){    // fc1 x4 (K=256, N=1024, ksBits=3)
    int f = (blk - 5248) * 256 + tid;
    int l = f >> 18, fl = f & 262143;
    packHi(fc1_w + (size_t)l * 262144, fc1Ph + (size_t)l * 262144, fl, 1024, 3);
  } else if (blk < 13440){   // fc2 x4 (K=1024, N=256, ksBits=5)
    int f = (blk - 9344) * 256 + tid;
    int l = f >> 18, fl = f & 262143;
    packHi(fc2_w + (size_t)l * 262144, fc2Ph + (size_t)l * 262144, fl, 256, 5);
  } else {                   // w3 top half (rows 0..255) frag-packed, ksBits=3
    int f = (blk - 13440) * 256 + tid;   // [0, 131072)
    int j = f & 7, lane = (f >> 3) & 63, ks = (f >> 9) & 7, nt = f >> 12;
    int k = ks * 32 + ((lane >> 4) & 3) * 8 + j, c = nt * 16 + (lane & 15);
    w3tp[f] = f32_to_bf16(w3f[(size_t)k * 512 + c]);
  }
}

// ---------------- FPS: one block per batch (R1-proven structure) ----------------
// NOTE: R4's "read far point from global" variant was a big regression
// (256 serial dependent global loads); owner-write LDS broadcast is faster.
__global__ __launch_bounds__(1024) void fps_kernel(const float* __restrict__ x, float* __restrict__ centers)
{
  int b = blockIdx.x;
  const float* xb = x + (size_t)b * N_ * 3;
  int tid = threadIdx.x;
  float px[8], py[8], pz[8], dist[8];
#pragma unroll
  for (int j = 0; j < 8; j++){
    int p = tid + j * 1024;
    px[j] = xb[p*3+0]; py[j] = xb[p*3+1]; pz[j] = xb[p*3+2];
    dist[j] = 1e10f;
  }
  __shared__ unsigned long long wred[16];
  __shared__ float sCen[3];
  if (tid == 0){ sCen[0] = xb[0]; sCen[1] = xb[1]; sCen[2] = xb[2]; }
  __syncthreads();
  for (int i = 0; i < G_; i++){
    float cx = sCen[0], cy = sCen[1], cz = sCen[2];
    if (tid < 3) centers[((size_t)b * G_ + i) * 3 + tid] = sCen[tid];
    unsigned long long best = 0ull;
#pragma unroll
    for (int j = 0; j < 8; j++){
      float dx = __fadd_rn(px[j], -cx);
      float dy = __fadd_rn(py[j], -cy);
      float dz = __fadd_rn(pz[j], -cz);
      float d  = __fadd_rn(__fadd_rn(__fmul_rn(dx,dx), __fmul_rn(dy,dy)), __fmul_rn(dz,dz));
      float dm = fminf(dist[j], d);
      dist[j] = dm;
      unsigned int pp = (unsigned int)(tid + j * 1024);
      unsigned long long key = (((unsigned long long)__float_as_uint(dm)) << 32) | (unsigned long long)(~pp);
      best = (key > best) ? key : best;
    }
#pragma unroll
    for (int o = 32; o; o >>= 1){
      unsigned long long t = __shfl_down(best, o);
      best = (t > best) ? t : best;
    }
    if ((tid & 63) == 0) wred[tid >> 6] = best;
    __syncthreads();
    unsigned long long m = wred[0];
#pragma unroll
    for (int w = 1; w < 16; w++){ unsigned long long t = wred[w]; m = (t > m) ? t : m; }
    int far = (int)(~(unsigned int)(m & 0xFFFFFFFFull));
    if (i + 1 < G_){
      if (tid == (far & 1023)){
        int jj = far >> 10;
        float fx=0.f, fy=0.f, fz=0.f;
#pragma unroll
        for (int j = 0; j < 8; j++) if (j == jj){ fx = px[j]; fy = py[j]; fz = pz[j]; }
        sCen[0] = fx; sCen[1] = fy; sCen[2] = fz;
      }
      __syncthreads();
    }
  }
}

// ---------------- KNN: one block per (b,g) ----------------
__global__ __launch_bounds__(256) void knn_kernel(const float* __restrict__ x, const float* __restrict__ centers,
                                                  int* __restrict__ knn_idx, float* __restrict__ neigh)
{
  int blk = blockIdx.x, b = blk >> 8;
  const float* xb = x + (size_t)b * N_ * 3;
  const float* cc = centers + (size_t)blk * 3;
  int tid = threadIdx.x;
  float c0 = cc[0], c1 = cc[1], c2v = cc[2];
  float c2s = __fadd_rn(__fadd_rn(__fmul_rn(c0,c0), __fmul_rn(c1,c1)), __fmul_rn(c2v,c2v));
  float d[32];
#pragma unroll
  for (int j = 0; j < 32; j++){
    int p = tid + j * 256;
    float x0 = xb[p*3+0], x1 = xb[p*3+1], x2 = xb[p*3+2];
    float xs = __fadd_rn(__fadd_rn(__fmul_rn(x0,x0), __fmul_rn(x1,x1)), __fmul_rn(x2,x2));
    float dt = __fadd_rn(__fadd_rn(__fmul_rn(c0,x0), __fmul_rn(c1,x1)), __fmul_rn(c2v,x2));
    d[j] = __fadd_rn(__fadd_rn(c2s, xs), -__fmul_rn(2.0f, dt));
  }
  const float FINF = __int_as_float(0x7F800000);
  float lmin = FINF; unsigned int lp = 0xFFFFFFFFu;
#pragma unroll
  for (int j = 0; j < 32; j++){ if (d[j] < lmin){ lmin = d[j]; lp = (unsigned int)(tid + j*256); } }
  __shared__ unsigned long long wred[2][4];
  for (int r = 0; r < K_; r++){
    unsigned int u = __float_as_uint(lmin);
    u = (u & 0x80000000u) ? ~u : (u | 0x80000000u);
    unsigned long long key = (((unsigned long long)u) << 32) | (unsigned long long)lp;
#pragma unroll
    for (int o = 32; o; o >>= 1){
      unsigned long long t = __shfl_down(key, o);
      key = (t < key) ? t : key;
    }
    int cur = r & 1;
    if ((tid & 63) == 0) wred[cur][tid >> 6] = key;
    __syncthreads();
    unsigned long long m = wred[cur][0];
#pragma unroll
    for (int w = 1; w < 4; w++){ unsigned long long t = wred[cur][w]; m = (t < m) ? t : m; }
    unsigned int p = (unsigned int)(m & 0xFFFFFFFFull);
    if (tid == (p & 255u)){
      knn_idx[(size_t)blk * K_ + r] = (int)p;
      float* np_ = neigh + ((size_t)blk * K_ + r) * 3;
      np_[0] = __fadd_rn(xb[p*3+0], -c0);
      np_[1] = __fadd_rn(xb[p*3+1], -c1);
      np_[2] = __fadd_rn(xb[p*3+2], -c2v);
      lmin = FINF; lp = 0xFFFFFFFFu;
#pragma unroll
      for (int j = 0; j < 32; j++){
        if ((unsigned int)(tid + j*256) == p) d[j] = FINF;
        if (d[j] < lmin){ lmin = d[j]; lp = (unsigned int)(tid + j*256); }
      }
    }
  }
}

// ---------------- fused group encoder (MFMA bf16): one block per (b,g) ----------------
// LDS = 17408 + 33792 + 1024 = 52224 B -> 3 blocks/CU by LDS.
// min-waves stays 2: forcing 3 caps VGPR at 84 and spills (R3: 248MB FETCH).
// gmax@w3_top is done via broadcast-A MFMA (gmax is exactly bf16: max of bf16s).
__global__ __launch_bounds__(256, 2) void encoder_kernel(
    const float* __restrict__ neigh,
    const float* __restrict__ w1f, const float* __restrict__ b1f,
    const unsigned short* __restrict__ w2ph, const unsigned short* __restrict__ w2pl,
    const float* __restrict__ b2,
    const float* __restrict__ b3f,
    const unsigned short* __restrict__ w3ph, const unsigned short* __restrict__ w3tp,
    const unsigned short* __restrict__ w4ph,
    const float* __restrict__ b4,
    float* __restrict__ tokens)
{
  __shared__ __align__(16) unsigned short sH1[64 * 136];  // h1 (64x128 bf16), reused as h3 chunk
  __shared__ __align__(16) unsigned short sH2[64 * 264];  // h2 (64x256 bf16)
  __shared__ __align__(16) float sShared[256];            // phase1: neigh[64][4]; phase3+: gmax bf16[256]
  float (*sNeigh)[4] = (float(*)[4])sShared;
  unsigned short* sGmaxBf = (unsigned short*)sShared;

  int tid  = threadIdx.x;
  int wave = tid >> 6, lane = tid & 63, quad = lane >> 4, lrow = lane & 15;
  size_t gid = blockIdx.x;

  if (tid < 192) sNeigh[tid / 3][tid % 3] = neigh[gid * 192 + tid];
  __syncthreads();

  // ---- phase 1: h1 = relu(bn(neigh @ w1)) -> bf16 LDS ----
  for (int e = tid; e < 8192; e += 256){
    int r = e >> 7, c = e & 127;
    float v = fmaf(sNeigh[r][2], w1f[256 + c], fmaf(sNeigh[r][1], w1f[128 + c], fmaf(sNeigh[r][0], w1f[c], b1f[c])));
    sH1[r * 136 + c] = bf16h(fmaxf(v, 0.0f));
  }
  __syncthreads();

  // ---- phase 2: h2 = h1 @ w2 + b2 (MFMA, hi/lo kept: first layer) ----
  {
    f32x4 acc[4][4];
    const f32x4 z = {0.f, 0.f, 0.f, 0.f};
#pragma unroll
    for (int mt = 0; mt < 4; mt++)
#pragma unroll
      for (int nl = 0; nl < 4; nl++) acc[mt][nl] = z;
#pragma unroll
    for (int ks = 0; ks < 4; ks++){
      bf16x8 af[4];
#pragma unroll
      for (int mt = 0; mt < 4; mt++)
        af[mt] = *(const bf16x8*)&sH1[(mt*16 + lrow)*136 + ks*32 + quad*8];
#pragma unroll
      for (int nl = 0; nl < 4; nl++){
        size_t bo = (((size_t)(wave*4 + nl)*4 + ks)*64 + lane)*8;
        bf16x8 bh = *(const bf16x8*)&w2ph[bo];
        bf16x8 bl = *(const bf16x8*)&w2pl[bo];
#pragma unroll
        for (int mt = 0; mt < 4; mt++){
          acc[mt][nl] = __builtin_amdgcn_mfma_f32_16x16x32_bf16(af[mt], bh, acc[mt][nl], 0, 0, 0);
          acc[mt][nl] = __builtin_amdgcn_mfma_f32_16x16x32_bf16(af[mt], bl, acc[mt][nl], 0, 0, 0);
        }
      }
    }
#pragma unroll
    for (int nl = 0; nl < 4; nl++){
      int col = wave*64 + nl*16 + lrow;
      float bias = b2[col];
#pragma unroll
      for (int mt = 0; mt < 4; mt++)
#pragma unroll
        for (int rg = 0; rg < 4; rg++)
          sH2[(mt*16 + quad*4 + rg)*264 + col] = bf16h(acc[mt][nl][rg] + bias);
    }
  }
  __syncthreads();

  // ---- phase 3: gmax = colmax(h2), stored bf16 (exact: max of bf16 values) ----
  {
    float mx = -3.4e38f;
#pragma unroll 8
    for (int r = 0; r < 64; r++) mx = fmaxf(mx, bf16_to_f32(sH2[r*264 + tid]));
    sGmaxBf[tid] = bf16h(mx);
  }
  __syncthreads();

  // ---- phase 4+5: h3 = relu(gmax@w3_top + h2@w3_bot + b3) chunks of 128 cols,
  //                 h4 accumulation (all MFMA) ----
  f32x4 acc4[4][4];
  {
    const f32x4 z = {0.f, 0.f, 0.f, 0.f};
#pragma unroll
    for (int mt = 0; mt < 4; mt++)
#pragma unroll
      for (int nl = 0; nl < 4; nl++) acc4[mt][nl] = z;
  }
  for (int cc = 0; cc < 4; cc++){
    f32x4 acc3[4][2], accg[2];
    {
      const f32x4 z = {0.f, 0.f, 0.f, 0.f};
#pragma unroll
      for (int mt = 0; mt < 4; mt++){ acc3[mt][0] = z; acc3[mt][1] = z; }
      accg[0] = z; accg[1] = z;
    }
    // gmax part: A rows all identical -> C rows identical; 16 MFMAs per wave
#pragma unroll
    for (int ks = 0; ks < 8; ks++){
      bf16x8 gf = *(const bf16x8*)&sGmaxBf[ks*32 + quad*8];
#pragma unroll
      for (int nl = 0; nl < 2; nl++){
        int nt = cc*8 + wave*2 + nl;
        size_t bo = (((size_t)nt*8 + ks)*64 + lane)*8;
        bf16x8 bh = *(const bf16x8*)&w3tp[bo];
        accg[nl] = __builtin_amdgcn_mfma_f32_16x16x32_bf16(gf, bh, accg[nl], 0, 0, 0);
      }
    }
    // h2 part
#pragma unroll
    for (int ks = 0; ks < 8; ks++){
      bf16x8 af[4];
#pragma unroll
      for (int mt = 0; mt < 4; mt++)
        af[mt] = *(const bf16x8*)&sH2[(mt*16 + lrow)*264 + ks*32 + quad*8];
#pragma unroll
      for (int nl = 0; nl < 2; nl++){
        int nt = cc*8 + wave*2 + nl;
        size_t bo = (((size_t)nt*8 + ks)*64 + lane)*8;
        bf16x8 bh = *(const bf16x8*)&w3ph[bo];
#pragma unroll
        for (int mt = 0; mt < 4; mt++)
          acc3[mt][nl] = __builtin_amdgcn_mfma_f32_16x16x32_bf16(af[mt], bh, acc3[mt][nl], 0, 0, 0);
      }
    }
    __syncthreads();
#pragma unroll
    for (int nl = 0; nl < 2; nl++){
      int cl = wave*32 + nl*16 + lrow;
      int c  = cc*128 + cl;
      float bb = b3f[c];
#pragma unroll
      for (int mt = 0; mt < 4; mt++)
#pragma unroll
        for (int rg = 0; rg < 4; rg++)
          sH1[(mt*16 + quad*4 + rg)*136 + cl] = bf16h(fmaxf(acc3[mt][nl][rg] + accg[nl][rg] + bb, 0.0f));
    }
    __syncthreads();
#pragma unroll
    for (int ks = 0; ks < 4; ks++){
      bf16x8 af[4];
#pragma unroll
      for (int mt = 0; mt < 4; mt++)
        af[mt] = *(const bf16x8*)&sH1[(mt*16 + lrow)*136 + ks*32 + quad*8];
#pragma unroll
      for (int nl = 0; nl < 4; nl++){
        int nt = wave*4 + nl;
        size_t bo = (((size_t)nt*16 + cc*4 + ks)*64 + lane)*8;
        bf16x8 bh = *(const bf16x8*)&w4ph[bo];
#pragma unroll
        for (int mt = 0; mt < 4; mt++)
          acc4[mt][nl] = __builtin_amdgcn_mfma_f32_16x16x32_bf16(af[mt], bh, acc4[mt][nl], 0, 0, 0);
      }
    }
  }

  // ---- phase 6: tokens = colmax(h4) + b4 ----
#pragma unroll
  for (int nl = 0; nl < 4; nl++){
    float mx = -3.4e38f;
#pragma unroll
    for (int mt = 0; mt < 4; mt++)
#pragma unroll
      for (int rg = 0; rg < 4; rg++) mx = fmaxf(mx, acc4[mt][nl][rg]);
    mx = fmaxf(mx, __shfl_xor(mx, 16));
    mx = fmaxf(mx, __shfl_xor(mx, 32));
    if (quad == 0){
      int col = wave*64 + nl*16 + lrow;
      tokens[gid * 256 + col] = mx + b4[col];
    }
  }
}

// ---------------- pos embed + assemble + first LN (fused) ----------------
__global__ __launch_bounds__(128) void pos_ln_kernel(
    const float* __restrict__ centers, const float* __restrict__ tokens,
    const float* __restrict__ cls_token, const float* __restrict__ cls_pos,
    const float* __restrict__ pw1, const float* __restrict__ pb1,
    const float* __restrict__ pw2, const float* __restrict__ pb2,
    const float* __restrict__ lng, const float* __restrict__ lnb,
    float* __restrict__ pt, float* __restrict__ xi, float* __restrict__ lnbuf)
{
  __shared__ float hS[128];
  __shared__ float red[2][2];
  int row = blockIdx.x;
  int b = row / 257, n = row - b * 257;
  int tid = threadIdx.x;
  size_t ro = (size_t)row * 256;
  float u0, u1;
  if (n == 0){
    float p0 = cls_pos[tid], p1 = cls_pos[128 + tid];
    u0 = cls_token[tid] + p0; u1 = cls_token[128 + tid] + p1;
    pt[ro + tid] = p0; pt[ro + 128 + tid] = p1;
  } else {
    int g = n - 1;
    const float* c = centers + ((size_t)b * 256 + g) * 3;
    float h = fmaf(c[2], pw1[256 + tid], fmaf(c[1], pw1[128 + tid], fmaf(c[0], pw1[tid], pb1[tid])));
    hS[tid] = gelu_exact(h);
    __syncthreads();
    const float* tok = tokens + ((size_t)b * 256 + g) * 256;
    float s0 = pb2[tid], s1 = pb2[128 + tid];
#pragma unroll 4
    for (int k = 0; k < 128; k++){
      s0 = fmaf(hS[k], pw2[(size_t)k * 256 + tid], s0);
      s1 = fmaf(hS[k], pw2[(size_t)k * 256 + 128 + tid], s1);
    }
    pt[ro + tid] = s0; pt[ro + 128 + tid] = s1;
    u0 = tok[tid] + s0; u1 = tok[128 + tid] + s1;
  }
  float s = u0 + u1, q = u0*u0 + u1*u1;
#pragma unroll
  for (int o = 32; o; o >>= 1){ s += __shfl_down(s, o); q += __shfl_down(q, o); }
  int wv = tid >> 6;
  if ((tid & 63) == 0){ red[0][wv] = s; red[1][wv] = q; }
  __syncthreads();
  float m  = (red[0][0] + red[0][1]) * (1.0f / 256.0f);
  float var = (red[1][0] + red[1][1]) * (1.0f / 256.0f) - m * m;
  float rs = 1.0f / sqrtf(var + EPS_);
  xi[ro + tid] = u0; xi[ro + 128 + tid] = u1;
  lnbuf[ro + tid] = (u0 - m) * rs * lng[tid] + lnb[tid];
  lnbuf[ro + 128 + tid] = (u1 - m) * rs * lng[128 + tid] + lnb[128 + tid];
}

// ---------------- MFMA GEMM: C = act(A@B + bias) ----------------
template<int ACT>
__global__ __launch_bounds__(256) void mfma_gemm(
    const float* __restrict__ A, const unsigned short* __restrict__ Bh,
    const float* __restrict__ bias, float* __restrict__ C, int M, int K, int N)
{
  __shared__ __align__(16) unsigned short sA[64 * 72];
  int tid = threadIdx.x;
  int wave = tid >> 6, lane = tid & 63, quad = lane >> 4, lrow = lane & 15;
  int row0 = blockIdx.x * 64;
  int col0 = blockIdx.y * 128;
  int ksTotal = K >> 5;
  f32x4 acc[4][2];
  const f32x4 z = {0.f, 0.f, 0.f, 0.f};
#pragma unroll
  for (int mt = 0; mt < 4; mt++){ acc[mt][0] = z; acc[mt][1] = z; }

  for (int k0 = 0; k0 < K; k0 += 64){
#pragma unroll
    for (int i = 0; i < 4; i++){
      int e = tid + i * 256;
      int r = e >> 4, c4 = (e & 15) * 4;
      int gr = row0 + r;
      float4 v = make_float4(0.f,0.f,0.f,0.f);
      if (gr < M) v = *(const float4*)(A + (size_t)gr * K + k0 + c4);
      unsigned int* dst = (unsigned int*)&sA[r * 72 + c4];
      dst[0] = pk_bf16(v.x, v.y); dst[1] = pk_bf16(v.z, v.w);
    }
    __syncthreads();
    int ksBase = k0 >> 5;
#pragma unroll
    for (int ks = 0; ks < 2; ks++){
      bf16x8 af[4];
#pragma unroll
      for (int mt = 0; mt < 4; mt++)
        af[mt] = *(const bf16x8*)&sA[(mt*16 + lrow)*72 + ks*32 + quad*8];
#pragma unroll
      for (int nl = 0; nl < 2; nl++){
        int nt = (col0 >> 4) + wave*2 + nl;
        size_t bo = (((size_t)nt * ksTotal + ksBase + ks)*64 + lane)*8;
        bf16x8 bh = *(const bf16x8*)&Bh[bo];
#pragma unroll
        for (int mt = 0; mt < 4; mt++)
          acc[mt][nl] = __builtin_amdgcn_mfma_f32_16x16x32_bf16(af[mt], bh, acc[mt][nl], 0, 0, 0);
      }
    }
    __syncthreads();
  }
#pragma unroll
  for (int nl = 0; nl < 2; nl++){
    int c = col0 + wave*32 + nl*16 + lrow;
    float bc = bias ? bias[c] : 0.0f;
#pragma unroll
    for (int mt = 0; mt < 4; mt++)
#pragma unroll
      for (int rg = 0; rg < 4; rg++){
        int r = row0 + mt*16 + quad*4 + rg;
        if (r < M){
          float v = acc[mt][nl][rg] + bc;
          if (ACT == 1) v = gelu_exact(v);
          C[(size_t)r * N + c] = v;
        }
      }
  }
}

// ---------------- MFMA GEMM + residual + LayerNorm epilogue (N=256 fixed) ----------------
__global__ __launch_bounds__(256) void mfma_gemm_ln(
    const float* __restrict__ A, const unsigned short* __restrict__ Bh,
    const float* __restrict__ bias, const float* __restrict__ res,
    const float* __restrict__ ptb,   // nullable: add before LN
    float* __restrict__ C, float* __restrict__ xiOut, float* __restrict__ lnOut,
    const float* __restrict__ lng, const float* __restrict__ lnb, int M, int K)
{
  __shared__ __align__(16) unsigned short sA[64 * 72];
  __shared__ float sRed[2][64][4];
  int tid = threadIdx.x;
  int wave = tid >> 6, lane = tid & 63, quad = lane >> 4, lrow = lane & 15;
  int row0 = blockIdx.x * 64;
  int ksTotal = K >> 5;
  f32x4 acc[4][4];
  const f32x4 z = {0.f, 0.f, 0.f, 0.f};
#pragma unroll
  for (int mt = 0; mt < 4; mt++)
#pragma unroll
    for (int nl = 0; nl < 4; nl++) acc[mt][nl] = z;

  for (int k0 = 0; k0 < K; k0 += 64){
#pragma unroll
    for (int i = 0; i < 4; i++){
      int e = tid + i * 256;
      int r = e >> 4, c4 = (e & 15) * 4;
      int gr = row0 + r;
      float4 v = make_float4(0.f,0.f,0.f,0.f);
      if (gr < M) v = *(const float4*)(A + (size_t)gr * K + k0 + c4);
      unsigned int* dst = (unsigned int*)&sA[r * 72 + c4];
      dst[0] = pk_bf16(v.x, v.y); dst[1] = pk_bf16(v.z, v.w);
    }
    __syncthreads();
    int ksBase = k0 >> 5;
#pragma unroll
    for (int ks = 0; ks < 2; ks++){
      bf16x8 af[4];
#pragma unroll
      for (int mt = 0; mt < 4; mt++)
        af[mt] = *(const bf16x8*)&sA[(mt*16 + lrow)*72 + ks*32 + quad*8];
#pragma unroll
      for (int nl = 0; nl < 4; nl++){
        int nt = wave*4 + nl;
        size_t bo = (((size_t)nt * ksTotal + ksBase + ks)*64 + lane)*8;
        bf16x8 bh = *(const bf16x8*)&Bh[bo];
#pragma unroll
        for (int mt = 0; mt < 4; mt++)
          acc[mt][nl] = __builtin_amdgcn_mfma_f32_16x16x32_bf16(af[mt], bh, acc[mt][nl], 0, 0, 0);
      }
    }
    __syncthreads();
  }
  // epilogue: v = acc + bias + res; C = v; acc := u = v (+pt)
#pragma unroll
  for (int nl = 0; nl < 4; nl++){
    int c = wave*64 + nl*16 + lrow;
    float bc = bias[c];
#pragma unroll
    for (int mt = 0; mt < 4; mt++)
#pragma unroll
      for (int rg = 0; rg < 4; rg++){
        int r = row0 + mt*16 + quad*4 + rg;
        if (r < M){
          float v = acc[mt][nl][rg] + bc + res[(size_t)r * 256 + c];
          C[(size_t)r * 256 + c] = v;
          float u = v;
          if (ptb) u += ptb[(size_t)r * 256 + c];
          acc[mt][nl][rg] = u;
        }
      }
  }
#pragma unroll
  for (int mt = 0; mt < 4; mt++)
#pragma unroll
    for (int rg = 0; rg < 4; rg++){
      int rloc = mt*16 + quad*4 + rg;
      float s = 0.0f, q = 0.0f;
#pragma unroll
      for (int nl = 0; nl < 4; nl++){ float u = acc[mt][nl][rg]; s += u; q += u*u; }
#pragma unroll
      for (int off = 1; off < 16; off <<= 1){ s += __shfl_xor(s, off); q += __shfl_xor(q, off); }
      if (lrow == 0){ sRed[0][rloc][wave] = s; sRed[1][rloc][wave] = q; }
    }
  __syncthreads();
#pragma unroll
  for (int mt = 0; mt < 4; mt++)
#pragma unroll
    for (int rg = 0; rg < 4; rg++){
      int rloc = mt*16 + quad*4 + rg;
      int r = row0 + rloc;
      if (r >= M) continue;
      float s = ((sRed[0][rloc][0] + sRed[0][rloc][1]) + sRed[0][rloc][2]) + sRed[0][rloc][3];
      float q = ((sRed[1][rloc][0] + sRed[1][rloc][1]) + sRed[1][rloc][2]) + sRed[1][rloc][3];
      float m  = s * (1.0f / 256.0f);
      float var = q * (1.0f / 256.0f) - m * m;
      float rs = 1.0f / sqrtf(var + EPS_);
#pragma unroll
      for (int nl = 0; nl < 4; nl++){
        int c = wave*64 + nl*16 + lrow;
        float u = acc[mt][nl][rg];
        lnOut[(size_t)r * 256 + c] = (u - m) * rs * lng[c] + lnb[c];
        if (xiOut) xiOut[(size_t)r * 256 + c] = u;
      }
    }
}

// ---------------- attention: block per (b,h,qchunk), flash-style ----------------
__global__ __launch_bounds__(64) void attn_kernel(const float* __restrict__ qkv, float* __restrict__ obuf)
{
  int bh = blockIdx.x;
  int b = bh >> 3, h = bh & 7;
  int qrow = blockIdx.y * 64 + threadIdx.x;
  bool act = qrow < 257;
  __shared__ float kS[128][33];
  __shared__ float vS[128][33];
  const float* qb = qkv + (size_t)b * 257 * 768;
  int tid = threadIdx.x;
  float q[32], o[32];
  float mrun = -3.4e38f, l = 0.0f;
  if (act){
    const float* qr = qb + (size_t)qrow * 768 + h * 32;
#pragma unroll
    for (int j = 0; j < 32; j++){ q[j] = qr[j]; o[j] = 0.0f; }
  }
  const float scale = 0.17677669529663687f;
  for (int m0 = 0; m0 < 257; m0 += 128){
    int cnt = min(128, 257 - m0);
    for (int e = tid; e < cnt * 32; e += 64){
      int mm = e >> 5, j = e & 31;
      const float* rowp = qb + (size_t)(m0 + mm) * 768 + h * 32;
      kS[mm][j] = rowp[256 + j];
      vS[mm][j] = rowp[512 + j];
    }
    __syncthreads();
    if (act){
      for (int mm = 0; mm < cnt; mm++){
        float s = 0.0f;
#pragma unroll
        for (int j = 0; j < 32; j++) s = fmaf(q[j], kS[mm][j], s);
        s *= scale;
        float nm = fmaxf(mrun, s);
        float alpha = expf(mrun - nm);
        float p = expf(s - nm);
        l = fmaf(l, alpha, p);
#pragma unroll
        for (int j = 0; j < 32; j++) o[j] = fmaf(p, vS[mm][j], o[j] * alpha);
        mrun = nm;
      }
    }
    __syncthreads();
  }
  if (act){
    float inv = 1.0f / l;
    float* orow = obuf + (size_t)(b * 257 + qrow) * 256 + h * 32;
#pragma unroll
    for (int j = 0; j < 32; j++) orow[j] = o[j] * inv;
  }
}

// ---------------- head MLP + scatter: one block per (b,g) ----------------
__global__ __launch_bounds__(256) void head_kernel(
    const float* __restrict__ gfeat, const float* __restrict__ neigh, const int* __restrict__ knn_idx,
    const float* __restrict__ w1, const float* __restrict__ b1,
    const float* __restrict__ w2, const float* __restrict__ b2,
    float* __restrict__ sums, float* __restrict__ cnts)
{
  int blk = blockIdx.x, b = blk >> 8;
  __shared__ float xS[256];
  __shared__ float nS[64][4];
  __shared__ float partH[2][128];
  __shared__ float sharedH[128];
  __shared__ float w2S[128];
  __shared__ float wtail[3][128];
  int tid = threadIdx.x;
  xS[tid] = gfeat[((size_t)b * 257 + 1 + (blk & 255)) * 256 + tid];
  if (tid < 192) nS[tid / 3][tid % 3] = neigh[(size_t)blk * 192 + tid];
  if (tid < 128){
    w2S[tid] = w2[tid];
    wtail[0][tid] = w1[256 * 128 + tid];
    wtail[1][tid] = w1[257 * 128 + tid];
    wtail[2][tid] = w1[258 * 128 + tid];
  }
  __syncthreads();
  {
    int half = tid >> 7, j = tid & 127;
    float s = 0.0f;
#pragma unroll 8
    for (int k = 0; k < 128; k++) s = fmaf(xS[half * 128 + k], w1[(size_t)(half * 128 + k) * 128 + j], s);
    partH[half][j] = s;
  }
  __syncthreads();
  if (tid < 128) sharedH[tid] = partH[0][tid] + partH[1][tid] + b1[tid];
  __syncthreads();
  int r = tid >> 2, q = tid & 3;
  float n0 = nS[r][0], n1 = nS[r][1], n2 = nS[r][2];
  float s = 0.0f;
#pragma unroll
  for (int j0 = 0; j0 < 32; j0++){
    int j = q * 32 + j0;
    float h = fmaf(n2, wtail[2][j], fmaf(n1, wtail[1][j], fmaf(n0, wtail[0][j], sharedH[j])));
    s = fmaf(fmaxf(h, 0.0f), w2S[j], s);
  }
  s += __shfl_xor(s, 1);
  s += __shfl_xor(s, 2);
  if (q == 0){
    float lg = s + b2[0];
    int p = knn_idx[(size_t)blk * K_ + r];
    atomicAdd(&sums[(size_t)b * N_ + p], lg);
    atomicAdd(&cnts[(size_t)b * N_ + p], 1.0f);
  }
}

__global__ void finalize_kernel(const float* __restrict__ sums, const float* __restrict__ cnts, float* __restrict__ out)
{
  int i = blockIdx.x * 256 + threadIdx.x;
  out[i] = sums[i] / fmaxf(cnts[i], 1.0f);
}

extern "C" void kernel_launch(void* const* d_in, const int* in_sizes, int n_in,
                              void* d_out, int out_size, void* d_ws, size_t ws_size,
                              hipStream_t stream)
{
  (void)in_sizes; (void)n_in; (void)out_size; (void)ws_size;
  const float* x        = (const float*)d_in[0];
  const float* enc_w1   = (const float*)d_in[1];
  const float* enc_b1   = (const float*)d_in[2];
  const float* enc_bn1g = (const float*)d_in[3];
  const float* enc_bn1b = (const float*)d_in[4];
  const float* enc_w2   = (const float*)d_in[5];
  const float* enc_b2   = (const float*)d_in[6];
  const float* enc_w3   = (const float*)d_in[7];
  const float* enc_b3   = (const float*)d_in[8];
  const float* enc_bn2g = (const float*)d_in[9];
  const float* enc_bn2b = (const float*)d_in[10];
  const float* enc_w4   = (const float*)d_in[11];
  const float* enc_b4   = (const float*)d_in[12];
  const float* cls_tok  = (const float*)d_in[13];
  const float* cls_pos  = (const float*)d_in[14];
  const float* pos_w1   = (const float*)d_in[15];
  const float* pos_b1   = (const float*)d_in[16];
  const float* pos_w2   = (const float*)d_in[17];
  const float* pos_b2   = (const float*)d_in[18];
  const float* ln1_g    = (const float*)d_in[19];
  const float* ln1_b    = (const float*)d_in[20];
  const float* qkv_w    = (const float*)d_in[21];
  const float* proj_w   = (const float*)d_in[22];
  const float* proj_b   = (const float*)d_in[23];
  const float* ln2_g    = (const float*)d_in[24];
  const float* ln2_b    = (const float*)d_in[25];
  const float* fc1_w    = (const float*)d_in[26];
  const float* fc1_b    = (const float*)d_in[27];
  const float* fc2_w    = (const float*)d_in[28];
  const float* fc2_b    = (const float*)d_in[29];
  const float* norm_g   = (const float*)d_in[30];
  const float* norm_b   = (const float*)d_in[31];
  const float* head_w1  = (const float*)d_in[32];
  const float* head_b1  = (const float*)d_in[33];
  const float* head_w2  = (const float*)d_in[34];
  const float* head_b2  = (const float*)d_in[35];

  float* ws = (float*)d_ws;
  size_t off = 0;
  auto alloc = [&](size_t n)->float*{ float* p = ws + off; off += (n + 63) & ~(size_t)63; return p; };

  float* centers = alloc((size_t)B_ * G_ * 3);
  float* w1f     = alloc(384);
  float* b1f     = alloc(128);
  float* w3f     = alloc(512 * 512);
  float* b3f     = alloc(512);
  unsigned short* w2ph = (unsigned short*)alloc(16384);
  unsigned short* w2pl = (unsigned short*)alloc(16384);
  unsigned short* w3ph = (unsigned short*)alloc(65536);
  unsigned short* w3tp = (unsigned short*)alloc(65536);
  unsigned short* w4ph = (unsigned short*)alloc(65536);
  unsigned short* qkvPh = (unsigned short*)alloc(393216);
  unsigned short* projPh = (unsigned short*)alloc(131072);
  unsigned short* fc1Ph = (unsigned short*)alloc(524288);
  unsigned short* fc2Ph = (unsigned short*)alloc(524288);
  float* tokens  = alloc((size_t)B_ * G_ * D_);
  float* neigh   = alloc((size_t)B_ * G_ * K_ * 3);
  int*   knn_idx = (int*)alloc((size_t)B_ * G_ * K_);
  float* pt      = alloc((size_t)B_ * 257 * D_);
  float* xt      = alloc((size_t)B_ * 257 * D_);
  float* xi      = alloc((size_t)B_ * 257 * D_);
  float* lnbuf   = alloc((size_t)B_ * 257 * D_);
  float* obuf    = alloc((size_t)B_ * 257 * D_);
  float* bigbuf  = alloc((size_t)B_ * 257 * HID_);
  float* gfeat   = alloc((size_t)B_ * 257 * D_);
  float* sums    = alloc((size_t)B_ * N_);
  float* cnts    = alloc((size_t)B_ * N_);

  hipMemsetAsync(sums, 0, (size_t)2 * B_ * N_ * sizeof(float), stream);

  fold_kernel<<<1024, 256, 0, stream>>>(enc_w1, enc_b1, enc_bn1g, enc_bn1b,
                                        enc_w3, enc_b3, enc_bn2g, enc_bn2b,
                                        w1f, b1f, w3f, b3f);
  pack_all_kernel<<<13952, 256, 0, stream>>>(enc_w2, w3f, enc_w4, qkv_w, proj_w, fc1_w, fc2_w,
                                             w2ph, w2pl, w3ph, w4ph, qkvPh, projPh, fc1Ph, fc2Ph, w3tp);

  fps_kernel<<<B_, 1024, 0, stream>>>(x, centers);
  knn_kernel<<<B_ * G_, 256, 0, stream>>>(x, centers, knn_idx, neigh);
  encoder_kernel<<<B_ * G_, 256, 0, stream>>>(neigh, w1f, b1f, w2ph, w2pl, enc_b2,
                                              b3f, w3ph, w3tp, w4ph, enc_b4, tokens);
  pos_ln_kernel<<<B_ * 257, 128, 0, stream>>>(centers, tokens, cls_tok, cls_pos,
                                              pos_w1, pos_b1, pos_w2, pos_b2,
                                              ln1_g, ln1_b, pt, xi, lnbuf);
  const int M = B_ * 257; // 4112
  for (int l = 0; l < 4; l++){
    mfma_gemm<0><<<dim3(65, 6), 256, 0, stream>>>(lnbuf, qkvPh + (size_t)l*196608, nullptr, bigbuf, M, 256, 768);
    attn_kernel<<<dim3(B_ * 8, 5), 64, 0, stream>>>(bigbuf, obuf);
    mfma_gemm_ln<<<65, 256, 0, stream>>>(obuf, projPh + (size_t)l*65536, proj_b + l*256, xi, nullptr,
                                         xi, nullptr, lnbuf, ln2_g + l*256, ln2_b + l*256, M, 256);
    mfma_gemm<1><<<dim3(65, 8), 256, 0, stream>>>(lnbuf, fc1Ph + (size_t)l*262144, fc1_b + l*1024, bigbuf, M, 256, 1024);
    if (l < 3){
      mfma_gemm_ln<<<65, 256, 0, stream>>>(bigbuf, fc2Ph + (size_t)l*262144, fc2_b + l*256, xi, pt,
                                           xt, xi, lnbuf, ln1_g + (l+1)*256, ln1_b + (l+1)*256, M, 1024);
    } else {
      mfma_gemm_ln<<<65, 256, 0, stream>>>(bigbuf, fc2Ph + (size_t)l*262144, fc2_b + l*256, xi, nullptr,
                                           xt, nullptr, gfeat, norm_g, norm_b, M, 1024);
    }
  }
  head_kernel<<<B_ * G_, 256, 0, stream>>>(gfeat, neigh, knn_idx, head_w1, head_b1, head_w2, head_b2, sums, cnts);
  finalize_kernel<<<(B_ * N_) / 256, 256, 0, stream>>>(sums, cnts, (float*)d_out);
}

// Round 6
// 2035.948 us; speedup vs baseline: 1.3771x; 1.0909x over previous
//
#include <hip/hip_runtime.h>
#include <hip/hip_bf16.h>

#define B_ 16
#define N_ 8192
#define G_ 256
#define K_ 64
#define D_ 256
#define HID_ 1024
#define EPS_ 1e-5f

typedef __attribute__((ext_vector_type(8))) short bf16x8;
typedef __attribute__((ext_vector_type(4))) float f32x4;

__device__ __forceinline__ float bf16_to_f32(unsigned short u){
  unsigned int v = ((unsigned int)u) << 16;
  return __uint_as_float(v);
}
__device__ __forceinline__ unsigned short f32_to_bf16(float f){
  unsigned int u = __float_as_uint(f);
  unsigned int r = (u + 0x7FFFu + ((u >> 16) & 1u)) >> 16;
  return (unsigned short)r;
}
// HW RNE converts (v_cvt_pk_bf16_f32)
__device__ __forceinline__ unsigned short bf16h(float a){
  __hip_bfloat16 h = __float2bfloat16(a);
  union { __hip_bfloat16 h; unsigned short u; } cv; cv.h = h; return cv.u;
}
__device__ __forceinline__ unsigned int pk_bf16(float a, float b){
  __hip_bfloat162 h = __float22bfloat162_rn(make_float2(a, b));
  union { __hip_bfloat162 h; unsigned int u; } cv; cv.h = h; return cv.u;
}
__device__ __forceinline__ float gelu_exact(float v){
  return 0.5f * v * (1.0f + erff(v * 0.70710678118654752440f));
}

// ---------------- fold BN into enc_w1/enc_w3 ----------------
__global__ void fold_kernel(const float* __restrict__ w1, const float* __restrict__ b1,
    const float* __restrict__ g1, const float* __restrict__ bb1,
    const float* __restrict__ w3, const float* __restrict__ b3,
    const float* __restrict__ g2, const float* __restrict__ bb2,
    float* __restrict__ w1f, float* __restrict__ b1f,
    float* __restrict__ w3f, float* __restrict__ b3f)
{
  int i = blockIdx.x * 256 + threadIdx.x;
  const float S = 0.99999500003749968f; // 1/sqrt(1+1e-5)
  if (i < 384) w1f[i] = w1[i] * g1[i & 127] * S;
  if (i < 128) b1f[i] = b1[i] * g1[i] * S + bb1[i];
  if (i < 262144) w3f[i] = w3[i] * g2[i & 511] * S;
  if (i < 512) b3f[i] = b3[i] * g2[i] * S + bb2[i];
}

// ---------------- ONE packing kernel for all weights ----------------
// B frag for 16x16x32: lane holds B[k=(lane>>4)*8+j][n=lane&15], j=0..7
// packed[((nt*KS + ks)*64 + lane)*8 + j],  KS = K/32
__device__ __forceinline__ void packHi(const float* __restrict__ W, unsigned short* __restrict__ hi,
                                       int f, int N, int ksBits){
  int j = f & 7, lane = (f >> 3) & 63;
  int ks = (f >> 9) & ((1 << ksBits) - 1);
  int nt = f >> (9 + ksBits);
  int k = ks * 32 + ((lane >> 4) & 3) * 8 + j, c = nt * 16 + (lane & 15);
  hi[f] = f32_to_bf16(W[(size_t)k * N + c]);
}
__global__ void pack_all_kernel(const float* __restrict__ enc_w2, const float* __restrict__ w3f,
    const float* __restrict__ enc_w4, const float* __restrict__ qkv_w, const float* __restrict__ proj_w,
    const float* __restrict__ fc1_w, const float* __restrict__ fc2_w,
    unsigned short* __restrict__ w2ph, unsigned short* __restrict__ w2pl,
    unsigned short* __restrict__ w3ph, unsigned short* __restrict__ w4ph,
    unsigned short* __restrict__ qkvPh, unsigned short* __restrict__ projPh,
    unsigned short* __restrict__ fc1Ph, unsigned short* __restrict__ fc2Ph,
    unsigned short* __restrict__ w3tp)
{
  int blk = blockIdx.x, tid = threadIdx.x;
  if (blk < 128){            // w2: hi+lo (K=128, N=256, ksBits=2)
    int f = blk * 256 + tid;
    int j = f & 7, lane = (f >> 3) & 63, ks = (f >> 9) & 3, nt = f >> 11;
    int k = ks * 32 + ((lane >> 4) & 3) * 8 + j, c = nt * 16 + (lane & 15);
    float v = enc_w2[(size_t)k * 256 + c];
    unsigned short h = f32_to_bf16(v);
    w2ph[f] = h; w2pl[f] = f32_to_bf16(v - bf16_to_f32(h));
  } else if (blk < 640){     // w3 bottom half (rows 256..511 of 512x512), ksBits=3
    int f = (blk - 128) * 256 + tid;
    int j = f & 7, lane = (f >> 3) & 63, ks = (f >> 9) & 7, nt = f >> 12;
    int k = ks * 32 + ((lane >> 4) & 3) * 8 + j, c = nt * 16 + (lane & 15);
    w3ph[f] = f32_to_bf16(w3f[(size_t)(256 + k) * 512 + c]);
  } else if (blk < 1152){    // w4 (K=512, N=256, ksBits=4)
    int f = (blk - 640) * 256 + tid;
    packHi(enc_w4, w4ph, f, 256, 4);
  } else if (blk < 4224){    // qkv x4 (K=256, N=768, ksBits=3)
    int f = (blk - 1152) * 256 + tid;
    int l = f / 196608, fl = f - l * 196608;
    packHi(qkv_w + (size_t)l * 196608, qkvPh + (size_t)l * 196608, fl, 768, 3);
  } else if (blk < 5248){    // proj x4 (K=256, N=256, ksBits=3)
    int f = (blk - 4224) * 256 + tid;
    int l = f >> 16, fl = f & 65535;
    packHi(proj_w + (size_t)l * 65536, projPh + (size_t)l * 65536, fl, 256, 3);
  } else if (blk < 9344){    // fc1 x4 (K=256, N=1024, ksBits=3)
    int f = (blk - 5248) * 256 + tid;
    int l = f >> 18, fl = f & 262143;
    packHi(fc1_w + (size_t)l * 262144, fc1Ph + (size_t)l * 262144, fl, 1024, 3);
  } else if (blk < 13440){   // fc2 x4 (K=1024, N=256, ksBits=5)
    int f = (blk - 9344) * 256 + tid;
    int l = f >> 18, fl = f & 262143;
    packHi(fc2_w + (size_t)l * 262144, fc2Ph + (size_t)l * 262144, fl, 256, 5);
  } else {                   // w3 top half (rows 0..255) frag-packed, ksBits=3
    int f = (blk - 13440) * 256 + tid;   // [0, 131072)
    int j = f & 7, lane = (f >> 3) & 63, ks = (f >> 9) & 7, nt = f >> 12;
    int k = ks * 32 + ((lane >> 4) & 3) * 8 + j, c = nt * 16 + (lane & 15);
    w3tp[f] = f32_to_bf16(w3f[(size_t)k * 512 + c]);
  }
}

// ---------------- FPS: one block per batch, ONE barrier per iteration ----------------
// 512 thr (8 waves). Wave-internal 64-lane xor-butterfly (all lanes know winner),
// winner lane writes (key,x,y,z) to its wave slot; single barrier; 8-slot reduce via
// lane-parallel b64 read + 3-step butterfly + broadcast; coords picked from winning slot.
// Double-buffered slots (parity) make one barrier sufficient (WAR-safe).
__global__ __launch_bounds__(512) void fps_kernel(const float* __restrict__ x, float* __restrict__ centers)
{
  int b = blockIdx.x;
  const float* xb = x + (size_t)b * N_ * 3;
  int tid = threadIdx.x, lane = tid & 63, wave = tid >> 6;
  float px[16], py[16], pz[16], dist[16];
#pragma unroll
  for (int j = 0; j < 16; j++){
    int p = tid + j * 512;
    px[j] = xb[p*3+0]; py[j] = xb[p*3+1]; pz[j] = xb[p*3+2];
    dist[j] = 1e10f;
  }
  __shared__ unsigned long long slotK[2][8];
  __shared__ float slotC[2][8][4];
  float cx = xb[0], cy = xb[1], cz = xb[2];
  for (int i = 0; i < G_; i++){
    if (tid == 0){
      float* cp = centers + ((size_t)b * G_ + i) * 3;
      cp[0] = cx; cp[1] = cy; cp[2] = cz;
    }
    float bestv = -1.0f; int bestj = 0;
#pragma unroll
    for (int j = 0; j < 16; j++){
      float dx = __fadd_rn(px[j], -cx);
      float dy = __fadd_rn(py[j], -cy);
      float dz = __fadd_rn(pz[j], -cz);
      float d  = __fadd_rn(__fadd_rn(__fmul_rn(dx,dx), __fmul_rn(dy,dy)), __fmul_rn(dz,dz));
      float dm = fminf(dist[j], d);
      dist[j] = dm;
      if (dm > bestv){ bestv = dm; bestj = j; }  // first max kept (lowest pid in thread)
    }
    unsigned int pid = (unsigned int)(tid + bestj * 512);
    unsigned long long key = (((unsigned long long)__float_as_uint(bestv)) << 32) | (unsigned long long)(~pid);
#pragma unroll
    for (int o = 1; o < 64; o <<= 1){
      unsigned long long t = __shfl_xor(key, o);
      key = (t > key) ? t : key;
    }
    int par = i & 1;
    unsigned int wpid = ~(unsigned int)key;       // wave winner's global pid
    if (lane == (int)(wpid & 63)){                // contributing lane is in this wave
      int jj = (int)(wpid >> 9);
      float fx = px[0], fy = py[0], fz = pz[0];
#pragma unroll
      for (int j = 1; j < 16; j++) if (jj == j){ fx = px[j]; fy = py[j]; fz = pz[j]; }
      slotK[par][wave] = key;
      slotC[par][wave][0] = fx; slotC[par][wave][1] = fy; slotC[par][wave][2] = fz;
    }
    __syncthreads();
    if (i + 1 < G_){
      unsigned long long k2 = (lane < 8) ? slotK[par][lane] : 0ull;
#pragma unroll
      for (int o = 1; o < 8; o <<= 1){
        unsigned long long t = __shfl_xor(k2, o);
        k2 = (t > k2) ? t : k2;
      }
      k2 = __shfl(k2, 0);
      unsigned int gpid = ~(unsigned int)k2;
      int s = (int)((gpid & 511u) >> 6);
      cx = slotC[par][s][0]; cy = slotC[par][s][1]; cz = slotC[par][s][2];
    }
  }
}

// ---------------- KNN: one block per (b,g) ----------------
__global__ __launch_bounds__(256) void knn_kernel(const float* __restrict__ x, const float* __restrict__ centers,
                                                  int* __restrict__ knn_idx, float* __restrict__ neigh)
{
  int blk = blockIdx.x, b = blk >> 8;
  const float* xb = x + (size_t)b * N_ * 3;
  const float* cc = centers + (size_t)blk * 3;
  int tid = threadIdx.x;
  float c0 = cc[0], c1 = cc[1], c2v = cc[2];
  float c2s = __fadd_rn(__fadd_rn(__fmul_rn(c0,c0), __fmul_rn(c1,c1)), __fmul_rn(c2v,c2v));
  float d[32];
#pragma unroll
  for (int j = 0; j < 32; j++){
    int p = tid + j * 256;
    float x0 = xb[p*3+0], x1 = xb[p*3+1], x2 = xb[p*3+2];
    float xs = __fadd_rn(__fadd_rn(__fmul_rn(x0,x0), __fmul_rn(x1,x1)), __fmul_rn(x2,x2));
    float dt = __fadd_rn(__fadd_rn(__fmul_rn(c0,x0), __fmul_rn(c1,x1)), __fmul_rn(c2v,x2));
    d[j] = __fadd_rn(__fadd_rn(c2s, xs), -__fmul_rn(2.0f, dt));
  }
  const float FINF = __int_as_float(0x7F800000);
  float lmin = FINF; unsigned int lp = 0xFFFFFFFFu;
#pragma unroll
  for (int j = 0; j < 32; j++){ if (d[j] < lmin){ lmin = d[j]; lp = (unsigned int)(tid + j*256); } }
  __shared__ unsigned long long wred[2][4];
  for (int r = 0; r < K_; r++){
    unsigned int u = __float_as_uint(lmin);
    u = (u & 0x80000000u) ? ~u : (u | 0x80000000u);
    unsigned long long key = (((unsigned long long)u) << 32) | (unsigned long long)lp;
#pragma unroll
    for (int o = 32; o; o >>= 1){
      unsigned long long t = __shfl_down(key, o);
      key = (t < key) ? t : key;
    }
    int cur = r & 1;
    if ((tid & 63) == 0) wred[cur][tid >> 6] = key;
    __syncthreads();
    unsigned long long m = wred[cur][0];
#pragma unroll
    for (int w = 1; w < 4; w++){ unsigned long long t = wred[cur][w]; m = (t < m) ? t : m; }
    unsigned int p = (unsigned int)(m & 0xFFFFFFFFull);
    if (tid == (p & 255u)){
      knn_idx[(size_t)blk * K_ + r] = (int)p;
      float* np_ = neigh + ((size_t)blk * K_ + r) * 3;
      np_[0] = __fadd_rn(xb[p*3+0], -c0);
      np_[1] = __fadd_rn(xb[p*3+1], -c1);
      np_[2] = __fadd_rn(xb[p*3+2], -c2v);
      lmin = FINF; lp = 0xFFFFFFFFu;
#pragma unroll
      for (int j = 0; j < 32; j++){
        if ((unsigned int)(tid + j*256) == p) d[j] = FINF;
        if (d[j] < lmin){ lmin = d[j]; lp = (unsigned int)(tid + j*256); }
      }
    }
  }
}

// ---------------- fused group encoder (MFMA bf16): one block per (b,g) ----------------
// LDS = 17408 + 33792 + 1024 = 52224 B -> 3 blocks/CU by LDS.
// min-waves stays 2: forcing 3 caps VGPR at 84 and spills (R3: 248MB FETCH).
// gmax@w3_top is done via broadcast-A MFMA (gmax is exactly bf16: max of bf16s).
__global__ __launch_bounds__(256, 2) void encoder_kernel(
    const float* __restrict__ neigh,
    const float* __restrict__ w1f, const float* __restrict__ b1f,
    const unsigned short* __restrict__ w2ph, const unsigned short* __restrict__ w2pl,
    const float* __restrict__ b2,
    const float* __restrict__ b3f,
    const unsigned short* __restrict__ w3ph, const unsigned short* __restrict__ w3tp,
    const unsigned short* __restrict__ w4ph,
    const float* __restrict__ b4,
    float* __restrict__ tokens)
{
  __shared__ __align__(16) unsigned short sH1[64 * 136];  // h1 (64x128 bf16), reused as h3 chunk
  __shared__ __align__(16) unsigned short sH2[64 * 264];  // h2 (64x256 bf16)
  __shared__ __align__(16) float sShared[256];            // phase1: neigh[64][4]; phase3+: gmax bf16[256]
  float (*sNeigh)[4] = (float(*)[4])sShared;
  unsigned short* sGmaxBf = (unsigned short*)sShared;

  int tid  = threadIdx.x;
  int wave = tid >> 6, lane = tid & 63, quad = lane >> 4, lrow = lane & 15;
  size_t gid = blockIdx.x;

  if (tid < 192) sNeigh[tid / 3][tid % 3] = neigh[gid * 192 + tid];
  __syncthreads();

  // ---- phase 1: h1 = relu(bn(neigh @ w1)) -> bf16 LDS ----
  for (int e = tid; e < 8192; e += 256){
    int r = e >> 7, c = e & 127;
    float v = fmaf(sNeigh[r][2], w1f[256 + c], fmaf(sNeigh[r][1], w1f[128 + c], fmaf(sNeigh[r][0], w1f[c], b1f[c])));
    sH1[r * 136 + c] = bf16h(fmaxf(v, 0.0f));
  }
  __syncthreads();

  // ---- phase 2: h2 = h1 @ w2 + b2 (MFMA, hi/lo kept: first layer) ----
  {
    f32x4 acc[4][4];
    const f32x4 z = {0.f, 0.f, 0.f, 0.f};
#pragma unroll
    for (int mt = 0; mt < 4; mt++)
#pragma unroll
      for (int nl = 0; nl < 4; nl++) acc[mt][nl] = z;
#pragma unroll
    for (int ks = 0; ks < 4; ks++){
      bf16x8 af[4];
#pragma unroll
      for (int mt = 0; mt < 4; mt++)
        af[mt] = *(const bf16x8*)&sH1[(mt*16 + lrow)*136 + ks*32 + quad*8];
#pragma unroll
      for (int nl = 0; nl < 4; nl++){
        size_t bo = (((size_t)(wave*4 + nl)*4 + ks)*64 + lane)*8;
        bf16x8 bh = *(const bf16x8*)&w2ph[bo];
        bf16x8 bl = *(const bf16x8*)&w2pl[bo];
#pragma unroll
        for (int mt = 0; mt < 4; mt++){
          acc[mt][nl] = __builtin_amdgcn_mfma_f32_16x16x32_bf16(af[mt], bh, acc[mt][nl], 0, 0, 0);
          acc[mt][nl] = __builtin_amdgcn_mfma_f32_16x16x32_bf16(af[mt], bl, acc[mt][nl], 0, 0, 0);
        }
      }
    }
#pragma unroll
    for (int nl = 0; nl < 4; nl++){
      int col = wave*64 + nl*16 + lrow;
      float bias = b2[col];
#pragma unroll
      for (int mt = 0; mt < 4; mt++)
#pragma unroll
        for (int rg = 0; rg < 4; rg++)
          sH2[(mt*16 + quad*4 + rg)*264 + col] = bf16h(acc[mt][nl][rg] + bias);
    }
  }
  __syncthreads();

  // ---- phase 3: gmax = colmax(h2), stored bf16 (exact: max of bf16 values) ----
  {
    float mx = -3.4e38f;
#pragma unroll 8
    for (int r = 0; r < 64; r++) mx = fmaxf(mx, bf16_to_f32(sH2[r*264 + tid]));
    sGmaxBf[tid] = bf16h(mx);
  }
  __syncthreads();

  // ---- phase 4+5: h3 = relu(gmax@w3_top + h2@w3_bot + b3) chunks of 128 cols,
  //                 h4 accumulation (all MFMA) ----
  f32x4 acc4[4][4];
  {
    const f32x4 z = {0.f, 0.f, 0.f, 0.f};
#pragma unroll
    for (int mt = 0; mt < 4; mt++)
#pragma unroll
      for (int nl = 0; nl < 4; nl++) acc4[mt][nl] = z;
  }
  for (int cc = 0; cc < 4; cc++){
    f32x4 acc3[4][2], accg[2];
    {
      const f32x4 z = {0.f, 0.f, 0.f, 0.f};
#pragma unroll
      for (int mt = 0; mt < 4; mt++){ acc3[mt][0] = z; acc3[mt][1] = z; }
      accg[0] = z; accg[1] = z;
    }
    // gmax part: A rows all identical -> C rows identical; 16 MFMAs per wave
#pragma unroll
    for (int ks = 0; ks < 8; ks++){
      bf16x8 gf = *(const bf16x8*)&sGmaxBf[ks*32 + quad*8];
#pragma unroll
      for (int nl = 0; nl < 2; nl++){
        int nt = cc*8 + wave*2 + nl;
        size_t bo = (((size_t)nt*8 + ks)*64 + lane)*8;
        bf16x8 bh = *(const bf16x8*)&w3tp[bo];
        accg[nl] = __builtin_amdgcn_mfma_f32_16x16x32_bf16(gf, bh, accg[nl], 0, 0, 0);
      }
    }
    // h2 part
#pragma unroll
    for (int ks = 0; ks < 8; ks++){
      bf16x8 af[4];
#pragma unroll
      for (int mt = 0; mt < 4; mt++)
        af[mt] = *(const bf16x8*)&sH2[(mt*16 + lrow)*264 + ks*32 + quad*8];
#pragma unroll
      for (int nl = 0; nl < 2; nl++){
        int nt = cc*8 + wave*2 + nl;
        size_t bo = (((size_t)nt*8 + ks)*64 + lane)*8;
        bf16x8 bh = *(const bf16x8*)&w3ph[bo];
#pragma unroll
        for (int mt = 0; mt < 4; mt++)
          acc3[mt][nl] = __builtin_amdgcn_mfma_f32_16x16x32_bf16(af[mt], bh, acc3[mt][nl], 0, 0, 0);
      }
    }
    __syncthreads();
#pragma unroll
    for (int nl = 0; nl < 2; nl++){
      int cl = wave*32 + nl*16 + lrow;
      int c  = cc*128 + cl;
      float bb = b3f[c];
#pragma unroll
      for (int mt = 0; mt < 4; mt++)
#pragma unroll
        for (int rg = 0; rg < 4; rg++)
          sH1[(mt*16 + quad*4 + rg)*136 + cl] = bf16h(fmaxf(acc3[mt][nl][rg] + accg[nl][rg] + bb, 0.0f));
    }
    __syncthreads();
#pragma unroll
    for (int ks = 0; ks < 4; ks++){
      bf16x8 af[4];
#pragma unroll
      for (int mt = 0; mt < 4; mt++)
        af[mt] = *(const bf16x8*)&sH1[(mt*16 + lrow)*136 + ks*32 + quad*8];
#pragma unroll
      for (int nl = 0; nl < 4; nl++){
        int nt = wave*4 + nl;
        size_t bo = (((size_t)nt*16 + cc*4 + ks)*64 + lane)*8;
        bf16x8 bh = *(const bf16x8*)&w4ph[bo];
#pragma unroll
        for (int mt = 0; mt < 4; mt++)
          acc4[mt][nl] = __builtin_amdgcn_mfma_f32_16x16x32_bf16(af[mt], bh, acc4[mt][nl], 0, 0, 0);
      }
    }
  }

  // ---- phase 6: tokens = colmax(h4) + b4 ----
#pragma unroll
  for (int nl = 0; nl < 4; nl++){
    float mx = -3.4e38f;
#pragma unroll
    for (int mt = 0; mt < 4; mt++)
#pragma unroll
      for (int rg = 0; rg < 4; rg++) mx = fmaxf(mx, acc4[mt][nl][rg]);
    mx = fmaxf(mx, __shfl_xor(mx, 16));
    mx = fmaxf(mx, __shfl_xor(mx, 32));
    if (quad == 0){
      int col = wave*64 + nl*16 + lrow;
      tokens[gid * 256 + col] = mx + b4[col];
    }
  }
}

// ---------------- pos embed + assemble + first LN (fused) ----------------
__global__ __launch_bounds__(128) void pos_ln_kernel(
    const float* __restrict__ centers, const float* __restrict__ tokens,
    const float* __restrict__ cls_token, const float* __restrict__ cls_pos,
    const float* __restrict__ pw1, const float* __restrict__ pb1,
    const float* __restrict__ pw2, const float* __restrict__ pb2,
    const float* __restrict__ lng, const float* __restrict__ lnb,
    float* __restrict__ pt, float* __restrict__ xi, float* __restrict__ lnbuf)
{
  __shared__ float hS[128];
  __shared__ float red[2][2];
  int row = blockIdx.x;
  int b = row / 257, n = row - b * 257;
  int tid = threadIdx.x;
  size_t ro = (size_t)row * 256;
  float u0, u1;
  if (n == 0){
    float p0 = cls_pos[tid], p1 = cls_pos[128 + tid];
    u0 = cls_token[tid] + p0; u1 = cls_token[128 + tid] + p1;
    pt[ro + tid] = p0; pt[ro + 128 + tid] = p1;
  } else {
    int g = n - 1;
    const float* c = centers + ((size_t)b * 256 + g) * 3;
    float h = fmaf(c[2], pw1[256 + tid], fmaf(c[1], pw1[128 + tid], fmaf(c[0], pw1[tid], pb1[tid])));
    hS[tid] = gelu_exact(h);
    __syncthreads();
    const float* tok = tokens + ((size_t)b * 256 + g) * 256;
    float s0 = pb2[tid], s1 = pb2[128 + tid];
#pragma unroll 4
    for (int k = 0; k < 128; k++){
      s0 = fmaf(hS[k], pw2[(size_t)k * 256 + tid], s0);
      s1 = fmaf(hS[k], pw2[(size_t)k * 256 + 128 + tid], s1);
    }
    pt[ro + tid] = s0; pt[ro + 128 + tid] = s1;
    u0 = tok[tid] + s0; u1 = tok[128 + tid] + s1;
  }
  float s = u0 + u1, q = u0*u0 + u1*u1;
#pragma unroll
  for (int o = 32; o; o >>= 1){ s += __shfl_down(s, o); q += __shfl_down(q, o); }
  int wv = tid >> 6;
  if ((tid & 63) == 0){ red[0][wv] = s; red[1][wv] = q; }
  __syncthreads();
  float m  = (red[0][0] + red[0][1]) * (1.0f / 256.0f);
  float var = (red[1][0] + red[1][1]) * (1.0f / 256.0f) - m * m;
  float rs = 1.0f / sqrtf(var + EPS_);
  xi[ro + tid] = u0; xi[ro + 128 + tid] = u1;
  lnbuf[ro + tid] = (u0 - m) * rs * lng[tid] + lnb[tid];
  lnbuf[ro + 128 + tid] = (u1 - m) * rs * lng[128 + tid] + lnb[128 + tid];
}

// ---------------- MFMA GEMM: C = act(A@B + bias) ----------------
template<int ACT>
__global__ __launch_bounds__(256) void mfma_gemm(
    const float* __restrict__ A, const unsigned short* __restrict__ Bh,
    const float* __restrict__ bias, float* __restrict__ C, int M, int K, int N)
{
  __shared__ __align__(16) unsigned short sA[64 * 72];
  int tid = threadIdx.x;
  int wave = tid >> 6, lane = tid & 63, quad = lane >> 4, lrow = lane & 15;
  int row0 = blockIdx.x * 64;
  int col0 = blockIdx.y * 128;
  int ksTotal = K >> 5;
  f32x4 acc[4][2];
  const f32x4 z = {0.f, 0.f, 0.f, 0.f};
#pragma unroll
  for (int mt = 0; mt < 4; mt++){ acc[mt][0] = z; acc[mt][1] = z; }

  for (int k0 = 0; k0 < K; k0 += 64){
#pragma unroll
    for (int i = 0; i < 4; i++){
      int e = tid + i * 256;
      int r = e >> 4, c4 = (e & 15) * 4;
      int gr = row0 + r;
      float4 v = make_float4(0.f,0.f,0.f,0.f);
      if (gr < M) v = *(const float4*)(A + (size_t)gr * K + k0 + c4);
      unsigned int* dst = (unsigned int*)&sA[r * 72 + c4];
      dst[0] = pk_bf16(v.x, v.y); dst[1] = pk_bf16(v.z, v.w);
    }
    __syncthreads();
    int ksBase = k0 >> 5;
#pragma unroll
    for (int ks = 0; ks < 2; ks++){
      bf16x8 af[4];
#pragma unroll
      for (int mt = 0; mt < 4; mt++)
        af[mt] = *(const bf16x8*)&sA[(mt*16 + lrow)*72 + ks*32 + quad*8];
#pragma unroll
      for (int nl = 0; nl < 2; nl++){
        int nt = (col0 >> 4) + wave*2 + nl;
        size_t bo = (((size_t)nt * ksTotal + ksBase + ks)*64 + lane)*8;
        bf16x8 bh = *(const bf16x8*)&Bh[bo];
#pragma unroll
        for (int mt = 0; mt < 4; mt++)
          acc[mt][nl] = __builtin_amdgcn_mfma_f32_16x16x32_bf16(af[mt], bh, acc[mt][nl], 0, 0, 0);
      }
    }
    __syncthreads();
  }
#pragma unroll
  for (int nl = 0; nl < 2; nl++){
    int c = col0 + wave*32 + nl*16 + lrow;
    float bc = bias ? bias[c] : 0.0f;
#pragma unroll
    for (int mt = 0; mt < 4; mt++)
#pragma unroll
      for (int rg = 0; rg < 4; rg++){
        int r = row0 + mt*16 + quad*4 + rg;
        if (r < M){
          float v = acc[mt][nl][rg] + bc;
          if (ACT == 1) v = gelu_exact(v);
          C[(size_t)r * N + c] = v;
        }
      }
  }
}

// ---------------- MFMA GEMM + residual + LayerNorm epilogue (N=256 fixed) ----------------
__global__ __launch_bounds__(256) void mfma_gemm_ln(
    const float* __restrict__ A, const unsigned short* __restrict__ Bh,
    const float* __restrict__ bias, const float* __restrict__ res,
    const float* __restrict__ ptb,   // nullable: add before LN
    float* __restrict__ C, float* __restrict__ xiOut, float* __restrict__ lnOut,
    const float* __restrict__ lng, const float* __restrict__ lnb, int M, int K)
{
  __shared__ __align__(16) unsigned short sA[64 * 72];
  __shared__ float sRed[2][64][4];
  int tid = threadIdx.x;
  int wave = tid >> 6, lane = tid & 63, quad = lane >> 4, lrow = lane & 15;
  int row0 = blockIdx.x * 64;
  int ksTotal = K >> 5;
  f32x4 acc[4][4];
  const f32x4 z = {0.f, 0.f, 0.f, 0.f};
#pragma unroll
  for (int mt = 0; mt < 4; mt++)
#pragma unroll
    for (int nl = 0; nl < 4; nl++) acc[mt][nl] = z;

  for (int k0 = 0; k0 < K; k0 += 64){
#pragma unroll
    for (int i = 0; i < 4; i++){
      int e = tid + i * 256;
      int r = e >> 4, c4 = (e & 15) * 4;
      int gr = row0 + r;
      float4 v = make_float4(0.f,0.f,0.f,0.f);
      if (gr < M) v = *(const float4*)(A + (size_t)gr * K + k0 + c4);
      unsigned int* dst = (unsigned int*)&sA[r * 72 + c4];
      dst[0] = pk_bf16(v.x, v.y); dst[1] = pk_bf16(v.z, v.w);
    }
    __syncthreads();
    int ksBase = k0 >> 5;
#pragma unroll
    for (int ks = 0; ks < 2; ks++){
      bf16x8 af[4];
#pragma unroll
      for (int mt = 0; mt < 4; mt++)
        af[mt] = *(const bf16x8*)&sA[(mt*16 + lrow)*72 + ks*32 + quad*8];
#pragma unroll
      for (int nl = 0; nl < 4; nl++){
        int nt = wave*4 + nl;
        size_t bo = (((size_t)nt * ksTotal + ksBase + ks)*64 + lane)*8;
        bf16x8 bh = *(const bf16x8*)&Bh[bo];
#pragma unroll
        for (int mt = 0; mt < 4; mt++)
          acc[mt][nl] = __builtin_amdgcn_mfma_f32_16x16x32_bf16(af[mt], bh, acc[mt][nl], 0, 0, 0);
      }
    }
    __syncthreads();
  }
  // epilogue: v = acc + bias + res; C = v; acc := u = v (+pt)
#pragma unroll
  for (int nl = 0; nl < 4; nl++){
    int c = wave*64 + nl*16 + lrow;
    float bc = bias[c];
#pragma unroll
    for (int mt = 0; mt < 4; mt++)
#pragma unroll
      for (int rg = 0; rg < 4; rg++){
        int r = row0 + mt*16 + quad*4 + rg;
        if (r < M){
          float v = acc[mt][nl][rg] + bc + res[(size_t)r * 256 + c];
          C[(size_t)r * 256 + c] = v;
          float u = v;
          if (ptb) u += ptb[(size_t)r * 256 + c];
          acc[mt][nl][rg] = u;
        }
      }
  }
#pragma unroll
  for (int mt = 0; mt < 4; mt++)
#pragma unroll
    for (int rg = 0; rg < 4; rg++){
      int rloc = mt*16 + quad*4 + rg;
      float s = 0.0f, q = 0.0f;
#pragma unroll
      for (int nl = 0; nl < 4; nl++){ float u = acc[mt][nl][rg]; s += u; q += u*u; }
#pragma unroll
      for (int off = 1; off < 16; off <<= 1){ s += __shfl_xor(s, off); q += __shfl_xor(q, off); }
      if (lrow == 0){ sRed[0][rloc][wave] = s; sRed[1][rloc][wave] = q; }
    }
  __syncthreads();
#pragma unroll
  for (int mt = 0; mt < 4; mt++)
#pragma unroll
    for (int rg = 0; rg < 4; rg++){
      int rloc = mt*16 + quad*4 + rg;
      int r = row0 + rloc;
      if (r >= M) continue;
      float s = ((sRed[0][rloc][0] + sRed[0][rloc][1]) + sRed[0][rloc][2]) + sRed[0][rloc][3];
      float q = ((sRed[1][rloc][0] + sRed[1][rloc][1]) + sRed[1][rloc][2]) + sRed[1][rloc][3];
      float m  = s * (1.0f / 256.0f);
      float var = q * (1.0f / 256.0f) - m * m;
      float rs = 1.0f / sqrtf(var + EPS_);
#pragma unroll
      for (int nl = 0; nl < 4; nl++){
        int c = wave*64 + nl*16 + lrow;
        float u = acc[mt][nl][rg];
        lnOut[(size_t)r * 256 + c] = (u - m) * rs * lng[c] + lnb[c];
        if (xiOut) xiOut[(size_t)r * 256 + c] = u;
      }
    }
}

// ---------------- attention: block per (b,h,qchunk), flash-style, k-split x4 ----------------
// 256 thr: thread (qi, kp) handles q-row qi with k-rows == kp (mod 4); 4 partials
// merged via shfl_xor flash-merge. The 4 partitions of a q-row are consecutive lanes.
__global__ __launch_bounds__(256) void attn_kernel(const float* __restrict__ qkv, float* __restrict__ obuf)
{
  int bh = blockIdx.x;
  int b = bh >> 3, h = bh & 7;
  int tid = threadIdx.x;
  int qi = tid >> 2, kp = tid & 3;
  int qrow = blockIdx.y * 64 + qi;
  bool act = qrow < 257;
  __shared__ float kS[128][33];
  __shared__ float vS[128][33];
  const float* qb = qkv + (size_t)b * 257 * 768;
  float q[32], o[32];
  float mrun = -3.4e38f, l = 0.0f;
  if (act){
    const float* qr = qb + (size_t)qrow * 768 + h * 32;
#pragma unroll
    for (int j = 0; j < 32; j++){ q[j] = qr[j]; o[j] = 0.0f; }
  }
  const float scale = 0.17677669529663687f;
  for (int m0 = 0; m0 < 257; m0 += 128){
    int cnt = min(128, 257 - m0);
    for (int e = tid; e < cnt * 32; e += 256){
      int mm = e >> 5, j = e & 31;
      const float* rowp = qb + (size_t)(m0 + mm) * 768 + h * 32;
      kS[mm][j] = rowp[256 + j];
      vS[mm][j] = rowp[512 + j];
    }
    __syncthreads();
    if (act){
      for (int mm = kp; mm < cnt; mm += 4){
        float s = 0.0f;
#pragma unroll
        for (int j = 0; j < 32; j++) s = fmaf(q[j], kS[mm][j], s);
        s *= scale;
        float nm = fmaxf(mrun, s);
        float alpha = expf(mrun - nm);
        float p = expf(s - nm);
        l = fmaf(l, alpha, p);
#pragma unroll
        for (int j = 0; j < 32; j++) o[j] = fmaf(p, vS[mm][j], o[j] * alpha);
        mrun = nm;
      }
    }
    __syncthreads();
  }
  if (act){
    // flash-merge the 4 k-partitions (consecutive lanes)
#pragma unroll
    for (int msk = 1; msk <= 2; msk <<= 1){
      float m2 = __shfl_xor(mrun, msk);
      float l2 = __shfl_xor(l, msk);
      float nm = fmaxf(mrun, m2);
      float a1 = expf(mrun - nm), a2 = expf(m2 - nm);
      l = l * a1 + l2 * a2;
#pragma unroll
      for (int j = 0; j < 32; j++){
        float o2 = __shfl_xor(o[j], msk);
        o[j] = o[j] * a1 + o2 * a2;
      }
      mrun = nm;
    }
    if (kp == 0){
      float inv = 1.0f / l;
      float* orow = obuf + (size_t)(b * 257 + qrow) * 256 + h * 32;
#pragma unroll
      for (int j = 0; j < 32; j++) orow[j] = o[j] * inv;
    }
  }
}

// ---------------- head MLP + scatter: one block per (b,g) ----------------
__global__ __launch_bounds__(256) void head_kernel(
    const float* __restrict__ gfeat, const float* __restrict__ neigh, const int* __restrict__ knn_idx,
    const float* __restrict__ w1, const float* __restrict__ b1,
    const float* __restrict__ w2, const float* __restrict__ b2,
    float* __restrict__ sums, float* __restrict__ cnts)
{
  int blk = blockIdx.x, b = blk >> 8;
  __shared__ float xS[256];
  __shared__ float nS[64][4];
  __shared__ float partH[2][128];
  __shared__ float sharedH[128];
  __shared__ float w2S[128];
  __shared__ float wtail[3][128];
  int tid = threadIdx.x;
  xS[tid] = gfeat[((size_t)b * 257 + 1 + (blk & 255)) * 256 + tid];
  if (tid < 192) nS[tid / 3][tid % 3] = neigh[(size_t)blk * 192 + tid];
  if (tid < 128){
    w2S[tid] = w2[tid];
    wtail[0][tid] = w1[256 * 128 + tid];
    wtail[1][tid] = w1[257 * 128 + tid];
    wtail[2][tid] = w1[258 * 128 + tid];
  }
  __syncthreads();
  {
    int half = tid >> 7, j = tid & 127;
    float s = 0.0f;
#pragma unroll 8
    for (int k = 0; k < 128; k++) s = fmaf(xS[half * 128 + k], w1[(size_t)(half * 128 + k) * 128 + j], s);
    partH[half][j] = s;
  }
  __syncthreads();
  if (tid < 128) sharedH[tid] = partH[0][tid] + partH[1][tid] + b1[tid];
  __syncthreads();
  int r = tid >> 2, q = tid & 3;
  float n0 = nS[r][0], n1 = nS[r][1], n2 = nS[r][2];
  float s = 0.0f;
#pragma unroll
  for (int j0 = 0; j0 < 32; j0++){
    int j = q * 32 + j0;
    float h = fmaf(n2, wtail[2][j], fmaf(n1, wtail[1][j], fmaf(n0, wtail[0][j], sharedH[j])));
    s = fmaf(fmaxf(h, 0.0f), w2S[j], s);
  }
  s += __shfl_xor(s, 1);
  s += __shfl_xor(s, 2);
  if (q == 0){
    float lg = s + b2[0];
    int p = knn_idx[(size_t)blk * K_ + r];
    atomicAdd(&sums[(size_t)b * N_ + p], lg);
    atomicAdd(&cnts[(size_t)b * N_ + p], 1.0f);
  }
}

__global__ void finalize_kernel(const float* __restrict__ sums, const float* __restrict__ cnts, float* __restrict__ out)
{
  int i = blockIdx.x * 256 + threadIdx.x;
  out[i] = sums[i] / fmaxf(cnts[i], 1.0f);
}

extern "C" void kernel_launch(void* const* d_in, const int* in_sizes, int n_in,
                              void* d_out, int out_size, void* d_ws, size_t ws_size,
                              hipStream_t stream)
{
  (void)in_sizes; (void)n_in; (void)out_size; (void)ws_size;
  const float* x        = (const float*)d_in[0];
  const float* enc_w1   = (const float*)d_in[1];
  const float* enc_b1   = (const float*)d_in[2];
  const float* enc_bn1g = (const float*)d_in[3];
  const float* enc_bn1b = (const float*)d_in[4];
  const float* enc_w2   = (const float*)d_in[5];
  const float* enc_b2   = (const float*)d_in[6];
  const float* enc_w3   = (const float*)d_in[7];
  const float* enc_b3   = (const float*)d_in[8];
  const float* enc_bn2g = (const float*)d_in[9];
  const float* enc_bn2b = (const float*)d_in[10];
  const float* enc_w4   = (const float*)d_in[11];
  const float* enc_b4   = (const float*)d_in[12];
  const float* cls_tok  = (const float*)d_in[13];
  const float* cls_pos  = (const float*)d_in[14];
  const float* pos_w1   = (const float*)d_in[15];
  const float* pos_b1   = (const float*)d_in[16];
  const float* pos_w2   = (const float*)d_in[17];
  const float* pos_b2   = (const float*)d_in[18];
  const float* ln1_g    = (const float*)d_in[19];
  const float* ln1_b    = (const float*)d_in[20];
  const float* qkv_w    = (const float*)d_in[21];
  const float* proj_w   = (const float*)d_in[22];
  const float* proj_b   = (const float*)d_in[23];
  const float* ln2_g    = (const float*)d_in[24];
  const float* ln2_b    = (const float*)d_in[25];
  const float* fc1_w    = (const float*)d_in[26];
  const float* fc1_b    = (const float*)d_in[27];
  const float* fc2_w    = (const float*)d_in[28];
  const float* fc2_b    = (const float*)d_in[29];
  const float* norm_g   = (const float*)d_in[30];
  const float* norm_b   = (const float*)d_in[31];
  const float* head_w1  = (const float*)d_in[32];
  const float* head_b1  = (const float*)d_in[33];
  const float* head_w2  = (const float*)d_in[34];
  const float* head_b2  = (const float*)d_in[35];

  float* ws = (float*)d_ws;
  size_t off = 0;
  auto alloc = [&](size_t n)->float*{ float* p = ws + off; off += (n + 63) & ~(size_t)63; return p; };

  float* centers = alloc((size_t)B_ * G_ * 3);
  float* w1f     = alloc(384);
  float* b1f     = alloc(128);
  float* w3f     = alloc(512 * 512);
  float* b3f     = alloc(512);
  unsigned short* w2ph = (unsigned short*)alloc(16384);
  unsigned short* w2pl = (unsigned short*)alloc(16384);
  unsigned short* w3ph = (unsigned short*)alloc(65536);
  unsigned short* w3tp = (unsigned short*)alloc(65536);
  unsigned short* w4ph = (unsigned short*)alloc(65536);
  unsigned short* qkvPh = (unsigned short*)alloc(393216);
  unsigned short* projPh = (unsigned short*)alloc(131072);
  unsigned short* fc1Ph = (unsigned short*)alloc(524288);
  unsigned short* fc2Ph = (unsigned short*)alloc(524288);
  float* tokens  = alloc((size_t)B_ * G_ * D_);
  float* neigh   = alloc((size_t)B_ * G_ * K_ * 3);
  int*   knn_idx = (int*)alloc((size_t)B_ * G_ * K_);
  float* pt      = alloc((size_t)B_ * 257 * D_);
  float* xt      = alloc((size_t)B_ * 257 * D_);
  float* xi      = alloc((size_t)B_ * 257 * D_);
  float* lnbuf   = alloc((size_t)B_ * 257 * D_);
  float* obuf    = alloc((size_t)B_ * 257 * D_);
  float* bigbuf  = alloc((size_t)B_ * 257 * HID_);
  float* gfeat   = alloc((size_t)B_ * 257 * D_);
  float* sums    = alloc((size_t)B_ * N_);
  float* cnts    = alloc((size_t)B_ * N_);

  hipMemsetAsync(sums, 0, (size_t)2 * B_ * N_ * sizeof(float), stream);

  fold_kernel<<<1024, 256, 0, stream>>>(enc_w1, enc_b1, enc_bn1g, enc_bn1b,
                                        enc_w3, enc_b3, enc_bn2g, enc_bn2b,
                                        w1f, b1f, w3f, b3f);
  pack_all_kernel<<<13952, 256, 0, stream>>>(enc_w2, w3f, enc_w4, qkv_w, proj_w, fc1_w, fc2_w,
                                             w2ph, w2pl, w3ph, w4ph, qkvPh, projPh, fc1Ph, fc2Ph, w3tp);

  fps_kernel<<<B_, 512, 0, stream>>>(x, centers);
  knn_kernel<<<B_ * G_, 256, 0, stream>>>(x, centers, knn_idx, neigh);
  encoder_kernel<<<B_ * G_, 256, 0, stream>>>(neigh, w1f, b1f, w2ph, w2pl, enc_b2,
                                              b3f, w3ph, w3tp, w4ph, enc_b4, tokens);
  pos_ln_kernel<<<B_ * 257, 128, 0, stream>>>(centers, tokens, cls_tok, cls_pos,
                                              pos_w1, pos_b1, pos_w2, pos_b2,
                                              ln1_g, ln1_b, pt, xi, lnbuf);
  const int M = B_ * 257; // 4112
  for (int l = 0; l < 4; l++){
    mfma_gemm<0><<<dim3(65, 6), 256, 0, stream>>>(lnbuf, qkvPh + (size_t)l*196608, nullptr, bigbuf, M, 256, 768);
    attn_kernel<<<dim3(B_ * 8, 5), 256, 0, stream>>>(bigbuf, obuf);
    mfma_gemm_ln<<<65, 256, 0, stream>>>(obuf, projPh + (size_t)l*65536, proj_b + l*256, xi, nullptr,
                                         xi, nullptr, lnbuf, ln2_g + l*256, ln2_b + l*256, M, 256);
    mfma_gemm<1><<<dim3(65, 8), 256, 0, stream>>>(lnbuf, fc1Ph + (size_t)l*262144, fc1_b + l*1024, bigbuf, M, 256, 1024);
    if (l < 3){
      mfma_gemm_ln<<<65, 256, 0, stream>>>(bigbuf, fc2Ph + (size_t)l*262144, fc2_b + l*256, xi, pt,
                                           xt, xi, lnbuf, ln1_g + (l+1)*256, ln1_b + (l+1)*256, M, 1024);
    } else {
      mfma_gemm_ln<<<65, 256, 0, stream>>>(bigbuf, fc2Ph + (size_t)l*262144, fc2_b + l*256, xi, nullptr,
                                           xt, nullptr, gfeat, norm_g, norm_b, M, 1024);
    }
  }
  head_kernel<<<B_ * G_, 256, 0, stream>>>(gfeat, neigh, knn_idx, head_w1, head_b1, head_w2, head_b2, sums, cnts);
  finalize_kernel<<<(B_ * N_) / 256, 256, 0, stream>>>(sums, cnts, (float*)d_out);
}

// Round 7
// 1926.788 us; speedup vs baseline: 1.4551x; 1.0567x over previous
//
#include <hip/hip_runtime.h>
#include <hip/hip_bf16.h>

#define B_ 16
#define N_ 8192
#define G_ 256
#define K_ 64
#define D_ 256
#define HID_ 1024
#define EPS_ 1e-5f

typedef __attribute__((ext_vector_type(8))) short bf16x8;
typedef __attribute__((ext_vector_type(4))) float f32x4;

__device__ __forceinline__ float bf16_to_f32(unsigned short u){
  unsigned int v = ((unsigned int)u) << 16;
  return __uint_as_float(v);
}
__device__ __forceinline__ unsigned short f32_to_bf16(float f){
  unsigned int u = __float_as_uint(f);
  unsigned int r = (u + 0x7FFFu + ((u >> 16) & 1u)) >> 16;
  return (unsigned short)r;
}
// HW RNE converts (v_cvt_pk_bf16_f32)
__device__ __forceinline__ unsigned short bf16h(float a){
  __hip_bfloat16 h = __float2bfloat16(a);
  union { __hip_bfloat16 h; unsigned short u; } cv; cv.h = h; return cv.u;
}
__device__ __forceinline__ unsigned int pk_bf16(float a, float b){
  __hip_bfloat162 h = __float22bfloat162_rn(make_float2(a, b));
  union { __hip_bfloat162 h; unsigned int u; } cv; cv.h = h; return cv.u;
}
__device__ __forceinline__ float gelu_exact(float v){
  return 0.5f * v * (1.0f + erff(v * 0.70710678118654752440f));
}

// ---------------- DPP cross-lane reduce (VALU-latency, not LDS-permute) ----------------
// update_dpp(old=self, src=self): out-of-range lanes keep own value (identity for min/max).
template<int CTRL>
__device__ __forceinline__ unsigned long long dpp64(unsigned long long k){
  int lo = (int)(unsigned int)k;
  int hi = (int)(unsigned int)(k >> 32);
  int dlo = __builtin_amdgcn_update_dpp(lo, lo, CTRL, 0xF, 0xF, false);
  int dhi = __builtin_amdgcn_update_dpp(hi, hi, CTRL, 0xF, 0xF, false);
  return (((unsigned long long)(unsigned int)dhi) << 32) | (unsigned int)dlo;
}
__device__ __forceinline__ unsigned long long bcast64(unsigned long long k, int lane){
  unsigned int lo = (unsigned int)__builtin_amdgcn_readlane((int)(unsigned int)k, lane);
  unsigned int hi = (unsigned int)__builtin_amdgcn_readlane((int)(unsigned int)(k >> 32), lane);
  return (((unsigned long long)hi) << 32) | lo;
}
// full 64-lane max: row_shr 1/2/4/8 + row_bcast 15/31 -> lane63, readlane-broadcast
__device__ __forceinline__ unsigned long long wave_max64(unsigned long long k){
  unsigned long long t;
  t = dpp64<0x111>(k); if (t > k) k = t;
  t = dpp64<0x112>(k); if (t > k) k = t;
  t = dpp64<0x114>(k); if (t > k) k = t;
  t = dpp64<0x118>(k); if (t > k) k = t;
  t = dpp64<0x142>(k); if (t > k) k = t;
  t = dpp64<0x143>(k); if (t > k) k = t;
  return bcast64(k, 63);
}
__device__ __forceinline__ unsigned long long wave_min64(unsigned long long k){
  unsigned long long t;
  t = dpp64<0x111>(k); if (t < k) k = t;
  t = dpp64<0x112>(k); if (t < k) k = t;
  t = dpp64<0x114>(k); if (t < k) k = t;
  t = dpp64<0x118>(k); if (t < k) k = t;
  t = dpp64<0x142>(k); if (t < k) k = t;
  t = dpp64<0x143>(k); if (t < k) k = t;
  return bcast64(k, 63);
}
// max over lanes 0..7 (values in lanes 0..7; others must be <= or duplicates)
__device__ __forceinline__ unsigned long long red8_max64(unsigned long long k){
  unsigned long long t;
  t = dpp64<0x111>(k); if (t > k) k = t;
  t = dpp64<0x112>(k); if (t > k) k = t;
  t = dpp64<0x114>(k); if (t > k) k = t;
  return bcast64(k, 7);
}
// min over lanes 0..3
__device__ __forceinline__ unsigned long long red4_min64(unsigned long long k){
  unsigned long long t;
  t = dpp64<0x111>(k); if (t < k) k = t;
  t = dpp64<0x112>(k); if (t < k) k = t;
  return bcast64(k, 3);
}

// ---- pack helper: B frag for 16x16x32: lane holds B[k=(lane>>4)*8+j][n=lane&15] ----
// packed[((nt*KS + ks)*64 + lane)*8 + j],  KS = K/32
__device__ __forceinline__ void packHi(const float* __restrict__ W, unsigned short* __restrict__ hi,
                                       int f, int N, int ksBits){
  int j = f & 7, lane = (f >> 3) & 63;
  int ks = (f >> 9) & ((1 << ksBits) - 1);
  int nt = f >> (9 + ksBits);
  int k = ks * 32 + ((lane >> 4) & 3) * 8 + j, c = nt * 16 + (lane & 15);
  hi[f] = f32_to_bf16(W[(size_t)k * N + c]);
}

// ---------------- FUSED prep + FPS kernel ----------------
// blocks 0..15: FPS (one per batch, 512 thr, DPP argmax, 1 barrier/iter)
// block 16:     small folds (w1f/b1f/b3f)
// blocks 17+ :  weight packing (BN fold applied inline for w3)
__global__ __launch_bounds__(512) void prep_fps_kernel(
    const float* __restrict__ x, float* __restrict__ centers,
    const float* __restrict__ w1, const float* __restrict__ b1,
    const float* __restrict__ g1, const float* __restrict__ bb1,
    const float* __restrict__ w3, const float* __restrict__ b3,
    const float* __restrict__ g2, const float* __restrict__ bb2,
    const float* __restrict__ enc_w2, const float* __restrict__ enc_w4,
    const float* __restrict__ qkv_w, const float* __restrict__ proj_w,
    const float* __restrict__ fc1_w, const float* __restrict__ fc2_w,
    float* __restrict__ w1f, float* __restrict__ b1f, float* __restrict__ b3f,
    unsigned short* __restrict__ w2ph, unsigned short* __restrict__ w2pl,
    unsigned short* __restrict__ w3ph, unsigned short* __restrict__ w4ph,
    unsigned short* __restrict__ qkvPh, unsigned short* __restrict__ projPh,
    unsigned short* __restrict__ fc1Ph, unsigned short* __restrict__ fc2Ph,
    unsigned short* __restrict__ w3tp)
{
  const float S = 0.99999500003749968f; // 1/sqrt(1+1e-5)
  int blk = blockIdx.x, tid = threadIdx.x;

  if (blk >= 17){
    // ---------- packing ----------
    int f = (blk - 17) * 512 + tid;
    if (f < 32768){              // w2 hi+lo (K=128,N=256,ksBits=2)
      int j = f & 7, lane = (f >> 3) & 63, ks = (f >> 9) & 3, nt = f >> 11;
      int k = ks * 32 + ((lane >> 4) & 3) * 8 + j, c = nt * 16 + (lane & 15);
      float v = enc_w2[(size_t)k * 256 + c];
      unsigned short h = f32_to_bf16(v);
      w2ph[f] = h; w2pl[f] = f32_to_bf16(v - bf16_to_f32(h));
    } else if (f < 163840){      // w3 bottom half (rows 256..511), fold inline, ksBits=3
      f -= 32768;
      int j = f & 7, lane = (f >> 3) & 63, ks = (f >> 9) & 7, nt = f >> 12;
      int k = ks * 32 + ((lane >> 4) & 3) * 8 + j, c = nt * 16 + (lane & 15);
      w3ph[f] = f32_to_bf16(w3[(size_t)(256 + k) * 512 + c] * g2[c] * S);
    } else if (f < 294912){      // w4 (K=512,N=256,ksBits=4)
      f -= 163840;
      packHi(enc_w4, w4ph, f, 256, 4);
    } else if (f < 1081344){     // qkv x4 (K=256,N=768,ksBits=3)
      f -= 294912;
      int l = f / 196608, fl = f - l * 196608;
      packHi(qkv_w + (size_t)l * 196608, qkvPh + (size_t)l * 196608, fl, 768, 3);
    } else if (f < 1343488){     // proj x4 (K=256,N=256,ksBits=3)
      f -= 1081344;
      int l = f >> 16, fl = f & 65535;
      packHi(proj_w + (size_t)l * 65536, projPh + (size_t)l * 65536, fl, 256, 3);
    } else if (f < 2392064){     // fc1 x4 (K=256,N=1024,ksBits=3)
      f -= 1343488;
      int l = f >> 18, fl = f & 262143;
      packHi(fc1_w + (size_t)l * 262144, fc1Ph + (size_t)l * 262144, fl, 1024, 3);
    } else if (f < 3440640){     // fc2 x4 (K=1024,N=256,ksBits=5)
      f -= 2392064;
      int l = f >> 18, fl = f & 262143;
      packHi(fc2_w + (size_t)l * 262144, fc2Ph + (size_t)l * 262144, fl, 256, 5);
    } else {                     // w3 top half (rows 0..255), fold inline, ksBits=3
      f -= 3440640;
      int j = f & 7, lane = (f >> 3) & 63, ks = (f >> 9) & 7, nt = f >> 12;
      int k = ks * 32 + ((lane >> 4) & 3) * 8 + j, c = nt * 16 + (lane & 15);
      w3tp[f] = f32_to_bf16(w3[(size_t)k * 512 + c] * g2[c] * S);
    }
    return;
  }
  if (blk == 16){
    // ---------- small folds ----------
    if (tid < 384) w1f[tid] = w1[tid] * g1[tid & 127] * S;
    if (tid < 128) b1f[tid] = b1[tid] * g1[tid] * S + bb1[tid];
    b3f[tid] = b3[tid] * g2[tid] * S + bb2[tid];
    return;
  }

  // ---------- FPS (blocks 0..15) ----------
  int b = blk;
  const float* xb = x + (size_t)b * N_ * 3;
  int lane = tid & 63, wave = tid >> 6;
  float px[16], py[16], pz[16], dist[16];
#pragma unroll
  for (int j = 0; j < 16; j++){
    int p = tid + j * 512;
    px[j] = xb[p*3+0]; py[j] = xb[p*3+1]; pz[j] = xb[p*3+2];
    dist[j] = 1e10f;
  }
  __shared__ unsigned long long slotK[2][8];
  __shared__ float slotC[2][8][4];
  float cx = xb[0], cy = xb[1], cz = xb[2];
  for (int i = 0; i < G_; i++){
    if (tid == 0){
      float* cp = centers + ((size_t)b * G_ + i) * 3;
      cp[0] = cx; cp[1] = cy; cp[2] = cz;
    }
    float bestv = -1.0f; int bestj = 0;
#pragma unroll
    for (int j = 0; j < 16; j++){
      float dx = __fadd_rn(px[j], -cx);
      float dy = __fadd_rn(py[j], -cy);
      float dz = __fadd_rn(pz[j], -cz);
      float d  = __fadd_rn(__fadd_rn(__fmul_rn(dx,dx), __fmul_rn(dy,dy)), __fmul_rn(dz,dz));
      float dm = fminf(dist[j], d);
      dist[j] = dm;
      if (dm > bestv){ bestv = dm; bestj = j; }  // first max kept (lowest pid in thread)
    }
    unsigned int pid = (unsigned int)(tid + bestj * 512);
    unsigned long long key = (((unsigned long long)__float_as_uint(bestv)) << 32) | (unsigned long long)(~pid);
    key = wave_max64(key);                        // DPP: all lanes get wave winner
    int par = i & 1;
    unsigned int wpid = ~(unsigned int)key;       // wave winner's global pid
    if (lane == (int)(wpid & 63)){                // winner lane (winner is in this wave)
      int jj = (int)(wpid >> 9);
      float fx = px[0], fy = py[0], fz = pz[0];
#pragma unroll
      for (int j = 1; j < 16; j++) if (jj == j){ fx = px[j]; fy = py[j]; fz = pz[j]; }
      slotK[par][wave] = key;
      slotC[par][wave][0] = fx; slotC[par][wave][1] = fy; slotC[par][wave][2] = fz;
    }
    __syncthreads();
    if (i + 1 < G_){
      unsigned long long k2 = slotK[par][lane & 7];   // lanes>=8 duplicate -> harmless for max
      k2 = red8_max64(k2);
      unsigned int gpid = ~(unsigned int)k2;
      int s = (int)((gpid & 511u) >> 6);
      cx = slotC[par][s][0]; cy = slotC[par][s][1]; cz = slotC[par][s][2];
    }
  }
}

// ---------------- KNN: one block per (b,g), DPP wave-min ----------------
__global__ __launch_bounds__(256) void knn_kernel(const float* __restrict__ x, const float* __restrict__ centers,
                                                  int* __restrict__ knn_idx, float* __restrict__ neigh)
{
  int blk = blockIdx.x, b = blk >> 8;
  const float* xb = x + (size_t)b * N_ * 3;
  const float* cc = centers + (size_t)blk * 3;
  int tid = threadIdx.x, lane = tid & 63, wave = tid >> 6;
  float c0 = cc[0], c1 = cc[1], c2v = cc[2];
  float c2s = __fadd_rn(__fadd_rn(__fmul_rn(c0,c0), __fmul_rn(c1,c1)), __fmul_rn(c2v,c2v));
  float d[32];
#pragma unroll
  for (int j = 0; j < 32; j++){
    int p = tid + j * 256;
    float x0 = xb[p*3+0], x1 = xb[p*3+1], x2 = xb[p*3+2];
    float xs = __fadd_rn(__fadd_rn(__fmul_rn(x0,x0), __fmul_rn(x1,x1)), __fmul_rn(x2,x2));
    float dt = __fadd_rn(__fadd_rn(__fmul_rn(c0,x0), __fmul_rn(c1,x1)), __fmul_rn(c2v,x2));
    d[j] = __fadd_rn(__fadd_rn(c2s, xs), -__fmul_rn(2.0f, dt));
  }
  const float FINF = __int_as_float(0x7F800000);
  float lmin = FINF; unsigned int lp = 0xFFFFFFFFu;
#pragma unroll
  for (int j = 0; j < 32; j++){ if (d[j] < lmin){ lmin = d[j]; lp = (unsigned int)(tid + j*256); } }
  __shared__ unsigned long long wred[2][4];
  for (int r = 0; r < K_; r++){
    unsigned int u = __float_as_uint(lmin);
    u = (u & 0x80000000u) ? ~u : (u | 0x80000000u);
    unsigned long long key = (((unsigned long long)u) << 32) | (unsigned long long)lp;
    key = wave_min64(key);                 // DPP: all lanes get wave min
    int cur = r & 1;
    if (lane == 0) wred[cur][wave] = key;
    __syncthreads();
    unsigned long long m = red4_min64(wred[cur][lane & 3]);
    unsigned int p = (unsigned int)(m & 0xFFFFFFFFull);
    if (tid == (p & 255u)){
      knn_idx[(size_t)blk * K_ + r] = (int)p;
      float* np_ = neigh + ((size_t)blk * K_ + r) * 3;
      np_[0] = __fadd_rn(xb[p*3+0], -c0);
      np_[1] = __fadd_rn(xb[p*3+1], -c1);
      np_[2] = __fadd_rn(xb[p*3+2], -c2v);
      lmin = FINF; lp = 0xFFFFFFFFu;
#pragma unroll
      for (int j = 0; j < 32; j++){
        if ((unsigned int)(tid + j*256) == p) d[j] = FINF;
        if (d[j] < lmin){ lmin = d[j]; lp = (unsigned int)(tid + j*256); }
      }
    }
  }
}

// ---------------- fused group encoder (MFMA bf16): one block per (b,g) ----------------
// LDS = 17408 + 33792 + 1024 = 52224 B. min-waves stays 2: forcing 3 caps VGPR at 84
// and spills (R3: 248MB FETCH). gmax@w3_top via broadcast-A MFMA (gmax exactly bf16).
__global__ __launch_bounds__(256, 2) void encoder_kernel(
    const float* __restrict__ neigh,
    const float* __restrict__ w1f, const float* __restrict__ b1f,
    const unsigned short* __restrict__ w2ph, const unsigned short* __restrict__ w2pl,
    const float* __restrict__ b2,
    const float* __restrict__ b3f,
    const unsigned short* __restrict__ w3ph, const unsigned short* __restrict__ w3tp,
    const unsigned short* __restrict__ w4ph,
    const float* __restrict__ b4,
    float* __restrict__ tokens)
{
  __shared__ __align__(16) unsigned short sH1[64 * 136];  // h1 (64x128 bf16), reused as h3 chunk
  __shared__ __align__(16) unsigned short sH2[64 * 264];  // h2 (64x256 bf16)
  __shared__ __align__(16) float sShared[256];            // phase1: neigh[64][4]; phase3+: gmax bf16
  float (*sNeigh)[4] = (float(*)[4])sShared;
  unsigned short* sGmaxBf = (unsigned short*)sShared;

  int tid  = threadIdx.x;
  int wave = tid >> 6, lane = tid & 63, quad = lane >> 4, lrow = lane & 15;
  size_t gid = blockIdx.x;

  if (tid < 192) sNeigh[tid / 3][tid % 3] = neigh[gid * 192 + tid];
  __syncthreads();

  // ---- phase 1: h1 = relu(bn(neigh @ w1)) -> bf16 LDS ----
  for (int e = tid; e < 8192; e += 256){
    int r = e >> 7, c = e & 127;
    float v = fmaf(sNeigh[r][2], w1f[256 + c], fmaf(sNeigh[r][1], w1f[128 + c], fmaf(sNeigh[r][0], w1f[c], b1f[c])));
    sH1[r * 136 + c] = bf16h(fmaxf(v, 0.0f));
  }
  __syncthreads();

  // ---- phase 2: h2 = h1 @ w2 + b2 (MFMA, hi/lo kept: first layer) ----
  {
    f32x4 acc[4][4];
    const f32x4 z = {0.f, 0.f, 0.f, 0.f};
#pragma unroll
    for (int mt = 0; mt < 4; mt++)
#pragma unroll
      for (int nl = 0; nl < 4; nl++) acc[mt][nl] = z;
#pragma unroll
    for (int ks = 0; ks < 4; ks++){
      bf16x8 af[4];
#pragma unroll
      for (int mt = 0; mt < 4; mt++)
        af[mt] = *(const bf16x8*)&sH1[(mt*16 + lrow)*136 + ks*32 + quad*8];
#pragma unroll
      for (int nl = 0; nl < 4; nl++){
        size_t bo = (((size_t)(wave*4 + nl)*4 + ks)*64 + lane)*8;
        bf16x8 bh = *(const bf16x8*)&w2ph[bo];
        bf16x8 bl = *(const bf16x8*)&w2pl[bo];
#pragma unroll
        for (int mt = 0; mt < 4; mt++){
          acc[mt][nl] = __builtin_amdgcn_mfma_f32_16x16x32_bf16(af[mt], bh, acc[mt][nl], 0, 0, 0);
          acc[mt][nl] = __builtin_amdgcn_mfma_f32_16x16x32_bf16(af[mt], bl, acc[mt][nl], 0, 0, 0);
        }
      }
    }
#pragma unroll
    for (int nl = 0; nl < 4; nl++){
      int col = wave*64 + nl*16 + lrow;
      float bias = b2[col];
#pragma unroll
      for (int mt = 0; mt < 4; mt++)
#pragma unroll
        for (int rg = 0; rg < 4; rg++)
          sH2[(mt*16 + quad*4 + rg)*264 + col] = bf16h(acc[mt][nl][rg] + bias);
    }
  }
  __syncthreads();

  // ---- phase 3: gmax = colmax(h2), stored bf16 (exact: max of bf16 values) ----
  {
    float mx = -3.4e38f;
#pragma unroll 8
    for (int r = 0; r < 64; r++) mx = fmaxf(mx, bf16_to_f32(sH2[r*264 + tid]));
    sGmaxBf[tid] = bf16h(mx);
  }
  __syncthreads();

  // ---- phase 4+5: h3 = relu(gmax@w3_top + h2@w3_bot + b3), h4 accumulation ----
  f32x4 acc4[4][4];
  {
    const f32x4 z = {0.f, 0.f, 0.f, 0.f};
#pragma unroll
    for (int mt = 0; mt < 4; mt++)
#pragma unroll
      for (int nl = 0; nl < 4; nl++) acc4[mt][nl] = z;
  }
  for (int cc = 0; cc < 4; cc++){
    f32x4 acc3[4][2], accg[2];
    {
      const f32x4 z = {0.f, 0.f, 0.f, 0.f};
#pragma unroll
      for (int mt = 0; mt < 4; mt++){ acc3[mt][0] = z; acc3[mt][1] = z; }
      accg[0] = z; accg[1] = z;
    }
#pragma unroll
    for (int ks = 0; ks < 8; ks++){
      bf16x8 gf = *(const bf16x8*)&sGmaxBf[ks*32 + quad*8];
#pragma unroll
      for (int nl = 0; nl < 2; nl++){
        int nt = cc*8 + wave*2 + nl;
        size_t bo = (((size_t)nt*8 + ks)*64 + lane)*8;
        bf16x8 bh = *(const bf16x8*)&w3tp[bo];
        accg[nl] = __builtin_amdgcn_mfma_f32_16x16x32_bf16(gf, bh, accg[nl], 0, 0, 0);
      }
    }
#pragma unroll
    for (int ks = 0; ks < 8; ks++){
      bf16x8 af[4];
#pragma unroll
      for (int mt = 0; mt < 4; mt++)
        af[mt] = *(const bf16x8*)&sH2[(mt*16 + lrow)*264 + ks*32 + quad*8];
#pragma unroll
      for (int nl = 0; nl < 2; nl++){
        int nt = cc*8 + wave*2 + nl;
        size_t bo = (((size_t)nt*8 + ks)*64 + lane)*8;
        bf16x8 bh = *(const bf16x8*)&w3ph[bo];
#pragma unroll
        for (int mt = 0; mt < 4; mt++)
          acc3[mt][nl] = __builtin_amdgcn_mfma_f32_16x16x32_bf16(af[mt], bh, acc3[mt][nl], 0, 0, 0);
      }
    }
    __syncthreads();
#pragma unroll
    for (int nl = 0; nl < 2; nl++){
      int cl = wave*32 + nl*16 + lrow;
      int c  = cc*128 + cl;
      float bb = b3f[c];
#pragma unroll
      for (int mt = 0; mt < 4; mt++)
#pragma unroll
        for (int rg = 0; rg < 4; rg++)
          sH1[(mt*16 + quad*4 + rg)*136 + cl] = bf16h(fmaxf(acc3[mt][nl][rg] + accg[nl][rg] + bb, 0.0f));
    }
    __syncthreads();
#pragma unroll
    for (int ks = 0; ks < 4; ks++){
      bf16x8 af[4];
#pragma unroll
      for (int mt = 0; mt < 4; mt++)
        af[mt] = *(const bf16x8*)&sH1[(mt*16 + lrow)*136 + ks*32 + quad*8];
#pragma unroll
      for (int nl = 0; nl < 4; nl++){
        int nt = wave*4 + nl;
        size_t bo = (((size_t)nt*16 + cc*4 + ks)*64 + lane)*8;
        bf16x8 bh = *(const bf16x8*)&w4ph[bo];
#pragma unroll
        for (int mt = 0; mt < 4; mt++)
          acc4[mt][nl] = __builtin_amdgcn_mfma_f32_16x16x32_bf16(af[mt], bh, acc4[mt][nl], 0, 0, 0);
      }
    }
  }

  // ---- phase 6: tokens = colmax(h4) + b4 ----
#pragma unroll
  for (int nl = 0; nl < 4; nl++){
    float mx = -3.4e38f;
#pragma unroll
    for (int mt = 0; mt < 4; mt++)
#pragma unroll
      for (int rg = 0; rg < 4; rg++) mx = fmaxf(mx, acc4[mt][nl][rg]);
    mx = fmaxf(mx, __shfl_xor(mx, 16));
    mx = fmaxf(mx, __shfl_xor(mx, 32));
    if (quad == 0){
      int col = wave*64 + nl*16 + lrow;
      tokens[gid * 256 + col] = mx + b4[col];
    }
  }
}

// ---------------- pos embed + assemble + first LN (fused) ----------------
__global__ __launch_bounds__(128) void pos_ln_kernel(
    const float* __restrict__ centers, const float* __restrict__ tokens,
    const float* __restrict__ cls_token, const float* __restrict__ cls_pos,
    const float* __restrict__ pw1, const float* __restrict__ pb1,
    const float* __restrict__ pw2, const float* __restrict__ pb2,
    const float* __restrict__ lng, const float* __restrict__ lnb,
    float* __restrict__ pt, float* __restrict__ xi, float* __restrict__ lnbuf)
{
  __shared__ float hS[128];
  __shared__ float red[2][2];
  int row = blockIdx.x;
  int b = row / 257, n = row - b * 257;
  int tid = threadIdx.x;
  size_t ro = (size_t)row * 256;
  float u0, u1;
  if (n == 0){
    float p0 = cls_pos[tid], p1 = cls_pos[128 + tid];
    u0 = cls_token[tid] + p0; u1 = cls_token[128 + tid] + p1;
    pt[ro + tid] = p0; pt[ro + 128 + tid] = p1;
  } else {
    int g = n - 1;
    const float* c = centers + ((size_t)b * 256 + g) * 3;
    float h = fmaf(c[2], pw1[256 + tid], fmaf(c[1], pw1[128 + tid], fmaf(c[0], pw1[tid], pb1[tid])));
    hS[tid] = gelu_exact(h);
    __syncthreads();
    const float* tok = tokens + ((size_t)b * 256 + g) * 256;
    float s0 = pb2[tid], s1 = pb2[128 + tid];
#pragma unroll 4
    for (int k = 0; k < 128; k++){
      s0 = fmaf(hS[k], pw2[(size_t)k * 256 + tid], s0);
      s1 = fmaf(hS[k], pw2[(size_t)k * 256 + 128 + tid], s1);
    }
    pt[ro + tid] = s0; pt[ro + 128 + tid] = s1;
    u0 = tok[tid] + s0; u1 = tok[128 + tid] + s1;
  }
  float s = u0 + u1, q = u0*u0 + u1*u1;
#pragma unroll
  for (int o = 32; o; o >>= 1){ s += __shfl_down(s, o); q += __shfl_down(q, o); }
  int wv = tid >> 6;
  if ((tid & 63) == 0){ red[0][wv] = s; red[1][wv] = q; }
  __syncthreads();
  float m  = (red[0][0] + red[0][1]) * (1.0f / 256.0f);
  float var = (red[1][0] + red[1][1]) * (1.0f / 256.0f) - m * m;
  float rs = 1.0f / sqrtf(var + EPS_);
  xi[ro + tid] = u0; xi[ro + 128 + tid] = u1;
  lnbuf[ro + tid] = (u0 - m) * rs * lng[tid] + lnb[tid];
  lnbuf[ro + 128 + tid] = (u1 - m) * rs * lng[128 + tid] + lnb[128 + tid];
}

// ---------------- MFMA GEMM: C = act(A@B + bias) ----------------
template<int ACT>
__global__ __launch_bounds__(256) void mfma_gemm(
    const float* __restrict__ A, const unsigned short* __restrict__ Bh,
    const float* __restrict__ bias, float* __restrict__ C, int M, int K, int N)
{
  __shared__ __align__(16) unsigned short sA[64 * 72];
  int tid = threadIdx.x;
  int wave = tid >> 6, lane = tid & 63, quad = lane >> 4, lrow = lane & 15;
  int row0 = blockIdx.x * 64;
  int col0 = blockIdx.y * 128;
  int ksTotal = K >> 5;
  f32x4 acc[4][2];
  const f32x4 z = {0.f, 0.f, 0.f, 0.f};
#pragma unroll
  for (int mt = 0; mt < 4; mt++){ acc[mt][0] = z; acc[mt][1] = z; }

  for (int k0 = 0; k0 < K; k0 += 64){
#pragma unroll
    for (int i = 0; i < 4; i++){
      int e = tid + i * 256;
      int r = e >> 4, c4 = (e & 15) * 4;
      int gr = row0 + r;
      float4 v = make_float4(0.f,0.f,0.f,0.f);
      if (gr < M) v = *(const float4*)(A + (size_t)gr * K + k0 + c4);
      unsigned int* dst = (unsigned int*)&sA[r * 72 + c4];
      dst[0] = pk_bf16(v.x, v.y); dst[1] = pk_bf16(v.z, v.w);
    }
    __syncthreads();
    int ksBase = k0 >> 5;
#pragma unroll
    for (int ks = 0; ks < 2; ks++){
      bf16x8 af[4];
#pragma unroll
      for (int mt = 0; mt < 4; mt++)
        af[mt] = *(const bf16x8*)&sA[(mt*16 + lrow)*72 + ks*32 + quad*8];
#pragma unroll
      for (int nl = 0; nl < 2; nl++){
        int nt = (col0 >> 4) + wave*2 + nl;
        size_t bo = (((size_t)nt * ksTotal + ksBase + ks)*64 + lane)*8;
        bf16x8 bh = *(const bf16x8*)&Bh[bo];
#pragma unroll
        for (int mt = 0; mt < 4; mt++)
          acc[mt][nl] = __builtin_amdgcn_mfma_f32_16x16x32_bf16(af[mt], bh, acc[mt][nl], 0, 0, 0);
      }
    }
    __syncthreads();
  }
#pragma unroll
  for (int nl = 0; nl < 2; nl++){
    int c = col0 + wave*32 + nl*16 + lrow;
    float bc = bias ? bias[c] : 0.0f;
#pragma unroll
    for (int mt = 0; mt < 4; mt++)
#pragma unroll
      for (int rg = 0; rg < 4; rg++){
        int r = row0 + mt*16 + quad*4 + rg;
        if (r < M){
          float v = acc[mt][nl][rg] + bc;
          if (ACT == 1) v = gelu_exact(v);
          C[(size_t)r * N + c] = v;
        }
      }
  }
}

// ---------------- MFMA GEMM + residual + LayerNorm epilogue (N=256 fixed) ----------------
__global__ __launch_bounds__(256) void mfma_gemm_ln(
    const float* __restrict__ A, const unsigned short* __restrict__ Bh,
    const float* __restrict__ bias, const float* __restrict__ res,
    const float* __restrict__ ptb,   // nullable: add before LN
    float* __restrict__ C, float* __restrict__ xiOut, float* __restrict__ lnOut,
    const float* __restrict__ lng, const float* __restrict__ lnb, int M, int K)
{
  __shared__ __align__(16) unsigned short sA[64 * 72];
  __shared__ float sRed[2][64][4];
  int tid = threadIdx.x;
  int wave = tid >> 6, lane = tid & 63, quad = lane >> 4, lrow = lane & 15;
  int row0 = blockIdx.x * 64;
  int ksTotal = K >> 5;
  f32x4 acc[4][4];
  const f32x4 z = {0.f, 0.f, 0.f, 0.f};
#pragma unroll
  for (int mt = 0; mt < 4; mt++)
#pragma unroll
    for (int nl = 0; nl < 4; nl++) acc[mt][nl] = z;

  for (int k0 = 0; k0 < K; k0 += 64){
#pragma unroll
    for (int i = 0; i < 4; i++){
      int e = tid + i * 256;
      int r = e >> 4, c4 = (e & 15) * 4;
      int gr = row0 + r;
      float4 v = make_float4(0.f,0.f,0.f,0.f);
      if (gr < M) v = *(const float4*)(A + (size_t)gr * K + k0 + c4);
      unsigned int* dst = (unsigned int*)&sA[r * 72 + c4];
      dst[0] = pk_bf16(v.x, v.y); dst[1] = pk_bf16(v.z, v.w);
    }
    __syncthreads();
    int ksBase = k0 >> 5;
#pragma unroll
    for (int ks = 0; ks < 2; ks++){
      bf16x8 af[4];
#pragma unroll
      for (int mt = 0; mt < 4; mt++)
        af[mt] = *(const bf16x8*)&sA[(mt*16 + lrow)*72 + ks*32 + quad*8];
#pragma unroll
      for (int nl = 0; nl < 4; nl++){
        int nt = wave*4 + nl;
        size_t bo = (((size_t)nt * ksTotal + ksBase + ks)*64 + lane)*8;
        bf16x8 bh = *(const bf16x8*)&Bh[bo];
#pragma unroll
        for (int mt = 0; mt < 4; mt++)
          acc[mt][nl] = __builtin_amdgcn_mfma_f32_16x16x32_bf16(af[mt], bh, acc[mt][nl], 0, 0, 0);
      }
    }
    __syncthreads();
  }
#pragma unroll
  for (int nl = 0; nl < 4; nl++){
    int c = wave*64 + nl*16 + lrow;
    float bc = bias[c];
#pragma unroll
    for (int mt = 0; mt < 4; mt++)
#pragma unroll
      for (int rg = 0; rg < 4; rg++){
        int r = row0 + mt*16 + quad*4 + rg;
        if (r < M){
          float v = acc[mt][nl][rg] + bc + res[(size_t)r * 256 + c];
          C[(size_t)r * 256 + c] = v;
          float u = v;
          if (ptb) u += ptb[(size_t)r * 256 + c];
          acc[mt][nl][rg] = u;
        }
      }
  }
#pragma unroll
  for (int mt = 0; mt < 4; mt++)
#pragma unroll
    for (int rg = 0; rg < 4; rg++){
      int rloc = mt*16 + quad*4 + rg;
      float s = 0.0f, q = 0.0f;
#pragma unroll
      for (int nl = 0; nl < 4; nl++){ float u = acc[mt][nl][rg]; s += u; q += u*u; }
#pragma unroll
      for (int off = 1; off < 16; off <<= 1){ s += __shfl_xor(s, off); q += __shfl_xor(q, off); }
      if (lrow == 0){ sRed[0][rloc][wave] = s; sRed[1][rloc][wave] = q; }
    }
  __syncthreads();
#pragma unroll
  for (int mt = 0; mt < 4; mt++)
#pragma unroll
    for (int rg = 0; rg < 4; rg++){
      int rloc = mt*16 + quad*4 + rg;
      int r = row0 + rloc;
      if (r >= M) continue;
      float s = ((sRed[0][rloc][0] + sRed[0][rloc][1]) + sRed[0][rloc][2]) + sRed[0][rloc][3];
      float q = ((sRed[1][rloc][0] + sRed[1][rloc][1]) + sRed[1][rloc][2]) + sRed[1][rloc][3];
      float m  = s * (1.0f / 256.0f);
      float var = q * (1.0f / 256.0f) - m * m;
      float rs = 1.0f / sqrtf(var + EPS_);
#pragma unroll
      for (int nl = 0; nl < 4; nl++){
        int c = wave*64 + nl*16 + lrow;
        float u = acc[mt][nl][rg];
        lnOut[(size_t)r * 256 + c] = (u - m) * rs * lng[c] + lnb[c];
        if (xiOut) xiOut[(size_t)r * 256 + c] = u;
      }
    }
}

// ---------------- attention: block per (b,h,qchunk), flash-style, k-split x4 ----------------
__global__ __launch_bounds__(256) void attn_kernel(const float* __restrict__ qkv, float* __restrict__ obuf)
{
  int bh = blockIdx.x;
  int b = bh >> 3, h = bh & 7;
  int tid = threadIdx.x;
  int qi = tid >> 2, kp = tid & 3;
  int qrow = blockIdx.y * 64 + qi;
  bool act = qrow < 257;
  __shared__ float kS[128][33];
  __shared__ float vS[128][33];
  const float* qb = qkv + (size_t)b * 257 * 768;
  float q[32], o[32];
  float mrun = -3.4e38f, l = 0.0f;
  if (act){
    const float* qr = qb + (size_t)qrow * 768 + h * 32;
#pragma unroll
    for (int j = 0; j < 32; j++){ q[j] = qr[j]; o[j] = 0.0f; }
  }
  const float scale = 0.17677669529663687f;
  for (int m0 = 0; m0 < 257; m0 += 128){
    int cnt = min(128, 257 - m0);
    for (int e = tid; e < cnt * 32; e += 256){
      int mm = e >> 5, j = e & 31;
      const float* rowp = qb + (size_t)(m0 + mm) * 768 + h * 32;
      kS[mm][j] = rowp[256 + j];
      vS[mm][j] = rowp[512 + j];
    }
    __syncthreads();
    if (act){
      for (int mm = kp; mm < cnt; mm += 4){
        float s = 0.0f;
#pragma unroll
        for (int j = 0; j < 32; j++) s = fmaf(q[j], kS[mm][j], s);
        s *= scale;
        float nm = fmaxf(mrun, s);
        float alpha = expf(mrun - nm);
        float p = expf(s - nm);
        l = fmaf(l, alpha, p);
#pragma unroll
        for (int j = 0; j < 32; j++) o[j] = fmaf(p, vS[mm][j], o[j] * alpha);
        mrun = nm;
      }
    }
    __syncthreads();
  }
  if (act){
#pragma unroll
    for (int msk = 1; msk <= 2; msk <<= 1){
      float m2 = __shfl_xor(mrun, msk);
      float l2 = __shfl_xor(l, msk);
      float nm = fmaxf(mrun, m2);
      float a1 = expf(mrun - nm), a2 = expf(m2 - nm);
      l = l * a1 + l2 * a2;
#pragma unroll
      for (int j = 0; j < 32; j++){
        float o2 = __shfl_xor(o[j], msk);
        o[j] = o[j] * a1 + o2 * a2;
      }
      mrun = nm;
    }
    if (kp == 0){
      float inv = 1.0f / l;
      float* orow = obuf + (size_t)(b * 257 + qrow) * 256 + h * 32;
#pragma unroll
      for (int j = 0; j < 32; j++) orow[j] = o[j] * inv;
    }
  }
}

// ---------------- head MLP + scatter: one block per (b,g) ----------------
__global__ __launch_bounds__(256) void head_kernel(
    const float* __restrict__ gfeat, const float* __restrict__ neigh, const int* __restrict__ knn_idx,
    const float* __restrict__ w1, const float* __restrict__ b1,
    const float* __restrict__ w2, const float* __restrict__ b2,
    float* __restrict__ sums, float* __restrict__ cnts)
{
  int blk = blockIdx.x, b = blk >> 8;
  __shared__ float xS[256];
  __shared__ float nS[64][4];
  __shared__ float partH[2][128];
  __shared__ float sharedH[128];
  __shared__ float w2S[128];
  __shared__ float wtail[3][128];
  int tid = threadIdx.x;
  xS[tid] = gfeat[((size_t)b * 257 + 1 + (blk & 255)) * 256 + tid];
  if (tid < 192) nS[tid / 3][tid % 3] = neigh[(size_t)blk * 192 + tid];
  if (tid < 128){
    w2S[tid] = w2[tid];
    wtail[0][tid] = w1[256 * 128 + tid];
    wtail[1][tid] = w1[257 * 128 + tid];
    wtail[2][tid] = w1[258 * 128 + tid];
  }
  __syncthreads();
  {
    int half = tid >> 7, j = tid & 127;
    float s = 0.0f;
#pragma unroll 8
    for (int k = 0; k < 128; k++) s = fmaf(xS[half * 128 + k], w1[(size_t)(half * 128 + k) * 128 + j], s);
    partH[half][j] = s;
  }
  __syncthreads();
  if (tid < 128) sharedH[tid] = partH[0][tid] + partH[1][tid] + b1[tid];
  __syncthreads();
  int r = tid >> 2, q = tid & 3;
  float n0 = nS[r][0], n1 = nS[r][1], n2 = nS[r][2];
  float s = 0.0f;
#pragma unroll
  for (int j0 = 0; j0 < 32; j0++){
    int j = q * 32 + j0;
    float h = fmaf(n2, wtail[2][j], fmaf(n1, wtail[1][j], fmaf(n0, wtail[0][j], sharedH[j])));
    s = fmaf(fmaxf(h, 0.0f), w2S[j], s);
  }
  s += __shfl_xor(s, 1);
  s += __shfl_xor(s, 2);
  if (q == 0){
    float lg = s + b2[0];
    int p = knn_idx[(size_t)blk * K_ + r];
    atomicAdd(&sums[(size_t)b * N_ + p], lg);
    atomicAdd(&cnts[(size_t)b * N_ + p], 1.0f);
  }
}

__global__ void finalize_kernel(const float* __restrict__ sums, const float* __restrict__ cnts, float* __restrict__ out)
{
  int i = blockIdx.x * 256 + threadIdx.x;
  out[i] = sums[i] / fmaxf(cnts[i], 1.0f);
}

extern "C" void kernel_launch(void* const* d_in, const int* in_sizes, int n_in,
                              void* d_out, int out_size, void* d_ws, size_t ws_size,
                              hipStream_t stream)
{
  (void)in_sizes; (void)n_in; (void)out_size; (void)ws_size;
  const float* x        = (const float*)d_in[0];
  const float* enc_w1   = (const float*)d_in[1];
  const float* enc_b1   = (const float*)d_in[2];
  const float* enc_bn1g = (const float*)d_in[3];
  const float* enc_bn1b = (const float*)d_in[4];
  const float* enc_w2   = (const float*)d_in[5];
  const float* enc_b2   = (const float*)d_in[6];
  const float* enc_w3   = (const float*)d_in[7];
  const float* enc_b3   = (const float*)d_in[8];
  const float* enc_bn2g = (const float*)d_in[9];
  const float* enc_bn2b = (const float*)d_in[10];
  const float* enc_w4   = (const float*)d_in[11];
  const float* enc_b4   = (const float*)d_in[12];
  const float* cls_tok  = (const float*)d_in[13];
  const float* cls_pos  = (const float*)d_in[14];
  const float* pos_w1   = (const float*)d_in[15];
  const float* pos_b1   = (const float*)d_in[16];
  const float* pos_w2   = (const float*)d_in[17];
  const float* pos_b2   = (const float*)d_in[18];
  const float* ln1_g    = (const float*)d_in[19];
  const float* ln1_b    = (const float*)d_in[20];
  const float* qkv_w    = (const float*)d_in[21];
  const float* proj_w   = (const float*)d_in[22];
  const float* proj_b   = (const float*)d_in[23];
  const float* ln2_g    = (const float*)d_in[24];
  const float* ln2_b    = (const float*)d_in[25];
  const float* fc1_w    = (const float*)d_in[26];
  const float* fc1_b    = (const float*)d_in[27];
  const float* fc2_w    = (const float*)d_in[28];
  const float* fc2_b    = (const float*)d_in[29];
  const float* norm_g   = (const float*)d_in[30];
  const float* norm_b   = (const float*)d_in[31];
  const float* head_w1  = (const float*)d_in[32];
  const float* head_b1  = (const float*)d_in[33];
  const float* head_w2  = (const float*)d_in[34];
  const float* head_b2  = (const float*)d_in[35];

  float* ws = (float*)d_ws;
  size_t off = 0;
  auto alloc = [&](size_t n)->float*{ float* p = ws + off; off += (n + 63) & ~(size_t)63; return p; };

  float* centers = alloc((size_t)B_ * G_ * 3);
  float* w1f     = alloc(384);
  float* b1f     = alloc(128);
  float* b3f     = alloc(512);
  unsigned short* w2ph = (unsigned short*)alloc(16384);
  unsigned short* w2pl = (unsigned short*)alloc(16384);
  unsigned short* w3ph = (unsigned short*)alloc(65536);
  unsigned short* w3tp = (unsigned short*)alloc(65536);
  unsigned short* w4ph = (unsigned short*)alloc(65536);
  unsigned short* qkvPh = (unsigned short*)alloc(393216);
  unsigned short* projPh = (unsigned short*)alloc(131072);
  unsigned short* fc1Ph = (unsigned short*)alloc(524288);
  unsigned short* fc2Ph = (unsigned short*)alloc(524288);
  float* tokens  = alloc((size_t)B_ * G_ * D_);
  float* neigh   = alloc((size_t)B_ * G_ * K_ * 3);
  int*   knn_idx = (int*)alloc((size_t)B_ * G_ * K_);
  float* pt      = alloc((size_t)B_ * 257 * D_);
  float* xt      = alloc((size_t)B_ * 257 * D_);
  float* xi      = alloc((size_t)B_ * 257 * D_);
  float* lnbuf   = alloc((size_t)B_ * 257 * D_);
  float* obuf    = alloc((size_t)B_ * 257 * D_);
  float* bigbuf  = alloc((size_t)B_ * 257 * HID_);
  float* gfeat   = alloc((size_t)B_ * 257 * D_);
  float* sums    = alloc((size_t)B_ * N_);
  float* cnts    = alloc((size_t)B_ * N_);

  hipMemsetAsync(sums, 0, (size_t)2 * B_ * N_ * sizeof(float), stream);

  // fused: FPS (blocks 0..15) + folds (16) + packing (17..6992)
  prep_fps_kernel<<<6993, 512, 0, stream>>>(x, centers,
      enc_w1, enc_b1, enc_bn1g, enc_bn1b, enc_w3, enc_b3, enc_bn2g, enc_bn2b,
      enc_w2, enc_w4, qkv_w, proj_w, fc1_w, fc2_w,
      w1f, b1f, b3f, w2ph, w2pl, w3ph, w4ph, qkvPh, projPh, fc1Ph, fc2Ph, w3tp);

  knn_kernel<<<B_ * G_, 256, 0, stream>>>(x, centers, knn_idx, neigh);
  encoder_kernel<<<B_ * G_, 256, 0, stream>>>(neigh, w1f, b1f, w2ph, w2pl, enc_b2,
                                              b3f, w3ph, w3tp, w4ph, enc_b4, tokens);
  pos_ln_kernel<<<B_ * 257, 128, 0, stream>>>(centers, tokens, cls_tok, cls_pos,
                                              pos_w1, pos_b1, pos_w2, pos_b2,
                                              ln1_g, ln1_b, pt, xi, lnbuf);
  const int M = B_ * 257; // 4112
  for (int l = 0; l < 4; l++){
    mfma_gemm<0><<<dim3(65, 6), 256, 0, stream>>>(lnbuf, qkvPh + (size_t)l*196608, nullptr, bigbuf, M, 256, 768);
    attn_kernel<<<dim3(B_ * 8, 5), 256, 0, stream>>>(bigbuf, obuf);
    mfma_gemm_ln<<<65, 256, 0, stream>>>(obuf, projPh + (size_t)l*65536, proj_b + l*256, xi, nullptr,
                                         xi, nullptr, lnbuf, ln2_g + l*256, ln2_b + l*256, M, 256);
    mfma_gemm<1><<<dim3(65, 8), 256, 0, stream>>>(lnbuf, fc1Ph + (size_t)l*262144, fc1_b + l*1024, bigbuf, M, 256, 1024);
    if (l < 3){
      mfma_gemm_ln<<<65, 256, 0, stream>>>(bigbuf, fc2Ph + (size_t)l*262144, fc2_b + l*256, xi, pt,
                                           xt, xi, lnbuf, ln1_g + (l+1)*256, ln1_b + (l+1)*256, M, 1024);
    } else {
      mfma_gemm_ln<<<65, 256, 0, stream>>>(bigbuf, fc2Ph + (size_t)l*262144, fc2_b + l*256, xi, nullptr,
                                           xt, nullptr, gfeat, norm_g, norm_b, M, 1024);
    }
  }
  head_kernel<<<B_ * G_, 256, 0, stream>>>(gfeat, neigh, knn_idx, head_w1, head_b1, head_w2, head_b2, sums, cnts);
  finalize_kernel<<<(B_ * N_) / 256, 256, 0, stream>>>(sums, cnts, (float*)d_out);
}

// Round 8
// 1813.846 us; speedup vs baseline: 1.5457x; 1.0623x over previous
//
#include <hip/hip_runtime.h>
#include <hip/hip_bf16.h>

#define B_ 16
#define N_ 8192
#define G_ 256
#define K_ 64
#define D_ 256
#define HID_ 1024
#define EPS_ 1e-5f

typedef __attribute__((ext_vector_type(8))) short bf16x8;
typedef __attribute__((ext_vector_type(4))) float f32x4;

__device__ __forceinline__ float bf16_to_f32(unsigned short u){
  unsigned int v = ((unsigned int)u) << 16;
  return __uint_as_float(v);
}
__device__ __forceinline__ unsigned short f32_to_bf16(float f){
  unsigned int u = __float_as_uint(f);
  unsigned int r = (u + 0x7FFFu + ((u >> 16) & 1u)) >> 16;
  return (unsigned short)r;
}
// HW RNE converts (v_cvt_pk_bf16_f32)
__device__ __forceinline__ unsigned short bf16h(float a){
  __hip_bfloat16 h = __float2bfloat16(a);
  union { __hip_bfloat16 h; unsigned short u; } cv; cv.h = h; return cv.u;
}
__device__ __forceinline__ float gelu_exact(float v){
  return 0.5f * v * (1.0f + erff(v * 0.70710678118654752440f));
}

// ---------------- DPP cross-lane reduce ----------------
template<int CTRL>
__device__ __forceinline__ unsigned long long dpp64(unsigned long long k){
  int lo = (int)(unsigned int)k;
  int hi = (int)(unsigned int)(k >> 32);
  int dlo = __builtin_amdgcn_update_dpp(lo, lo, CTRL, 0xF, 0xF, false);
  int dhi = __builtin_amdgcn_update_dpp(hi, hi, CTRL, 0xF, 0xF, false);
  return (((unsigned long long)(unsigned int)dhi) << 32) | (unsigned int)dlo;
}
__device__ __forceinline__ unsigned long long bcast64(unsigned long long k, int lane){
  unsigned int lo = (unsigned int)__builtin_amdgcn_readlane((int)(unsigned int)k, lane);
  unsigned int hi = (unsigned int)__builtin_amdgcn_readlane((int)(unsigned int)(k >> 32), lane);
  return (((unsigned long long)hi) << 32) | lo;
}
__device__ __forceinline__ unsigned long long wave_max64(unsigned long long k){
  unsigned long long t;
  t = dpp64<0x111>(k); if (t > k) k = t;
  t = dpp64<0x112>(k); if (t > k) k = t;
  t = dpp64<0x114>(k); if (t > k) k = t;
  t = dpp64<0x118>(k); if (t > k) k = t;
  t = dpp64<0x142>(k); if (t > k) k = t;
  t = dpp64<0x143>(k); if (t > k) k = t;
  return bcast64(k, 63);
}
__device__ __forceinline__ unsigned long long wave_min64(unsigned long long k){
  unsigned long long t;
  t = dpp64<0x111>(k); if (t < k) k = t;
  t = dpp64<0x112>(k); if (t < k) k = t;
  t = dpp64<0x114>(k); if (t < k) k = t;
  t = dpp64<0x118>(k); if (t < k) k = t;
  t = dpp64<0x142>(k); if (t < k) k = t;
  t = dpp64<0x143>(k); if (t < k) k = t;
  return bcast64(k, 63);
}
__device__ __forceinline__ unsigned long long red8_max64(unsigned long long k){
  unsigned long long t;
  t = dpp64<0x111>(k); if (t > k) k = t;
  t = dpp64<0x112>(k); if (t > k) k = t;
  t = dpp64<0x114>(k); if (t > k) k = t;
  return bcast64(k, 7);
}
__device__ __forceinline__ unsigned long long red4_min64(unsigned long long k){
  unsigned long long t;
  t = dpp64<0x111>(k); if (t < k) k = t;
  t = dpp64<0x112>(k); if (t < k) k = t;
  return bcast64(k, 3);
}

// ---- pack helper: B frag for 16x16x32: lane holds B[k=(lane>>4)*8+j][n=lane&15] ----
__device__ __forceinline__ void packHi(const float* __restrict__ W, unsigned short* __restrict__ hi,
                                       int f, int N, int ksBits){
  int j = f & 7, lane = (f >> 3) & 63;
  int ks = (f >> 9) & ((1 << ksBits) - 1);
  int nt = f >> (9 + ksBits);
  int k = ks * 32 + ((lane >> 4) & 3) * 8 + j, c = nt * 16 + (lane & 15);
  hi[f] = f32_to_bf16(W[(size_t)k * N + c]);
}

// ---------------- FUSED prep + FPS kernel ----------------
__global__ __launch_bounds__(512) void prep_fps_kernel(
    const float* __restrict__ x, float* __restrict__ centers,
    const float* __restrict__ w1, const float* __restrict__ b1,
    const float* __restrict__ g1, const float* __restrict__ bb1,
    const float* __restrict__ w3, const float* __restrict__ b3,
    const float* __restrict__ g2, const float* __restrict__ bb2,
    const float* __restrict__ enc_w2, const float* __restrict__ enc_w4,
    const float* __restrict__ qkv_w, const float* __restrict__ proj_w,
    const float* __restrict__ fc1_w, const float* __restrict__ fc2_w,
    float* __restrict__ w1f, float* __restrict__ b1f, float* __restrict__ b3f,
    unsigned short* __restrict__ w2ph, unsigned short* __restrict__ w2pl,
    unsigned short* __restrict__ w3ph, unsigned short* __restrict__ w4ph,
    unsigned short* __restrict__ qkvPh, unsigned short* __restrict__ projPh,
    unsigned short* __restrict__ fc1Ph, unsigned short* __restrict__ fc2Ph,
    unsigned short* __restrict__ w3tp)
{
  const float S = 0.99999500003749968f; // 1/sqrt(1+1e-5)
  int blk = blockIdx.x, tid = threadIdx.x;

  if (blk >= 17){
    int f = (blk - 17) * 512 + tid;
    if (f < 32768){              // w2 hi+lo (K=128,N=256,ksBits=2)
      int j = f & 7, lane = (f >> 3) & 63, ks = (f >> 9) & 3, nt = f >> 11;
      int k = ks * 32 + ((lane >> 4) & 3) * 8 + j, c = nt * 16 + (lane & 15);
      float v = enc_w2[(size_t)k * 256 + c];
      unsigned short h = f32_to_bf16(v);
      w2ph[f] = h; w2pl[f] = f32_to_bf16(v - bf16_to_f32(h));
    } else if (f < 163840){      // w3 bottom half, fold inline, ksBits=3
      f -= 32768;
      int j = f & 7, lane = (f >> 3) & 63, ks = (f >> 9) & 7, nt = f >> 12;
      int k = ks * 32 + ((lane >> 4) & 3) * 8 + j, c = nt * 16 + (lane & 15);
      w3ph[f] = f32_to_bf16(w3[(size_t)(256 + k) * 512 + c] * g2[c] * S);
    } else if (f < 294912){      // w4
      f -= 163840;
      packHi(enc_w4, w4ph, f, 256, 4);
    } else if (f < 1081344){     // qkv x4
      f -= 294912;
      int l = f / 196608, fl = f - l * 196608;
      packHi(qkv_w + (size_t)l * 196608, qkvPh + (size_t)l * 196608, fl, 768, 3);
    } else if (f < 1343488){     // proj x4
      f -= 1081344;
      int l = f >> 16, fl = f & 65535;
      packHi(proj_w + (size_t)l * 65536, projPh + (size_t)l * 65536, fl, 256, 3);
    } else if (f < 2392064){     // fc1 x4
      f -= 1343488;
      int l = f >> 18, fl = f & 262143;
      packHi(fc1_w + (size_t)l * 262144, fc1Ph + (size_t)l * 262144, fl, 1024, 3);
    } else if (f < 3440640){     // fc2 x4
      f -= 2392064;
      int l = f >> 18, fl = f & 262143;
      packHi(fc2_w + (size_t)l * 262144, fc2Ph + (size_t)l * 262144, fl, 256, 5);
    } else {                     // w3 top half, fold inline
      f -= 3440640;
      int j = f & 7, lane = (f >> 3) & 63, ks = (f >> 9) & 7, nt = f >> 12;
      int k = ks * 32 + ((lane >> 4) & 3) * 8 + j, c = nt * 16 + (lane & 15);
      w3tp[f] = f32_to_bf16(w3[(size_t)k * 512 + c] * g2[c] * S);
    }
    return;
  }
  if (blk == 16){
    if (tid < 384) w1f[tid] = w1[tid] * g1[tid & 127] * S;
    if (tid < 128) b1f[tid] = b1[tid] * g1[tid] * S + bb1[tid];
    b3f[tid] = b3[tid] * g2[tid] * S + bb2[tid];
    return;
  }

  // ---------- FPS (blocks 0..15) ----------
  int b = blk;
  const float* xb = x + (size_t)b * N_ * 3;
  int lane = tid & 63, wave = tid >> 6;
  float px[16], py[16], pz[16], dist[16];
#pragma unroll
  for (int j = 0; j < 16; j++){
    int p = tid + j * 512;
    px[j] = xb[p*3+0]; py[j] = xb[p*3+1]; pz[j] = xb[p*3+2];
    dist[j] = 1e10f;
  }
  __shared__ unsigned long long slotK[2][8];
  __shared__ float4 slotC[2][8];
  float cx = xb[0], cy = xb[1], cz = xb[2];
  for (int i = 0; i < G_; i++){
    if (tid == 0){
      float* cp = centers + ((size_t)b * G_ + i) * 3;
      cp[0] = cx; cp[1] = cy; cp[2] = cz;
    }
    float bestv = -1.0f; int bestj = 0;
#pragma unroll
    for (int j = 0; j < 16; j++){
      float dx = __fadd_rn(px[j], -cx);
      float dy = __fadd_rn(py[j], -cy);
      float dz = __fadd_rn(pz[j], -cz);
      float d  = __fadd_rn(__fadd_rn(__fmul_rn(dx,dx), __fmul_rn(dy,dy)), __fmul_rn(dz,dz));
      float dm = fminf(dist[j], d);
      dist[j] = dm;
      if (dm > bestv){ bestv = dm; bestj = j; }
    }
    unsigned int pid = (unsigned int)(tid + bestj * 512);
    unsigned long long key = (((unsigned long long)__float_as_uint(bestv)) << 32) | (unsigned long long)(~pid);
    key = wave_max64(key);
    int par = i & 1;
    unsigned int wpid = ~(unsigned int)key;
    if (lane == (int)(wpid & 63)){
      int jj = (int)(wpid >> 9);
      float fx = px[0], fy = py[0], fz = pz[0];
#pragma unroll
      for (int j = 1; j < 16; j++) if (jj == j){ fx = px[j]; fy = py[j]; fz = pz[j]; }
      slotK[par][wave] = key;
      slotC[par][wave] = make_float4(fx, fy, fz, 0.0f);
    }
    __syncthreads();
    if (i + 1 < G_){
      int sl = lane & 7;
      unsigned long long k2 = slotK[par][sl];
      float4 cc4 = slotC[par][sl];          // issued in parallel with k2 read
      k2 = red8_max64(k2);
      unsigned int gpid = ~(unsigned int)k2;
      int s = (int)((gpid & 511u) >> 6);
      cx = __uint_as_float((unsigned int)__builtin_amdgcn_readlane((int)__float_as_uint(cc4.x), s));
      cy = __uint_as_float((unsigned int)__builtin_amdgcn_readlane((int)__float_as_uint(cc4.y), s));
      cz = __uint_as_float((unsigned int)__builtin_amdgcn_readlane((int)__float_as_uint(cc4.z), s));
    }
  }
}

// ---------------- KNN: one block per (b,g), DPP wave-min ----------------
__global__ __launch_bounds__(256) void knn_kernel(const float* __restrict__ x, const float* __restrict__ centers,
                                                  int* __restrict__ knn_idx, float* __restrict__ neigh)
{
  int blk = blockIdx.x, b = blk >> 8;
  const float* xb = x + (size_t)b * N_ * 3;
  const float* cc = centers + (size_t)blk * 3;
  int tid = threadIdx.x, lane = tid & 63, wave = tid >> 6;
  float c0 = cc[0], c1 = cc[1], c2v = cc[2];
  float c2s = __fadd_rn(__fadd_rn(__fmul_rn(c0,c0), __fmul_rn(c1,c1)), __fmul_rn(c2v,c2v));
  float d[32];
#pragma unroll
  for (int j = 0; j < 32; j++){
    int p = tid + j * 256;
    float x0 = xb[p*3+0], x1 = xb[p*3+1], x2 = xb[p*3+2];
    float xs = __fadd_rn(__fadd_rn(__fmul_rn(x0,x0), __fmul_rn(x1,x1)), __fmul_rn(x2,x2));
    float dt = __fadd_rn(__fadd_rn(__fmul_rn(c0,x0), __fmul_rn(c1,x1)), __fmul_rn(c2v,x2));
    d[j] = __fadd_rn(__fadd_rn(c2s, xs), -__fmul_rn(2.0f, dt));
  }
  const float FINF = __int_as_float(0x7F800000);
  float lmin = FINF; unsigned int lp = 0xFFFFFFFFu;
#pragma unroll
  for (int j = 0; j < 32; j++){ if (d[j] < lmin){ lmin = d[j]; lp = (unsigned int)(tid + j*256); } }
  __shared__ unsigned long long wred[2][4];
  for (int r = 0; r < K_; r++){
    unsigned int u = __float_as_uint(lmin);
    u = (u & 0x80000000u) ? ~u : (u | 0x80000000u);
    unsigned long long key = (((unsigned long long)u) << 32) | (unsigned long long)lp;
    key = wave_min64(key);
    int cur = r & 1;
    if (lane == 0) wred[cur][wave] = key;
    __syncthreads();
    unsigned long long m = red4_min64(wred[cur][lane & 3]);
    unsigned int p = (unsigned int)(m & 0xFFFFFFFFull);
    if (tid == (p & 255u)){
      knn_idx[(size_t)blk * K_ + r] = (int)p;
      float* np_ = neigh + ((size_t)blk * K_ + r) * 3;
      np_[0] = __fadd_rn(xb[p*3+0], -c0);
      np_[1] = __fadd_rn(xb[p*3+1], -c1);
      np_[2] = __fadd_rn(xb[p*3+2], -c2v);
      lmin = FINF; lp = 0xFFFFFFFFu;
#pragma unroll
      for (int j = 0; j < 32; j++){
        if ((unsigned int)(tid + j*256) == p) d[j] = FINF;
        if (d[j] < lmin){ lmin = d[j]; lp = (unsigned int)(tid + j*256); }
      }
    }
  }
}

// ---------------- fused group encoder (MFMA bf16): one block per (b,g) ----------------
__global__ __launch_bounds__(256, 2) void encoder_kernel(
    const float* __restrict__ neigh,
    const float* __restrict__ w1f, const float* __restrict__ b1f,
    const unsigned short* __restrict__ w2ph, const unsigned short* __restrict__ w2pl,
    const float* __restrict__ b2,
    const float* __restrict__ b3f,
    const unsigned short* __restrict__ w3ph, const unsigned short* __restrict__ w3tp,
    const unsigned short* __restrict__ w4ph,
    const float* __restrict__ b4,
    float* __restrict__ tokens)
{
  __shared__ __align__(16) unsigned short sH1[64 * 136];
  __shared__ __align__(16) unsigned short sH2[64 * 264];
  __shared__ __align__(16) float sShared[256];
  float (*sNeigh)[4] = (float(*)[4])sShared;
  unsigned short* sGmaxBf = (unsigned short*)sShared;

  int tid  = threadIdx.x;
  int wave = tid >> 6, lane = tid & 63, quad = lane >> 4, lrow = lane & 15;
  size_t gid = blockIdx.x;

  if (tid < 192) sNeigh[tid / 3][tid % 3] = neigh[gid * 192 + tid];
  __syncthreads();

  for (int e = tid; e < 8192; e += 256){
    int r = e >> 7, c = e & 127;
    float v = fmaf(sNeigh[r][2], w1f[256 + c], fmaf(sNeigh[r][1], w1f[128 + c], fmaf(sNeigh[r][0], w1f[c], b1f[c])));
    sH1[r * 136 + c] = bf16h(fmaxf(v, 0.0f));
  }
  __syncthreads();

  {
    f32x4 acc[4][4];
    const f32x4 z = {0.f, 0.f, 0.f, 0.f};
#pragma unroll
    for (int mt = 0; mt < 4; mt++)
#pragma unroll
      for (int nl = 0; nl < 4; nl++) acc[mt][nl] = z;
#pragma unroll
    for (int ks = 0; ks < 4; ks++){
      bf16x8 af[4];
#pragma unroll
      for (int mt = 0; mt < 4; mt++)
        af[mt] = *(const bf16x8*)&sH1[(mt*16 + lrow)*136 + ks*32 + quad*8];
#pragma unroll
      for (int nl = 0; nl < 4; nl++){
        size_t bo = (((size_t)(wave*4 + nl)*4 + ks)*64 + lane)*8;
        bf16x8 bh = *(const bf16x8*)&w2ph[bo];
        bf16x8 bl = *(const bf16x8*)&w2pl[bo];
#pragma unroll
        for (int mt = 0; mt < 4; mt++){
          acc[mt][nl] = __builtin_amdgcn_mfma_f32_16x16x32_bf16(af[mt], bh, acc[mt][nl], 0, 0, 0);
          acc[mt][nl] = __builtin_amdgcn_mfma_f32_16x16x32_bf16(af[mt], bl, acc[mt][nl], 0, 0, 0);
        }
      }
    }
#pragma unroll
    for (int nl = 0; nl < 4; nl++){
      int col = wave*64 + nl*16 + lrow;
      float bias = b2[col];
#pragma unroll
      for (int mt = 0; mt < 4; mt++)
#pragma unroll
        for (int rg = 0; rg < 4; rg++)
          sH2[(mt*16 + quad*4 + rg)*264 + col] = bf16h(acc[mt][nl][rg] + bias);
    }
  }
  __syncthreads();

  {
    float mx = -3.4e38f;
#pragma unroll 8
    for (int r = 0; r < 64; r++) mx = fmaxf(mx, bf16_to_f32(sH2[r*264 + tid]));
    sGmaxBf[tid] = bf16h(mx);
  }
  __syncthreads();

  f32x4 acc4[4][4];
  {
    const f32x4 z = {0.f, 0.f, 0.f, 0.f};
#pragma unroll
    for (int mt = 0; mt < 4; mt++)
#pragma unroll
      for (int nl = 0; nl < 4; nl++) acc4[mt][nl] = z;
  }
  for (int cc = 0; cc < 4; cc++){
    f32x4 acc3[4][2], accg[2];
    {
      const f32x4 z = {0.f, 0.f, 0.f, 0.f};
#pragma unroll
      for (int mt = 0; mt < 4; mt++){ acc3[mt][0] = z; acc3[mt][1] = z; }
      accg[0] = z; accg[1] = z;
    }
#pragma unroll
    for (int ks = 0; ks < 8; ks++){
      bf16x8 gf = *(const bf16x8*)&sGmaxBf[ks*32 + quad*8];
#pragma unroll
      for (int nl = 0; nl < 2; nl++){
        int nt = cc*8 + wave*2 + nl;
        size_t bo = (((size_t)nt*8 + ks)*64 + lane)*8;
        bf16x8 bh = *(const bf16x8*)&w3tp[bo];
        accg[nl] = __builtin_amdgcn_mfma_f32_16x16x32_bf16(gf, bh, accg[nl], 0, 0, 0);
      }
    }
#pragma unroll
    for (int ks = 0; ks < 8; ks++){
      bf16x8 af[4];
#pragma unroll
      for (int mt = 0; mt < 4; mt++)
        af[mt] = *(const bf16x8*)&sH2[(mt*16 + lrow)*264 + ks*32 + quad*8];
#pragma unroll
      for (int nl = 0; nl < 2; nl++){
        int nt = cc*8 + wave*2 + nl;
        size_t bo = (((size_t)nt*8 + ks)*64 + lane)*8;
        bf16x8 bh = *(const bf16x8*)&w3ph[bo];
#pragma unroll
        for (int mt = 0; mt < 4; mt++)
          acc3[mt][nl] = __builtin_amdgcn_mfma_f32_16x16x32_bf16(af[mt], bh, acc3[mt][nl], 0, 0, 0);
      }
    }
    __syncthreads();
#pragma unroll
    for (int nl = 0; nl < 2; nl++){
      int cl = wave*32 + nl*16 + lrow;
      int c  = cc*128 + cl;
      float bb = b3f[c];
#pragma unroll
      for (int mt = 0; mt < 4; mt++)
#pragma unroll
        for (int rg = 0; rg < 4; rg++)
          sH1[(mt*16 + quad*4 + rg)*136 + cl] = bf16h(fmaxf(acc3[mt][nl][rg] + accg[nl][rg] + bb, 0.0f));
    }
    __syncthreads();
#pragma unroll
    for (int ks = 0; ks < 4; ks++){
      bf16x8 af[4];
#pragma unroll
      for (int mt = 0; mt < 4; mt++)
        af[mt] = *(const bf16x8*)&sH1[(mt*16 + lrow)*136 + ks*32 + quad*8];
#pragma unroll
      for (int nl = 0; nl < 4; nl++){
        int nt = wave*4 + nl;
        size_t bo = (((size_t)nt*16 + cc*4 + ks)*64 + lane)*8;
        bf16x8 bh = *(const bf16x8*)&w4ph[bo];
#pragma unroll
        for (int mt = 0; mt < 4; mt++)
          acc4[mt][nl] = __builtin_amdgcn_mfma_f32_16x16x32_bf16(af[mt], bh, acc4[mt][nl], 0, 0, 0);
      }
    }
  }

#pragma unroll
  for (int nl = 0; nl < 4; nl++){
    float mx = -3.4e38f;
#pragma unroll
    for (int mt = 0; mt < 4; mt++)
#pragma unroll
      for (int rg = 0; rg < 4; rg++) mx = fmaxf(mx, acc4[mt][nl][rg]);
    mx = fmaxf(mx, __shfl_xor(mx, 16));
    mx = fmaxf(mx, __shfl_xor(mx, 32));
    if (quad == 0){
      int col = wave*64 + nl*16 + lrow;
      tokens[gid * 256 + col] = mx + b4[col];
    }
  }
}

// ---------------- pos embed + assemble + first LN (fused); LN out bf16 ----------------
__global__ __launch_bounds__(128) void pos_ln_kernel(
    const float* __restrict__ centers, const float* __restrict__ tokens,
    const float* __restrict__ cls_token, const float* __restrict__ cls_pos,
    const float* __restrict__ pw1, const float* __restrict__ pb1,
    const float* __restrict__ pw2, const float* __restrict__ pb2,
    const float* __restrict__ lng, const float* __restrict__ lnb,
    float* __restrict__ pt, float* __restrict__ xi, unsigned short* __restrict__ lnbuf)
{
  __shared__ float hS[128];
  __shared__ float red[2][2];
  int row = blockIdx.x;
  int b = row / 257, n = row - b * 257;
  int tid = threadIdx.x;
  size_t ro = (size_t)row * 256;
  float u0, u1;
  if (n == 0){
    float p0 = cls_pos[tid], p1 = cls_pos[128 + tid];
    u0 = cls_token[tid] + p0; u1 = cls_token[128 + tid] + p1;
    pt[ro + tid] = p0; pt[ro + 128 + tid] = p1;
  } else {
    int g = n - 1;
    const float* c = centers + ((size_t)b * 256 + g) * 3;
    float h = fmaf(c[2], pw1[256 + tid], fmaf(c[1], pw1[128 + tid], fmaf(c[0], pw1[tid], pb1[tid])));
    hS[tid] = gelu_exact(h);
    __syncthreads();
    const float* tok = tokens + ((size_t)b * 256 + g) * 256;
    float s0 = pb2[tid], s1 = pb2[128 + tid];
#pragma unroll 4
    for (int k = 0; k < 128; k++){
      s0 = fmaf(hS[k], pw2[(size_t)k * 256 + tid], s0);
      s1 = fmaf(hS[k], pw2[(size_t)k * 256 + 128 + tid], s1);
    }
    pt[ro + tid] = s0; pt[ro + 128 + tid] = s1;
    u0 = tok[tid] + s0; u1 = tok[128 + tid] + s1;
  }
  float s = u0 + u1, q = u0*u0 + u1*u1;
#pragma unroll
  for (int o = 32; o; o >>= 1){ s += __shfl_down(s, o); q += __shfl_down(q, o); }
  int wv = tid >> 6;
  if ((tid & 63) == 0){ red[0][wv] = s; red[1][wv] = q; }
  __syncthreads();
  float m  = (red[0][0] + red[0][1]) * (1.0f / 256.0f);
  float var = (red[1][0] + red[1][1]) * (1.0f / 256.0f) - m * m;
  float rs = 1.0f / sqrtf(var + EPS_);
  xi[ro + tid] = u0; xi[ro + 128 + tid] = u1;
  lnbuf[ro + tid] = bf16h((u0 - m) * rs * lng[tid] + lnb[tid]);
  lnbuf[ro + 128 + tid] = bf16h((u1 - m) * rs * lng[128 + tid] + lnb[128 + tid]);
}

// ---------------- MFMA GEMM: bf16 A -> bf16 C = act(A@B + bias) ----------------
template<int ACT>
__global__ __launch_bounds__(256) void mfma_gemm(
    const unsigned short* __restrict__ A, const unsigned short* __restrict__ Bh,
    const float* __restrict__ bias, unsigned short* __restrict__ C, int M, int K, int N)
{
  __shared__ __align__(16) unsigned short sA[64 * 72];
  int tid = threadIdx.x;
  int wave = tid >> 6, lane = tid & 63, quad = lane >> 4, lrow = lane & 15;
  int row0 = blockIdx.x * 64;
  int col0 = blockIdx.y * 128;
  int ksTotal = K >> 5;
  f32x4 acc[4][2];
  const f32x4 z = {0.f, 0.f, 0.f, 0.f};
#pragma unroll
  for (int mt = 0; mt < 4; mt++){ acc[mt][0] = z; acc[mt][1] = z; }

  for (int k0 = 0; k0 < K; k0 += 64){
#pragma unroll
    for (int i = 0; i < 2; i++){
      int e = tid + i * 256;          // [0,512): r = e>>3, c8 = (e&7)*8
      int r = e >> 3, c8 = (e & 7) * 8;
      int gr = row0 + r;
      bf16x8 v = {0,0,0,0,0,0,0,0};
      if (gr < M) v = *(const bf16x8*)(A + (size_t)gr * K + k0 + c8);
      *(bf16x8*)&sA[r * 72 + c8] = v;
    }
    __syncthreads();
    int ksBase = k0 >> 5;
#pragma unroll
    for (int ks = 0; ks < 2; ks++){
      bf16x8 af[4];
#pragma unroll
      for (int mt = 0; mt < 4; mt++)
        af[mt] = *(const bf16x8*)&sA[(mt*16 + lrow)*72 + ks*32 + quad*8];
#pragma unroll
      for (int nl = 0; nl < 2; nl++){
        int nt = (col0 >> 4) + wave*2 + nl;
        size_t bo = (((size_t)nt * ksTotal + ksBase + ks)*64 + lane)*8;
        bf16x8 bh = *(const bf16x8*)&Bh[bo];
#pragma unroll
        for (int mt = 0; mt < 4; mt++)
          acc[mt][nl] = __builtin_amdgcn_mfma_f32_16x16x32_bf16(af[mt], bh, acc[mt][nl], 0, 0, 0);
      }
    }
    __syncthreads();
  }
#pragma unroll
  for (int nl = 0; nl < 2; nl++){
    int c = col0 + wave*32 + nl*16 + lrow;
    float bc = bias ? bias[c] : 0.0f;
#pragma unroll
    for (int mt = 0; mt < 4; mt++)
#pragma unroll
      for (int rg = 0; rg < 4; rg++){
        int r = row0 + mt*16 + quad*4 + rg;
        if (r < M){
          float v = acc[mt][nl][rg] + bc;
          if (ACT == 1) v = gelu_exact(v);
          C[(size_t)r * N + c] = bf16h(v);
        }
      }
  }
}

// ---------------- MFMA GEMM + residual + LayerNorm epilogue (N=256) ----------------
// A bf16; res/xi f32; C (f32, nullable), xiOut (f32, nullable), lnOut bf16
__global__ __launch_bounds__(256) void mfma_gemm_ln(
    const unsigned short* __restrict__ A, const unsigned short* __restrict__ Bh,
    const float* __restrict__ bias, const float* __restrict__ res,
    const float* __restrict__ ptb,
    float* __restrict__ C, float* __restrict__ xiOut, unsigned short* __restrict__ lnOut,
    const float* __restrict__ lng, const float* __restrict__ lnb, int M, int K)
{
  __shared__ __align__(16) unsigned short sA[64 * 72];
  __shared__ float sRed[2][64][4];
  int tid = threadIdx.x;
  int wave = tid >> 6, lane = tid & 63, quad = lane >> 4, lrow = lane & 15;
  int row0 = blockIdx.x * 64;
  int ksTotal = K >> 5;
  f32x4 acc[4][4];
  const f32x4 z = {0.f, 0.f, 0.f, 0.f};
#pragma unroll
  for (int mt = 0; mt < 4; mt++)
#pragma unroll
    for (int nl = 0; nl < 4; nl++) acc[mt][nl] = z;

  for (int k0 = 0; k0 < K; k0 += 64){
#pragma unroll
    for (int i = 0; i < 2; i++){
      int e = tid + i * 256;
      int r = e >> 3, c8 = (e & 7) * 8;
      int gr = row0 + r;
      bf16x8 v = {0,0,0,0,0,0,0,0};
      if (gr < M) v = *(const bf16x8*)(A + (size_t)gr * K + k0 + c8);
      *(bf16x8*)&sA[r * 72 + c8] = v;
    }
    __syncthreads();
    int ksBase = k0 >> 5;
#pragma unroll
    for (int ks = 0; ks < 2; ks++){
      bf16x8 af[4];
#pragma unroll
      for (int mt = 0; mt < 4; mt++)
        af[mt] = *(const bf16x8*)&sA[(mt*16 + lrow)*72 + ks*32 + quad*8];
#pragma unroll
      for (int nl = 0; nl < 4; nl++){
        int nt = wave*4 + nl;
        size_t bo = (((size_t)nt * ksTotal + ksBase + ks)*64 + lane)*8;
        bf16x8 bh = *(const bf16x8*)&Bh[bo];
#pragma unroll
        for (int mt = 0; mt < 4; mt++)
          acc[mt][nl] = __builtin_amdgcn_mfma_f32_16x16x32_bf16(af[mt], bh, acc[mt][nl], 0, 0, 0);
      }
    }
    __syncthreads();
  }
#pragma unroll
  for (int nl = 0; nl < 4; nl++){
    int c = wave*64 + nl*16 + lrow;
    float bc = bias[c];
#pragma unroll
    for (int mt = 0; mt < 4; mt++)
#pragma unroll
      for (int rg = 0; rg < 4; rg++){
        int r = row0 + mt*16 + quad*4 + rg;
        if (r < M){
          float v = acc[mt][nl][rg] + bc + res[(size_t)r * 256 + c];
          if (C) C[(size_t)r * 256 + c] = v;
          float u = v;
          if (ptb) u += ptb[(size_t)r * 256 + c];
          acc[mt][nl][rg] = u;
        }
      }
  }
#pragma unroll
  for (int mt = 0; mt < 4; mt++)
#pragma unroll
    for (int rg = 0; rg < 4; rg++){
      int rloc = mt*16 + quad*4 + rg;
      float s = 0.0f, q = 0.0f;
#pragma unroll
      for (int nl = 0; nl < 4; nl++){ float u = acc[mt][nl][rg]; s += u; q += u*u; }
#pragma unroll
      for (int off = 1; off < 16; off <<= 1){ s += __shfl_xor(s, off); q += __shfl_xor(q, off); }
      if (lrow == 0){ sRed[0][rloc][wave] = s; sRed[1][rloc][wave] = q; }
    }
  __syncthreads();
#pragma unroll
  for (int mt = 0; mt < 4; mt++)
#pragma unroll
    for (int rg = 0; rg < 4; rg++){
      int rloc = mt*16 + quad*4 + rg;
      int r = row0 + rloc;
      if (r >= M) continue;
      float s = ((sRed[0][rloc][0] + sRed[0][rloc][1]) + sRed[0][rloc][2]) + sRed[0][rloc][3];
      float q = ((sRed[1][rloc][0] + sRed[1][rloc][1]) + sRed[1][rloc][2]) + sRed[1][rloc][3];
      float m  = s * (1.0f / 256.0f);
      float var = q * (1.0f / 256.0f) - m * m;
      float rs = 1.0f / sqrtf(var + EPS_);
#pragma unroll
      for (int nl = 0; nl < 4; nl++){
        int c = wave*64 + nl*16 + lrow;
        float u = acc[mt][nl][rg];
        lnOut[(size_t)r * 256 + c] = bf16h((u - m) * rs * lng[c] + lnb[c]);
        if (xiOut) xiOut[(size_t)r * 256 + c] = u;
      }
    }
}

// ---------------- attention: bf16 in/out, flash-style, k-split x4 ----------------
__global__ __launch_bounds__(256) void attn_kernel(const unsigned short* __restrict__ qkv, unsigned short* __restrict__ obuf)
{
  int bh = blockIdx.x;
  int b = bh >> 3, h = bh & 7;
  int tid = threadIdx.x;
  int qi = tid >> 2, kp = tid & 3;
  int qrow = blockIdx.y * 64 + qi;
  bool act = qrow < 257;
  __shared__ float kS[128][33];
  __shared__ float vS[128][33];
  const unsigned short* qb = qkv + (size_t)b * 257 * 768;
  float q[32], o[32];
  float mrun = -3.4e38f, l = 0.0f;
  if (act){
    const unsigned short* qr = qb + (size_t)qrow * 768 + h * 32;
#pragma unroll
    for (int j = 0; j < 32; j++){ q[j] = bf16_to_f32(qr[j]); o[j] = 0.0f; }
  }
  const float scale = 0.17677669529663687f;
  for (int m0 = 0; m0 < 257; m0 += 128){
    int cnt = min(128, 257 - m0);
    for (int e = tid; e < cnt * 32; e += 256){
      int mm = e >> 5, j = e & 31;
      const unsigned short* rowp = qb + (size_t)(m0 + mm) * 768 + h * 32;
      kS[mm][j] = bf16_to_f32(rowp[256 + j]);
      vS[mm][j] = bf16_to_f32(rowp[512 + j]);
    }
    __syncthreads();
    if (act){
      for (int mm = kp; mm < cnt; mm += 4){
        float s = 0.0f;
#pragma unroll
        for (int j = 0; j < 32; j++) s = fmaf(q[j], kS[mm][j], s);
        s *= scale;
        float nm = fmaxf(mrun, s);
        float alpha = expf(mrun - nm);
        float p = expf(s - nm);
        l = fmaf(l, alpha, p);
#pragma unroll
        for (int j = 0; j < 32; j++) o[j] = fmaf(p, vS[mm][j], o[j] * alpha);
        mrun = nm;
      }
    }
    __syncthreads();
  }
  if (act){
#pragma unroll
    for (int msk = 1; msk <= 2; msk <<= 1){
      float m2 = __shfl_xor(mrun, msk);
      float l2 = __shfl_xor(l, msk);
      float nm = fmaxf(mrun, m2);
      float a1 = expf(mrun - nm), a2 = expf(m2 - nm);
      l = l * a1 + l2 * a2;
#pragma unroll
      for (int j = 0; j < 32; j++){
        float o2 = __shfl_xor(o[j], msk);
        o[j] = o[j] * a1 + o2 * a2;
      }
      mrun = nm;
    }
    if (kp == 0){
      float inv = 1.0f / l;
      unsigned short* orow = obuf + (size_t)(b * 257 + qrow) * 256 + h * 32;
#pragma unroll
      for (int j = 0; j < 32; j++) orow[j] = bf16h(o[j] * inv);
    }
  }
}

// ---------------- head MLP + scatter: one block per (b,g); gfeat bf16 ----------------
__global__ __launch_bounds__(256) void head_kernel(
    const unsigned short* __restrict__ gfeat, const float* __restrict__ neigh, const int* __restrict__ knn_idx,
    const float* __restrict__ w1, const float* __restrict__ b1,
    const float* __restrict__ w2, const float* __restrict__ b2,
    float* __restrict__ sums, float* __restrict__ cnts)
{
  int blk = blockIdx.x, b = blk >> 8;
  __shared__ float xS[256];
  __shared__ float nS[64][4];
  __shared__ float partH[2][128];
  __shared__ float sharedH[128];
  __shared__ float w2S[128];
  __shared__ float wtail[3][128];
  int tid = threadIdx.x;
  xS[tid] = bf16_to_f32(gfeat[((size_t)b * 257 + 1 + (blk & 255)) * 256 + tid]);
  if (tid < 192) nS[tid / 3][tid % 3] = neigh[(size_t)blk * 192 + tid];
  if (tid < 128){
    w2S[tid] = w2[tid];
    wtail[0][tid] = w1[256 * 128 + tid];
    wtail[1][tid] = w1[257 * 128 + tid];
    wtail[2][tid] = w1[258 * 128 + tid];
  }
  __syncthreads();
  {
    int half = tid >> 7, j = tid & 127;
    float s = 0.0f;
#pragma unroll 8
    for (int k = 0; k < 128; k++) s = fmaf(xS[half * 128 + k], w1[(size_t)(half * 128 + k) * 128 + j], s);
    partH[half][j] = s;
  }
  __syncthreads();
  if (tid < 128) sharedH[tid] = partH[0][tid] + partH[1][tid] + b1[tid];
  __syncthreads();
  int r = tid >> 2, q = tid & 3;
  float n0 = nS[r][0], n1 = nS[r][1], n2 = nS[r][2];
  float s = 0.0f;
#pragma unroll
  for (int j0 = 0; j0 < 32; j0++){
    int j = q * 32 + j0;
    float h = fmaf(n2, wtail[2][j], fmaf(n1, wtail[1][j], fmaf(n0, wtail[0][j], sharedH[j])));
    s = fmaf(fmaxf(h, 0.0f), w2S[j], s);
  }
  s += __shfl_xor(s, 1);
  s += __shfl_xor(s, 2);
  if (q == 0){
    float lg = s + b2[0];
    int p = knn_idx[(size_t)blk * K_ + r];
    atomicAdd(&sums[(size_t)b * N_ + p], lg);
    atomicAdd(&cnts[(size_t)b * N_ + p], 1.0f);
  }
}

__global__ void finalize_kernel(const float* __restrict__ sums, const float* __restrict__ cnts, float* __restrict__ out)
{
  int i = blockIdx.x * 256 + threadIdx.x;
  out[i] = sums[i] / fmaxf(cnts[i], 1.0f);
}

extern "C" void kernel_launch(void* const* d_in, const int* in_sizes, int n_in,
                              void* d_out, int out_size, void* d_ws, size_t ws_size,
                              hipStream_t stream)
{
  (void)in_sizes; (void)n_in; (void)out_size; (void)ws_size;
  const float* x        = (const float*)d_in[0];
  const float* enc_w1   = (const float*)d_in[1];
  const float* enc_b1   = (const float*)d_in[2];
  const float* enc_bn1g = (const float*)d_in[3];
  const float* enc_bn1b = (const float*)d_in[4];
  const float* enc_w2   = (const float*)d_in[5];
  const float* enc_b2   = (const float*)d_in[6];
  const float* enc_w3   = (const float*)d_in[7];
  const float* enc_b3   = (const float*)d_in[8];
  const float* enc_bn2g = (const float*)d_in[9];
  const float* enc_bn2b = (const float*)d_in[10];
  const float* enc_w4   = (const float*)d_in[11];
  const float* enc_b4   = (const float*)d_in[12];
  const float* cls_tok  = (const float*)d_in[13];
  const float* cls_pos  = (const float*)d_in[14];
  const float* pos_w1   = (const float*)d_in[15];
  const float* pos_b1   = (const float*)d_in[16];
  const float* pos_w2   = (const float*)d_in[17];
  const float* pos_b2   = (const float*)d_in[18];
  const float* ln1_g    = (const float*)d_in[19];
  const float* ln1_b    = (const float*)d_in[20];
  const float* qkv_w    = (const float*)d_in[21];
  const float* proj_w   = (const float*)d_in[22];
  const float* proj_b   = (const float*)d_in[23];
  const float* ln2_g    = (const float*)d_in[24];
  const float* ln2_b    = (const float*)d_in[25];
  const float* fc1_w    = (const float*)d_in[26];
  const float* fc1_b    = (const float*)d_in[27];
  const float* fc2_w    = (const float*)d_in[28];
  const float* fc2_b    = (const float*)d_in[29];
  const float* norm_g   = (const float*)d_in[30];
  const float* norm_b   = (const float*)d_in[31];
  const float* head_w1  = (const float*)d_in[32];
  const float* head_b1  = (const float*)d_in[33];
  const float* head_w2  = (const float*)d_in[34];
  const float* head_b2  = (const float*)d_in[35];

  float* ws = (float*)d_ws;
  size_t off = 0;
  auto alloc = [&](size_t n)->float*{ float* p = ws + off; off += (n + 63) & ~(size_t)63; return p; };

  float* centers = alloc((size_t)B_ * G_ * 3);
  float* w1f     = alloc(384);
  float* b1f     = alloc(128);
  float* b3f     = alloc(512);
  unsigned short* w2ph = (unsigned short*)alloc(16384);
  unsigned short* w2pl = (unsigned short*)alloc(16384);
  unsigned short* w3ph = (unsigned short*)alloc(65536);
  unsigned short* w3tp = (unsigned short*)alloc(65536);
  unsigned short* w4ph = (unsigned short*)alloc(65536);
  unsigned short* qkvPh = (unsigned short*)alloc(393216);
  unsigned short* projPh = (unsigned short*)alloc(131072);
  unsigned short* fc1Ph = (unsigned short*)alloc(524288);
  unsigned short* fc2Ph = (unsigned short*)alloc(524288);
  float* tokens  = alloc((size_t)B_ * G_ * D_);
  float* neigh   = alloc((size_t)B_ * G_ * K_ * 3);
  int*   knn_idx = (int*)alloc((size_t)B_ * G_ * K_);
  float* pt      = alloc((size_t)B_ * 257 * D_);
  float* xi      = alloc((size_t)B_ * 257 * D_);
  unsigned short* lnbufB = (unsigned short*)alloc((size_t)B_ * 257 * D_ / 2 + 64);
  unsigned short* obufB  = (unsigned short*)alloc((size_t)B_ * 257 * D_ / 2 + 64);
  unsigned short* bigbufB= (unsigned short*)alloc((size_t)B_ * 257 * HID_ / 2 + 64);
  unsigned short* gfeatB = (unsigned short*)alloc((size_t)B_ * 257 * D_ / 2 + 64);
  float* sums    = alloc((size_t)B_ * N_);
  float* cnts    = alloc((size_t)B_ * N_);

  hipMemsetAsync(sums, 0, (size_t)2 * B_ * N_ * sizeof(float), stream);

  // fused: FPS (blocks 0..15) + folds (16) + packing (17..6992)
  prep_fps_kernel<<<6993, 512, 0, stream>>>(x, centers,
      enc_w1, enc_b1, enc_bn1g, enc_bn1b, enc_w3, enc_b3, enc_bn2g, enc_bn2b,
      enc_w2, enc_w4, qkv_w, proj_w, fc1_w, fc2_w,
      w1f, b1f, b3f, w2ph, w2pl, w3ph, w4ph, qkvPh, projPh, fc1Ph, fc2Ph, w3tp);

  knn_kernel<<<B_ * G_, 256, 0, stream>>>(x, centers, knn_idx, neigh);
  encoder_kernel<<<B_ * G_, 256, 0, stream>>>(neigh, w1f, b1f, w2ph, w2pl, enc_b2,
                                              b3f, w3ph, w3tp, w4ph, enc_b4, tokens);
  pos_ln_kernel<<<B_ * 257, 128, 0, stream>>>(centers, tokens, cls_tok, cls_pos,
                                              pos_w1, pos_b1, pos_w2, pos_b2,
                                              ln1_g, ln1_b, pt, xi, lnbufB);
  const int M = B_ * 257; // 4112
  for (int l = 0; l < 4; l++){
    mfma_gemm<0><<<dim3(65, 6), 256, 0, stream>>>(lnbufB, qkvPh + (size_t)l*196608, nullptr, bigbufB, M, 256, 768);
    attn_kernel<<<dim3(B_ * 8, 5), 256, 0, stream>>>(bigbufB, obufB);
    mfma_gemm_ln<<<65, 256, 0, stream>>>(obufB, projPh + (size_t)l*65536, proj_b + l*256, xi, nullptr,
                                         xi, nullptr, lnbufB, ln2_g + l*256, ln2_b + l*256, M, 256);
    mfma_gemm<1><<<dim3(65, 8), 256, 0, stream>>>(lnbufB, fc1Ph + (size_t)l*262144, fc1_b + l*1024, bigbufB, M, 256, 1024);
    if (l < 3){
      mfma_gemm_ln<<<65, 256, 0, stream>>>(bigbufB, fc2Ph + (size_t)l*262144, fc2_b + l*256, xi, pt,
                                           nullptr, xi, lnbufB, ln1_g + (l+1)*256, ln1_b + (l+1)*256, M, 1024);
    } else {
      mfma_gemm_ln<<<65, 256, 0, stream>>>(bigbufB, fc2Ph + (size_t)l*262144, fc2_b + l*256, xi, nullptr,
                                           nullptr, nullptr, gfeatB, norm_g, norm_b, M, 1024);
    }
  }
  head_kernel<<<B_ * G_, 256, 0, stream>>>(gfeatB, neigh, knn_idx, head_w1, head_b1, head_w2, head_b2, sums, cnts);
  finalize_kernel<<<(B_ * N_) / 256, 256, 0, stream>>>(sums, cnts, (float*)d_out);
}

// Round 9
// 1649.621 us; speedup vs baseline: 1.6996x; 1.0996x over previous
//
#include <hip/hip_runtime.h>
#include <hip/hip_bf16.h>

#define B_ 16
#define N_ 8192
#define G_ 256
#define K_ 64
#define D_ 256
#define HID_ 1024
#define EPS_ 1e-5f

typedef __attribute__((ext_vector_type(8))) short bf16x8;
typedef __attribute__((ext_vector_type(4))) float f32x4;

__device__ __forceinline__ float bf16_to_f32(unsigned short u){
  unsigned int v = ((unsigned int)u) << 16;
  return __uint_as_float(v);
}
__device__ __forceinline__ unsigned short f32_to_bf16(float f){
  unsigned int u = __float_as_uint(f);
  unsigned int r = (u + 0x7FFFu + ((u >> 16) & 1u)) >> 16;
  return (unsigned short)r;
}
__device__ __forceinline__ unsigned short bf16h(float a){
  __hip_bfloat16 h = __float2bfloat16(a);
  union { __hip_bfloat16 h; unsigned short u; } cv; cv.h = h; return cv.u;
}
__device__ __forceinline__ float gelu_exact(float v){
  return 0.5f * v * (1.0f + erff(v * 0.70710678118654752440f));
}

// ---------------- DPP cross-lane reduce ----------------
template<int CTRL>
__device__ __forceinline__ unsigned long long dpp64(unsigned long long k){
  int lo = (int)(unsigned int)k;
  int hi = (int)(unsigned int)(k >> 32);
  int dlo = __builtin_amdgcn_update_dpp(lo, lo, CTRL, 0xF, 0xF, false);
  int dhi = __builtin_amdgcn_update_dpp(hi, hi, CTRL, 0xF, 0xF, false);
  return (((unsigned long long)(unsigned int)dhi) << 32) | (unsigned int)dlo;
}
__device__ __forceinline__ unsigned long long bcast64(unsigned long long k, int lane){
  unsigned int lo = (unsigned int)__builtin_amdgcn_readlane((int)(unsigned int)k, lane);
  unsigned int hi = (unsigned int)__builtin_amdgcn_readlane((int)(unsigned int)(k >> 32), lane);
  return (((unsigned long long)hi) << 32) | lo;
}
__device__ __forceinline__ unsigned long long wave_max64(unsigned long long k){
  unsigned long long t;
  t = dpp64<0x111>(k); if (t > k) k = t;
  t = dpp64<0x112>(k); if (t > k) k = t;
  t = dpp64<0x114>(k); if (t > k) k = t;
  t = dpp64<0x118>(k); if (t > k) k = t;
  t = dpp64<0x142>(k); if (t > k) k = t;
  t = dpp64<0x143>(k); if (t > k) k = t;
  return bcast64(k, 63);
}
__device__ __forceinline__ unsigned long long wave_min64(unsigned long long k){
  unsigned long long t;
  t = dpp64<0x111>(k); if (t < k) k = t;
  t = dpp64<0x112>(k); if (t < k) k = t;
  t = dpp64<0x114>(k); if (t < k) k = t;
  t = dpp64<0x118>(k); if (t < k) k = t;
  t = dpp64<0x142>(k); if (t < k) k = t;
  t = dpp64<0x143>(k); if (t < k) k = t;
  return bcast64(k, 63);
}
__device__ __forceinline__ unsigned long long red8_max64(unsigned long long k){
  unsigned long long t;
  t = dpp64<0x111>(k); if (t > k) k = t;
  t = dpp64<0x112>(k); if (t > k) k = t;
  t = dpp64<0x114>(k); if (t > k) k = t;
  return bcast64(k, 7);
}
__device__ __forceinline__ unsigned long long red4_min64(unsigned long long k){
  unsigned long long t;
  t = dpp64<0x111>(k); if (t < k) k = t;
  t = dpp64<0x112>(k); if (t < k) k = t;
  return bcast64(k, 3);
}

// ---- pack helper: B frag for 16x16x32: lane holds B[k=(lane>>4)*8+j][n=lane&15] ----
__device__ __forceinline__ void packHi(const float* __restrict__ W, unsigned short* __restrict__ hi,
                                       int f, int N, int ksBits){
  int j = f & 7, lane = (f >> 3) & 63;
  int ks = (f >> 9) & ((1 << ksBits) - 1);
  int nt = f >> (9 + ksBits);
  int k = ks * 32 + ((lane >> 4) & 3) * 8 + j, c = nt * 16 + (lane & 15);
  hi[f] = f32_to_bf16(W[(size_t)k * N + c]);
}

// ---------------- FUSED prep + FPS kernel ----------------
// blocks 0..15: FPS (centers buffered in LDS; NO global store inside the
// barrier loop -- the compiler's vmcnt(0) drain before s_barrier would put
// store-retire latency on the serial critical path every iteration).
__global__ __launch_bounds__(512) void prep_fps_kernel(
    const float* __restrict__ x, float* __restrict__ centers,
    const float* __restrict__ w1, const float* __restrict__ b1,
    const float* __restrict__ g1, const float* __restrict__ bb1,
    const float* __restrict__ w3, const float* __restrict__ b3,
    const float* __restrict__ g2, const float* __restrict__ bb2,
    const float* __restrict__ enc_w2, const float* __restrict__ enc_w4,
    const float* __restrict__ qkv_w, const float* __restrict__ proj_w,
    const float* __restrict__ fc1_w, const float* __restrict__ fc2_w,
    float* __restrict__ w1f, float* __restrict__ b1f, float* __restrict__ b3f,
    unsigned short* __restrict__ w2ph, unsigned short* __restrict__ w2pl,
    unsigned short* __restrict__ w3ph, unsigned short* __restrict__ w4ph,
    unsigned short* __restrict__ qkvPh, unsigned short* __restrict__ projPh,
    unsigned short* __restrict__ fc1Ph, unsigned short* __restrict__ fc2Ph,
    unsigned short* __restrict__ w3tp)
{
  const float S = 0.99999500003749968f; // 1/sqrt(1+1e-5)
  int blk = blockIdx.x, tid = threadIdx.x;

  if (blk >= 17){
    int f = (blk - 17) * 512 + tid;
    if (f < 32768){              // w2 hi+lo (K=128,N=256,ksBits=2)
      int j = f & 7, lane = (f >> 3) & 63, ks = (f >> 9) & 3, nt = f >> 11;
      int k = ks * 32 + ((lane >> 4) & 3) * 8 + j, c = nt * 16 + (lane & 15);
      float v = enc_w2[(size_t)k * 256 + c];
      unsigned short h = f32_to_bf16(v);
      w2ph[f] = h; w2pl[f] = f32_to_bf16(v - bf16_to_f32(h));
    } else if (f < 163840){      // w3 bottom half, fold inline, ksBits=3
      f -= 32768;
      int j = f & 7, lane = (f >> 3) & 63, ks = (f >> 9) & 7, nt = f >> 12;
      int k = ks * 32 + ((lane >> 4) & 3) * 8 + j, c = nt * 16 + (lane & 15);
      w3ph[f] = f32_to_bf16(w3[(size_t)(256 + k) * 512 + c] * g2[c] * S);
    } else if (f < 294912){      // w4
      f -= 163840;
      packHi(enc_w4, w4ph, f, 256, 4);
    } else if (f < 1081344){     // qkv x4
      f -= 294912;
      int l = f / 196608, fl = f - l * 196608;
      packHi(qkv_w + (size_t)l * 196608, qkvPh + (size_t)l * 196608, fl, 768, 3);
    } else if (f < 1343488){     // proj x4
      f -= 1081344;
      int l = f >> 16, fl = f & 65535;
      packHi(proj_w + (size_t)l * 65536, projPh + (size_t)l * 65536, fl, 256, 3);
    } else if (f < 2392064){     // fc1 x4
      f -= 1343488;
      int l = f >> 18, fl = f & 262143;
      packHi(fc1_w + (size_t)l * 262144, fc1Ph + (size_t)l * 262144, fl, 1024, 3);
    } else if (f < 3440640){     // fc2 x4
      f -= 2392064;
      int l = f >> 18, fl = f & 262143;
      packHi(fc2_w + (size_t)l * 262144, fc2Ph + (size_t)l * 262144, fl, 256, 5);
    } else {                     // w3 top half, fold inline
      f -= 3440640;
      int j = f & 7, lane = (f >> 3) & 63, ks = (f >> 9) & 7, nt = f >> 12;
      int k = ks * 32 + ((lane >> 4) & 3) * 8 + j, c = nt * 16 + (lane & 15);
      w3tp[f] = f32_to_bf16(w3[(size_t)k * 512 + c] * g2[c] * S);
    }
    return;
  }
  if (blk == 16){
    if (tid < 384) w1f[tid] = w1[tid] * g1[tid & 127] * S;
    if (tid < 128) b1f[tid] = b1[tid] * g1[tid] * S + bb1[tid];
    b3f[tid] = b3[tid] * g2[tid] * S + bb2[tid];
    return;
  }

  // ---------- FPS (blocks 0..15) ----------
  int b = blk;
  const float* xb = x + (size_t)b * N_ * 3;
  int lane = tid & 63, wave = tid >> 6;
  float px[16], py[16], pz[16], dist[16];
#pragma unroll
  for (int j = 0; j < 16; j++){
    int p = tid + j * 512;
    px[j] = xb[p*3+0]; py[j] = xb[p*3+1]; pz[j] = xb[p*3+2];
    dist[j] = 1e10f;
  }
  __shared__ unsigned long long slotK[2][8];
  __shared__ float4 slotC[2][8];
  __shared__ float sCen[G_ * 3];
  float cx = xb[0], cy = xb[1], cz = xb[2];
  for (int i = 0; i < G_; i++){
    if (tid == 0){
      sCen[i*3+0] = cx; sCen[i*3+1] = cy; sCen[i*3+2] = cz;  // LDS only, no vmcnt drain
    }
    float bestv = -1.0f; int bestj = 0;
#pragma unroll
    for (int j = 0; j < 16; j++){
      float dx = __fadd_rn(px[j], -cx);
      float dy = __fadd_rn(py[j], -cy);
      float dz = __fadd_rn(pz[j], -cz);
      float d  = __fadd_rn(__fadd_rn(__fmul_rn(dx,dx), __fmul_rn(dy,dy)), __fmul_rn(dz,dz));
      float dm = fminf(dist[j], d);
      dist[j] = dm;
      if (dm > bestv){ bestv = dm; bestj = j; }
    }
    unsigned int pid = (unsigned int)(tid + bestj * 512);
    unsigned long long key = (((unsigned long long)__float_as_uint(bestv)) << 32) | (unsigned long long)(~pid);
    key = wave_max64(key);
    int par = i & 1;
    unsigned int wpid = ~(unsigned int)key;
    if (lane == (int)(wpid & 63)){
      int jj = (int)(wpid >> 9);
      float fx = px[0], fy = py[0], fz = pz[0];
#pragma unroll
      for (int j = 1; j < 16; j++) if (jj == j){ fx = px[j]; fy = py[j]; fz = pz[j]; }
      slotK[par][wave] = key;
      slotC[par][wave] = make_float4(fx, fy, fz, 0.0f);
    }
    __syncthreads();
    if (i + 1 < G_){
      int sl = lane & 7;
      unsigned long long k2 = slotK[par][sl];
      float4 cc4 = slotC[par][sl];
      k2 = red8_max64(k2);
      unsigned int gpid = ~(unsigned int)k2;
      int s = (int)((gpid & 511u) >> 6);
      cx = __uint_as_float((unsigned int)__builtin_amdgcn_readlane((int)__float_as_uint(cc4.x), s));
      cy = __uint_as_float((unsigned int)__builtin_amdgcn_readlane((int)__float_as_uint(cc4.y), s));
      cz = __uint_as_float((unsigned int)__builtin_amdgcn_readlane((int)__float_as_uint(cc4.z), s));
    }
  }
  __syncthreads();
  for (int e = tid; e < G_ * 3; e += 512)
    centers[(size_t)b * G_ * 3 + e] = sCen[e];
}

// ---------------- KNN: one block per (b,g); outputs buffered in LDS ----------------
__global__ __launch_bounds__(256) void knn_kernel(const float* __restrict__ x, const float* __restrict__ centers,
                                                  int* __restrict__ knn_idx, float* __restrict__ neigh)
{
  int blk = blockIdx.x, b = blk >> 8;
  const float* xb = x + (size_t)b * N_ * 3;
  const float* cc = centers + (size_t)blk * 3;
  int tid = threadIdx.x, lane = tid & 63, wave = tid >> 6;
  float c0 = cc[0], c1 = cc[1], c2v = cc[2];
  float c2s = __fadd_rn(__fadd_rn(__fmul_rn(c0,c0), __fmul_rn(c1,c1)), __fmul_rn(c2v,c2v));
  float d[32];
#pragma unroll
  for (int j = 0; j < 32; j++){
    int p = tid + j * 256;
    float x0 = xb[p*3+0], x1 = xb[p*3+1], x2 = xb[p*3+2];
    float xs = __fadd_rn(__fadd_rn(__fmul_rn(x0,x0), __fmul_rn(x1,x1)), __fmul_rn(x2,x2));
    float dt = __fadd_rn(__fadd_rn(__fmul_rn(c0,x0), __fmul_rn(c1,x1)), __fmul_rn(c2v,x2));
    d[j] = __fadd_rn(__fadd_rn(c2s, xs), -__fmul_rn(2.0f, dt));
  }
  const float FINF = __int_as_float(0x7F800000);
  float lmin = FINF; unsigned int lp = 0xFFFFFFFFu;
#pragma unroll
  for (int j = 0; j < 32; j++){ if (d[j] < lmin){ lmin = d[j]; lp = (unsigned int)(tid + j*256); } }
  __shared__ unsigned long long wred[2][4];
  __shared__ int sIdx[K_];
  __shared__ float sNei[K_ * 3];
  for (int r = 0; r < K_; r++){
    unsigned int u = __float_as_uint(lmin);
    u = (u & 0x80000000u) ? ~u : (u | 0x80000000u);
    unsigned long long key = (((unsigned long long)u) << 32) | (unsigned long long)lp;
    key = wave_min64(key);
    int cur = r & 1;
    if (lane == 0) wred[cur][wave] = key;
    __syncthreads();
    unsigned long long m = red4_min64(wred[cur][lane & 3]);
    unsigned int p = (unsigned int)(m & 0xFFFFFFFFull);
    if (tid == (p & 255u)){
      sIdx[r] = (int)p;
      sNei[r*3+0] = __fadd_rn(xb[p*3+0], -c0);
      sNei[r*3+1] = __fadd_rn(xb[p*3+1], -c1);
      sNei[r*3+2] = __fadd_rn(xb[p*3+2], -c2v);
      lmin = FINF; lp = 0xFFFFFFFFu;
#pragma unroll
      for (int j = 0; j < 32; j++){
        if ((unsigned int)(tid + j*256) == p) d[j] = FINF;
        if (d[j] < lmin){ lmin = d[j]; lp = (unsigned int)(tid + j*256); }
      }
    }
  }
  __syncthreads();
  if (tid < K_) knn_idx[(size_t)blk * K_ + tid] = sIdx[tid];
  if (tid < K_ * 3) neigh[(size_t)blk * K_ * 3 + tid] = sNei[tid];
}

// ---------------- fused group encoder (MFMA bf16): one block per (b,g) ----------------
__global__ __launch_bounds__(256, 2) void encoder_kernel(
    const float* __restrict__ neigh,
    const float* __restrict__ w1f, const float* __restrict__ b1f,
    const unsigned short* __restrict__ w2ph, const unsigned short* __restrict__ w2pl,
    const float* __restrict__ b2,
    const float* __restrict__ b3f,
    const unsigned short* __restrict__ w3ph, const unsigned short* __restrict__ w3tp,
    const unsigned short* __restrict__ w4ph,
    const float* __restrict__ b4,
    float* __restrict__ tokens)
{
  __shared__ __align__(16) unsigned short sH1[64 * 136];
  __shared__ __align__(16) unsigned short sH2[64 * 264];
  __shared__ __align__(16) float sShared[256];
  float (*sNeigh)[4] = (float(*)[4])sShared;
  unsigned short* sGmaxBf = (unsigned short*)sShared;

  int tid  = threadIdx.x;
  int wave = tid >> 6, lane = tid & 63, quad = lane >> 4, lrow = lane & 15;
  size_t gid = blockIdx.x;

  if (tid < 192) sNeigh[tid / 3][tid % 3] = neigh[gid * 192 + tid];
  __syncthreads();

  for (int e = tid; e < 8192; e += 256){
    int r = e >> 7, c = e & 127;
    float v = fmaf(sNeigh[r][2], w1f[256 + c], fmaf(sNeigh[r][1], w1f[128 + c], fmaf(sNeigh[r][0], w1f[c], b1f[c])));
    sH1[r * 136 + c] = bf16h(fmaxf(v, 0.0f));
  }
  __syncthreads();

  {
    f32x4 acc[4][4];
    const f32x4 z = {0.f, 0.f, 0.f, 0.f};
#pragma unroll
    for (int mt = 0; mt < 4; mt++)
#pragma unroll
      for (int nl = 0; nl < 4; nl++) acc[mt][nl] = z;
#pragma unroll
    for (int ks = 0; ks < 4; ks++){
      bf16x8 af[4];
#pragma unroll
      for (int mt = 0; mt < 4; mt++)
        af[mt] = *(const bf16x8*)&sH1[(mt*16 + lrow)*136 + ks*32 + quad*8];
#pragma unroll
      for (int nl = 0; nl < 4; nl++){
        size_t bo = (((size_t)(wave*4 + nl)*4 + ks)*64 + lane)*8;
        bf16x8 bh = *(const bf16x8*)&w2ph[bo];
        bf16x8 bl = *(const bf16x8*)&w2pl[bo];
#pragma unroll
        for (int mt = 0; mt < 4; mt++){
          acc[mt][nl] = __builtin_amdgcn_mfma_f32_16x16x32_bf16(af[mt], bh, acc[mt][nl], 0, 0, 0);
          acc[mt][nl] = __builtin_amdgcn_mfma_f32_16x16x32_bf16(af[mt], bl, acc[mt][nl], 0, 0, 0);
        }
      }
    }
#pragma unroll
    for (int nl = 0; nl < 4; nl++){
      int col = wave*64 + nl*16 + lrow;
      float bias = b2[col];
#pragma unroll
      for (int mt = 0; mt < 4; mt++)
#pragma unroll
        for (int rg = 0; rg < 4; rg++)
          sH2[(mt*16 + quad*4 + rg)*264 + col] = bf16h(acc[mt][nl][rg] + bias);
    }
  }
  __syncthreads();

  {
    float mx = -3.4e38f;
#pragma unroll 8
    for (int r = 0; r < 64; r++) mx = fmaxf(mx, bf16_to_f32(sH2[r*264 + tid]));
    sGmaxBf[tid] = bf16h(mx);
  }
  __syncthreads();

  f32x4 acc4[4][4];
  {
    const f32x4 z = {0.f, 0.f, 0.f, 0.f};
#pragma unroll
    for (int mt = 0; mt < 4; mt++)
#pragma unroll
      for (int nl = 0; nl < 4; nl++) acc4[mt][nl] = z;
  }
  for (int cc = 0; cc < 4; cc++){
    f32x4 acc3[4][2], accg[2];
    {
      const f32x4 z = {0.f, 0.f, 0.f, 0.f};
#pragma unroll
      for (int mt = 0; mt < 4; mt++){ acc3[mt][0] = z; acc3[mt][1] = z; }
      accg[0] = z; accg[1] = z;
    }
#pragma unroll
    for (int ks = 0; ks < 8; ks++){
      bf16x8 gf = *(const bf16x8*)&sGmaxBf[ks*32 + quad*8];
#pragma unroll
      for (int nl = 0; nl < 2; nl++){
        int nt = cc*8 + wave*2 + nl;
        size_t bo = (((size_t)nt*8 + ks)*64 + lane)*8;
        bf16x8 bh = *(const bf16x8*)&w3tp[bo];
        accg[nl] = __builtin_amdgcn_mfma_f32_16x16x32_bf16(gf, bh, accg[nl], 0, 0, 0);
      }
    }
#pragma unroll
    for (int ks = 0; ks < 8; ks++){
      bf16x8 af[4];
#pragma unroll
      for (int mt = 0; mt < 4; mt++)
        af[mt] = *(const bf16x8*)&sH2[(mt*16 + lrow)*264 + ks*32 + quad*8];
#pragma unroll
      for (int nl = 0; nl < 2; nl++){
        int nt = cc*8 + wave*2 + nl;
        size_t bo = (((size_t)nt*8 + ks)*64 + lane)*8;
        bf16x8 bh = *(const bf16x8*)&w3ph[bo];
#pragma unroll
        for (int mt = 0; mt < 4; mt++)
          acc3[mt][nl] = __builtin_amdgcn_mfma_f32_16x16x32_bf16(af[mt], bh, acc3[mt][nl], 0, 0, 0);
      }
    }
    __syncthreads();
#pragma unroll
    for (int nl = 0; nl < 2; nl++){
      int cl = wave*32 + nl*16 + lrow;
      int c  = cc*128 + cl;
      float bb = b3f[c];
#pragma unroll
      for (int mt = 0; mt < 4; mt++)
#pragma unroll
        for (int rg = 0; rg < 4; rg++)
          sH1[(mt*16 + quad*4 + rg)*136 + cl] = bf16h(fmaxf(acc3[mt][nl][rg] + accg[nl][rg] + bb, 0.0f));
    }
    __syncthreads();
#pragma unroll
    for (int ks = 0; ks < 4; ks++){
      bf16x8 af[4];
#pragma unroll
      for (int mt = 0; mt < 4; mt++)
        af[mt] = *(const bf16x8*)&sH1[(mt*16 + lrow)*136 + ks*32 + quad*8];
#pragma unroll
      for (int nl = 0; nl < 4; nl++){
        int nt = wave*4 + nl;
        size_t bo = (((size_t)nt*16 + cc*4 + ks)*64 + lane)*8;
        bf16x8 bh = *(const bf16x8*)&w4ph[bo];
#pragma unroll
        for (int mt = 0; mt < 4; mt++)
          acc4[mt][nl] = __builtin_amdgcn_mfma_f32_16x16x32_bf16(af[mt], bh, acc4[mt][nl], 0, 0, 0);
      }
    }
  }

#pragma unroll
  for (int nl = 0; nl < 4; nl++){
    float mx = -3.4e38f;
#pragma unroll
    for (int mt = 0; mt < 4; mt++)
#pragma unroll
      for (int rg = 0; rg < 4; rg++) mx = fmaxf(mx, acc4[mt][nl][rg]);
    mx = fmaxf(mx, __shfl_xor(mx, 16));
    mx = fmaxf(mx, __shfl_xor(mx, 32));
    if (quad == 0){
      int col = wave*64 + nl*16 + lrow;
      tokens[gid * 256 + col] = mx + b4[col];
    }
  }
}

// ---------------- pos embed + assemble + first LN (fused); LN out bf16 ----------------
__global__ __launch_bounds__(128) void pos_ln_kernel(
    const float* __restrict__ centers, const float* __restrict__ tokens,
    const float* __restrict__ cls_token, const float* __restrict__ cls_pos,
    const float* __restrict__ pw1, const float* __restrict__ pb1,
    const float* __restrict__ pw2, const float* __restrict__ pb2,
    const float* __restrict__ lng, const float* __restrict__ lnb,
    float* __restrict__ pt, float* __restrict__ xi, unsigned short* __restrict__ lnbuf)
{
  __shared__ float hS[128];
  __shared__ float red[2][2];
  int row = blockIdx.x;
  int b = row / 257, n = row - b * 257;
  int tid = threadIdx.x;
  size_t ro = (size_t)row * 256;
  float u0, u1;
  if (n == 0){
    float p0 = cls_pos[tid], p1 = cls_pos[128 + tid];
    u0 = cls_token[tid] + p0; u1 = cls_token[128 + tid] + p1;
    pt[ro + tid] = p0; pt[ro + 128 + tid] = p1;
  } else {
    int g = n - 1;
    const float* c = centers + ((size_t)b * 256 + g) * 3;
    float h = fmaf(c[2], pw1[256 + tid], fmaf(c[1], pw1[128 + tid], fmaf(c[0], pw1[tid], pb1[tid])));
    hS[tid] = gelu_exact(h);
    __syncthreads();
    const float* tok = tokens + ((size_t)b * 256 + g) * 256;
    float s0 = pb2[tid], s1 = pb2[128 + tid];
#pragma unroll 4
    for (int k = 0; k < 128; k++){
      s0 = fmaf(hS[k], pw2[(size_t)k * 256 + tid], s0);
      s1 = fmaf(hS[k], pw2[(size_t)k * 256 + 128 + tid], s1);
    }
    pt[ro + tid] = s0; pt[ro + 128 + tid] = s1;
    u0 = tok[tid] + s0; u1 = tok[128 + tid] + s1;
  }
  float s = u0 + u1, q = u0*u0 + u1*u1;
#pragma unroll
  for (int o = 32; o; o >>= 1){ s += __shfl_down(s, o); q += __shfl_down(q, o); }
  int wv = tid >> 6;
  if ((tid & 63) == 0){ red[0][wv] = s; red[1][wv] = q; }
  __syncthreads();
  float m  = (red[0][0] + red[0][1]) * (1.0f / 256.0f);
  float var = (red[1][0] + red[1][1]) * (1.0f / 256.0f) - m * m;
  float rs = 1.0f / sqrtf(var + EPS_);
  xi[ro + tid] = u0; xi[ro + 128 + tid] = u1;
  lnbuf[ro + tid] = bf16h((u0 - m) * rs * lng[tid] + lnb[tid]);
  lnbuf[ro + 128 + tid] = bf16h((u1 - m) * rs * lng[128 + tid] + lnb[128 + tid]);
}

// ---------------- MFMA GEMM: bf16 A -> bf16 C; 32-row x 128-col tiles ----------------
template<int ACT>
__global__ __launch_bounds__(256) void mfma_gemm(
    const unsigned short* __restrict__ A, const unsigned short* __restrict__ Bh,
    const float* __restrict__ bias, unsigned short* __restrict__ C, int M, int K, int N)
{
  __shared__ __align__(16) unsigned short sA[32 * 72];
  int tid = threadIdx.x;
  int wave = tid >> 6, lane = tid & 63, quad = lane >> 4, lrow = lane & 15;
  int row0 = blockIdx.x * 32;
  int col0 = blockIdx.y * 128;
  int ksTotal = K >> 5;
  f32x4 acc[2][2];
  const f32x4 z = {0.f, 0.f, 0.f, 0.f};
#pragma unroll
  for (int mt = 0; mt < 2; mt++){ acc[mt][0] = z; acc[mt][1] = z; }

  for (int k0 = 0; k0 < K; k0 += 64){
    {
      int r = tid >> 3, c8 = (tid & 7) * 8;
      int gr = row0 + r;
      bf16x8 v = {0,0,0,0,0,0,0,0};
      if (gr < M) v = *(const bf16x8*)(A + (size_t)gr * K + k0 + c8);
      *(bf16x8*)&sA[r * 72 + c8] = v;
    }
    __syncthreads();
    int ksBase = k0 >> 5;
#pragma unroll
    for (int ks = 0; ks < 2; ks++){
      bf16x8 af[2];
#pragma unroll
      for (int mt = 0; mt < 2; mt++)
        af[mt] = *(const bf16x8*)&sA[(mt*16 + lrow)*72 + ks*32 + quad*8];
#pragma unroll
      for (int nl = 0; nl < 2; nl++){
        int nt = (col0 >> 4) + wave*2 + nl;
        size_t bo = (((size_t)nt * ksTotal + ksBase + ks)*64 + lane)*8;
        bf16x8 bh = *(const bf16x8*)&Bh[bo];
#pragma unroll
        for (int mt = 0; mt < 2; mt++)
          acc[mt][nl] = __builtin_amdgcn_mfma_f32_16x16x32_bf16(af[mt], bh, acc[mt][nl], 0, 0, 0);
      }
    }
    __syncthreads();
  }
#pragma unroll
  for (int nl = 0; nl < 2; nl++){
    int c = col0 + wave*32 + nl*16 + lrow;
    float bc = bias ? bias[c] : 0.0f;
#pragma unroll
    for (int mt = 0; mt < 2; mt++)
#pragma unroll
      for (int rg = 0; rg < 4; rg++){
        int r = row0 + mt*16 + quad*4 + rg;
        if (r < M){
          float v = acc[mt][nl][rg] + bc;
          if (ACT == 1) v = gelu_exact(v);
          C[(size_t)r * N + c] = bf16h(v);
        }
      }
  }
}

// ---------------- MFMA GEMM + residual + LN epilogue; 16-row x 256-col tiles ----------------
// grid.x = M/16 (=257) -- one block per CU instead of the old 65.
__global__ __launch_bounds__(256) void mfma_gemm_ln(
    const unsigned short* __restrict__ A, const unsigned short* __restrict__ Bh,
    const float* __restrict__ bias, const float* __restrict__ res,
    const float* __restrict__ ptb,
    float* __restrict__ C, float* __restrict__ xiOut, unsigned short* __restrict__ lnOut,
    const float* __restrict__ lng, const float* __restrict__ lnb, int M, int K)
{
  __shared__ __align__(16) unsigned short sA[16 * 72];
  __shared__ float sRed[2][16][4];
  int tid = threadIdx.x;
  int wave = tid >> 6, lane = tid & 63, quad = lane >> 4, lrow = lane & 15;
  int row0 = blockIdx.x * 16;
  int ksTotal = K >> 5;
  f32x4 acc[4];
  const f32x4 z = {0.f, 0.f, 0.f, 0.f};
#pragma unroll
  for (int nl = 0; nl < 4; nl++) acc[nl] = z;

  for (int k0 = 0; k0 < K; k0 += 64){
    if (tid < 128){
      int r = tid >> 3, c8 = (tid & 7) * 8;
      int gr = row0 + r;
      bf16x8 v = {0,0,0,0,0,0,0,0};
      if (gr < M) v = *(const bf16x8*)(A + (size_t)gr * K + k0 + c8);
      *(bf16x8*)&sA[r * 72 + c8] = v;
    }
    __syncthreads();
    int ksBase = k0 >> 5;
#pragma unroll
    for (int ks = 0; ks < 2; ks++){
      bf16x8 af = *(const bf16x8*)&sA[lrow*72 + ks*32 + quad*8];
#pragma unroll
      for (int nl = 0; nl < 4; nl++){
        int nt = wave*4 + nl;
        size_t bo = (((size_t)nt * ksTotal + ksBase + ks)*64 + lane)*8;
        bf16x8 bh = *(const bf16x8*)&Bh[bo];
        acc[nl] = __builtin_amdgcn_mfma_f32_16x16x32_bf16(af, bh, acc[nl], 0, 0, 0);
      }
    }
    __syncthreads();
  }
#pragma unroll
  for (int nl = 0; nl < 4; nl++){
    int c = wave*64 + nl*16 + lrow;
    float bc = bias[c];
#pragma unroll
    for (int rg = 0; rg < 4; rg++){
      int r = row0 + quad*4 + rg;
      if (r < M){
        float v = acc[nl][rg] + bc + res[(size_t)r * 256 + c];
        if (C) C[(size_t)r * 256 + c] = v;
        float u = v;
        if (ptb) u += ptb[(size_t)r * 256 + c];
        acc[nl][rg] = u;
      }
    }
  }
#pragma unroll
  for (int rg = 0; rg < 4; rg++){
    int rloc = quad*4 + rg;
    float s = 0.0f, q = 0.0f;
#pragma unroll
    for (int nl = 0; nl < 4; nl++){ float u = acc[nl][rg]; s += u; q += u*u; }
#pragma unroll
    for (int off = 1; off < 16; off <<= 1){ s += __shfl_xor(s, off); q += __shfl_xor(q, off); }
    if (lrow == 0){ sRed[0][rloc][wave] = s; sRed[1][rloc][wave] = q; }
  }
  __syncthreads();
#pragma unroll
  for (int rg = 0; rg < 4; rg++){
    int rloc = quad*4 + rg;
    int r = row0 + rloc;
    if (r >= M) continue;
    float s = ((sRed[0][rloc][0] + sRed[0][rloc][1]) + sRed[0][rloc][2]) + sRed[0][rloc][3];
    float q = ((sRed[1][rloc][0] + sRed[1][rloc][1]) + sRed[1][rloc][2]) + sRed[1][rloc][3];
    float m  = s * (1.0f / 256.0f);
    float var = q * (1.0f / 256.0f) - m * m;
    float rs = 1.0f / sqrtf(var + EPS_);
#pragma unroll
    for (int nl = 0; nl < 4; nl++){
      int c = wave*64 + nl*16 + lrow;
      float u = acc[nl][rg];
      lnOut[(size_t)r * 256 + c] = bf16h((u - m) * rs * lng[c] + lnb[c]);
      if (xiOut) xiOut[(size_t)r * 256 + c] = u;
    }
  }
}

// ---------------- attention: bf16 in/out, flash-style, k-split x4 ----------------
__global__ __launch_bounds__(256) void attn_kernel(const unsigned short* __restrict__ qkv, unsigned short* __restrict__ obuf)
{
  int bh = blockIdx.x;
  int b = bh >> 3, h = bh & 7;
  int tid = threadIdx.x;
  int qi = tid >> 2, kp = tid & 3;
  int qrow = blockIdx.y * 64 + qi;
  bool act = qrow < 257;
  __shared__ float kS[128][33];
  __shared__ float vS[128][33];
  const unsigned short* qb = qkv + (size_t)b * 257 * 768;
  float q[32], o[32];
  float mrun = -3.4e38f, l = 0.0f;
  if (act){
    const unsigned short* qr = qb + (size_t)qrow * 768 + h * 32;
#pragma unroll
    for (int j = 0; j < 32; j++){ q[j] = bf16_to_f32(qr[j]); o[j] = 0.0f; }
  }
  const float scale = 0.17677669529663687f;
  for (int m0 = 0; m0 < 257; m0 += 128){
    int cnt = min(128, 257 - m0);
    for (int e = tid; e < cnt * 32; e += 256){
      int mm = e >> 5, j = e & 31;
      const unsigned short* rowp = qb + (size_t)(m0 + mm) * 768 + h * 32;
      kS[mm][j] = bf16_to_f32(rowp[256 + j]);
      vS[mm][j] = bf16_to_f32(rowp[512 + j]);
    }
    __syncthreads();
    if (act){
      for (int mm = kp; mm < cnt; mm += 4){
        float s = 0.0f;
#pragma unroll
        for (int j = 0; j < 32; j++) s = fmaf(q[j], kS[mm][j], s);
        s *= scale;
        float nm = fmaxf(mrun, s);
        float alpha = expf(mrun - nm);
        float p = expf(s - nm);
        l = fmaf(l, alpha, p);
#pragma unroll
        for (int j = 0; j < 32; j++) o[j] = fmaf(p, vS[mm][j], o[j] * alpha);
        mrun = nm;
      }
    }
    __syncthreads();
  }
  if (act){
#pragma unroll
    for (int msk = 1; msk <= 2; msk <<= 1){
      float m2 = __shfl_xor(mrun, msk);
      float l2 = __shfl_xor(l, msk);
      float nm = fmaxf(mrun, m2);
      float a1 = expf(mrun - nm), a2 = expf(m2 - nm);
      l = l * a1 + l2 * a2;
#pragma unroll
      for (int j = 0; j < 32; j++){
        float o2 = __shfl_xor(o[j], msk);
        o[j] = o[j] * a1 + o2 * a2;
      }
      mrun = nm;
    }
    if (kp == 0){
      float inv = 1.0f / l;
      unsigned short* orow = obuf + (size_t)(b * 257 + qrow) * 256 + h * 32;
#pragma unroll
      for (int j = 0; j < 32; j++) orow[j] = bf16h(o[j] * inv);
    }
  }
}

// ---------------- head MLP + scatter: one block per (b,g); gfeat bf16 ----------------
__global__ __launch_bounds__(256) void head_kernel(
    const unsigned short* __restrict__ gfeat, const float* __restrict__ neigh, const int* __restrict__ knn_idx,
    const float* __restrict__ w1, const float* __restrict__ b1,
    const float* __restrict__ w2, const float* __restrict__ b2,
    float* __restrict__ sums, float* __restrict__ cnts)
{
  int blk = blockIdx.x, b = blk >> 8;
  __shared__ float xS[256];
  __shared__ float nS[64][4];
  __shared__ float partH[2][128];
  __shared__ float sharedH[128];
  __shared__ float w2S[128];
  __shared__ float wtail[3][128];
  int tid = threadIdx.x;
  xS[tid] = bf16_to_f32(gfeat[((size_t)b * 257 + 1 + (blk & 255)) * 256 + tid]);
  if (tid < 192) nS[tid / 3][tid % 3] = neigh[(size_t)blk * 192 + tid];
  if (tid < 128){
    w2S[tid] = w2[tid];
    wtail[0][tid] = w1[256 * 128 + tid];
    wtail[1][tid] = w1[257 * 128 + tid];
    wtail[2][tid] = w1[258 * 128 + tid];
  }
  __syncthreads();
  {
    int half = tid >> 7, j = tid & 127;
    float s = 0.0f;
#pragma unroll 8
    for (int k = 0; k < 128; k++) s = fmaf(xS[half * 128 + k], w1[(size_t)(half * 128 + k) * 128 + j], s);
    partH[half][j] = s;
  }
  __syncthreads();
  if (tid < 128) sharedH[tid] = partH[0][tid] + partH[1][tid] + b1[tid];
  __syncthreads();
  int r = tid >> 2, q = tid & 3;
  float n0 = nS[r][0], n1 = nS[r][1], n2 = nS[r][2];
  float s = 0.0f;
#pragma unroll
  for (int j0 = 0; j0 < 32; j0++){
    int j = q * 32 + j0;
    float h = fmaf(n2, wtail[2][j], fmaf(n1, wtail[1][j], fmaf(n0, wtail[0][j], sharedH[j])));
    s = fmaf(fmaxf(h, 0.0f), w2S[j], s);
  }
  s += __shfl_xor(s, 1);
  s += __shfl_xor(s, 2);
  if (q == 0){
    float lg = s + b2[0];
    int p = knn_idx[(size_t)blk * K_ + r];
    atomicAdd(&sums[(size_t)b * N_ + p], lg);
    atomicAdd(&cnts[(size_t)b * N_ + p], 1.0f);
  }
}

__global__ void finalize_kernel(const float* __restrict__ sums, const float* __restrict__ cnts, float* __restrict__ out)
{
  int i = blockIdx.x * 256 + threadIdx.x;
  out[i] = sums[i] / fmaxf(cnts[i], 1.0f);
}

extern "C" void kernel_launch(void* const* d_in, const int* in_sizes, int n_in,
                              void* d_out, int out_size, void* d_ws, size_t ws_size,
                              hipStream_t stream)
{
  (void)in_sizes; (void)n_in; (void)out_size; (void)ws_size;
  const float* x        = (const float*)d_in[0];
  const float* enc_w1   = (const float*)d_in[1];
  const float* enc_b1   = (const float*)d_in[2];
  const float* enc_bn1g = (const float*)d_in[3];
  const float* enc_bn1b = (const float*)d_in[4];
  const float* enc_w2   = (const float*)d_in[5];
  const float* enc_b2   = (const float*)d_in[6];
  const float* enc_w3   = (const float*)d_in[7];
  const float* enc_b3   = (const float*)d_in[8];
  const float* enc_bn2g = (const float*)d_in[9];
  const float* enc_bn2b = (const float*)d_in[10];
  const float* enc_w4   = (const float*)d_in[11];
  const float* enc_b4   = (const float*)d_in[12];
  const float* cls_tok  = (const float*)d_in[13];
  const float* cls_pos  = (const float*)d_in[14];
  const float* pos_w1   = (const float*)d_in[15];
  const float* pos_b1   = (const float*)d_in[16];
  const float* pos_w2   = (const float*)d_in[17];
  const float* pos_b2   = (const float*)d_in[18];
  const float* ln1_g    = (const float*)d_in[19];
  const float* ln1_b    = (const float*)d_in[20];
  const float* qkv_w    = (const float*)d_in[21];
  const float* proj_w   = (const float*)d_in[22];
  const float* proj_b   = (const float*)d_in[23];
  const float* ln2_g    = (const float*)d_in[24];
  const float* ln2_b    = (const float*)d_in[25];
  const float* fc1_w    = (const float*)d_in[26];
  const float* fc1_b    = (const float*)d_in[27];
  const float* fc2_w    = (const float*)d_in[28];
  const float* fc2_b    = (const float*)d_in[29];
  const float* norm_g   = (const float*)d_in[30];
  const float* norm_b   = (const float*)d_in[31];
  const float* head_w1  = (const float*)d_in[32];
  const float* head_b1  = (const float*)d_in[33];
  const float* head_w2  = (const float*)d_in[34];
  const float* head_b2  = (const float*)d_in[35];

  float* ws = (float*)d_ws;
  size_t off = 0;
  auto alloc = [&](size_t n)->float*{ float* p = ws + off; off += (n + 63) & ~(size_t)63; return p; };

  float* centers = alloc((size_t)B_ * G_ * 3);
  float* w1f     = alloc(384);
  float* b1f     = alloc(128);
  float* b3f     = alloc(512);
  unsigned short* w2ph = (unsigned short*)alloc(16384);
  unsigned short* w2pl = (unsigned short*)alloc(16384);
  unsigned short* w3ph = (unsigned short*)alloc(65536);
  unsigned short* w3tp = (unsigned short*)alloc(65536);
  unsigned short* w4ph = (unsigned short*)alloc(65536);
  unsigned short* qkvPh = (unsigned short*)alloc(393216);
  unsigned short* projPh = (unsigned short*)alloc(131072);
  unsigned short* fc1Ph = (unsigned short*)alloc(524288);
  unsigned short* fc2Ph = (unsigned short*)alloc(524288);
  float* tokens  = alloc((size_t)B_ * G_ * D_);
  float* neigh   = alloc((size_t)B_ * G_ * K_ * 3);
  int*   knn_idx = (int*)alloc((size_t)B_ * G_ * K_);
  float* pt      = alloc((size_t)B_ * 257 * D_);
  float* xi      = alloc((size_t)B_ * 257 * D_);
  unsigned short* lnbufB = (unsigned short*)alloc((size_t)B_ * 257 * D_ / 2 + 64);
  unsigned short* obufB  = (unsigned short*)alloc((size_t)B_ * 257 * D_ / 2 + 64);
  unsigned short* bigbufB= (unsigned short*)alloc((size_t)B_ * 257 * HID_ / 2 + 64);
  unsigned short* gfeatB = (unsigned short*)alloc((size_t)B_ * 257 * D_ / 2 + 64);
  float* sums    = alloc((size_t)B_ * N_);
  float* cnts    = alloc((size_t)B_ * N_);

  hipMemsetAsync(sums, 0, (size_t)2 * B_ * N_ * sizeof(float), stream);

  prep_fps_kernel<<<6993, 512, 0, stream>>>(x, centers,
      enc_w1, enc_b1, enc_bn1g, enc_bn1b, enc_w3, enc_b3, enc_bn2g, enc_bn2b,
      enc_w2, enc_w4, qkv_w, proj_w, fc1_w, fc2_w,
      w1f, b1f, b3f, w2ph, w2pl, w3ph, w4ph, qkvPh, projPh, fc1Ph, fc2Ph, w3tp);

  knn_kernel<<<B_ * G_, 256, 0, stream>>>(x, centers, knn_idx, neigh);
  encoder_kernel<<<B_ * G_, 256, 0, stream>>>(neigh, w1f, b1f, w2ph, w2pl, enc_b2,
                                              b3f, w3ph, w3tp, w4ph, enc_b4, tokens);
  pos_ln_kernel<<<B_ * 257, 128, 0, stream>>>(centers, tokens, cls_tok, cls_pos,
                                              pos_w1, pos_b1, pos_w2, pos_b2,
                                              ln1_g, ln1_b, pt, xi, lnbufB);
  const int M = B_ * 257; // 4112
  for (int l = 0; l < 4; l++){
    mfma_gemm<0><<<dim3(129, 6), 256, 0, stream>>>(lnbufB, qkvPh + (size_t)l*196608, nullptr, bigbufB, M, 256, 768);
    attn_kernel<<<dim3(B_ * 8, 5), 256, 0, stream>>>(bigbufB, obufB);
    mfma_gemm_ln<<<257, 256, 0, stream>>>(obufB, projPh + (size_t)l*65536, proj_b + l*256, xi, nullptr,
                                          xi, nullptr, lnbufB, ln2_g + l*256, ln2_b + l*256, M, 256);
    mfma_gemm<1><<<dim3(129, 8), 256, 0, stream>>>(lnbufB, fc1Ph + (size_t)l*262144, fc1_b + l*1024, bigbufB, M, 256, 1024);
    if (l < 3){
      mfma_gemm_ln<<<257, 256, 0, stream>>>(bigbufB, fc2Ph + (size_t)l*262144, fc2_b + l*256, xi, pt,
                                            nullptr, xi, lnbufB, ln1_g + (l+1)*256, ln1_b + (l+1)*256, M, 1024);
    } else {
      mfma_gemm_ln<<<257, 256, 0, stream>>>(bigbufB, fc2Ph + (size_t)l*262144, fc2_b + l*256, xi, nullptr,
                                            nullptr, nullptr, gfeatB, norm_g, norm_b, M, 1024);
    }
  }
  head_kernel<<<B_ * G_, 256, 0, stream>>>(gfeatB, neigh, knn_idx, head_w1, head_b1, head_w2, head_b2, sums, cnts);
  finalize_kernel<<<(B_ * N_) / 256, 256, 0, stream>>>(sums, cnts, (float*)d_out);
}

// Round 10
// 1583.600 us; speedup vs baseline: 1.7704x; 1.0417x over previous
//
#include <hip/hip_runtime.h>
#include <hip/hip_bf16.h>

#define B_ 16
#define N_ 8192
#define G_ 256
#define K_ 64
#define D_ 256
#define HID_ 1024
#define EPS_ 1e-5f

typedef __attribute__((ext_vector_type(8))) short bf16x8;
typedef __attribute__((ext_vector_type(4))) float f32x4;

__device__ __forceinline__ float bf16_to_f32(unsigned short u){
  unsigned int v = ((unsigned int)u) << 16;
  return __uint_as_float(v);
}
__device__ __forceinline__ unsigned short f32_to_bf16(float f){
  unsigned int u = __float_as_uint(f);
  unsigned int r = (u + 0x7FFFu + ((u >> 16) & 1u)) >> 16;
  return (unsigned short)r;
}
__device__ __forceinline__ unsigned short bf16h(float a){
  __hip_bfloat16 h = __float2bfloat16(a);
  union { __hip_bfloat16 h; unsigned short u; } cv; cv.h = h; return cv.u;
}
__device__ __forceinline__ float gelu_exact(float v){
  return 0.5f * v * (1.0f + erff(v * 0.70710678118654752440f));
}

// ---------------- DPP cross-lane reduce ----------------
template<int CTRL>
__device__ __forceinline__ unsigned long long dpp64(unsigned long long k){
  int lo = (int)(unsigned int)k;
  int hi = (int)(unsigned int)(k >> 32);
  int dlo = __builtin_amdgcn_update_dpp(lo, lo, CTRL, 0xF, 0xF, false);
  int dhi = __builtin_amdgcn_update_dpp(hi, hi, CTRL, 0xF, 0xF, false);
  return (((unsigned long long)(unsigned int)dhi) << 32) | (unsigned int)dlo;
}
__device__ __forceinline__ unsigned long long bcast64(unsigned long long k, int lane){
  unsigned int lo = (unsigned int)__builtin_amdgcn_readlane((int)(unsigned int)k, lane);
  unsigned int hi = (unsigned int)__builtin_amdgcn_readlane((int)(unsigned int)(k >> 32), lane);
  return (((unsigned long long)hi) << 32) | lo;
}
__device__ __forceinline__ unsigned long long wave_max64(unsigned long long k){
  unsigned long long t;
  t = dpp64<0x111>(k); if (t > k) k = t;
  t = dpp64<0x112>(k); if (t > k) k = t;
  t = dpp64<0x114>(k); if (t > k) k = t;
  t = dpp64<0x118>(k); if (t > k) k = t;
  t = dpp64<0x142>(k); if (t > k) k = t;
  t = dpp64<0x143>(k); if (t > k) k = t;
  return bcast64(k, 63);
}
__device__ __forceinline__ unsigned long long wave_min64(unsigned long long k){
  unsigned long long t;
  t = dpp64<0x111>(k); if (t < k) k = t;
  t = dpp64<0x112>(k); if (t < k) k = t;
  t = dpp64<0x114>(k); if (t < k) k = t;
  t = dpp64<0x118>(k); if (t < k) k = t;
  t = dpp64<0x142>(k); if (t < k) k = t;
  t = dpp64<0x143>(k); if (t < k) k = t;
  return bcast64(k, 63);
}
__device__ __forceinline__ unsigned long long red8_max64(unsigned long long k){
  unsigned long long t;
  t = dpp64<0x111>(k); if (t > k) k = t;
  t = dpp64<0x112>(k); if (t > k) k = t;
  t = dpp64<0x114>(k); if (t > k) k = t;
  return bcast64(k, 7);
}
__device__ __forceinline__ unsigned long long red4_min64(unsigned long long k){
  unsigned long long t;
  t = dpp64<0x111>(k); if (t < k) k = t;
  t = dpp64<0x112>(k); if (t < k) k = t;
  return bcast64(k, 3);
}

// ---- pack helper: B frag for 16x16x32: lane holds B[k=(lane>>4)*8+j][n=lane&15] ----
__device__ __forceinline__ void packHi(const float* __restrict__ W, unsigned short* __restrict__ hi,
                                       int f, int N, int ksBits){
  int j = f & 7, lane = (f >> 3) & 63;
  int ks = (f >> 9) & ((1 << ksBits) - 1);
  int nt = f >> (9 + ksBits);
  int k = ks * 32 + ((lane >> 4) & 3) * 8 + j, c = nt * 16 + (lane & 15);
  hi[f] = f32_to_bf16(W[(size_t)k * N + c]);
}

// ---------------- FUSED prep + FPS kernel ----------------
// min-waves=2 (VGPR cap 256): the default heuristic caps 512-thr kernels at
// 64 VGPR, which SPILLS px/py/pz/dist[16] (64 floats/thread) to scratch --
// that spill was the invisible ~3400cyc/iter floor in R5-R9 (L2 traffic,
// not in FETCH_SIZE).
__global__ __launch_bounds__(512, 2) void prep_fps_kernel(
    const float* __restrict__ x, float* __restrict__ centers,
    const float* __restrict__ w1, const float* __restrict__ b1,
    const float* __restrict__ g1, const float* __restrict__ bb1,
    const float* __restrict__ w3, const float* __restrict__ b3,
    const float* __restrict__ g2, const float* __restrict__ bb2,
    const float* __restrict__ enc_w2, const float* __restrict__ enc_w4,
    const float* __restrict__ qkv_w, const float* __restrict__ proj_w,
    const float* __restrict__ fc1_w, const float* __restrict__ fc2_w,
    float* __restrict__ w1f, float* __restrict__ b1f, float* __restrict__ b3f,
    unsigned short* __restrict__ w2ph, unsigned short* __restrict__ w2pl,
    unsigned short* __restrict__ w3ph, unsigned short* __restrict__ w4ph,
    unsigned short* __restrict__ qkvPh, unsigned short* __restrict__ projPh,
    unsigned short* __restrict__ fc1Ph, unsigned short* __restrict__ fc2Ph,
    unsigned short* __restrict__ w3tp)
{
  const float S = 0.99999500003749968f; // 1/sqrt(1+1e-5)
  int blk = blockIdx.x, tid = threadIdx.x;

  if (blk >= 17){
    int f = (blk - 17) * 512 + tid;
    if (f < 32768){              // w2 hi+lo (K=128,N=256,ksBits=2)
      int j = f & 7, lane = (f >> 3) & 63, ks = (f >> 9) & 3, nt = f >> 11;
      int k = ks * 32 + ((lane >> 4) & 3) * 8 + j, c = nt * 16 + (lane & 15);
      float v = enc_w2[(size_t)k * 256 + c];
      unsigned short h = f32_to_bf16(v);
      w2ph[f] = h; w2pl[f] = f32_to_bf16(v - bf16_to_f32(h));
    } else if (f < 163840){      // w3 bottom half, fold inline, ksBits=3
      f -= 32768;
      int j = f & 7, lane = (f >> 3) & 63, ks = (f >> 9) & 7, nt = f >> 12;
      int k = ks * 32 + ((lane >> 4) & 3) * 8 + j, c = nt * 16 + (lane & 15);
      w3ph[f] = f32_to_bf16(w3[(size_t)(256 + k) * 512 + c] * g2[c] * S);
    } else if (f < 294912){      // w4
      f -= 163840;
      packHi(enc_w4, w4ph, f, 256, 4);
    } else if (f < 1081344){     // qkv x4
      f -= 294912;
      int l = f / 196608, fl = f - l * 196608;
      packHi(qkv_w + (size_t)l * 196608, qkvPh + (size_t)l * 196608, fl, 768, 3);
    } else if (f < 1343488){     // proj x4
      f -= 1081344;
      int l = f >> 16, fl = f & 65535;
      packHi(proj_w + (size_t)l * 65536, projPh + (size_t)l * 65536, fl, 256, 3);
    } else if (f < 2392064){     // fc1 x4
      f -= 1343488;
      int l = f >> 18, fl = f & 262143;
      packHi(fc1_w + (size_t)l * 262144, fc1Ph + (size_t)l * 262144, fl, 1024, 3);
    } else if (f < 3440640){     // fc2 x4
      f -= 2392064;
      int l = f >> 18, fl = f & 262143;
      packHi(fc2_w + (size_t)l * 262144, fc2Ph + (size_t)l * 262144, fl, 256, 5);
    } else {                     // w3 top half, fold inline
      f -= 3440640;
      int j = f & 7, lane = (f >> 3) & 63, ks = (f >> 9) & 7, nt = f >> 12;
      int k = ks * 32 + ((lane >> 4) & 3) * 8 + j, c = nt * 16 + (lane & 15);
      w3tp[f] = f32_to_bf16(w3[(size_t)k * 512 + c] * g2[c] * S);
    }
    return;
  }
  if (blk == 16){
    if (tid < 384) w1f[tid] = w1[tid] * g1[tid & 127] * S;
    if (tid < 128) b1f[tid] = b1[tid] * g1[tid] * S + bb1[tid];
    b3f[tid] = b3[tid] * g2[tid] * S + bb2[tid];
    return;
  }

  // ---------- FPS (blocks 0..15) ----------
  int b = blk;
  const float* xb = x + (size_t)b * N_ * 3;
  int lane = tid & 63, wave = tid >> 6;
  float px[16], py[16], pz[16], dist[16];
#pragma unroll
  for (int j = 0; j < 16; j++){
    int p = tid + j * 512;
    px[j] = xb[p*3+0]; py[j] = xb[p*3+1]; pz[j] = xb[p*3+2];
    dist[j] = 1e10f;
  }
  __shared__ unsigned long long slotK[2][8];
  __shared__ float4 slotC[2][8];
  __shared__ float sCen[G_ * 3];
  float cx = xb[0], cy = xb[1], cz = xb[2];
  for (int i = 0; i < G_; i++){
    if (tid == 0){
      sCen[i*3+0] = cx; sCen[i*3+1] = cy; sCen[i*3+2] = cz;
    }
    float bestv = -1.0f; int bestj = 0;
#pragma unroll
    for (int j = 0; j < 16; j++){
      float dx = __fadd_rn(px[j], -cx);
      float dy = __fadd_rn(py[j], -cy);
      float dz = __fadd_rn(pz[j], -cz);
      float d  = __fadd_rn(__fadd_rn(__fmul_rn(dx,dx), __fmul_rn(dy,dy)), __fmul_rn(dz,dz));
      float dm = fminf(dist[j], d);
      dist[j] = dm;
      if (dm > bestv){ bestv = dm; bestj = j; }
    }
    unsigned int pid = (unsigned int)(tid + bestj * 512);
    unsigned long long key = (((unsigned long long)__float_as_uint(bestv)) << 32) | (unsigned long long)(~pid);
    key = wave_max64(key);
    int par = i & 1;
    unsigned int wpid = ~(unsigned int)key;
    if (lane == (int)(wpid & 63)){
      int jj = (int)(wpid >> 9);
      float fx = px[0], fy = py[0], fz = pz[0];
#pragma unroll
      for (int j = 1; j < 16; j++) if (jj == j){ fx = px[j]; fy = py[j]; fz = pz[j]; }
      slotK[par][wave] = key;
      slotC[par][wave] = make_float4(fx, fy, fz, 0.0f);
    }
    __syncthreads();
    if (i + 1 < G_){
      int sl = lane & 7;
      unsigned long long k2 = slotK[par][sl];
      float4 cc4 = slotC[par][sl];
      k2 = red8_max64(k2);
      unsigned int gpid = ~(unsigned int)k2;
      int s = (int)((gpid & 511u) >> 6);
      cx = __uint_as_float((unsigned int)__builtin_amdgcn_readlane((int)__float_as_uint(cc4.x), s));
      cy = __uint_as_float((unsigned int)__builtin_amdgcn_readlane((int)__float_as_uint(cc4.y), s));
      cz = __uint_as_float((unsigned int)__builtin_amdgcn_readlane((int)__float_as_uint(cc4.z), s));
    }
  }
  __syncthreads();
  for (int e = tid; e < G_ * 3; e += 512)
    centers[(size_t)b * G_ * 3 + e] = sCen[e];
}

// ---------------- KNN: one block per (b,g); min-waves=4 (VGPR cap 128, no d[32] spill) ----
__global__ __launch_bounds__(256, 4) void knn_kernel(const float* __restrict__ x, const float* __restrict__ centers,
                                                     int* __restrict__ knn_idx, float* __restrict__ neigh)
{
  int blk = blockIdx.x, b = blk >> 8;
  const float* xb = x + (size_t)b * N_ * 3;
  const float* cc = centers + (size_t)blk * 3;
  int tid = threadIdx.x, lane = tid & 63, wave = tid >> 6;
  float c0 = cc[0], c1 = cc[1], c2v = cc[2];
  float c2s = __fadd_rn(__fadd_rn(__fmul_rn(c0,c0), __fmul_rn(c1,c1)), __fmul_rn(c2v,c2v));
  float d[32];
#pragma unroll
  for (int j = 0; j < 32; j++){
    int p = tid + j * 256;
    float x0 = xb[p*3+0], x1 = xb[p*3+1], x2 = xb[p*3+2];
    float xs = __fadd_rn(__fadd_rn(__fmul_rn(x0,x0), __fmul_rn(x1,x1)), __fmul_rn(x2,x2));
    float dt = __fadd_rn(__fadd_rn(__fmul_rn(c0,x0), __fmul_rn(c1,x1)), __fmul_rn(c2v,x2));
    d[j] = __fadd_rn(__fadd_rn(c2s, xs), -__fmul_rn(2.0f, dt));
  }
  const float FINF = __int_as_float(0x7F800000);
  float lmin = FINF; unsigned int lp = 0xFFFFFFFFu;
#pragma unroll
  for (int j = 0; j < 32; j++){ if (d[j] < lmin){ lmin = d[j]; lp = (unsigned int)(tid + j*256); } }
  __shared__ unsigned long long wred[2][4];
  __shared__ int sIdx[K_];
  __shared__ float sNei[K_ * 3];
  for (int r = 0; r < K_; r++){
    unsigned int u = __float_as_uint(lmin);
    u = (u & 0x80000000u) ? ~u : (u | 0x80000000u);
    unsigned long long key = (((unsigned long long)u) << 32) | (unsigned long long)lp;
    key = wave_min64(key);
    int cur = r & 1;
    if (lane == 0) wred[cur][wave] = key;
    __syncthreads();
    unsigned long long m = red4_min64(wred[cur][lane & 3]);
    unsigned int p = (unsigned int)(m & 0xFFFFFFFFull);
    if (tid == (p & 255u)){
      sIdx[r] = (int)p;
      sNei[r*3+0] = __fadd_rn(xb[p*3+0], -c0);
      sNei[r*3+1] = __fadd_rn(xb[p*3+1], -c1);
      sNei[r*3+2] = __fadd_rn(xb[p*3+2], -c2v);
      lmin = FINF; lp = 0xFFFFFFFFu;
#pragma unroll
      for (int j = 0; j < 32; j++){
        if ((unsigned int)(tid + j*256) == p) d[j] = FINF;
        if (d[j] < lmin){ lmin = d[j]; lp = (unsigned int)(tid + j*256); }
      }
    }
  }
  __syncthreads();
  if (tid < K_) knn_idx[(size_t)blk * K_ + tid] = sIdx[tid];
  if (tid < K_ * 3) neigh[(size_t)blk * K_ * 3 + tid] = sNei[tid];
}

// ---------------- fused group encoder (MFMA bf16): one block per (b,g) ----------------
__global__ __launch_bounds__(256, 2) void encoder_kernel(
    const float* __restrict__ neigh,
    const float* __restrict__ w1f, const float* __restrict__ b1f,
    const unsigned short* __restrict__ w2ph, const unsigned short* __restrict__ w2pl,
    const float* __restrict__ b2,
    const float* __restrict__ b3f,
    const unsigned short* __restrict__ w3ph, const unsigned short* __restrict__ w3tp,
    const unsigned short* __restrict__ w4ph,
    const float* __restrict__ b4,
    float* __restrict__ tokens)
{
  __shared__ __align__(16) unsigned short sH1[64 * 136];
  __shared__ __align__(16) unsigned short sH2[64 * 264];
  __shared__ __align__(16) float sShared[256];
  float (*sNeigh)[4] = (float(*)[4])sShared;
  unsigned short* sGmaxBf = (unsigned short*)sShared;

  int tid  = threadIdx.x;
  int wave = tid >> 6, lane = tid & 63, quad = lane >> 4, lrow = lane & 15;
  size_t gid = blockIdx.x;

  if (tid < 192) sNeigh[tid / 3][tid % 3] = neigh[gid * 192 + tid];
  __syncthreads();

  for (int e = tid; e < 8192; e += 256){
    int r = e >> 7, c = e & 127;
    float v = fmaf(sNeigh[r][2], w1f[256 + c], fmaf(sNeigh[r][1], w1f[128 + c], fmaf(sNeigh[r][0], w1f[c], b1f[c])));
    sH1[r * 136 + c] = bf16h(fmaxf(v, 0.0f));
  }
  __syncthreads();

  {
    f32x4 acc[4][4];
    const f32x4 z = {0.f, 0.f, 0.f, 0.f};
#pragma unroll
    for (int mt = 0; mt < 4; mt++)
#pragma unroll
      for (int nl = 0; nl < 4; nl++) acc[mt][nl] = z;
#pragma unroll
    for (int ks = 0; ks < 4; ks++){
      bf16x8 af[4];
#pragma unroll
      for (int mt = 0; mt < 4; mt++)
        af[mt] = *(const bf16x8*)&sH1[(mt*16 + lrow)*136 + ks*32 + quad*8];
#pragma unroll
      for (int nl = 0; nl < 4; nl++){
        size_t bo = (((size_t)(wave*4 + nl)*4 + ks)*64 + lane)*8;
        bf16x8 bh = *(const bf16x8*)&w2ph[bo];
        bf16x8 bl = *(const bf16x8*)&w2pl[bo];
#pragma unroll
        for (int mt = 0; mt < 4; mt++){
          acc[mt][nl] = __builtin_amdgcn_mfma_f32_16x16x32_bf16(af[mt], bh, acc[mt][nl], 0, 0, 0);
          acc[mt][nl] = __builtin_amdgcn_mfma_f32_16x16x32_bf16(af[mt], bl, acc[mt][nl], 0, 0, 0);
        }
      }
    }
#pragma unroll
    for (int nl = 0; nl < 4; nl++){
      int col = wave*64 + nl*16 + lrow;
      float bias = b2[col];
#pragma unroll
      for (int mt = 0; mt < 4; mt++)
#pragma unroll
        for (int rg = 0; rg < 4; rg++)
          sH2[(mt*16 + quad*4 + rg)*264 + col] = bf16h(acc[mt][nl][rg] + bias);
    }
  }
  __syncthreads();

  {
    float mx = -3.4e38f;
#pragma unroll 8
    for (int r = 0; r < 64; r++) mx = fmaxf(mx, bf16_to_f32(sH2[r*264 + tid]));
    sGmaxBf[tid] = bf16h(mx);
  }
  __syncthreads();

  f32x4 acc4[4][4];
  {
    const f32x4 z = {0.f, 0.f, 0.f, 0.f};
#pragma unroll
    for (int mt = 0; mt < 4; mt++)
#pragma unroll
      for (int nl = 0; nl < 4; nl++) acc4[mt][nl] = z;
  }
  for (int cc = 0; cc < 4; cc++){
    f32x4 acc3[4][2], accg[2];
    {
      const f32x4 z = {0.f, 0.f, 0.f, 0.f};
#pragma unroll
      for (int mt = 0; mt < 4; mt++){ acc3[mt][0] = z; acc3[mt][1] = z; }
      accg[0] = z; accg[1] = z;
    }
#pragma unroll
    for (int ks = 0; ks < 8; ks++){
      bf16x8 gf = *(const bf16x8*)&sGmaxBf[ks*32 + quad*8];
#pragma unroll
      for (int nl = 0; nl < 2; nl++){
        int nt = cc*8 + wave*2 + nl;
        size_t bo = (((size_t)nt*8 + ks)*64 + lane)*8;
        bf16x8 bh = *(const bf16x8*)&w3tp[bo];
        accg[nl] = __builtin_amdgcn_mfma_f32_16x16x32_bf16(gf, bh, accg[nl], 0, 0, 0);
      }
    }
#pragma unroll
    for (int ks = 0; ks < 8; ks++){
      bf16x8 af[4];
#pragma unroll
      for (int mt = 0; mt < 4; mt++)
        af[mt] = *(const bf16x8*)&sH2[(mt*16 + lrow)*264 + ks*32 + quad*8];
#pragma unroll
      for (int nl = 0; nl < 2; nl++){
        int nt = cc*8 + wave*2 + nl;
        size_t bo = (((size_t)nt*8 + ks)*64 + lane)*8;
        bf16x8 bh = *(const bf16x8*)&w3ph[bo];
#pragma unroll
        for (int mt = 0; mt < 4; mt++)
          acc3[mt][nl] = __builtin_amdgcn_mfma_f32_16x16x32_bf16(af[mt], bh, acc3[mt][nl], 0, 0, 0);
      }
    }
    __syncthreads();
#pragma unroll
    for (int nl = 0; nl < 2; nl++){
      int cl = wave*32 + nl*16 + lrow;
      int c  = cc*128 + cl;
      float bb = b3f[c];
#pragma unroll
      for (int mt = 0; mt < 4; mt++)
#pragma unroll
        for (int rg = 0; rg < 4; rg++)
          sH1[(mt*16 + quad*4 + rg)*136 + cl] = bf16h(fmaxf(acc3[mt][nl][rg] + accg[nl][rg] + bb, 0.0f));
    }
    __syncthreads();
#pragma unroll
    for (int ks = 0; ks < 4; ks++){
      bf16x8 af[4];
#pragma unroll
      for (int mt = 0; mt < 4; mt++)
        af[mt] = *(const bf16x8*)&sH1[(mt*16 + lrow)*136 + ks*32 + quad*8];
#pragma unroll
      for (int nl = 0; nl < 4; nl++){
        int nt = wave*4 + nl;
        size_t bo = (((size_t)nt*16 + cc*4 + ks)*64 + lane)*8;
        bf16x8 bh = *(const bf16x8*)&w4ph[bo];
#pragma unroll
        for (int mt = 0; mt < 4; mt++)
          acc4[mt][nl] = __builtin_amdgcn_mfma_f32_16x16x32_bf16(af[mt], bh, acc4[mt][nl], 0, 0, 0);
      }
    }
  }

#pragma unroll
  for (int nl = 0; nl < 4; nl++){
    float mx = -3.4e38f;
#pragma unroll
    for (int mt = 0; mt < 4; mt++)
#pragma unroll
      for (int rg = 0; rg < 4; rg++) mx = fmaxf(mx, acc4[mt][nl][rg]);
    mx = fmaxf(mx, __shfl_xor(mx, 16));
    mx = fmaxf(mx, __shfl_xor(mx, 32));
    if (quad == 0){
      int col = wave*64 + nl*16 + lrow;
      tokens[gid * 256 + col] = mx + b4[col];
    }
  }
}

// ---------------- pos embed + assemble + first LN (fused); LN out bf16 ----------------
__global__ __launch_bounds__(128) void pos_ln_kernel(
    const float* __restrict__ centers, const float* __restrict__ tokens,
    const float* __restrict__ cls_token, const float* __restrict__ cls_pos,
    const float* __restrict__ pw1, const float* __restrict__ pb1,
    const float* __restrict__ pw2, const float* __restrict__ pb2,
    const float* __restrict__ lng, const float* __restrict__ lnb,
    float* __restrict__ pt, float* __restrict__ xi, unsigned short* __restrict__ lnbuf)
{
  __shared__ float hS[128];
  __shared__ float red[2][2];
  int row = blockIdx.x;
  int b = row / 257, n = row - b * 257;
  int tid = threadIdx.x;
  size_t ro = (size_t)row * 256;
  float u0, u1;
  if (n == 0){
    float p0 = cls_pos[tid], p1 = cls_pos[128 + tid];
    u0 = cls_token[tid] + p0; u1 = cls_token[128 + tid] + p1;
    pt[ro + tid] = p0; pt[ro + 128 + tid] = p1;
  } else {
    int g = n - 1;
    const float* c = centers + ((size_t)b * 256 + g) * 3;
    float h = fmaf(c[2], pw1[256 + tid], fmaf(c[1], pw1[128 + tid], fmaf(c[0], pw1[tid], pb1[tid])));
    hS[tid] = gelu_exact(h);
    __syncthreads();
    const float* tok = tokens + ((size_t)b * 256 + g) * 256;
    float s0 = pb2[tid], s1 = pb2[128 + tid];
#pragma unroll 4
    for (int k = 0; k < 128; k++){
      s0 = fmaf(hS[k], pw2[(size_t)k * 256 + tid], s0);
      s1 = fmaf(hS[k], pw2[(size_t)k * 256 + 128 + tid], s1);
    }
    pt[ro + tid] = s0; pt[ro + 128 + tid] = s1;
    u0 = tok[tid] + s0; u1 = tok[128 + tid] + s1;
  }
  float s = u0 + u1, q = u0*u0 + u1*u1;
#pragma unroll
  for (int o = 32; o; o >>= 1){ s += __shfl_down(s, o); q += __shfl_down(q, o); }
  int wv = tid >> 6;
  if ((tid & 63) == 0){ red[0][wv] = s; red[1][wv] = q; }
  __syncthreads();
  float m  = (red[0][0] + red[0][1]) * (1.0f / 256.0f);
  float var = (red[1][0] + red[1][1]) * (1.0f / 256.0f) - m * m;
  float rs = 1.0f / sqrtf(var + EPS_);
  xi[ro + tid] = u0; xi[ro + 128 + tid] = u1;
  lnbuf[ro + tid] = bf16h((u0 - m) * rs * lng[tid] + lnb[tid]);
  lnbuf[ro + 128 + tid] = bf16h((u1 - m) * rs * lng[128 + tid] + lnb[128 + tid]);
}

// ---------------- MFMA GEMM (qkv): bf16 A -> bf16 C; 32-row x 128-col tiles ----------------
template<int ACT>
__global__ __launch_bounds__(256, 2) void mfma_gemm(
    const unsigned short* __restrict__ A, const unsigned short* __restrict__ Bh,
    const float* __restrict__ bias, unsigned short* __restrict__ C, int M, int K, int N)
{
  __shared__ __align__(16) unsigned short sA[32 * 72];
  int tid = threadIdx.x;
  int wave = tid >> 6, lane = tid & 63, quad = lane >> 4, lrow = lane & 15;
  int row0 = blockIdx.x * 32;
  int col0 = blockIdx.y * 128;
  int ksTotal = K >> 5;
  f32x4 acc[2][2];
  const f32x4 z = {0.f, 0.f, 0.f, 0.f};
#pragma unroll
  for (int mt = 0; mt < 2; mt++){ acc[mt][0] = z; acc[mt][1] = z; }

  for (int k0 = 0; k0 < K; k0 += 64){
    {
      int r = tid >> 3, c8 = (tid & 7) * 8;
      int gr = row0 + r;
      bf16x8 v = {0,0,0,0,0,0,0,0};
      if (gr < M) v = *(const bf16x8*)(A + (size_t)gr * K + k0 + c8);
      *(bf16x8*)&sA[r * 72 + c8] = v;
    }
    __syncthreads();
    int ksBase = k0 >> 5;
#pragma unroll
    for (int ks = 0; ks < 2; ks++){
      bf16x8 af[2];
#pragma unroll
      for (int mt = 0; mt < 2; mt++)
        af[mt] = *(const bf16x8*)&sA[(mt*16 + lrow)*72 + ks*32 + quad*8];
#pragma unroll
      for (int nl = 0; nl < 2; nl++){
        int nt = (col0 >> 4) + wave*2 + nl;
        size_t bo = (((size_t)nt * ksTotal + ksBase + ks)*64 + lane)*8;
        bf16x8 bh = *(const bf16x8*)&Bh[bo];
#pragma unroll
        for (int mt = 0; mt < 2; mt++)
          acc[mt][nl] = __builtin_amdgcn_mfma_f32_16x16x32_bf16(af[mt], bh, acc[mt][nl], 0, 0, 0);
      }
    }
    __syncthreads();
  }
#pragma unroll
  for (int nl = 0; nl < 2; nl++){
    int c = col0 + wave*32 + nl*16 + lrow;
    float bc = bias ? bias[c] : 0.0f;
#pragma unroll
    for (int mt = 0; mt < 2; mt++)
#pragma unroll
      for (int rg = 0; rg < 4; rg++){
        int r = row0 + mt*16 + quad*4 + rg;
        if (r < M){
          float v = acc[mt][nl][rg] + bc;
          if (ACT == 1) v = gelu_exact(v);
          C[(size_t)r * N + c] = bf16h(v);
        }
      }
  }
}

// ---------------- MFMA GEMM + residual + LN epilogue (proj); 16-row x 256-col ----------------
__global__ __launch_bounds__(256, 2) void mfma_gemm_ln(
    const unsigned short* __restrict__ A, const unsigned short* __restrict__ Bh,
    const float* __restrict__ bias, const float* __restrict__ res,
    const float* __restrict__ ptb,
    float* __restrict__ C, float* __restrict__ xiOut, unsigned short* __restrict__ lnOut,
    const float* __restrict__ lng, const float* __restrict__ lnb, int M, int K)
{
  __shared__ __align__(16) unsigned short sA[16 * 72];
  __shared__ float sRed[2][16][4];
  int tid = threadIdx.x;
  int wave = tid >> 6, lane = tid & 63, quad = lane >> 4, lrow = lane & 15;
  int row0 = blockIdx.x * 16;
  int ksTotal = K >> 5;
  f32x4 acc[4];
  const f32x4 z = {0.f, 0.f, 0.f, 0.f};
#pragma unroll
  for (int nl = 0; nl < 4; nl++) acc[nl] = z;

  for (int k0 = 0; k0 < K; k0 += 64){
    if (tid < 128){
      int r = tid >> 3, c8 = (tid & 7) * 8;
      int gr = row0 + r;
      bf16x8 v = {0,0,0,0,0,0,0,0};
      if (gr < M) v = *(const bf16x8*)(A + (size_t)gr * K + k0 + c8);
      *(bf16x8*)&sA[r * 72 + c8] = v;
    }
    __syncthreads();
    int ksBase = k0 >> 5;
#pragma unroll
    for (int ks = 0; ks < 2; ks++){
      bf16x8 af = *(const bf16x8*)&sA[lrow*72 + ks*32 + quad*8];
#pragma unroll
      for (int nl = 0; nl < 4; nl++){
        int nt = wave*4 + nl;
        size_t bo = (((size_t)nt * ksTotal + ksBase + ks)*64 + lane)*8;
        bf16x8 bh = *(const bf16x8*)&Bh[bo];
        acc[nl] = __builtin_amdgcn_mfma_f32_16x16x32_bf16(af, bh, acc[nl], 0, 0, 0);
      }
    }
    __syncthreads();
  }
#pragma unroll
  for (int nl = 0; nl < 4; nl++){
    int c = wave*64 + nl*16 + lrow;
    float bc = bias[c];
#pragma unroll
    for (int rg = 0; rg < 4; rg++){
      int r = row0 + quad*4 + rg;
      if (r < M){
        float v = acc[nl][rg] + bc + res[(size_t)r * 256 + c];
        if (C) C[(size_t)r * 256 + c] = v;
        float u = v;
        if (ptb) u += ptb[(size_t)r * 256 + c];
        acc[nl][rg] = u;
      }
    }
  }
#pragma unroll
  for (int rg = 0; rg < 4; rg++){
    int rloc = quad*4 + rg;
    float s = 0.0f, q = 0.0f;
#pragma unroll
    for (int nl = 0; nl < 4; nl++){ float u = acc[nl][rg]; s += u; q += u*u; }
#pragma unroll
    for (int off = 1; off < 16; off <<= 1){ s += __shfl_xor(s, off); q += __shfl_xor(q, off); }
    if (lrow == 0){ sRed[0][rloc][wave] = s; sRed[1][rloc][wave] = q; }
  }
  __syncthreads();
#pragma unroll
  for (int rg = 0; rg < 4; rg++){
    int rloc = quad*4 + rg;
    int r = row0 + rloc;
    if (r >= M) continue;
    float s = ((sRed[0][rloc][0] + sRed[0][rloc][1]) + sRed[0][rloc][2]) + sRed[0][rloc][3];
    float q = ((sRed[1][rloc][0] + sRed[1][rloc][1]) + sRed[1][rloc][2]) + sRed[1][rloc][3];
    float m  = s * (1.0f / 256.0f);
    float var = q * (1.0f / 256.0f) - m * m;
    float rs = 1.0f / sqrtf(var + EPS_);
#pragma unroll
    for (int nl = 0; nl < 4; nl++){
      int c = wave*64 + nl*16 + lrow;
      float u = acc[nl][rg];
      lnOut[(size_t)r * 256 + c] = bf16h((u - m) * rs * lng[c] + lnb[c]);
      if (xiOut) xiOut[(size_t)r * 256 + c] = u;
    }
  }
}

// ---------------- FUSED MLP: ln2-out -> fc1 -> gelu -> fc2 -> +res(+pt) -> LN ----------------
// One block per 16-row tile; gelu(fc1) intermediate lives in 33 KB LDS.
// Accumulation/rounding order identical to the unfused mfma_gemm<1> + mfma_gemm_ln pair.
__global__ __launch_bounds__(256, 2) void mlp_fused(
    const unsigned short* __restrict__ A,     // ln2-out bf16 [M,256]
    const unsigned short* __restrict__ B1,    // fc1 packed (KS=8)
    const float* __restrict__ bias1,
    const unsigned short* __restrict__ B2,    // fc2 packed (KS=32)
    const float* __restrict__ bias2,
    const float* __restrict__ res,            // xi f32
    const float* __restrict__ ptb,            // nullable
    float* __restrict__ xiOut, unsigned short* __restrict__ lnOut,
    const float* __restrict__ lng, const float* __restrict__ lnb, int M)
{
  __shared__ __align__(16) unsigned short sA[16 * 264];
  __shared__ __align__(16) unsigned short sH[16 * 1032];
  __shared__ float sRed[2][16][4];
  int tid = threadIdx.x;
  int wave = tid >> 6, lane = tid & 63, quad = lane >> 4, lrow = lane & 15;
  int row0 = blockIdx.x * 16;

  for (int e = tid; e < 512; e += 256){
    int r = e >> 5, c8 = (e & 31) * 8;
    int gr = row0 + r;
    bf16x8 v = {0,0,0,0,0,0,0,0};
    if (gr < M) v = *(const bf16x8*)(A + (size_t)gr * 256 + c8);
    *(bf16x8*)&sA[r * 264 + c8] = v;
  }
  __syncthreads();

  // fc1: wave w handles cols w*256 .. w*256+255 (nt = w*16 .. w*16+15)
  {
    f32x4 acc1[16];
    const f32x4 z = {0.f, 0.f, 0.f, 0.f};
#pragma unroll
    for (int nl = 0; nl < 16; nl++) acc1[nl] = z;
#pragma unroll
    for (int ks = 0; ks < 8; ks++){
      bf16x8 af = *(const bf16x8*)&sA[lrow*264 + ks*32 + quad*8];
#pragma unroll
      for (int nl = 0; nl < 16; nl++){
        int nt = wave*16 + nl;
        size_t bo = (((size_t)nt*8 + ks)*64 + lane)*8;
        bf16x8 bh = *(const bf16x8*)&B1[bo];
        acc1[nl] = __builtin_amdgcn_mfma_f32_16x16x32_bf16(af, bh, acc1[nl], 0, 0, 0);
      }
    }
#pragma unroll
    for (int nl = 0; nl < 16; nl++){
      int c = wave*256 + nl*16 + lrow;
      float bc = bias1[c];
#pragma unroll
      for (int rg = 0; rg < 4; rg++)
        sH[(quad*4+rg)*1032 + c] = bf16h(gelu_exact(acc1[nl][rg] + bc));
    }
  }
  __syncthreads();

  // fc2: wave w handles cols w*64 .. w*64+63 (nt = w*4 .. w*4+3), K=1024
  f32x4 acc[4];
  const f32x4 z = {0.f, 0.f, 0.f, 0.f};
#pragma unroll
  for (int nl = 0; nl < 4; nl++) acc[nl] = z;
#pragma unroll 4
  for (int ks = 0; ks < 32; ks++){
    bf16x8 af = *(const bf16x8*)&sH[lrow*1032 + ks*32 + quad*8];
#pragma unroll
    for (int nl = 0; nl < 4; nl++){
      int nt = wave*4 + nl;
      size_t bo = (((size_t)nt*32 + ks)*64 + lane)*8;
      bf16x8 bh = *(const bf16x8*)&B2[bo];
      acc[nl] = __builtin_amdgcn_mfma_f32_16x16x32_bf16(af, bh, acc[nl], 0, 0, 0);
    }
  }
  // epilogue: + bias + res (+pt), row LN
#pragma unroll
  for (int nl = 0; nl < 4; nl++){
    int c = wave*64 + nl*16 + lrow;
    float bc = bias2[c];
#pragma unroll
    for (int rg = 0; rg < 4; rg++){
      int r = row0 + quad*4 + rg;
      if (r < M){
        float v = acc[nl][rg] + bc + res[(size_t)r * 256 + c];
        float u = v;
        if (ptb) u += ptb[(size_t)r * 256 + c];
        acc[nl][rg] = u;
      }
    }
  }
#pragma unroll
  for (int rg = 0; rg < 4; rg++){
    int rloc = quad*4 + rg;
    float s = 0.0f, q = 0.0f;
#pragma unroll
    for (int nl = 0; nl < 4; nl++){ float u = acc[nl][rg]; s += u; q += u*u; }
#pragma unroll
    for (int off = 1; off < 16; off <<= 1){ s += __shfl_xor(s, off); q += __shfl_xor(q, off); }
    if (lrow == 0){ sRed[0][rloc][wave] = s; sRed[1][rloc][wave] = q; }
  }
  __syncthreads();
#pragma unroll
  for (int rg = 0; rg < 4; rg++){
    int rloc = quad*4 + rg;
    int r = row0 + rloc;
    if (r >= M) continue;
    float s = ((sRed[0][rloc][0] + sRed[0][rloc][1]) + sRed[0][rloc][2]) + sRed[0][rloc][3];
    float q = ((sRed[1][rloc][0] + sRed[1][rloc][1]) + sRed[1][rloc][2]) + sRed[1][rloc][3];
    float m  = s * (1.0f / 256.0f);
    float var = q * (1.0f / 256.0f) - m * m;
    float rs = 1.0f / sqrtf(var + EPS_);
#pragma unroll
    for (int nl = 0; nl < 4; nl++){
      int c = wave*64 + nl*16 + lrow;
      float u = acc[nl][rg];
      lnOut[(size_t)r * 256 + c] = bf16h((u - m) * rs * lng[c] + lnb[c]);
      if (xiOut) xiOut[(size_t)r * 256 + c] = u;
    }
  }
}

// ---------------- attention: bf16 in/out, flash-style, k-split x4 ----------------
// min-waves=2 (VGPR cap 256): q[32]+o[32] = 64 floats/thread was spilling
// under the default 64-reg heuristic cap.
__global__ __launch_bounds__(256, 2) void attn_kernel(const unsigned short* __restrict__ qkv, unsigned short* __restrict__ obuf)
{
  int bh = blockIdx.x;
  int b = bh >> 3, h = bh & 7;
  int tid = threadIdx.x;
  int qi = tid >> 2, kp = tid & 3;
  int qrow = blockIdx.y * 64 + qi;
  bool act = qrow < 257;
  __shared__ float kS[128][33];
  __shared__ float vS[128][33];
  const unsigned short* qb = qkv + (size_t)b * 257 * 768;
  float q[32], o[32];
  float mrun = -3.4e38f, l = 0.0f;
  if (act){
    const unsigned short* qr = qb + (size_t)qrow * 768 + h * 32;
#pragma unroll
    for (int j = 0; j < 32; j++){ q[j] = bf16_to_f32(qr[j]); o[j] = 0.0f; }
  }
  const float scale = 0.17677669529663687f;
  for (int m0 = 0; m0 < 257; m0 += 128){
    int cnt = min(128, 257 - m0);
    for (int e = tid; e < cnt * 32; e += 256){
      int mm = e >> 5, j = e & 31;
      const unsigned short* rowp = qb + (size_t)(m0 + mm) * 768 + h * 32;
      kS[mm][j] = bf16_to_f32(rowp[256 + j]);
      vS[mm][j] = bf16_to_f32(rowp[512 + j]);
    }
    __syncthreads();
    if (act){
      for (int mm = kp; mm < cnt; mm += 4){
        float s = 0.0f;
#pragma unroll
        for (int j = 0; j < 32; j++) s = fmaf(q[j], kS[mm][j], s);
        s *= scale;
        float nm = fmaxf(mrun, s);
        float alpha = expf(mrun - nm);
        float p = expf(s - nm);
        l = fmaf(l, alpha, p);
#pragma unroll
        for (int j = 0; j < 32; j++) o[j] = fmaf(p, vS[mm][j], o[j] * alpha);
        mrun = nm;
      }
    }
    __syncthreads();
  }
  if (act){
#pragma unroll
    for (int msk = 1; msk <= 2; msk <<= 1){
      float m2 = __shfl_xor(mrun, msk);
      float l2 = __shfl_xor(l, msk);
      float nm = fmaxf(mrun, m2);
      float a1 = expf(mrun - nm), a2 = expf(m2 - nm);
      l = l * a1 + l2 * a2;
#pragma unroll
      for (int j = 0; j < 32; j++){
        float o2 = __shfl_xor(o[j], msk);
        o[j] = o[j] * a1 + o2 * a2;
      }
      mrun = nm;
    }
    if (kp == 0){
      float inv = 1.0f / l;
      unsigned short* orow = obuf + (size_t)(b * 257 + qrow) * 256 + h * 32;
#pragma unroll
      for (int j = 0; j < 32; j++) orow[j] = bf16h(o[j] * inv);
    }
  }
}

// ---------------- head MLP + scatter: one block per (b,g); gfeat bf16 ----------------
__global__ __launch_bounds__(256) void head_kernel(
    const unsigned short* __restrict__ gfeat, const float* __restrict__ neigh, const int* __restrict__ knn_idx,
    const float* __restrict__ w1, const float* __restrict__ b1,
    const float* __restrict__ w2, const float* __restrict__ b2,
    float* __restrict__ sums, float* __restrict__ cnts)
{
  int blk = blockIdx.x, b = blk >> 8;
  __shared__ float xS[256];
  __shared__ float nS[64][4];
  __shared__ float partH[2][128];
  __shared__ float sharedH[128];
  __shared__ float w2S[128];
  __shared__ float wtail[3][128];
  int tid = threadIdx.x;
  xS[tid] = bf16_to_f32(gfeat[((size_t)b * 257 + 1 + (blk & 255)) * 256 + tid]);
  if (tid < 192) nS[tid / 3][tid % 3] = neigh[(size_t)blk * 192 + tid];
  if (tid < 128){
    w2S[tid] = w2[tid];
    wtail[0][tid] = w1[256 * 128 + tid];
    wtail[1][tid] = w1[257 * 128 + tid];
    wtail[2][tid] = w1[258 * 128 + tid];
  }
  __syncthreads();
  {
    int half = tid >> 7, j = tid & 127;
    float s = 0.0f;
#pragma unroll 8
    for (int k = 0; k < 128; k++) s = fmaf(xS[half * 128 + k], w1[(size_t)(half * 128 + k) * 128 + j], s);
    partH[half][j] = s;
  }
  __syncthreads();
  if (tid < 128) sharedH[tid] = partH[0][tid] + partH[1][tid] + b1[tid];
  __syncthreads();
  int r = tid >> 2, q = tid & 3;
  float n0 = nS[r][0], n1 = nS[r][1], n2 = nS[r][2];
  float s = 0.0f;
#pragma unroll
  for (int j0 = 0; j0 < 32; j0++){
    int j = q * 32 + j0;
    float h = fmaf(n2, wtail[2][j], fmaf(n1, wtail[1][j], fmaf(n0, wtail[0][j], sharedH[j])));
    s = fmaf(fmaxf(h, 0.0f), w2S[j], s);
  }
  s += __shfl_xor(s, 1);
  s += __shfl_xor(s, 2);
  if (q == 0){
    float lg = s + b2[0];
    int p = knn_idx[(size_t)blk * K_ + r];
    atomicAdd(&sums[(size_t)b * N_ + p], lg);
    atomicAdd(&cnts[(size_t)b * N_ + p], 1.0f);
  }
}

__global__ void finalize_kernel(const float* __restrict__ sums, const float* __restrict__ cnts, float* __restrict__ out)
{
  int i = blockIdx.x * 256 + threadIdx.x;
  out[i] = sums[i] / fmaxf(cnts[i], 1.0f);
}

extern "C" void kernel_launch(void* const* d_in, const int* in_sizes, int n_in,
                              void* d_out, int out_size, void* d_ws, size_t ws_size,
                              hipStream_t stream)
{
  (void)in_sizes; (void)n_in; (void)out_size; (void)ws_size;
  const float* x        = (const float*)d_in[0];
  const float* enc_w1   = (const float*)d_in[1];
  const float* enc_b1   = (const float*)d_in[2];
  const float* enc_bn1g = (const float*)d_in[3];
  const float* enc_bn1b = (const float*)d_in[4];
  const float* enc_w2   = (const float*)d_in[5];
  const float* enc_b2   = (const float*)d_in[6];
  const float* enc_w3   = (const float*)d_in[7];
  const float* enc_b3   = (const float*)d_in[8];
  const float* enc_bn2g = (const float*)d_in[9];
  const float* enc_bn2b = (const float*)d_in[10];
  const float* enc_w4   = (const float*)d_in[11];
  const float* enc_b4   = (const float*)d_in[12];
  const float* cls_tok  = (const float*)d_in[13];
  const float* cls_pos  = (const float*)d_in[14];
  const float* pos_w1   = (const float*)d_in[15];
  const float* pos_b1   = (const float*)d_in[16];
  const float* pos_w2   = (const float*)d_in[17];
  const float* pos_b2   = (const float*)d_in[18];
  const float* ln1_g    = (const float*)d_in[19];
  const float* ln1_b    = (const float*)d_in[20];
  const float* qkv_w    = (const float*)d_in[21];
  const float* proj_w   = (const float*)d_in[22];
  const float* proj_b   = (const float*)d_in[23];
  const float* ln2_g    = (const float*)d_in[24];
  const float* ln2_b    = (const float*)d_in[25];
  const float* fc1_w    = (const float*)d_in[26];
  const float* fc1_b    = (const float*)d_in[27];
  const float* fc2_w    = (const float*)d_in[28];
  const float* fc2_b    = (const float*)d_in[29];
  const float* norm_g   = (const float*)d_in[30];
  const float* norm_b   = (const float*)d_in[31];
  const float* head_w1  = (const float*)d_in[32];
  const float* head_b1  = (const float*)d_in[33];
  const float* head_w2  = (const float*)d_in[34];
  const float* head_b2  = (const float*)d_in[35];

  float* ws = (float*)d_ws;
  size_t off = 0;
  auto alloc = [&](size_t n)->float*{ float* p = ws + off; off += (n + 63) & ~(size_t)63; return p; };

  float* centers = alloc((size_t)B_ * G_ * 3);
  float* w1f     = alloc(384);
  float* b1f     = alloc(128);
  float* b3f     = alloc(512);
  unsigned short* w2ph = (unsigned short*)alloc(16384);
  unsigned short* w2pl = (unsigned short*)alloc(16384);
  unsigned short* w3ph = (unsigned short*)alloc(65536);
  unsigned short* w3tp = (unsigned short*)alloc(65536);
  unsigned short* w4ph = (unsigned short*)alloc(65536);
  unsigned short* qkvPh = (unsigned short*)alloc(393216);
  unsigned short* projPh = (unsigned short*)alloc(131072);
  unsigned short* fc1Ph = (unsigned short*)alloc(524288);
  unsigned short* fc2Ph = (unsigned short*)alloc(524288);
  float* tokens  = alloc((size_t)B_ * G_ * D_);
  float* neigh   = alloc((size_t)B_ * G_ * K_ * 3);
  int*   knn_idx = (int*)alloc((size_t)B_ * G_ * K_);
  float* pt      = alloc((size_t)B_ * 257 * D_);
  float* xi      = alloc((size_t)B_ * 257 * D_);
  unsigned short* lnbufB = (unsigned short*)alloc((size_t)B_ * 257 * D_ / 2 + 64);
  unsigned short* obufB  = (unsigned short*)alloc((size_t)B_ * 257 * D_ / 2 + 64);
  unsigned short* bigbufB= (unsigned short*)alloc((size_t)B_ * 257 * HID_ / 2 + 64);
  unsigned short* gfeatB = (unsigned short*)alloc((size_t)B_ * 257 * D_ / 2 + 64);
  float* sums    = alloc((size_t)B_ * N_);
  float* cnts    = alloc((size_t)B_ * N_);

  hipMemsetAsync(sums, 0, (size_t)2 * B_ * N_ * sizeof(float), stream);

  prep_fps_kernel<<<6993, 512, 0, stream>>>(x, centers,
      enc_w1, enc_b1, enc_bn1g, enc_bn1b, enc_w3, enc_b3, enc_bn2g, enc_bn2b,
      enc_w2, enc_w4, qkv_w, proj_w, fc1_w, fc2_w,
      w1f, b1f, b3f, w2ph, w2pl, w3ph, w4ph, qkvPh, projPh, fc1Ph, fc2Ph, w3tp);

  knn_kernel<<<B_ * G_, 256, 0, stream>>>(x, centers, knn_idx, neigh);
  encoder_kernel<<<B_ * G_, 256, 0, stream>>>(neigh, w1f, b1f, w2ph, w2pl, enc_b2,
                                              b3f, w3ph, w3tp, w4ph, enc_b4, tokens);
  pos_ln_kernel<<<B_ * 257, 128, 0, stream>>>(centers, tokens, cls_tok, cls_pos,
                                              pos_w1, pos_b1, pos_w2, pos_b2,
                                              ln1_g, ln1_b, pt, xi, lnbufB);
  const int M = B_ * 257; // 4112
  for (int l = 0; l < 4; l++){
    mfma_gemm<0><<<dim3(129, 6), 256, 0, stream>>>(lnbufB, qkvPh + (size_t)l*196608, nullptr, bigbufB, M, 256, 768);
    attn_kernel<<<dim3(B_ * 8, 5), 256, 0, stream>>>(bigbufB, obufB);
    mfma_gemm_ln<<<257, 256, 0, stream>>>(obufB, projPh + (size_t)l*65536, proj_b + l*256, xi, nullptr,
                                          xi, nullptr, lnbufB, ln2_g + l*256, ln2_b + l*256, M, 256);
    if (l < 3){
      mlp_fused<<<257, 256, 0, stream>>>(lnbufB, fc1Ph + (size_t)l*262144, fc1_b + l*1024,
                                         fc2Ph + (size_t)l*262144, fc2_b + l*256, xi, pt,
                                         xi, lnbufB, ln1_g + (l+1)*256, ln1_b + (l+1)*256, M);
    } else {
      mlp_fused<<<257, 256, 0, stream>>>(lnbufB, fc1Ph + (size_t)l*262144, fc1_b + l*1024,
                                         fc2Ph + (size_t)l*262144, fc2_b + l*256, xi, nullptr,
                                         nullptr, gfeatB, norm_g, norm_b, M);
    }
  }
  head_kernel<<<B_ * G_, 256, 0, stream>>>(gfeatB, neigh, knn_idx, head_w1, head_b1, head_w2, head_b2, sums, cnts);
  finalize_kernel<<<(B_ * N_) / 256, 256, 0, stream>>>(sums, cnts, (float*)d_out);
}

// Round 11
// 1580.273 us; speedup vs baseline: 1.7742x; 1.0021x over previous
//
#include <hip/hip_runtime.h>
#include <hip/hip_bf16.h>

#define B_ 16
#define N_ 8192
#define G_ 256
#define K_ 64
#define D_ 256
#define HID_ 1024
#define EPS_ 1e-5f

typedef __attribute__((ext_vector_type(8))) short bf16x8;
typedef __attribute__((ext_vector_type(4))) float f32x4;

__device__ __forceinline__ float bf16_to_f32(unsigned short u){
  unsigned int v = ((unsigned int)u) << 16;
  return __uint_as_float(v);
}
__device__ __forceinline__ unsigned short f32_to_bf16(float f){
  unsigned int u = __float_as_uint(f);
  unsigned int r = (u + 0x7FFFu + ((u >> 16) & 1u)) >> 16;
  return (unsigned short)r;
}
__device__ __forceinline__ unsigned short bf16h(float a){
  __hip_bfloat16 h = __float2bfloat16(a);
  union { __hip_bfloat16 h; unsigned short u; } cv; cv.h = h; return cv.u;
}
__device__ __forceinline__ float gelu_exact(float v){
  return 0.5f * v * (1.0f + erff(v * 0.70710678118654752440f));
}

// ---------------- DPP cross-lane reduce ----------------
template<int CTRL>
__device__ __forceinline__ unsigned long long dpp64(unsigned long long k){
  int lo = (int)(unsigned int)k;
  int hi = (int)(unsigned int)(k >> 32);
  int dlo = __builtin_amdgcn_update_dpp(lo, lo, CTRL, 0xF, 0xF, false);
  int dhi = __builtin_amdgcn_update_dpp(hi, hi, CTRL, 0xF, 0xF, false);
  return (((unsigned long long)(unsigned int)dhi) << 32) | (unsigned int)dlo;
}
__device__ __forceinline__ unsigned long long bcast64(unsigned long long k, int lane){
  unsigned int lo = (unsigned int)__builtin_amdgcn_readlane((int)(unsigned int)k, lane);
  unsigned int hi = (unsigned int)__builtin_amdgcn_readlane((int)(unsigned int)(k >> 32), lane);
  return (((unsigned long long)hi) << 32) | lo;
}
__device__ __forceinline__ unsigned long long wave_max64(unsigned long long k){
  unsigned long long t;
  t = dpp64<0x111>(k); if (t > k) k = t;
  t = dpp64<0x112>(k); if (t > k) k = t;
  t = dpp64<0x114>(k); if (t > k) k = t;
  t = dpp64<0x118>(k); if (t > k) k = t;
  t = dpp64<0x142>(k); if (t > k) k = t;
  t = dpp64<0x143>(k); if (t > k) k = t;
  return bcast64(k, 63);
}
__device__ __forceinline__ unsigned long long wave_min64(unsigned long long k){
  unsigned long long t;
  t = dpp64<0x111>(k); if (t < k) k = t;
  t = dpp64<0x112>(k); if (t < k) k = t;
  t = dpp64<0x114>(k); if (t < k) k = t;
  t = dpp64<0x118>(k); if (t < k) k = t;
  t = dpp64<0x142>(k); if (t < k) k = t;
  t = dpp64<0x143>(k); if (t < k) k = t;
  return bcast64(k, 63);
}
__device__ __forceinline__ unsigned long long red8_max64(unsigned long long k){
  unsigned long long t;
  t = dpp64<0x111>(k); if (t > k) k = t;
  t = dpp64<0x112>(k); if (t > k) k = t;
  t = dpp64<0x114>(k); if (t > k) k = t;
  return bcast64(k, 7);
}
__device__ __forceinline__ unsigned long long red4_min64(unsigned long long k){
  unsigned long long t;
  t = dpp64<0x111>(k); if (t < k) k = t;
  t = dpp64<0x112>(k); if (t < k) k = t;
  return bcast64(k, 3);
}

// ---- pack helper: B frag for 16x16x32: lane holds B[k=(lane>>4)*8+j][n=lane&15] ----
__device__ __forceinline__ void packHi(const float* __restrict__ W, unsigned short* __restrict__ hi,
                                       int f, int N, int ksBits){
  int j = f & 7, lane = (f >> 3) & 63;
  int ks = (f >> 9) & ((1 << ksBits) - 1);
  int nt = f >> (9 + ksBits);
  int k = ks * 32 + ((lane >> 4) & 3) * 8 + j, c = nt * 16 + (lane & 15);
  hi[f] = f32_to_bf16(W[(size_t)k * N + c]);
}

// ---------------- FUSED prep + FPS kernel ----------------
// FPS blocks: px/py/pz are PINNED into VGPRs via empty inline asm. Without the
// pin, the compiler rematerializes these loop-invariant loads from L2 every
// iteration (VGPR_Count stayed 64 in R7-R10) -- ~96 KB re-read per iteration
// per block was the invisible serial floor (L2 traffic, not in FETCH_SIZE).
__global__ __launch_bounds__(512, 2) void prep_fps_kernel(
    const float* __restrict__ x, float* __restrict__ centers,
    const float* __restrict__ w1, const float* __restrict__ b1,
    const float* __restrict__ g1, const float* __restrict__ bb1,
    const float* __restrict__ w3, const float* __restrict__ b3,
    const float* __restrict__ g2, const float* __restrict__ bb2,
    const float* __restrict__ enc_w2, const float* __restrict__ enc_w4,
    const float* __restrict__ qkv_w, const float* __restrict__ proj_w,
    const float* __restrict__ fc1_w, const float* __restrict__ fc2_w,
    float* __restrict__ w1f, float* __restrict__ b1f, float* __restrict__ b3f,
    unsigned short* __restrict__ w2ph, unsigned short* __restrict__ w2pl,
    unsigned short* __restrict__ w3ph, unsigned short* __restrict__ w4ph,
    unsigned short* __restrict__ qkvPh, unsigned short* __restrict__ projPh,
    unsigned short* __restrict__ fc1Ph, unsigned short* __restrict__ fc2Ph,
    unsigned short* __restrict__ w3tp)
{
  const float S = 0.99999500003749968f; // 1/sqrt(1+1e-5)
  int blk = blockIdx.x, tid = threadIdx.x;

  if (blk >= 17){
    int f = (blk - 17) * 512 + tid;
    if (f < 32768){              // w2 hi+lo (K=128,N=256,ksBits=2)
      int j = f & 7, lane = (f >> 3) & 63, ks = (f >> 9) & 3, nt = f >> 11;
      int k = ks * 32 + ((lane >> 4) & 3) * 8 + j, c = nt * 16 + (lane & 15);
      float v = enc_w2[(size_t)k * 256 + c];
      unsigned short h = f32_to_bf16(v);
      w2ph[f] = h; w2pl[f] = f32_to_bf16(v - bf16_to_f32(h));
    } else if (f < 163840){      // w3 bottom half, fold inline, ksBits=3
      f -= 32768;
      int j = f & 7, lane = (f >> 3) & 63, ks = (f >> 9) & 7, nt = f >> 12;
      int k = ks * 32 + ((lane >> 4) & 3) * 8 + j, c = nt * 16 + (lane & 15);
      w3ph[f] = f32_to_bf16(w3[(size_t)(256 + k) * 512 + c] * g2[c] * S);
    } else if (f < 294912){      // w4
      f -= 163840;
      packHi(enc_w4, w4ph, f, 256, 4);
    } else if (f < 1081344){     // qkv x4
      f -= 294912;
      int l = f / 196608, fl = f - l * 196608;
      packHi(qkv_w + (size_t)l * 196608, qkvPh + (size_t)l * 196608, fl, 768, 3);
    } else if (f < 1343488){     // proj x4
      f -= 1081344;
      int l = f >> 16, fl = f & 65535;
      packHi(proj_w + (size_t)l * 65536, projPh + (size_t)l * 65536, fl, 256, 3);
    } else if (f < 2392064){     // fc1 x4
      f -= 1343488;
      int l = f >> 18, fl = f & 262143;
      packHi(fc1_w + (size_t)l * 262144, fc1Ph + (size_t)l * 262144, fl, 1024, 3);
    } else if (f < 3440640){     // fc2 x4
      f -= 2392064;
      int l = f >> 18, fl = f & 262143;
      packHi(fc2_w + (size_t)l * 262144, fc2Ph + (size_t)l * 262144, fl, 256, 5);
    } else {                     // w3 top half, fold inline
      f -= 3440640;
      int j = f & 7, lane = (f >> 3) & 63, ks = (f >> 9) & 7, nt = f >> 12;
      int k = ks * 32 + ((lane >> 4) & 3) * 8 + j, c = nt * 16 + (lane & 15);
      w3tp[f] = f32_to_bf16(w3[(size_t)k * 512 + c] * g2[c] * S);
    }
    return;
  }
  if (blk == 16){
    if (tid < 384) w1f[tid] = w1[tid] * g1[tid & 127] * S;
    if (tid < 128) b1f[tid] = b1[tid] * g1[tid] * S + bb1[tid];
    b3f[tid] = b3[tid] * g2[tid] * S + bb2[tid];
    return;
  }

  // ---------- FPS (blocks 0..15) ----------
  int b = blk;
  const float* xb = x + (size_t)b * N_ * 3;
  int lane = tid & 63, wave = tid >> 6;
  float px[16], py[16], pz[16], dist[16];
#pragma unroll
  for (int j = 0; j < 16; j++){
    int p = tid + j * 512;
    px[j] = xb[p*3+0]; py[j] = xb[p*3+1]; pz[j] = xb[p*3+2];
    dist[j] = 1e10f;
  }
  // PIN to VGPRs: opaque asm output cannot be rematerialized from memory.
#pragma unroll
  for (int j = 0; j < 16; j++)
    asm volatile("" : "+v"(px[j]), "+v"(py[j]), "+v"(pz[j]));

  __shared__ unsigned long long slotK[2][8];
  __shared__ float4 slotC[2][8];
  __shared__ float sCen[G_ * 3];
  float cx = xb[0], cy = xb[1], cz = xb[2];
  for (int i = 0; i < G_; i++){
    if (tid == 0){
      sCen[i*3+0] = cx; sCen[i*3+1] = cy; sCen[i*3+2] = cz;
    }
    float bestv = -1.0f; int bestj = 0;
#pragma unroll
    for (int j = 0; j < 16; j++){
      float dx = __fadd_rn(px[j], -cx);
      float dy = __fadd_rn(py[j], -cy);
      float dz = __fadd_rn(pz[j], -cz);
      float d  = __fadd_rn(__fadd_rn(__fmul_rn(dx,dx), __fmul_rn(dy,dy)), __fmul_rn(dz,dz));
      float dm = fminf(dist[j], d);
      dist[j] = dm;
      if (dm > bestv){ bestv = dm; bestj = j; }
    }
    unsigned int pid = (unsigned int)(tid + bestj * 512);
    unsigned long long key = (((unsigned long long)__float_as_uint(bestv)) << 32) | (unsigned long long)(~pid);
    key = wave_max64(key);
    int par = i & 1;
    unsigned int wpid = ~(unsigned int)key;
    if (lane == (int)(wpid & 63)){
      int jj = (int)(wpid >> 9);
      float fx = px[0], fy = py[0], fz = pz[0];
#pragma unroll
      for (int j = 1; j < 16; j++) if (jj == j){ fx = px[j]; fy = py[j]; fz = pz[j]; }
      slotK[par][wave] = key;
      slotC[par][wave] = make_float4(fx, fy, fz, 0.0f);
    }
    __syncthreads();
    if (i + 1 < G_){
      int sl = lane & 7;
      unsigned long long k2 = slotK[par][sl];
      float4 cc4 = slotC[par][sl];
      k2 = red8_max64(k2);
      unsigned int gpid = ~(unsigned int)k2;
      int s = (int)((gpid & 511u) >> 6);
      cx = __uint_as_float((unsigned int)__builtin_amdgcn_readlane((int)__float_as_uint(cc4.x), s));
      cy = __uint_as_float((unsigned int)__builtin_amdgcn_readlane((int)__float_as_uint(cc4.y), s));
      cz = __uint_as_float((unsigned int)__builtin_amdgcn_readlane((int)__float_as_uint(cc4.z), s));
    }
  }
  __syncthreads();
  for (int e = tid; e < G_ * 3; e += 512)
    centers[(size_t)b * G_ * 3 + e] = sCen[e];
}

// ---------------- KNN: one block per (b,g); min-waves=4 ----------------
__global__ __launch_bounds__(256, 4) void knn_kernel(const float* __restrict__ x, const float* __restrict__ centers,
                                                     int* __restrict__ knn_idx, float* __restrict__ neigh)
{
  int blk = blockIdx.x, b = blk >> 8;
  const float* xb = x + (size_t)b * N_ * 3;
  const float* cc = centers + (size_t)blk * 3;
  int tid = threadIdx.x, lane = tid & 63, wave = tid >> 6;
  float c0 = cc[0], c1 = cc[1], c2v = cc[2];
  float c2s = __fadd_rn(__fadd_rn(__fmul_rn(c0,c0), __fmul_rn(c1,c1)), __fmul_rn(c2v,c2v));
  float d[32];
#pragma unroll
  for (int j = 0; j < 32; j++){
    int p = tid + j * 256;
    float x0 = xb[p*3+0], x1 = xb[p*3+1], x2 = xb[p*3+2];
    float xs = __fadd_rn(__fadd_rn(__fmul_rn(x0,x0), __fmul_rn(x1,x1)), __fmul_rn(x2,x2));
    float dt = __fadd_rn(__fadd_rn(__fmul_rn(c0,x0), __fmul_rn(c1,x1)), __fmul_rn(c2v,x2));
    d[j] = __fadd_rn(__fadd_rn(c2s, xs), -__fmul_rn(2.0f, dt));
  }
  const float FINF = __int_as_float(0x7F800000);
  float lmin = FINF; unsigned int lp = 0xFFFFFFFFu;
#pragma unroll
  for (int j = 0; j < 32; j++){ if (d[j] < lmin){ lmin = d[j]; lp = (unsigned int)(tid + j*256); } }
  __shared__ unsigned long long wred[2][4];
  __shared__ int sIdx[K_];
  __shared__ float sNei[K_ * 3];
  for (int r = 0; r < K_; r++){
    unsigned int u = __float_as_uint(lmin);
    u = (u & 0x80000000u) ? ~u : (u | 0x80000000u);
    unsigned long long key = (((unsigned long long)u) << 32) | (unsigned long long)lp;
    key = wave_min64(key);
    int cur = r & 1;
    if (lane == 0) wred[cur][wave] = key;
    __syncthreads();
    unsigned long long m = red4_min64(wred[cur][lane & 3]);
    unsigned int p = (unsigned int)(m & 0xFFFFFFFFull);
    if (tid == (p & 255u)){
      sIdx[r] = (int)p;
      sNei[r*3+0] = __fadd_rn(xb[p*3+0], -c0);
      sNei[r*3+1] = __fadd_rn(xb[p*3+1], -c1);
      sNei[r*3+2] = __fadd_rn(xb[p*3+2], -c2v);
      lmin = FINF; lp = 0xFFFFFFFFu;
#pragma unroll
      for (int j = 0; j < 32; j++){
        if ((unsigned int)(tid + j*256) == p) d[j] = FINF;
        if (d[j] < lmin){ lmin = d[j]; lp = (unsigned int)(tid + j*256); }
      }
    }
  }
  __syncthreads();
  if (tid < K_) knn_idx[(size_t)blk * K_ + tid] = sIdx[tid];
  if (tid < K_ * 3) neigh[(size_t)blk * K_ * 3 + tid] = sNei[tid];
}

// ---------------- fused group encoder (MFMA bf16): one block per (b,g) ----------------
__global__ __launch_bounds__(256, 2) void encoder_kernel(
    const float* __restrict__ neigh,
    const float* __restrict__ w1f, const float* __restrict__ b1f,
    const unsigned short* __restrict__ w2ph, const unsigned short* __restrict__ w2pl,
    const float* __restrict__ b2,
    const float* __restrict__ b3f,
    const unsigned short* __restrict__ w3ph, const unsigned short* __restrict__ w3tp,
    const unsigned short* __restrict__ w4ph,
    const float* __restrict__ b4,
    float* __restrict__ tokens)
{
  __shared__ __align__(16) unsigned short sH1[64 * 136];
  __shared__ __align__(16) unsigned short sH2[64 * 264];
  __shared__ __align__(16) float sShared[256];
  float (*sNeigh)[4] = (float(*)[4])sShared;
  unsigned short* sGmaxBf = (unsigned short*)sShared;

  int tid  = threadIdx.x;
  int wave = tid >> 6, lane = tid & 63, quad = lane >> 4, lrow = lane & 15;
  size_t gid = blockIdx.x;

  if (tid < 192) sNeigh[tid / 3][tid % 3] = neigh[gid * 192 + tid];
  __syncthreads();

  for (int e = tid; e < 8192; e += 256){
    int r = e >> 7, c = e & 127;
    float v = fmaf(sNeigh[r][2], w1f[256 + c], fmaf(sNeigh[r][1], w1f[128 + c], fmaf(sNeigh[r][0], w1f[c], b1f[c])));
    sH1[r * 136 + c] = bf16h(fmaxf(v, 0.0f));
  }
  __syncthreads();

  {
    f32x4 acc[4][4];
    const f32x4 z = {0.f, 0.f, 0.f, 0.f};
#pragma unroll
    for (int mt = 0; mt < 4; mt++)
#pragma unroll
      for (int nl = 0; nl < 4; nl++) acc[mt][nl] = z;
#pragma unroll
    for (int ks = 0; ks < 4; ks++){
      bf16x8 af[4];
#pragma unroll
      for (int mt = 0; mt < 4; mt++)
        af[mt] = *(const bf16x8*)&sH1[(mt*16 + lrow)*136 + ks*32 + quad*8];
#pragma unroll
      for (int nl = 0; nl < 4; nl++){
        size_t bo = (((size_t)(wave*4 + nl)*4 + ks)*64 + lane)*8;
        bf16x8 bh = *(const bf16x8*)&w2ph[bo];
        bf16x8 bl = *(const bf16x8*)&w2pl[bo];
#pragma unroll
        for (int mt = 0; mt < 4; mt++){
          acc[mt][nl] = __builtin_amdgcn_mfma_f32_16x16x32_bf16(af[mt], bh, acc[mt][nl], 0, 0, 0);
          acc[mt][nl] = __builtin_amdgcn_mfma_f32_16x16x32_bf16(af[mt], bl, acc[mt][nl], 0, 0, 0);
        }
      }
    }
#pragma unroll
    for (int nl = 0; nl < 4; nl++){
      int col = wave*64 + nl*16 + lrow;
      float bias = b2[col];
#pragma unroll
      for (int mt = 0; mt < 4; mt++)
#pragma unroll
        for (int rg = 0; rg < 4; rg++)
          sH2[(mt*16 + quad*4 + rg)*264 + col] = bf16h(acc[mt][nl][rg] + bias);
    }
  }
  __syncthreads();

  {
    float mx = -3.4e38f;
#pragma unroll 8
    for (int r = 0; r < 64; r++) mx = fmaxf(mx, bf16_to_f32(sH2[r*264 + tid]));
    sGmaxBf[tid] = bf16h(mx);
  }
  __syncthreads();

  f32x4 acc4[4][4];
  {
    const f32x4 z = {0.f, 0.f, 0.f, 0.f};
#pragma unroll
    for (int mt = 0; mt < 4; mt++)
#pragma unroll
      for (int nl = 0; nl < 4; nl++) acc4[mt][nl] = z;
  }
  for (int cc = 0; cc < 4; cc++){
    f32x4 acc3[4][2], accg[2];
    {
      const f32x4 z = {0.f, 0.f, 0.f, 0.f};
#pragma unroll
      for (int mt = 0; mt < 4; mt++){ acc3[mt][0] = z; acc3[mt][1] = z; }
      accg[0] = z; accg[1] = z;
    }
#pragma unroll
    for (int ks = 0; ks < 8; ks++){
      bf16x8 gf = *(const bf16x8*)&sGmaxBf[ks*32 + quad*8];
#pragma unroll
      for (int nl = 0; nl < 2; nl++){
        int nt = cc*8 + wave*2 + nl;
        size_t bo = (((size_t)nt*8 + ks)*64 + lane)*8;
        bf16x8 bh = *(const bf16x8*)&w3tp[bo];
        accg[nl] = __builtin_amdgcn_mfma_f32_16x16x32_bf16(gf, bh, accg[nl], 0, 0, 0);
      }
    }
#pragma unroll
    for (int ks = 0; ks < 8; ks++){
      bf16x8 af[4];
#pragma unroll
      for (int mt = 0; mt < 4; mt++)
        af[mt] = *(const bf16x8*)&sH2[(mt*16 + lrow)*264 + ks*32 + quad*8];
#pragma unroll
      for (int nl = 0; nl < 2; nl++){
        int nt = cc*8 + wave*2 + nl;
        size_t bo = (((size_t)nt*8 + ks)*64 + lane)*8;
        bf16x8 bh = *(const bf16x8*)&w3ph[bo];
#pragma unroll
        for (int mt = 0; mt < 4; mt++)
          acc3[mt][nl] = __builtin_amdgcn_mfma_f32_16x16x32_bf16(af[mt], bh, acc3[mt][nl], 0, 0, 0);
      }
    }
    __syncthreads();
#pragma unroll
    for (int nl = 0; nl < 2; nl++){
      int cl = wave*32 + nl*16 + lrow;
      int c  = cc*128 + cl;
      float bb = b3f[c];
#pragma unroll
      for (int mt = 0; mt < 4; mt++)
#pragma unroll
        for (int rg = 0; rg < 4; rg++)
          sH1[(mt*16 + quad*4 + rg)*136 + cl] = bf16h(fmaxf(acc3[mt][nl][rg] + accg[nl][rg] + bb, 0.0f));
    }
    __syncthreads();
#pragma unroll
    for (int ks = 0; ks < 4; ks++){
      bf16x8 af[4];
#pragma unroll
      for (int mt = 0; mt < 4; mt++)
        af[mt] = *(const bf16x8*)&sH1[(mt*16 + lrow)*136 + ks*32 + quad*8];
#pragma unroll
      for (int nl = 0; nl < 4; nl++){
        int nt = wave*4 + nl;
        size_t bo = (((size_t)nt*16 + cc*4 + ks)*64 + lane)*8;
        bf16x8 bh = *(const bf16x8*)&w4ph[bo];
#pragma unroll
        for (int mt = 0; mt < 4; mt++)
          acc4[mt][nl] = __builtin_amdgcn_mfma_f32_16x16x32_bf16(af[mt], bh, acc4[mt][nl], 0, 0, 0);
      }
    }
  }

#pragma unroll
  for (int nl = 0; nl < 4; nl++){
    float mx = -3.4e38f;
#pragma unroll
    for (int mt = 0; mt < 4; mt++)
#pragma unroll
      for (int rg = 0; rg < 4; rg++) mx = fmaxf(mx, acc4[mt][nl][rg]);
    mx = fmaxf(mx, __shfl_xor(mx, 16));
    mx = fmaxf(mx, __shfl_xor(mx, 32));
    if (quad == 0){
      int col = wave*64 + nl*16 + lrow;
      tokens[gid * 256 + col] = mx + b4[col];
    }
  }
}

// ---------------- pos embed + assemble + first LN (fused); LN out bf16 ----------------
__global__ __launch_bounds__(128) void pos_ln_kernel(
    const float* __restrict__ centers, const float* __restrict__ tokens,
    const float* __restrict__ cls_token, const float* __restrict__ cls_pos,
    const float* __restrict__ pw1, const float* __restrict__ pb1,
    const float* __restrict__ pw2, const float* __restrict__ pb2,
    const float* __restrict__ lng, const float* __restrict__ lnb,
    float* __restrict__ pt, float* __restrict__ xi, unsigned short* __restrict__ lnbuf)
{
  __shared__ float hS[128];
  __shared__ float red[2][2];
  int row = blockIdx.x;
  int b = row / 257, n = row - b * 257;
  int tid = threadIdx.x;
  size_t ro = (size_t)row * 256;
  float u0, u1;
  if (n == 0){
    float p0 = cls_pos[tid], p1 = cls_pos[128 + tid];
    u0 = cls_token[tid] + p0; u1 = cls_token[128 + tid] + p1;
    pt[ro + tid] = p0; pt[ro + 128 + tid] = p1;
  } else {
    int g = n - 1;
    const float* c = centers + ((size_t)b * 256 + g) * 3;
    float h = fmaf(c[2], pw1[256 + tid], fmaf(c[1], pw1[128 + tid], fmaf(c[0], pw1[tid], pb1[tid])));
    hS[tid] = gelu_exact(h);
    __syncthreads();
    const float* tok = tokens + ((size_t)b * 256 + g) * 256;
    float s0 = pb2[tid], s1 = pb2[128 + tid];
#pragma unroll 4
    for (int k = 0; k < 128; k++){
      s0 = fmaf(hS[k], pw2[(size_t)k * 256 + tid], s0);
      s1 = fmaf(hS[k], pw2[(size_t)k * 256 + 128 + tid], s1);
    }
    pt[ro + tid] = s0; pt[ro + 128 + tid] = s1;
    u0 = tok[tid] + s0; u1 = tok[128 + tid] + s1;
  }
  float s = u0 + u1, q = u0*u0 + u1*u1;
#pragma unroll
  for (int o = 32; o; o >>= 1){ s += __shfl_down(s, o); q += __shfl_down(q, o); }
  int wv = tid >> 6;
  if ((tid & 63) == 0){ red[0][wv] = s; red[1][wv] = q; }
  __syncthreads();
  float m  = (red[0][0] + red[0][1]) * (1.0f / 256.0f);
  float var = (red[1][0] + red[1][1]) * (1.0f / 256.0f) - m * m;
  float rs = 1.0f / sqrtf(var + EPS_);
  xi[ro + tid] = u0; xi[ro + 128 + tid] = u1;
  lnbuf[ro + tid] = bf16h((u0 - m) * rs * lng[tid] + lnb[tid]);
  lnbuf[ro + 128 + tid] = bf16h((u1 - m) * rs * lng[128 + tid] + lnb[128 + tid]);
}

// ---------------- MFMA GEMM (qkv): bf16 A -> bf16 C; 32-row x 128-col tiles ----------------
template<int ACT>
__global__ __launch_bounds__(256, 2) void mfma_gemm(
    const unsigned short* __restrict__ A, const unsigned short* __restrict__ Bh,
    const float* __restrict__ bias, unsigned short* __restrict__ C, int M, int K, int N)
{
  __shared__ __align__(16) unsigned short sA[32 * 72];
  int tid = threadIdx.x;
  int wave = tid >> 6, lane = tid & 63, quad = lane >> 4, lrow = lane & 15;
  int row0 = blockIdx.x * 32;
  int col0 = blockIdx.y * 128;
  int ksTotal = K >> 5;
  f32x4 acc[2][2];
  const f32x4 z = {0.f, 0.f, 0.f, 0.f};
#pragma unroll
  for (int mt = 0; mt < 2; mt++){ acc[mt][0] = z; acc[mt][1] = z; }

  for (int k0 = 0; k0 < K; k0 += 64){
    {
      int r = tid >> 3, c8 = (tid & 7) * 8;
      int gr = row0 + r;
      bf16x8 v = {0,0,0,0,0,0,0,0};
      if (gr < M) v = *(const bf16x8*)(A + (size_t)gr * K + k0 + c8);
      *(bf16x8*)&sA[r * 72 + c8] = v;
    }
    __syncthreads();
    int ksBase = k0 >> 5;
#pragma unroll
    for (int ks = 0; ks < 2; ks++){
      bf16x8 af[2];
#pragma unroll
      for (int mt = 0; mt < 2; mt++)
        af[mt] = *(const bf16x8*)&sA[(mt*16 + lrow)*72 + ks*32 + quad*8];
#pragma unroll
      for (int nl = 0; nl < 2; nl++){
        int nt = (col0 >> 4) + wave*2 + nl;
        size_t bo = (((size_t)nt * ksTotal + ksBase + ks)*64 + lane)*8;
        bf16x8 bh = *(const bf16x8*)&Bh[bo];
#pragma unroll
        for (int mt = 0; mt < 2; mt++)
          acc[mt][nl] = __builtin_amdgcn_mfma_f32_16x16x32_bf16(af[mt], bh, acc[mt][nl], 0, 0, 0);
      }
    }
    __syncthreads();
  }
#pragma unroll
  for (int nl = 0; nl < 2; nl++){
    int c = col0 + wave*32 + nl*16 + lrow;
    float bc = bias ? bias[c] : 0.0f;
#pragma unroll
    for (int mt = 0; mt < 2; mt++)
#pragma unroll
      for (int rg = 0; rg < 4; rg++){
        int r = row0 + mt*16 + quad*4 + rg;
        if (r < M){
          float v = acc[mt][nl][rg] + bc;
          if (ACT == 1) v = gelu_exact(v);
          C[(size_t)r * N + c] = bf16h(v);
        }
      }
  }
}

// ---------------- MFMA GEMM + residual + LN epilogue (proj); 16-row x 256-col ----------------
__global__ __launch_bounds__(256, 2) void mfma_gemm_ln(
    const unsigned short* __restrict__ A, const unsigned short* __restrict__ Bh,
    const float* __restrict__ bias, const float* __restrict__ res,
    const float* __restrict__ ptb,
    float* __restrict__ C, float* __restrict__ xiOut, unsigned short* __restrict__ lnOut,
    const float* __restrict__ lng, const float* __restrict__ lnb, int M, int K)
{
  __shared__ __align__(16) unsigned short sA[16 * 72];
  __shared__ float sRed[2][16][4];
  int tid = threadIdx.x;
  int wave = tid >> 6, lane = tid & 63, quad = lane >> 4, lrow = lane & 15;
  int row0 = blockIdx.x * 16;
  int ksTotal = K >> 5;
  f32x4 acc[4];
  const f32x4 z = {0.f, 0.f, 0.f, 0.f};
#pragma unroll
  for (int nl = 0; nl < 4; nl++) acc[nl] = z;

  for (int k0 = 0; k0 < K; k0 += 64){
    if (tid < 128){
      int r = tid >> 3, c8 = (tid & 7) * 8;
      int gr = row0 + r;
      bf16x8 v = {0,0,0,0,0,0,0,0};
      if (gr < M) v = *(const bf16x8*)(A + (size_t)gr * K + k0 + c8);
      *(bf16x8*)&sA[r * 72 + c8] = v;
    }
    __syncthreads();
    int ksBase = k0 >> 5;
#pragma unroll
    for (int ks = 0; ks < 2; ks++){
      bf16x8 af = *(const bf16x8*)&sA[lrow*72 + ks*32 + quad*8];
#pragma unroll
      for (int nl = 0; nl < 4; nl++){
        int nt = wave*4 + nl;
        size_t bo = (((size_t)nt * ksTotal + ksBase + ks)*64 + lane)*8;
        bf16x8 bh = *(const bf16x8*)&Bh[bo];
        acc[nl] = __builtin_amdgcn_mfma_f32_16x16x32_bf16(af, bh, acc[nl], 0, 0, 0);
      }
    }
    __syncthreads();
  }
#pragma unroll
  for (int nl = 0; nl < 4; nl++){
    int c = wave*64 + nl*16 + lrow;
    float bc = bias[c];
#pragma unroll
    for (int rg = 0; rg < 4; rg++){
      int r = row0 + quad*4 + rg;
      if (r < M){
        float v = acc[nl][rg] + bc + res[(size_t)r * 256 + c];
        if (C) C[(size_t)r * 256 + c] = v;
        float u = v;
        if (ptb) u += ptb[(size_t)r * 256 + c];
        acc[nl][rg] = u;
      }
    }
  }
#pragma unroll
  for (int rg = 0; rg < 4; rg++){
    int rloc = quad*4 + rg;
    float s = 0.0f, q = 0.0f;
#pragma unroll
    for (int nl = 0; nl < 4; nl++){ float u = acc[nl][rg]; s += u; q += u*u; }
#pragma unroll
    for (int off = 1; off < 16; off <<= 1){ s += __shfl_xor(s, off); q += __shfl_xor(q, off); }
    if (lrow == 0){ sRed[0][rloc][wave] = s; sRed[1][rloc][wave] = q; }
  }
  __syncthreads();
#pragma unroll
  for (int rg = 0; rg < 4; rg++){
    int rloc = quad*4 + rg;
    int r = row0 + rloc;
    if (r >= M) continue;
    float s = ((sRed[0][rloc][0] + sRed[0][rloc][1]) + sRed[0][rloc][2]) + sRed[0][rloc][3];
    float q = ((sRed[1][rloc][0] + sRed[1][rloc][1]) + sRed[1][rloc][2]) + sRed[1][rloc][3];
    float m  = s * (1.0f / 256.0f);
    float var = q * (1.0f / 256.0f) - m * m;
    float rs = 1.0f / sqrtf(var + EPS_);
#pragma unroll
    for (int nl = 0; nl < 4; nl++){
      int c = wave*64 + nl*16 + lrow;
      float u = acc[nl][rg];
      lnOut[(size_t)r * 256 + c] = bf16h((u - m) * rs * lng[c] + lnb[c]);
      if (xiOut) xiOut[(size_t)r * 256 + c] = u;
    }
  }
}

// ---------------- FUSED MLP: ln2-out -> fc1 -> gelu -> fc2 -> +res(+pt) -> LN ----------------
__global__ __launch_bounds__(256, 2) void mlp_fused(
    const unsigned short* __restrict__ A,
    const unsigned short* __restrict__ B1,
    const float* __restrict__ bias1,
    const unsigned short* __restrict__ B2,
    const float* __restrict__ bias2,
    const float* __restrict__ res,
    const float* __restrict__ ptb,
    float* __restrict__ xiOut, unsigned short* __restrict__ lnOut,
    const float* __restrict__ lng, const float* __restrict__ lnb, int M)
{
  __shared__ __align__(16) unsigned short sA[16 * 264];
  __shared__ __align__(16) unsigned short sH[16 * 1032];
  __shared__ float sRed[2][16][4];
  int tid = threadIdx.x;
  int wave = tid >> 6, lane = tid & 63, quad = lane >> 4, lrow = lane & 15;
  int row0 = blockIdx.x * 16;

  for (int e = tid; e < 512; e += 256){
    int r = e >> 5, c8 = (e & 31) * 8;
    int gr = row0 + r;
    bf16x8 v = {0,0,0,0,0,0,0,0};
    if (gr < M) v = *(const bf16x8*)(A + (size_t)gr * 256 + c8);
    *(bf16x8*)&sA[r * 264 + c8] = v;
  }
  __syncthreads();

  {
    f32x4 acc1[16];
    const f32x4 z = {0.f, 0.f, 0.f, 0.f};
#pragma unroll
    for (int nl = 0; nl < 16; nl++) acc1[nl] = z;
#pragma unroll
    for (int ks = 0; ks < 8; ks++){
      bf16x8 af = *(const bf16x8*)&sA[lrow*264 + ks*32 + quad*8];
#pragma unroll
      for (int nl = 0; nl < 16; nl++){
        int nt = wave*16 + nl;
        size_t bo = (((size_t)nt*8 + ks)*64 + lane)*8;
        bf16x8 bh = *(const bf16x8*)&B1[bo];
        acc1[nl] = __builtin_amdgcn_mfma_f32_16x16x32_bf16(af, bh, acc1[nl], 0, 0, 0);
      }
    }
#pragma unroll
    for (int nl = 0; nl < 16; nl++){
      int c = wave*256 + nl*16 + lrow;
      float bc = bias1[c];
#pragma unroll
      for (int rg = 0; rg < 4; rg++)
        sH[(quad*4+rg)*1032 + c] = bf16h(gelu_exact(acc1[nl][rg] + bc));
    }
  }
  __syncthreads();

  f32x4 acc[4];
  const f32x4 z = {0.f, 0.f, 0.f, 0.f};
#pragma unroll
  for (int nl = 0; nl < 4; nl++) acc[nl] = z;
#pragma unroll 4
  for (int ks = 0; ks < 32; ks++){
    bf16x8 af = *(const bf16x8*)&sH[lrow*1032 + ks*32 + quad*8];
#pragma unroll
    for (int nl = 0; nl < 4; nl++){
      int nt = wave*4 + nl;
      size_t bo = (((size_t)nt*32 + ks)*64 + lane)*8;
      bf16x8 bh = *(const bf16x8*)&B2[bo];
      acc[nl] = __builtin_amdgcn_mfma_f32_16x16x32_bf16(af, bh, acc[nl], 0, 0, 0);
    }
  }
#pragma unroll
  for (int nl = 0; nl < 4; nl++){
    int c = wave*64 + nl*16 + lrow;
    float bc = bias2[c];
#pragma unroll
    for (int rg = 0; rg < 4; rg++){
      int r = row0 + quad*4 + rg;
      if (r < M){
        float v = acc[nl][rg] + bc + res[(size_t)r * 256 + c];
        float u = v;
        if (ptb) u += ptb[(size_t)r * 256 + c];
        acc[nl][rg] = u;
      }
    }
  }
#pragma unroll
  for (int rg = 0; rg < 4; rg++){
    int rloc = quad*4 + rg;
    float s = 0.0f, q = 0.0f;
#pragma unroll
    for (int nl = 0; nl < 4; nl++){ float u = acc[nl][rg]; s += u; q += u*u; }
#pragma unroll
    for (int off = 1; off < 16; off <<= 1){ s += __shfl_xor(s, off); q += __shfl_xor(q, off); }
    if (lrow == 0){ sRed[0][rloc][wave] = s; sRed[1][rloc][wave] = q; }
  }
  __syncthreads();
#pragma unroll
  for (int rg = 0; rg < 4; rg++){
    int rloc = quad*4 + rg;
    int r = row0 + rloc;
    if (r >= M) continue;
    float s = ((sRed[0][rloc][0] + sRed[0][rloc][1]) + sRed[0][rloc][2]) + sRed[0][rloc][3];
    float q = ((sRed[1][rloc][0] + sRed[1][rloc][1]) + sRed[1][rloc][2]) + sRed[1][rloc][3];
    float m  = s * (1.0f / 256.0f);
    float var = q * (1.0f / 256.0f) - m * m;
    float rs = 1.0f / sqrtf(var + EPS_);
#pragma unroll
    for (int nl = 0; nl < 4; nl++){
      int c = wave*64 + nl*16 + lrow;
      float u = acc[nl][rg];
      lnOut[(size_t)r * 256 + c] = bf16h((u - m) * rs * lng[c] + lnb[c]);
      if (xiOut) xiOut[(size_t)r * 256 + c] = u;
    }
  }
}

// ---------------- attention: bf16 in/out, flash-style, k-split x4 ----------------
__global__ __launch_bounds__(256, 2) void attn_kernel(const unsigned short* __restrict__ qkv, unsigned short* __restrict__ obuf)
{
  int bh = blockIdx.x;
  int b = bh >> 3, h = bh & 7;
  int tid = threadIdx.x;
  int qi = tid >> 2, kp = tid & 3;
  int qrow = blockIdx.y * 64 + qi;
  bool act = qrow < 257;
  __shared__ float kS[128][33];
  __shared__ float vS[128][33];
  const unsigned short* qb = qkv + (size_t)b * 257 * 768;
  float q[32], o[32];
  float mrun = -3.4e38f, l = 0.0f;
  if (act){
    const unsigned short* qr = qb + (size_t)qrow * 768 + h * 32;
#pragma unroll
    for (int j = 0; j < 32; j++){ q[j] = bf16_to_f32(qr[j]); o[j] = 0.0f; }
  } else {
#pragma unroll
    for (int j = 0; j < 32; j++){ q[j] = 0.0f; o[j] = 0.0f; }
  }
  // pin q: prevent per-use rematerialization from global
#pragma unroll
  for (int j = 0; j < 32; j++) asm volatile("" : "+v"(q[j]));
  const float scale = 0.17677669529663687f;
  for (int m0 = 0; m0 < 257; m0 += 128){
    int cnt = min(128, 257 - m0);
    for (int e = tid; e < cnt * 32; e += 256){
      int mm = e >> 5, j = e & 31;
      const unsigned short* rowp = qb + (size_t)(m0 + mm) * 768 + h * 32;
      kS[mm][j] = bf16_to_f32(rowp[256 + j]);
      vS[mm][j] = bf16_to_f32(rowp[512 + j]);
    }
    __syncthreads();
    if (act){
      for (int mm = kp; mm < cnt; mm += 4){
        float s = 0.0f;
#pragma unroll
        for (int j = 0; j < 32; j++) s = fmaf(q[j], kS[mm][j], s);
        s *= scale;
        float nm = fmaxf(mrun, s);
        float alpha = expf(mrun - nm);
        float p = expf(s - nm);
        l = fmaf(l, alpha, p);
#pragma unroll
        for (int j = 0; j < 32; j++) o[j] = fmaf(p, vS[mm][j], o[j] * alpha);
        mrun = nm;
      }
    }
    __syncthreads();
  }
  if (act){
#pragma unroll
    for (int msk = 1; msk <= 2; msk <<= 1){
      float m2 = __shfl_xor(mrun, msk);
      float l2 = __shfl_xor(l, msk);
      float nm = fmaxf(mrun, m2);
      float a1 = expf(mrun - nm), a2 = expf(m2 - nm);
      l = l * a1 + l2 * a2;
#pragma unroll
      for (int j = 0; j < 32; j++){
        float o2 = __shfl_xor(o[j], msk);
        o[j] = o[j] * a1 + o2 * a2;
      }
      mrun = nm;
    }
    if (kp == 0){
      float inv = 1.0f / l;
      unsigned short* orow = obuf + (size_t)(b * 257 + qrow) * 256 + h * 32;
#pragma unroll
      for (int j = 0; j < 32; j++) orow[j] = bf16h(o[j] * inv);
    }
  }
}

// ---------------- head MLP + scatter: one block per (b,g); gfeat bf16 ----------------
__global__ __launch_bounds__(256) void head_kernel(
    const unsigned short* __restrict__ gfeat, const float* __restrict__ neigh, const int* __restrict__ knn_idx,
    const float* __restrict__ w1, const float* __restrict__ b1,
    const float* __restrict__ w2, const float* __restrict__ b2,
    float* __restrict__ sums, float* __restrict__ cnts)
{
  int blk = blockIdx.x, b = blk >> 8;
  __shared__ float xS[256];
  __shared__ float nS[64][4];
  __shared__ float partH[2][128];
  __shared__ float sharedH[128];
  __shared__ float w2S[128];
  __shared__ float wtail[3][128];
  int tid = threadIdx.x;
  xS[tid] = bf16_to_f32(gfeat[((size_t)b * 257 + 1 + (blk & 255)) * 256 + tid]);
  if (tid < 192) nS[tid / 3][tid % 3] = neigh[(size_t)blk * 192 + tid];
  if (tid < 128){
    w2S[tid] = w2[tid];
    wtail[0][tid] = w1[256 * 128 + tid];
    wtail[1][tid] = w1[257 * 128 + tid];
    wtail[2][tid] = w1[258 * 128 + tid];
  }
  __syncthreads();
  {
    int half = tid >> 7, j = tid & 127;
    float s = 0.0f;
#pragma unroll 8
    for (int k = 0; k < 128; k++) s = fmaf(xS[half * 128 + k], w1[(size_t)(half * 128 + k) * 128 + j], s);
    partH[half][j] = s;
  }
  __syncthreads();
  if (tid < 128) sharedH[tid] = partH[0][tid] + partH[1][tid] + b1[tid];
  __syncthreads();
  int r = tid >> 2, q = tid & 3;
  float n0 = nS[r][0], n1 = nS[r][1], n2 = nS[r][2];
  float s = 0.0f;
#pragma unroll
  for (int j0 = 0; j0 < 32; j0++){
    int j = q * 32 + j0;
    float h = fmaf(n2, wtail[2][j], fmaf(n1, wtail[1][j], fmaf(n0, wtail[0][j], sharedH[j])));
    s = fmaf(fmaxf(h, 0.0f), w2S[j], s);
  }
  s += __shfl_xor(s, 1);
  s += __shfl_xor(s, 2);
  if (q == 0){
    float lg = s + b2[0];
    int p = knn_idx[(size_t)blk * K_ + r];
    atomicAdd(&sums[(size_t)b * N_ + p], lg);
    atomicAdd(&cnts[(size_t)b * N_ + p], 1.0f);
  }
}

__global__ void finalize_kernel(const float* __restrict__ sums, const float* __restrict__ cnts, float* __restrict__ out)
{
  int i = blockIdx.x * 256 + threadIdx.x;
  out[i] = sums[i] / fmaxf(cnts[i], 1.0f);
}

extern "C" void kernel_launch(void* const* d_in, const int* in_sizes, int n_in,
                              void* d_out, int out_size, void* d_ws, size_t ws_size,
                              hipStream_t stream)
{
  (void)in_sizes; (void)n_in; (void)out_size; (void)ws_size;
  const float* x        = (const float*)d_in[0];
  const float* enc_w1   = (const float*)d_in[1];
  const float* enc_b1   = (const float*)d_in[2];
  const float* enc_bn1g = (const float*)d_in[3];
  const float* enc_bn1b = (const float*)d_in[4];
  const float* enc_w2   = (const float*)d_in[5];
  const float* enc_b2   = (const float*)d_in[6];
  const float* enc_w3   = (const float*)d_in[7];
  const float* enc_b3   = (const float*)d_in[8];
  const float* enc_bn2g = (const float*)d_in[9];
  const float* enc_bn2b = (const float*)d_in[10];
  const float* enc_w4   = (const float*)d_in[11];
  const float* enc_b4   = (const float*)d_in[12];
  const float* cls_tok  = (const float*)d_in[13];
  const float* cls_pos  = (const float*)d_in[14];
  const float* pos_w1   = (const float*)d_in[15];
  const float* pos_b1   = (const float*)d_in[16];
  const float* pos_w2   = (const float*)d_in[17];
  const float* pos_b2   = (const float*)d_in[18];
  const float* ln1_g    = (const float*)d_in[19];
  const float* ln1_b    = (const float*)d_in[20];
  const float* qkv_w    = (const float*)d_in[21];
  const float* proj_w   = (const float*)d_in[22];
  const float* proj_b   = (const float*)d_in[23];
  const float* ln2_g    = (const float*)d_in[24];
  const float* ln2_b    = (const float*)d_in[25];
  const float* fc1_w    = (const float*)d_in[26];
  const float* fc1_b    = (const float*)d_in[27];
  const float* fc2_w    = (const float*)d_in[28];
  const float* fc2_b    = (const float*)d_in[29];
  const float* norm_g   = (const float*)d_in[30];
  const float* norm_b   = (const float*)d_in[31];
  const float* head_w1  = (const float*)d_in[32];
  const float* head_b1  = (const float*)d_in[33];
  const float* head_w2  = (const float*)d_in[34];
  const float* head_b2  = (const float*)d_in[35];

  float* ws = (float*)d_ws;
  size_t off = 0;
  auto alloc = [&](size_t n)->float*{ float* p = ws + off; off += (n + 63) & ~(size_t)63; return p; };

  float* centers = alloc((size_t)B_ * G_ * 3);
  float* w1f     = alloc(384);
  float* b1f     = alloc(128);
  float* b3f     = alloc(512);
  unsigned short* w2ph = (unsigned short*)alloc(16384);
  unsigned short* w2pl = (unsigned short*)alloc(16384);
  unsigned short* w3ph = (unsigned short*)alloc(65536);
  unsigned short* w3tp = (unsigned short*)alloc(65536);
  unsigned short* w4ph = (unsigned short*)alloc(65536);
  unsigned short* qkvPh = (unsigned short*)alloc(393216);
  unsigned short* projPh = (unsigned short*)alloc(131072);
  unsigned short* fc1Ph = (unsigned short*)alloc(524288);
  unsigned short* fc2Ph = (unsigned short*)alloc(524288);
  float* tokens  = alloc((size_t)B_ * G_ * D_);
  float* neigh   = alloc((size_t)B_ * G_ * K_ * 3);
  int*   knn_idx = (int*)alloc((size_t)B_ * G_ * K_);
  float* pt      = alloc((size_t)B_ * 257 * D_);
  float* xi      = alloc((size_t)B_ * 257 * D_);
  unsigned short* lnbufB = (unsigned short*)alloc((size_t)B_ * 257 * D_ / 2 + 64);
  unsigned short* obufB  = (unsigned short*)alloc((size_t)B_ * 257 * D_ / 2 + 64);
  unsigned short* bigbufB= (unsigned short*)alloc((size_t)B_ * 257 * HID_ / 2 + 64);
  unsigned short* gfeatB = (unsigned short*)alloc((size_t)B_ * 257 * D_ / 2 + 64);
  float* sums    = alloc((size_t)B_ * N_);
  float* cnts    = alloc((size_t)B_ * N_);

  hipMemsetAsync(sums, 0, (size_t)2 * B_ * N_ * sizeof(float), stream);

  prep_fps_kernel<<<6993, 512, 0, stream>>>(x, centers,
      enc_w1, enc_b1, enc_bn1g, enc_bn1b, enc_w3, enc_b3, enc_bn2g, enc_bn2b,
      enc_w2, enc_w4, qkv_w, proj_w, fc1_w, fc2_w,
      w1f, b1f, b3f, w2ph, w2pl, w3ph, w4ph, qkvPh, projPh, fc1Ph, fc2Ph, w3tp);

  knn_kernel<<<B_ * G_, 256, 0, stream>>>(x, centers, knn_idx, neigh);
  encoder_kernel<<<B_ * G_, 256, 0, stream>>>(neigh, w1f, b1f, w2ph, w2pl, enc_b2,
                                              b3f, w3ph, w3tp, w4ph, enc_b4, tokens);
  pos_ln_kernel<<<B_ * 257, 128, 0, stream>>>(centers, tokens, cls_tok, cls_pos,
                                              pos_w1, pos_b1, pos_w2, pos_b2,
                                              ln1_g, ln1_b, pt, xi, lnbufB);
  const int M = B_ * 257; // 4112
  for (int l = 0; l < 4; l++){
    mfma_gemm<0><<<dim3(129, 6), 256, 0, stream>>>(lnbufB, qkvPh + (size_t)l*196608, nullptr, bigbufB, M, 256, 768);
    attn_kernel<<<dim3(B_ * 8, 5), 256, 0, stream>>>(bigbufB, obufB);
    mfma_gemm_ln<<<257, 256, 0, stream>>>(obufB, projPh + (size_t)l*65536, proj_b + l*256, xi, nullptr,
                                          xi, nullptr, lnbufB, ln2_g + l*256, ln2_b + l*256, M, 256);
    if (l < 3){
      mlp_fused<<<257, 256, 0, stream>>>(lnbufB, fc1Ph + (size_t)l*262144, fc1_b + l*1024,
                                         fc2Ph + (size_t)l*262144, fc2_b + l*256, xi, pt,
                                         xi, lnbufB, ln1_g + (l+1)*256, ln1_b + (l+1)*256, M);
    } else {
      mlp_fused<<<257, 256, 0, stream>>>(lnbufB, fc1Ph + (size_t)l*262144, fc1_b + l*1024,
                                         fc2Ph + (size_t)l*262144, fc2_b + l*256, xi, nullptr,
                                         nullptr, gfeatB, norm_g, norm_b, M);
    }
  }
  head_kernel<<<B_ * G_, 256, 0, stream>>>(gfeatB, neigh, knn_idx, head_w1, head_b1, head_w2, head_b2, sums, cnts);
  finalize_kernel<<<(B_ * N_) / 256, 256, 0, stream>>>(sums, cnts, (float*)d_out);
}